// Round 1
// baseline (1736.360 us; speedup 1.0000x reference)
//
#include <hip/hip_runtime.h>
#include <math.h>

#define N_NODES 50000
#define N_EDGES 1000000
#define NGRAPH  512
#define INC     39

__device__ __forceinline__ float lrelu(float x){ return x > 0.f ? x : 0.01f*x; }
__device__ __forceinline__ float eluf (float x){ return x > 0.f ? x : expm1f(x); }
__device__ __forceinline__ float sigm (float x){ return 1.f/(1.f+expf(-x)); }
__device__ __forceinline__ float rdlane(float v, int l){
  return __int_as_float(__builtin_amdgcn_readlane(__float_as_int(v), l));
}

// ---------------- lin1: out[n][o] = lrelu(sum_k x[n][k]*W[o][k] + b[o]), K=39 ----------------
__global__ __launch_bounds__(256) void k_lin1(const float* __restrict__ x,
                                              const float* __restrict__ W,
                                              const float* __restrict__ b,
                                              float* __restrict__ out) {
  __shared__ float wl[64*41];
  for (int idx = threadIdx.x; idx < 64*INC; idx += 256) {
    int r = idx / INC, c = idx - r*INC;
    wl[r*41+c] = W[idx];
  }
  __syncthreads();
  const int lane = threadIdx.x & 63;
  const int base = blockIdx.x*32 + (threadIdx.x>>6)*8;
  float h[8];
  #pragma unroll
  for (int i = 0; i < 8; ++i) {
    int n = base + i;
    h[i] = (n < N_NODES && lane < INC) ? x[n*INC + lane] : 0.f;
  }
  float acc[8] = {0,0,0,0,0,0,0,0};
  #pragma unroll
  for (int k = 0; k < INC; ++k) {
    float wv = wl[lane*41+k];
    #pragma unroll
    for (int i = 0; i < 8; ++i) acc[i] += rdlane(h[i], k) * wv;
  }
  float bb = b[lane];
  #pragma unroll
  for (int i = 0; i < 8; ++i) {
    int n = base + i;
    if (n < N_NODES) out[n*64+lane] = lrelu(acc[i] + bb);
  }
}

// ---------------- generic [R,64] @ W[64,rs -> take 64 cols].T ----------------
__global__ __launch_bounds__(256) void k_mm64(const float* __restrict__ in,
                                              const float* __restrict__ W, int rs,
                                              float* __restrict__ out, int R) {
  __shared__ float wl[64*65];
  for (int idx = threadIdx.x; idx < 4096; idx += 256) {
    int r = idx >> 6, c = idx & 63;
    wl[r*65+c] = W[r*rs + c];
  }
  __syncthreads();
  const int lane = threadIdx.x & 63;
  const int base = blockIdx.x*32 + (threadIdx.x>>6)*8;
  float h[8];
  #pragma unroll
  for (int i = 0; i < 8; ++i) { int n = base+i; h[i] = (n < R) ? in[n*64+lane] : 0.f; }
  float acc[8] = {0,0,0,0,0,0,0,0};
  for (int k = 0; k < 64; ++k) {
    float wv = wl[lane*65+k];
    #pragma unroll
    for (int i = 0; i < 8; ++i) acc[i] += rdlane(h[i], k) * wv;
  }
  #pragma unroll
  for (int i = 0; i < 8; ++i) { int n = base+i; if (n < R) out[n*64+lane] = acc[i]; }
}

// ---------------- per-row dot(s) with 64-vector(s) ----------------
__global__ __launch_bounds__(256) void k_dots(const float* __restrict__ m,
                                              const float* __restrict__ v1,
                                              const float* __restrict__ v2,
                                              float* __restrict__ o1,
                                              float* __restrict__ o2, int R) {
  int n = blockIdx.x*4 + (threadIdx.x>>6);
  if (n >= R) return;
  int lane = threadIdx.x & 63;
  float mv = m[n*64+lane];
  float p1 = mv * v1[lane];
  float p2 = v2 ? mv * v2[lane] : 0.f;
  #pragma unroll
  for (int s = 32; s > 0; s >>= 1) { p1 += __shfl_xor(p1, s, 64); p2 += __shfl_xor(p2, s, 64); }
  if (lane == 0) { o1[n] = p1; if (o2) o2[n] = p2; }
}

// ---------------- GATEConv edge pass A ----------------
__global__ __launch_bounds__(256) void k_gateA(const int* __restrict__ src,
                                               const int* __restrict__ dst,
                                               const float* __restrict__ ea,
                                               const float* __restrict__ glin1, // [64][80]
                                               const float* __restrict__ attl,
                                               const float* __restrict__ u,
                                               const float* __restrict__ xr,
                                               float* __restrict__ ealpha,
                                               float* __restrict__ ssum) {
  __shared__ float w2[64*17];
  __shared__ float al[64];
  for (int idx = threadIdx.x; idx < 1024; idx += 256) {
    int r = idx >> 4, j = idx & 15;
    w2[r*17+j] = glin1[r*80 + 64 + j];
  }
  if (threadIdx.x < 64) al[threadIdx.x] = attl[threadIdx.x];
  __syncthreads();
  int e = blockIdx.x*4 + (threadIdx.x>>6);
  if (e >= N_EDGES) return;
  int lane = threadIdx.x & 63;
  int s = src[e], d = dst[e];
  float eav = (lane < 16) ? ea[e*16 + lane] : 0.f;
  float v = 0.f;
  #pragma unroll
  for (int j = 0; j < 16; ++j) v += rdlane(eav, j) * w2[lane*17+j];
  float t = lrelu(u[s*64+lane] + v);
  float p = t * al[lane];
  #pragma unroll
  for (int sh = 32; sh > 0; sh >>= 1) p += __shfl_xor(p, sh, 64);
  if (lane == 0) {
    float a = lrelu(p + xr[d]);
    float ev = expf(a);
    ealpha[e] = ev;
    unsafeAtomicAdd(&ssum[d], ev);
  }
}

// ---------------- GATConv edge pass A (scalar) ----------------
__global__ __launch_bounds__(256) void k_convA(const int* __restrict__ src,
                                               const int* __restrict__ dst,
                                               const float* __restrict__ asn,
                                               const float* __restrict__ adn,
                                               float* __restrict__ ealpha,
                                               float* __restrict__ ssum) {
  int e = blockIdx.x*256 + threadIdx.x;
  if (e >= N_EDGES) return;
  int s = src[e], d = dst[e];
  float ev = expf(lrelu(asn[s] + adn[d]));
  ealpha[e] = ev;
  unsafeAtomicAdd(&ssum[d], ev);
}

// ---------------- edge aggregation: hagg[d] += mat[s]*alpha ----------------
__global__ __launch_bounds__(256) void k_agg(const int* __restrict__ src,
                                             const int* __restrict__ dst,
                                             const float* __restrict__ mat,
                                             const float* __restrict__ ealpha,
                                             const float* __restrict__ ssum,
                                             float* __restrict__ hagg) {
  int e = blockIdx.x*4 + (threadIdx.x>>6);
  if (e >= N_EDGES) return;
  int lane = threadIdx.x & 63;
  int s = src[e], d = dst[e];
  float w = ealpha[e] / (ssum[d] + 1e-16f);
  unsafeAtomicAdd(&hagg[d*64+lane], mat[s*64+lane] * w);
}

// ---------------- fused GRU: out = relu(GRU(elu(inp+pbias), hid)) ----------------
__global__ __launch_bounds__(256) void k_gru(const float* __restrict__ inp,
                                             const float* __restrict__ pbias,
                                             const float* __restrict__ hid,
                                             const float* __restrict__ wi,
                                             const float* __restrict__ wh,
                                             const float* __restrict__ bi,
                                             const float* __restrict__ bh,
                                             float* __restrict__ out, int R) {
  __shared__ float wl[192*65];
  const int lane = threadIdx.x & 63;
  const int base = blockIdx.x*32 + (threadIdx.x>>6)*8;
  float pb = pbias[lane];
  float hin[8], hh[8];
  #pragma unroll
  for (int i = 0; i < 8; ++i) {
    int n = base + i;
    if (n < R) { hin[i] = eluf(inp[n*64+lane] + pb); hh[i] = hid[n*64+lane]; }
    else       { hin[i] = 0.f; hh[i] = 0.f; }
  }
  for (int idx = threadIdx.x; idx < 192*64; idx += 256)
    wl[(idx>>6)*65 + (idx&63)] = wi[idx];
  __syncthreads();
  float gr[8]={0,0,0,0,0,0,0,0}, gz[8]={0,0,0,0,0,0,0,0}, gn[8]={0,0,0,0,0,0,0,0};
  #pragma unroll 16
  for (int k = 0; k < 64; ++k) {
    float wr = wl[lane*65+k], wz = wl[(64+lane)*65+k], wn = wl[(128+lane)*65+k];
    #pragma unroll
    for (int i = 0; i < 8; ++i) {
      float hk = rdlane(hin[i], k);
      gr[i] += hk*wr; gz[i] += hk*wz; gn[i] += hk*wn;
    }
  }
  __syncthreads();
  for (int idx = threadIdx.x; idx < 192*64; idx += 256)
    wl[(idx>>6)*65 + (idx&63)] = wh[idx];
  __syncthreads();
  float hr[8]={0,0,0,0,0,0,0,0}, hz[8]={0,0,0,0,0,0,0,0}, hn[8]={0,0,0,0,0,0,0,0};
  #pragma unroll 16
  for (int k = 0; k < 64; ++k) {
    float wr = wl[lane*65+k], wz = wl[(64+lane)*65+k], wn = wl[(128+lane)*65+k];
    #pragma unroll
    for (int i = 0; i < 8; ++i) {
      float hk = rdlane(hh[i], k);
      hr[i] += hk*wr; hz[i] += hk*wz; hn[i] += hk*wn;
    }
  }
  float bir = bi[lane], biz = bi[64+lane], bin_ = bi[128+lane];
  float bhr = bh[lane], bhz = bh[64+lane], bhn = bh[128+lane];
  #pragma unroll
  for (int i = 0; i < 8; ++i) {
    int n = base + i;
    if (n >= R) continue;
    float r  = sigm(gr[i]+bir + hr[i]+bhr);
    float z  = sigm(gz[i]+biz + hz[i]+bhz);
    float nn = tanhf(gn[i]+bin_ + r*(hn[i]+bhn));
    float o  = (1.f - z)*nn + z*hh[i];
    out[n*64+lane] = fmaxf(o, 0.f);
  }
}

// ---------------- molecule readout ----------------
__global__ __launch_bounds__(256) void k_molsum(const float* __restrict__ x,
                                                const int* __restrict__ batch,
                                                float* __restrict__ outg) {
  int n = blockIdx.x*4 + (threadIdx.x>>6);
  if (n >= N_NODES) return;
  int lane = threadIdx.x & 63;
  unsafeAtomicAdd(&outg[batch[n]*64+lane], x[n*64+lane]);
}

__global__ __launch_bounds__(256) void k_relu(float* __restrict__ p, int n) {
  int i = blockIdx.x*256 + threadIdx.x;
  if (i < n) p[i] = fmaxf(p[i], 0.f);
}

__global__ __launch_bounds__(256) void k_molhd(const float* __restrict__ outg,
                                               const float* __restrict__ W,
                                               const float* __restrict__ attd,
                                               float* __restrict__ add_g) {
  int g = blockIdx.x*4 + (threadIdx.x>>6);
  if (g >= NGRAPH) return;
  int lane = threadIdx.x & 63;
  float og = outg[g*64+lane];
  float hd = 0.f;
  for (int k = 0; k < 64; ++k) hd += rdlane(og, k) * W[lane*64+k];
  float p = hd * attd[lane];
  #pragma unroll
  for (int sh = 32; sh > 0; sh >>= 1) p += __shfl_xor(p, sh, 64);
  if (lane == 0) add_g[g] = p;
}

__global__ __launch_bounds__(256) void k_molA(const int* __restrict__ batch,
                                              const float* __restrict__ asn,
                                              const float* __restrict__ addg,
                                              float* __restrict__ en,
                                              float* __restrict__ ssum) {
  int n = blockIdx.x*256 + threadIdx.x;
  if (n >= N_NODES) return;
  int b = batch[n];
  float ev = expf(lrelu(asn[n] + addg[b]));
  en[n] = ev;
  unsafeAtomicAdd(&ssum[b], ev);
}

__global__ __launch_bounds__(256) void k_molB(const int* __restrict__ batch,
                                              const float* __restrict__ hs,
                                              const float* __restrict__ en,
                                              const float* __restrict__ ssum,
                                              float* __restrict__ hg) {
  int n = blockIdx.x*4 + (threadIdx.x>>6);
  if (n >= N_NODES) return;
  int lane = threadIdx.x & 63;
  int b = batch[n];
  float w = en[n] / (ssum[b] + 1e-16f);
  unsafeAtomicAdd(&hg[b*64+lane], hs[n*64+lane] * w);
}

__global__ __launch_bounds__(128) void k_final(const float* __restrict__ outg,
                                               const float* __restrict__ W,
                                               const float* __restrict__ b,
                                               float* __restrict__ out) {
  __shared__ float og[64];
  int g = blockIdx.x;
  if (threadIdx.x < 64) og[threadIdx.x] = outg[g*64+threadIdx.x];
  __syncthreads();
  int o = threadIdx.x;
  float acc = b[o];
  for (int k = 0; k < 64; ++k) acc += og[k]*W[o*64+k];
  out[g*128+o] = acc;
}

extern "C" void kernel_launch(void* const* d_in, const int* in_sizes, int n_in,
                              void* d_out, int out_size, void* d_ws, size_t ws_size,
                              hipStream_t stream) {
  const float* x_in     = (const float*)d_in[0];
  const int*   eidx     = (const int*)  d_in[1];
  const float* eattr    = (const float*)d_in[2];
  const int*   batch    = (const int*)  d_in[3];
  const float* lin1_w   = (const float*)d_in[4];
  const float* lin1_b   = (const float*)d_in[5];
  const float* g_lin1_w = (const float*)d_in[6];
  const float* g_att_l  = (const float*)d_in[7];
  const float* g_att_r  = (const float*)d_in[8];
  const float* g_lin2_w = (const float*)d_in[9];
  const float* g_bias   = (const float*)d_in[10];
  const float* gru0_wi  = (const float*)d_in[11];
  const float* gru0_wh  = (const float*)d_in[12];
  const float* gru0_bi  = (const float*)d_in[13];
  const float* gru0_bh  = (const float*)d_in[14];
  const float* conv_lin_w   = (const float*)d_in[15];
  const float* conv_att_src = (const float*)d_in[16];
  const float* conv_att_dst = (const float*)d_in[17];
  const float* conv_bias    = (const float*)d_in[18];
  const float* grul_wi  = (const float*)d_in[19];
  const float* grul_wh  = (const float*)d_in[20];
  const float* grul_bi  = (const float*)d_in[21];
  const float* grul_bh  = (const float*)d_in[22];
  const float* mol_lin_w    = (const float*)d_in[23];
  const float* mol_att_src  = (const float*)d_in[24];
  const float* mol_att_dst  = (const float*)d_in[25];
  const float* mol_bias     = (const float*)d_in[26];
  const float* mgru_wi  = (const float*)d_in[27];
  const float* mgru_wh  = (const float*)d_in[28];
  const float* mgru_bi  = (const float*)d_in[29];
  const float* mgru_bh  = (const float*)d_in[30];
  const float* lin2_w   = (const float*)d_in[31];
  const float* lin2_b   = (const float*)d_in[32];

  const int N64 = N_NODES*64;
  float* ws     = (float*)d_ws;
  float* xA     = ws;               // N*64
  float* xB     = xA + N64;         // N*64
  float* u      = xB + N64;         // N*64 (also hs for conv layers)
  float* y      = u  + N64;         // N*64 (also hs_mol)
  float* hagg   = y  + N64;         // N*64 (also hmol G*64)
  float* ealpha = hagg + N64;       // E     (also en[N])
  float* ssum   = ealpha + N_EDGES; // N     (also G sums)
  float* sc1    = ssum + N_NODES;   // N
  float* sc2    = sc1 + N_NODES;    // N     (also add_g[G])
  float* outg   = sc2 + N_NODES;    // G*64

  const int* src = eidx;
  const int* dst = eidx + N_EDGES;

  const int nbN32 = (N_NODES + 31)/32;
  const int nbN4  = (N_NODES + 3)/4;
  const int nbE4  = (N_EDGES + 3)/4;

  // ---- lin1 ----
  k_lin1<<<nbN32, 256, 0, stream>>>(x_in, lin1_w, lin1_b, xA);

  // ---- GATEConv ----
  k_mm64<<<nbN32, 256, 0, stream>>>(xA, g_lin1_w, 80, u, N_NODES);      // u = x @ W1a.T
  k_mm64<<<nbN32, 256, 0, stream>>>(xA, g_lin2_w, 64, y, N_NODES);      // y = x @ g_lin2.T
  k_dots<<<nbN4, 256, 0, stream>>>(xA, g_att_r, nullptr, sc1, nullptr, N_NODES); // xr
  hipMemsetAsync(ssum, 0, N_NODES*4, stream);
  hipMemsetAsync(hagg, 0, (size_t)N64*4, stream);
  k_gateA<<<nbE4, 256, 0, stream>>>(src, dst, eattr, g_lin1_w, g_att_l, u, sc1, ealpha, ssum);
  k_agg<<<nbE4, 256, 0, stream>>>(src, dst, y, ealpha, ssum, hagg);
  k_gru<<<nbN32, 256, 0, stream>>>(hagg, g_bias, xA, gru0_wi, gru0_wh, gru0_bi, gru0_bh, xB, N_NODES);

  float* xcur = xB; float* xoth = xA;

  // ---- GATConv layers ----
  for (int l = 0; l < 2; ++l) {
    k_mm64<<<nbN32, 256, 0, stream>>>(xcur, conv_lin_w + l*64*64, 64, u, N_NODES); // hs
    k_dots<<<nbN4, 256, 0, stream>>>(u, conv_att_src + l*64, conv_att_dst + l*64, sc1, sc2, N_NODES);
    hipMemsetAsync(ssum, 0, N_NODES*4, stream);
    hipMemsetAsync(hagg, 0, (size_t)N64*4, stream);
    k_convA<<<(N_EDGES+255)/256, 256, 0, stream>>>(src, dst, sc1, sc2, ealpha, ssum);
    k_agg<<<nbE4, 256, 0, stream>>>(src, dst, u, ealpha, ssum, hagg);
    k_gru<<<nbN32, 256, 0, stream>>>(hagg, conv_bias + l*64, xcur,
                                     grul_wi + l*192*64, grul_wh + l*192*64,
                                     grul_bi + l*192, grul_bh + l*192, xoth, N_NODES);
    float* t = xcur; xcur = xoth; xoth = t;
  }

  // ---- molecule readout ----
  hipMemsetAsync(outg, 0, (size_t)NGRAPH*64*4, stream);
  k_molsum<<<nbN4, 256, 0, stream>>>(xcur, batch, outg);
  k_relu<<<(NGRAPH*64+255)/256, 256, 0, stream>>>(outg, NGRAPH*64);
  k_mm64<<<nbN32, 256, 0, stream>>>(xcur, mol_lin_w, 64, y, N_NODES);   // hs_mol
  k_dots<<<nbN4, 256, 0, stream>>>(y, mol_att_src, nullptr, sc1, nullptr, N_NODES);
  for (int t = 0; t < 2; ++t) {
    k_molhd<<<(NGRAPH+3)/4, 256, 0, stream>>>(outg, mol_lin_w, mol_att_dst, sc2);
    hipMemsetAsync(ssum, 0, NGRAPH*4, stream);
    hipMemsetAsync(hagg, 0, (size_t)NGRAPH*64*4, stream);
    k_molA<<<(N_NODES+255)/256, 256, 0, stream>>>(batch, sc1, sc2, ealpha, ssum);
    k_molB<<<nbN4, 256, 0, stream>>>(batch, y, ealpha, ssum, hagg);
    k_gru<<<(NGRAPH+31)/32, 256, 0, stream>>>(hagg, mol_bias, outg,
                                              mgru_wi, mgru_wh, mgru_bi, mgru_bh, outg, NGRAPH);
  }

  // ---- final linear ----
  k_final<<<NGRAPH, 128, 0, stream>>>(outg, lin2_w, lin2_b, (float*)d_out);
}

// Round 2
// 1065.643 us; speedup vs baseline: 1.6294x; 1.6294x over previous
//
#include <hip/hip_runtime.h>
#include <math.h>

#define N_NODES 50000
#define N_EDGES 1000000
#define NGRAPH  512
#define INC     39

__device__ __forceinline__ float lrelu(float x){ return x > 0.f ? x : 0.01f*x; }
__device__ __forceinline__ float eluf (float x){ return x > 0.f ? x : expm1f(x); }
__device__ __forceinline__ float sigm (float x){ return 1.f/(1.f+expf(-x)); }
__device__ __forceinline__ float rdlane(float v, int l){
  return __int_as_float(__builtin_amdgcn_readlane(__float_as_int(v), l));
}

// ================= CSR build =================
__global__ __launch_bounds__(256) void k_hist(const int* __restrict__ dst,
                                              int* __restrict__ cnt) {
  int e = blockIdx.x*256 + threadIdx.x;
  if (e < N_EDGES) atomicAdd(&cnt[dst[e]], 1);
}

__global__ __launch_bounds__(1024) void k_scan(const int* __restrict__ cnt,
                                               int* __restrict__ rowptr,
                                               int* __restrict__ cursor) {
  __shared__ int part[1024];
  const int t = threadIdx.x;
  const int CH = (N_NODES + 1023) / 1024;   // 49
  const int base = t * CH;
  int s = 0;
  for (int i = 0; i < CH; ++i) { int idx = base + i; if (idx < N_NODES) s += cnt[idx]; }
  part[t] = s;
  __syncthreads();
  for (int off = 1; off < 1024; off <<= 1) {
    int add = (t >= off) ? part[t - off] : 0;
    __syncthreads();
    part[t] += add;
    __syncthreads();
  }
  int run = (t == 0) ? 0 : part[t - 1];
  for (int i = 0; i < CH; ++i) {
    int idx = base + i;
    if (idx < N_NODES) { rowptr[idx] = run; cursor[idx] = run; run += cnt[idx]; }
  }
  if (t == 1023) rowptr[N_NODES] = run;
}

__global__ __launch_bounds__(256) void k_scatter(const int* __restrict__ dst,
                                                 int* __restrict__ cursor,
                                                 int* __restrict__ eids) {
  int e = blockIdx.x*256 + threadIdx.x;
  if (e < N_EDGES) { int p = atomicAdd(&cursor[dst[e]], 1); eids[p] = e; }
}

__global__ __launch_bounds__(512) void k_gbound(const int* __restrict__ batch,
                                                int* __restrict__ gstart) {
  int g = threadIdx.x;
  int lo = 0, hi = N_NODES;
  while (lo < hi) { int mid = (lo+hi)>>1; if (batch[mid] < g) lo = mid+1; else hi = mid; }
  gstart[g] = lo;
  if (g == 0) gstart[NGRAPH] = N_NODES;
}

// ================= lin1: K=39 =================
__global__ __launch_bounds__(256) void k_lin1(const float* __restrict__ x,
                                              const float* __restrict__ W,
                                              const float* __restrict__ b,
                                              float* __restrict__ out) {
  __shared__ float wl[64*41];
  for (int idx = threadIdx.x; idx < 64*INC; idx += 256) {
    int r = idx / INC, c = idx - r*INC;
    wl[r*41+c] = W[idx];
  }
  __syncthreads();
  const int lane = threadIdx.x & 63;
  const int base = blockIdx.x*32 + (threadIdx.x>>6)*8;
  float h[8];
  #pragma unroll
  for (int i = 0; i < 8; ++i) {
    int n = base + i;
    h[i] = (n < N_NODES && lane < INC) ? x[n*INC + lane] : 0.f;
  }
  float acc[8] = {0,0,0,0,0,0,0,0};
  #pragma unroll
  for (int k = 0; k < INC; ++k) {
    float wv = wl[lane*41+k];
    #pragma unroll
    for (int i = 0; i < 8; ++i) acc[i] += rdlane(h[i], k) * wv;
  }
  float bb = b[lane];
  #pragma unroll
  for (int i = 0; i < 8; ++i) {
    int n = base + i;
    if (n < N_NODES) out[n*64+lane] = lrelu(acc[i] + bb);
  }
}

// ========== [R,64] @ W(64 rows, rs stride).T, optional fused per-row dots ==========
__global__ __launch_bounds__(256) void k_mm64(const float* __restrict__ in,
                                              const float* __restrict__ W, int rs,
                                              float* __restrict__ out, int R,
                                              const float* __restrict__ v1,
                                              const float* __restrict__ v2,
                                              float* __restrict__ o1,
                                              float* __restrict__ o2) {
  __shared__ float wl[64*65];
  for (int idx = threadIdx.x; idx < 4096; idx += 256) {
    int r = idx >> 6, c = idx & 63;
    wl[r*65+c] = W[r*rs + c];
  }
  __syncthreads();
  const int lane = threadIdx.x & 63;
  const int base = blockIdx.x*32 + (threadIdx.x>>6)*8;
  float h[8];
  #pragma unroll
  for (int i = 0; i < 8; ++i) { int n = base+i; h[i] = (n < R) ? in[n*64+lane] : 0.f; }
  float acc[8] = {0,0,0,0,0,0,0,0};
  for (int k = 0; k < 64; ++k) {
    float wv = wl[lane*65+k];
    #pragma unroll
    for (int i = 0; i < 8; ++i) acc[i] += rdlane(h[i], k) * wv;
  }
  float v1v = v1 ? v1[lane] : 0.f;
  float v2v = v2 ? v2[lane] : 0.f;
  #pragma unroll
  for (int i = 0; i < 8; ++i) {
    int n = base+i; if (n >= R) continue;
    out[n*64+lane] = acc[i];
    if (o1) {
      float p1 = acc[i]*v1v;
      float p2 = acc[i]*v2v;
      #pragma unroll
      for (int s2 = 32; s2 > 0; s2 >>= 1) { p1 += __shfl_xor(p1, s2, 64); p2 += __shfl_xor(p2, s2, 64); }
      if (lane == 0) { o1[n] = p1; if (o2) o2[n] = p2; }
    }
  }
}

// ================= per-row dot with one 64-vector =================
__global__ __launch_bounds__(256) void k_dots(const float* __restrict__ m,
                                              const float* __restrict__ v1,
                                              float* __restrict__ o1, int R) {
  int n = blockIdx.x*4 + (threadIdx.x>>6);
  if (n >= R) return;
  int lane = threadIdx.x & 63;
  float p1 = m[n*64+lane] * v1[lane];
  #pragma unroll
  for (int s = 32; s > 0; s >>= 1) p1 += __shfl_xor(p1, s, 64);
  if (lane == 0) o1[n] = p1;
}

// ===== GATEConv fused: per-dst wave, one pass (score + softmax + aggregate) =====
__global__ __launch_bounds__(256) void k_gate_fused(const int* __restrict__ rowptr,
                                                    const int* __restrict__ eids,
                                                    const int* __restrict__ src,
                                                    const float* __restrict__ ea,
                                                    const float* __restrict__ glin1, // [64][80]
                                                    const float* __restrict__ attl,
                                                    const float* __restrict__ u,
                                                    const float* __restrict__ y,
                                                    const float* __restrict__ xr,
                                                    float* __restrict__ hagg) {
  const int lane = threadIdx.x & 63;
  float w2r[16];
  #pragma unroll
  for (int j = 0; j < 16; ++j) w2r[j] = glin1[lane*80 + 64 + j];
  float alv = attl[lane];
  int d = blockIdx.x*4 + (threadIdx.x>>6);
  if (d >= N_NODES) return;
  int r0 = rowptr[d], r1 = rowptr[d+1];
  float xrd = xr[d];
  float acc = 0.f, ssum = 0.f;
  int i = r0, eid = 0, s = 0;
  if (i < r1) { eid = eids[i]; s = src[eid]; }
  while (i < r1) {
    float uv  = u[s*64+lane];
    float yv  = y[s*64+lane];
    float eav = (lane < 16) ? ea[eid*16 + lane] : 0.f;
    int ni = i + 1, neid = 0, ns = 0;
    if (ni < r1) { neid = eids[ni]; ns = src[neid]; }
    float v = 0.f;
    #pragma unroll
    for (int j = 0; j < 16; ++j) v += rdlane(eav, j) * w2r[j];
    float t = lrelu(uv + v);
    float p = t * alv;
    #pragma unroll
    for (int sh = 32; sh > 0; sh >>= 1) p += __shfl_xor(p, sh, 64);
    float ev = expf(lrelu(p + xrd));
    acc += ev * yv;
    ssum += ev;
    i = ni; eid = neid; s = ns;
  }
  hagg[d*64+lane] = acc / (ssum + 1e-16f);
}

// ===== GATConv fused: lane-parallel scores, channel-parallel aggregate =====
__global__ __launch_bounds__(256) void k_conv_fused(const int* __restrict__ rowptr,
                                                    const int* __restrict__ eids,
                                                    const int* __restrict__ src,
                                                    const float* __restrict__ asn,
                                                    const float* __restrict__ adn,
                                                    const float* __restrict__ hs,
                                                    float* __restrict__ hagg) {
  __shared__ int   sS[4][64];
  __shared__ float sE[4][64];
  const int w = threadIdx.x >> 6, lane = threadIdx.x & 63;
  int d = blockIdx.x*4 + w;
  if (d >= N_NODES) return;
  int r0 = rowptr[d], r1 = rowptr[d+1];
  float adnd = adn[d];
  float acc = 0.f, ssum = 0.f;
  for (int base = r0; base < r1; base += 64) {
    int i = base + lane;
    int cnt = r1 - base; if (cnt > 64) cnt = 64;
    float ev = 0.f; int s = 0;
    if (i < r1) { int eid = eids[i]; s = src[eid]; ev = expf(lrelu(asn[s] + adnd)); }
    sS[w][lane] = s; sE[w][lane] = ev;
    ssum += ev;
    #pragma unroll 4
    for (int j = 0; j < cnt; ++j)
      acc += sE[w][j] * hs[sS[w][j]*64 + lane];
  }
  #pragma unroll
  for (int sh = 32; sh > 0; sh >>= 1) ssum += __shfl_xor(ssum, sh, 64);
  hagg[d*64+lane] = acc / (ssum + 1e-16f);
}

// ===== fused GRU: out = relu(GRU(elu(inp+pbias), hid)) =====
__global__ __launch_bounds__(256) void k_gru(const float* __restrict__ inp,
                                             const float* __restrict__ pbias,
                                             const float* __restrict__ hid,
                                             const float* __restrict__ wi,
                                             const float* __restrict__ wh,
                                             const float* __restrict__ bi,
                                             const float* __restrict__ bh,
                                             float* __restrict__ out, int R) {
  __shared__ float wl[192*65];
  const int lane = threadIdx.x & 63;
  const int base = blockIdx.x*32 + (threadIdx.x>>6)*8;
  float pb = pbias[lane];
  float hin[8], hh[8];
  #pragma unroll
  for (int i = 0; i < 8; ++i) {
    int n = base + i;
    if (n < R) { hin[i] = eluf(inp[n*64+lane] + pb); hh[i] = hid[n*64+lane]; }
    else       { hin[i] = 0.f; hh[i] = 0.f; }
  }
  for (int idx = threadIdx.x; idx < 192*64; idx += 256)
    wl[(idx>>6)*65 + (idx&63)] = wi[idx];
  __syncthreads();
  float gr[8]={0,0,0,0,0,0,0,0}, gz[8]={0,0,0,0,0,0,0,0}, gn[8]={0,0,0,0,0,0,0,0};
  #pragma unroll 16
  for (int k = 0; k < 64; ++k) {
    float wr = wl[lane*65+k], wz = wl[(64+lane)*65+k], wn = wl[(128+lane)*65+k];
    #pragma unroll
    for (int i = 0; i < 8; ++i) {
      float hk = rdlane(hin[i], k);
      gr[i] += hk*wr; gz[i] += hk*wz; gn[i] += hk*wn;
    }
  }
  __syncthreads();
  for (int idx = threadIdx.x; idx < 192*64; idx += 256)
    wl[(idx>>6)*65 + (idx&63)] = wh[idx];
  __syncthreads();
  float hr[8]={0,0,0,0,0,0,0,0}, hz[8]={0,0,0,0,0,0,0,0}, hn[8]={0,0,0,0,0,0,0,0};
  #pragma unroll 16
  for (int k = 0; k < 64; ++k) {
    float wr = wl[lane*65+k], wz = wl[(64+lane)*65+k], wn = wl[(128+lane)*65+k];
    #pragma unroll
    for (int i = 0; i < 8; ++i) {
      float hk = rdlane(hh[i], k);
      hr[i] += hk*wr; hz[i] += hk*wz; hn[i] += hk*wn;
    }
  }
  float bir = bi[lane], biz = bi[64+lane], bin_ = bi[128+lane];
  float bhr = bh[lane], bhz = bh[64+lane], bhn = bh[128+lane];
  #pragma unroll
  for (int i = 0; i < 8; ++i) {
    int n = base + i;
    if (n >= R) continue;
    float r  = sigm(gr[i]+bir + hr[i]+bhr);
    float z  = sigm(gz[i]+biz + hz[i]+bhz);
    float nn = tanhf(gn[i]+bin_ + r*(hn[i]+bhn));
    float o  = (1.f - z)*nn + z*hh[i];
    out[n*64+lane] = fmaxf(o, 0.f);
  }
}

// ================= molecule readout (CSR over sorted batch) =================
__global__ __launch_bounds__(256) void k_molsum_f(const int* __restrict__ gstart,
                                                  const float* __restrict__ x,
                                                  float* __restrict__ outg) {
  int g = blockIdx.x*4 + (threadIdx.x>>6);
  if (g >= NGRAPH) return;
  int lane = threadIdx.x & 63;
  float acc = 0.f;
  int n1 = gstart[g+1];
  for (int n = gstart[g]; n < n1; ++n) acc += x[n*64+lane];
  outg[g*64+lane] = fmaxf(acc, 0.f);
}

__global__ __launch_bounds__(256) void k_mol_fused(const int* __restrict__ gstart,
                                                   const float* __restrict__ outg,
                                                   const float* __restrict__ W,
                                                   const float* __restrict__ attd,
                                                   const float* __restrict__ asn,
                                                   const float* __restrict__ y,
                                                   float* __restrict__ hg) {
  __shared__ float wl[64*65];
  for (int idx = threadIdx.x; idx < 4096; idx += 256) wl[(idx>>6)*65+(idx&63)] = W[idx];
  __syncthreads();
  int g = blockIdx.x*4 + (threadIdx.x>>6);
  if (g >= NGRAPH) return;
  int lane = threadIdx.x & 63;
  float og = outg[g*64+lane];
  float hd = 0.f;
  #pragma unroll
  for (int k = 0; k < 64; ++k) hd += rdlane(og, k) * wl[lane*65+k];
  float p = hd * attd[lane];
  #pragma unroll
  for (int sh = 32; sh > 0; sh >>= 1) p += __shfl_xor(p, sh, 64);
  float addg = p;
  float acc = 0.f, ssum = 0.f;
  int n1 = gstart[g+1];
  for (int n = gstart[g]; n < n1; ++n) {
    float ev = expf(lrelu(asn[n] + addg));
    acc += ev * y[n*64+lane];
    ssum += ev;
  }
  hg[g*64+lane] = acc / (ssum + 1e-16f);
}

__global__ __launch_bounds__(128) void k_final(const float* __restrict__ outg,
                                               const float* __restrict__ W,
                                               const float* __restrict__ b,
                                               float* __restrict__ out) {
  __shared__ float og[64];
  int g = blockIdx.x;
  if (threadIdx.x < 64) og[threadIdx.x] = outg[g*64+threadIdx.x];
  __syncthreads();
  int o = threadIdx.x;
  float acc = b[o];
  for (int k = 0; k < 64; ++k) acc += og[k]*W[o*64+k];
  out[g*128+o] = acc;
}

extern "C" void kernel_launch(void* const* d_in, const int* in_sizes, int n_in,
                              void* d_out, int out_size, void* d_ws, size_t ws_size,
                              hipStream_t stream) {
  const float* x_in     = (const float*)d_in[0];
  const int*   eidx     = (const int*)  d_in[1];
  const float* eattr    = (const float*)d_in[2];
  const int*   batch    = (const int*)  d_in[3];
  const float* lin1_w   = (const float*)d_in[4];
  const float* lin1_b   = (const float*)d_in[5];
  const float* g_lin1_w = (const float*)d_in[6];
  const float* g_att_l  = (const float*)d_in[7];
  const float* g_att_r  = (const float*)d_in[8];
  const float* g_lin2_w = (const float*)d_in[9];
  const float* g_bias   = (const float*)d_in[10];
  const float* gru0_wi  = (const float*)d_in[11];
  const float* gru0_wh  = (const float*)d_in[12];
  const float* gru0_bi  = (const float*)d_in[13];
  const float* gru0_bh  = (const float*)d_in[14];
  const float* conv_lin_w   = (const float*)d_in[15];
  const float* conv_att_src = (const float*)d_in[16];
  const float* conv_att_dst = (const float*)d_in[17];
  const float* conv_bias    = (const float*)d_in[18];
  const float* grul_wi  = (const float*)d_in[19];
  const float* grul_wh  = (const float*)d_in[20];
  const float* grul_bi  = (const float*)d_in[21];
  const float* grul_bh  = (const float*)d_in[22];
  const float* mol_lin_w    = (const float*)d_in[23];
  const float* mol_att_src  = (const float*)d_in[24];
  const float* mol_att_dst  = (const float*)d_in[25];
  const float* mol_bias     = (const float*)d_in[26];
  const float* mgru_wi  = (const float*)d_in[27];
  const float* mgru_wh  = (const float*)d_in[28];
  const float* mgru_bi  = (const float*)d_in[29];
  const float* mgru_bh  = (const float*)d_in[30];
  const float* lin2_w   = (const float*)d_in[31];
  const float* lin2_b   = (const float*)d_in[32];

  const int N64 = N_NODES*64;
  float* ws     = (float*)d_ws;
  float* xA     = ws;               // N*64
  float* xB     = xA + N64;         // N*64
  float* u      = xB + N64;         // N*64 (hs for conv layers)
  float* y      = u  + N64;         // N*64 (y for gate, hs_mol)
  float* hagg   = y  + N64;         // N*64 (also hmol G*64)
  float* sc1    = hagg + N64;       // N
  float* sc2    = sc1 + N_NODES;    // N
  float* outg   = sc2 + N_NODES;    // G*64
  int* icnt   = (int*)(outg + NGRAPH*64); // N
  int* rowptr = icnt + N_NODES;     // N+1
  int* cursor = rowptr + N_NODES+1; // N
  int* geids  = cursor + N_NODES;   // E
  int* gstart = geids + N_EDGES;    // G+1

  const int* src = eidx;
  const int* dst = eidx + N_EDGES;

  const int nbN32 = (N_NODES + 31)/32;
  const int nbN4  = (N_NODES + 3)/4;
  const int nbE   = (N_EDGES + 255)/256;
  const int nbG4  = (NGRAPH + 3)/4;

  // ---- CSR build (per call; graph static within call) ----
  hipMemsetAsync(icnt, 0, N_NODES*sizeof(int), stream);
  k_hist<<<nbE, 256, 0, stream>>>(dst, icnt);
  k_scan<<<1, 1024, 0, stream>>>(icnt, rowptr, cursor);
  k_scatter<<<nbE, 256, 0, stream>>>(dst, cursor, geids);
  k_gbound<<<1, 512, 0, stream>>>(batch, gstart);

  // ---- lin1 ----
  k_lin1<<<nbN32, 256, 0, stream>>>(x_in, lin1_w, lin1_b, xA);

  // ---- GATEConv ----
  k_mm64<<<nbN32, 256, 0, stream>>>(xA, g_lin1_w, 80, u, N_NODES, nullptr, nullptr, nullptr, nullptr);
  k_mm64<<<nbN32, 256, 0, stream>>>(xA, g_lin2_w, 64, y, N_NODES, nullptr, nullptr, nullptr, nullptr);
  k_dots<<<nbN4, 256, 0, stream>>>(xA, g_att_r, sc1, N_NODES);
  k_gate_fused<<<nbN4, 256, 0, stream>>>(rowptr, geids, src, eattr, g_lin1_w, g_att_l, u, y, sc1, hagg);
  k_gru<<<nbN32, 256, 0, stream>>>(hagg, g_bias, xA, gru0_wi, gru0_wh, gru0_bi, gru0_bh, xB, N_NODES);

  float* xcur = xB; float* xoth = xA;

  // ---- GATConv layers ----
  for (int l = 0; l < 2; ++l) {
    k_mm64<<<nbN32, 256, 0, stream>>>(xcur, conv_lin_w + l*64*64, 64, u, N_NODES,
                                      conv_att_src + l*64, conv_att_dst + l*64, sc1, sc2);
    k_conv_fused<<<nbN4, 256, 0, stream>>>(rowptr, geids, src, sc1, sc2, u, hagg);
    k_gru<<<nbN32, 256, 0, stream>>>(hagg, conv_bias + l*64, xcur,
                                     grul_wi + l*192*64, grul_wh + l*192*64,
                                     grul_bi + l*192, grul_bh + l*192, xoth, N_NODES);
    float* t = xcur; xcur = xoth; xoth = t;
  }

  // ---- molecule readout ----
  k_molsum_f<<<nbG4, 256, 0, stream>>>(gstart, xcur, outg);
  k_mm64<<<nbN32, 256, 0, stream>>>(xcur, mol_lin_w, 64, y, N_NODES,
                                    mol_att_src, nullptr, sc1, nullptr);
  for (int t = 0; t < 2; ++t) {
    k_mol_fused<<<nbG4, 256, 0, stream>>>(gstart, outg, mol_lin_w, mol_att_dst, sc1, y, hagg);
    k_gru<<<(NGRAPH+31)/32, 256, 0, stream>>>(hagg, mol_bias, outg,
                                              mgru_wi, mgru_wh, mgru_bi, mgru_bh, outg, NGRAPH);
  }

  // ---- final linear ----
  k_final<<<NGRAPH, 128, 0, stream>>>(outg, lin2_w, lin2_b, (float*)d_out);
}

// Round 3
// 999.550 us; speedup vs baseline: 1.7371x; 1.0661x over previous
//
#include <hip/hip_runtime.h>
#include <math.h>

#define N_NODES 50000
#define N_EDGES 1000000
#define NGRAPH  512
#define INC     39

__device__ __forceinline__ float lrelu(float x){ return x > 0.f ? x : 0.01f*x; }
__device__ __forceinline__ float eluf (float x){ return x > 0.f ? x : expm1f(x); }
__device__ __forceinline__ float sigm (float x){ return 1.f/(1.f+expf(-x)); }
__device__ __forceinline__ float rdlane(float v, int l){
  return __int_as_float(__builtin_amdgcn_readlane(__float_as_int(v), l));
}

// ================= CSR build =================
__global__ __launch_bounds__(256) void k_hist(const int* __restrict__ dst,
                                              int* __restrict__ cnt) {
  int e = blockIdx.x*256 + threadIdx.x;
  if (e < N_EDGES) atomicAdd(&cnt[dst[e]], 1);
}

__global__ __launch_bounds__(1024) void k_scan(const int* __restrict__ cnt,
                                               int* __restrict__ rowptr,
                                               int* __restrict__ cursor) {
  __shared__ int part[1024];
  const int t = threadIdx.x;
  const int CH = (N_NODES + 1023) / 1024;   // 49
  const int base = t * CH;
  int s = 0;
  for (int i = 0; i < CH; ++i) { int idx = base + i; if (idx < N_NODES) s += cnt[idx]; }
  part[t] = s;
  __syncthreads();
  for (int off = 1; off < 1024; off <<= 1) {
    int add = (t >= off) ? part[t - off] : 0;
    __syncthreads();
    part[t] += add;
    __syncthreads();
  }
  int run = (t == 0) ? 0 : part[t - 1];
  for (int i = 0; i < CH; ++i) {
    int idx = base + i;
    if (idx < N_NODES) { rowptr[idx] = run; cursor[idx] = run; run += cnt[idx]; }
  }
  if (t == 1023) rowptr[N_NODES] = run;
}

__global__ __launch_bounds__(256) void k_scatter(const int* __restrict__ dst,
                                                 const int* __restrict__ src,
                                                 int* __restrict__ cursor,
                                                 int* __restrict__ eids,
                                                 int* __restrict__ srcp) {
  int e = blockIdx.x*256 + threadIdx.x;
  if (e < N_EDGES) {
    int p = atomicAdd(&cursor[dst[e]], 1);
    eids[p] = e;
    srcp[p] = src[e];
  }
}

__global__ __launch_bounds__(512) void k_gbound(const int* __restrict__ batch,
                                                int* __restrict__ gstart) {
  int g = threadIdx.x;
  int lo = 0, hi = N_NODES;
  while (lo < hi) { int mid = (lo+hi)>>1; if (batch[mid] < g) lo = mid+1; else hi = mid; }
  gstart[g] = lo;
  if (g == 0) gstart[NGRAPH] = N_NODES;
}

// ================= lin1: K=39, fused per-row dot with v1 =================
__global__ __launch_bounds__(256) void k_lin1(const float* __restrict__ x,
                                              const float* __restrict__ W,
                                              const float* __restrict__ b,
                                              float* __restrict__ out,
                                              const float* __restrict__ v1,
                                              float* __restrict__ o1) {
  __shared__ float wl[64*41];
  for (int idx = threadIdx.x; idx < 64*INC; idx += 256) {
    int r = idx / INC, c = idx - r*INC;
    wl[r*41+c] = W[idx];
  }
  __syncthreads();
  const int lane = threadIdx.x & 63;
  const int base = blockIdx.x*32 + (threadIdx.x>>6)*8;
  float h[8];
  #pragma unroll
  for (int i = 0; i < 8; ++i) {
    int n = base + i;
    h[i] = (n < N_NODES && lane < INC) ? x[n*INC + lane] : 0.f;
  }
  float acc[8] = {0,0,0,0,0,0,0,0};
  #pragma unroll
  for (int k = 0; k < INC; ++k) {
    float wv = wl[lane*41+k];
    #pragma unroll
    for (int i = 0; i < 8; ++i) acc[i] += rdlane(h[i], k) * wv;
  }
  float bb = b[lane];
  float attv = v1[lane];
  #pragma unroll
  for (int i = 0; i < 8; ++i) {
    int n = base + i;
    if (n >= N_NODES) continue;
    float val = lrelu(acc[i] + bb);
    out[n*64+lane] = val;
    float p = val * attv;
    #pragma unroll
    for (int s2 = 32; s2 > 0; s2 >>= 1) p += __shfl_xor(p, s2, 64);
    if (lane == 0) o1[n] = p;
  }
}

// ========== dual matmul: uy[n][0:64]=in@W1a.T (stride-80 W), uy[n][64:128]=in@W2.T ==========
__global__ __launch_bounds__(256) void k_mmdual(const float* __restrict__ in,
                                                const float* __restrict__ W1, // [64][80], cols 0..63
                                                const float* __restrict__ W2, // [64][64]
                                                float* __restrict__ uy, int R) {
  __shared__ float wl[128*65];
  for (int idx = threadIdx.x; idx < 4096; idx += 256) {
    int r = idx >> 6, c = idx & 63;
    wl[r*65+c]      = W1[r*80 + c];
    wl[(64+r)*65+c] = W2[r*64 + c];
  }
  __syncthreads();
  const int lane = threadIdx.x & 63;
  const int base = blockIdx.x*32 + (threadIdx.x>>6)*8;
  float h[8];
  #pragma unroll
  for (int i = 0; i < 8; ++i) { int n = base+i; h[i] = (n < R) ? in[n*64+lane] : 0.f; }
  float accU[8] = {0,0,0,0,0,0,0,0};
  float accY[8] = {0,0,0,0,0,0,0,0};
  for (int k = 0; k < 64; ++k) {
    float wu = wl[lane*65+k], wy = wl[(64+lane)*65+k];
    #pragma unroll
    for (int i = 0; i < 8; ++i) {
      float hk = rdlane(h[i], k);
      accU[i] += hk*wu; accY[i] += hk*wy;
    }
  }
  #pragma unroll
  for (int i = 0; i < 8; ++i) {
    int n = base+i; if (n >= R) continue;
    uy[n*128 + lane]      = accU[i];
    uy[n*128 + 64 + lane] = accY[i];
  }
}

// ========== [R,64] @ W(64 rows, rs stride).T, optional fused per-row dots ==========
__global__ __launch_bounds__(256) void k_mm64(const float* __restrict__ in,
                                              const float* __restrict__ W, int rs,
                                              float* __restrict__ out, int R,
                                              const float* __restrict__ v1,
                                              const float* __restrict__ v2,
                                              float* __restrict__ o1,
                                              float* __restrict__ o2) {
  __shared__ float wl[64*65];
  for (int idx = threadIdx.x; idx < 4096; idx += 256) {
    int r = idx >> 6, c = idx & 63;
    wl[r*65+c] = W[r*rs + c];
  }
  __syncthreads();
  const int lane = threadIdx.x & 63;
  const int base = blockIdx.x*32 + (threadIdx.x>>6)*8;
  float h[8];
  #pragma unroll
  for (int i = 0; i < 8; ++i) { int n = base+i; h[i] = (n < R) ? in[n*64+lane] : 0.f; }
  float acc[8] = {0,0,0,0,0,0,0,0};
  for (int k = 0; k < 64; ++k) {
    float wv = wl[lane*65+k];
    #pragma unroll
    for (int i = 0; i < 8; ++i) acc[i] += rdlane(h[i], k) * wv;
  }
  float v1v = v1 ? v1[lane] : 0.f;
  float v2v = v2 ? v2[lane] : 0.f;
  #pragma unroll
  for (int i = 0; i < 8; ++i) {
    int n = base+i; if (n >= R) continue;
    out[n*64+lane] = acc[i];
    if (o1) {
      float p1 = acc[i]*v1v;
      float p2 = acc[i]*v2v;
      #pragma unroll
      for (int s2 = 32; s2 > 0; s2 >>= 1) { p1 += __shfl_xor(p1, s2, 64); p2 += __shfl_xor(p2, s2, 64); }
      if (lane == 0) { o1[n] = p1; if (o2) o2[n] = p2; }
    }
  }
}

// ===== GATEConv fused: per-dst wave, 4-edge batched software pipeline =====
#define NB 4
__global__ __launch_bounds__(256) void k_gate_fused(const int* __restrict__ rowptr,
                                                    const int* __restrict__ eids,
                                                    const int* __restrict__ srcp,
                                                    const float* __restrict__ ea,
                                                    const float* __restrict__ glin1, // [64][80]
                                                    const float* __restrict__ attl,
                                                    const float* __restrict__ uy,
                                                    const float* __restrict__ xr,
                                                    float* __restrict__ hagg) {
  const int lane = threadIdx.x & 63;
  float w2r[16];
  #pragma unroll
  for (int j = 0; j < 16; ++j) w2r[j] = glin1[lane*80 + 64 + j];
  float alv = attl[lane];
  int d = blockIdx.x*4 + (threadIdx.x>>6);
  if (d >= N_NODES) return;
  int r0 = rowptr[d], r1 = rowptr[d+1];
  float xrd = xr[d];
  float acc = 0.f, ssum = 0.f;

  int eidC[NB], sC[NB]; float uC[NB], yC[NB], eaC[NB];
  #pragma unroll
  for (int j = 0; j < NB; ++j) {
    int i = r0 + j;
    eidC[j] = (i < r1) ? eids[i] : -1;
    sC[j]   = (i < r1) ? srcp[i] : 0;
  }
  #pragma unroll
  for (int j = 0; j < NB; ++j) {
    uC[j]  = uy[sC[j]*128 + lane];
    yC[j]  = uy[sC[j]*128 + 64 + lane];
    eaC[j] = (lane < 16 && eidC[j] >= 0) ? ea[eidC[j]*16 + lane] : 0.f;
  }

  for (int b = r0; b < r1; b += NB) {
    int bn = b + NB;
    int eidN[NB], sN[NB]; float uN[NB], yN[NB], eaN[NB];
    #pragma unroll
    for (int j = 0; j < NB; ++j) {
      int i = bn + j;
      eidN[j] = (i < r1) ? eids[i] : -1;
      sN[j]   = (i < r1) ? srcp[i] : 0;
    }
    #pragma unroll
    for (int j = 0; j < NB; ++j) {
      uN[j]  = uy[sN[j]*128 + lane];
      yN[j]  = uy[sN[j]*128 + 64 + lane];
      eaN[j] = (lane < 16 && eidN[j] >= 0) ? ea[eidN[j]*16 + lane] : 0.f;
    }
    #pragma unroll
    for (int j = 0; j < NB; ++j) {
      if (eidC[j] >= 0) {
        float v = 0.f;
        #pragma unroll
        for (int jj = 0; jj < 16; ++jj) v += rdlane(eaC[j], jj) * w2r[jj];
        float t = lrelu(uC[j] + v);
        float p = t * alv;
        #pragma unroll
        for (int sh = 32; sh > 0; sh >>= 1) p += __shfl_xor(p, sh, 64);
        float ev = expf(lrelu(p + xrd));
        acc  += ev * yC[j];
        ssum += ev;
      }
    }
    #pragma unroll
    for (int j = 0; j < NB; ++j) {
      eidC[j]=eidN[j]; sC[j]=sN[j]; uC[j]=uN[j]; yC[j]=yN[j]; eaC[j]=eaN[j];
    }
  }
  hagg[d*64+lane] = acc / (ssum + 1e-16f);
}

// ===== GATConv fused: lane-parallel scores, 8-wide register-batched aggregate =====
__global__ __launch_bounds__(256) void k_conv_fused(const int* __restrict__ rowptr,
                                                    const int* __restrict__ srcp,
                                                    const float* __restrict__ asn,
                                                    const float* __restrict__ adn,
                                                    const float* __restrict__ hs,
                                                    float* __restrict__ hagg) {
  __shared__ int   sS[4][64];
  __shared__ float sE[4][64];
  const int w = threadIdx.x >> 6, lane = threadIdx.x & 63;
  int d = blockIdx.x*4 + w;
  if (d >= N_NODES) return;
  int r0 = rowptr[d], r1 = rowptr[d+1];
  float adnd = adn[d];
  float acc = 0.f, ssum = 0.f;
  for (int base = r0; base < r1; base += 64) {
    int i = base + lane;
    int cnt = r1 - base; if (cnt > 64) cnt = 64;
    float ev = 0.f; int s = 0;
    if (i < r1) { s = srcp[i]; ev = expf(lrelu(asn[s] + adnd)); }
    sS[w][lane] = s; sE[w][lane] = ev;
    ssum += ev;
    for (int jb = 0; jb < cnt; jb += 8) {
      float h8[8], e8[8];
      #pragma unroll
      for (int j = 0; j < 8; ++j) {
        int jj = jb + j;
        if (jj < cnt) {
          int sv = sS[w][jj];
          e8[j] = sE[w][jj];
          h8[j] = hs[sv*64 + lane];
        } else { e8[j] = 0.f; h8[j] = 0.f; }
      }
      #pragma unroll
      for (int j = 0; j < 8; ++j) acc += e8[j] * h8[j];
    }
  }
  #pragma unroll
  for (int sh = 32; sh > 0; sh >>= 1) ssum += __shfl_xor(ssum, sh, 64);
  hagg[d*64+lane] = acc / (ssum + 1e-16f);
}

// ===== fused GRU: out = relu(GRU(elu(inp+pbias), hid)) =====
__global__ __launch_bounds__(256) void k_gru(const float* __restrict__ inp,
                                             const float* __restrict__ pbias,
                                             const float* __restrict__ hid,
                                             const float* __restrict__ wi,
                                             const float* __restrict__ wh,
                                             const float* __restrict__ bi,
                                             const float* __restrict__ bh,
                                             float* __restrict__ out, int R) {
  __shared__ float wl[192*65];
  const int lane = threadIdx.x & 63;
  const int base = blockIdx.x*32 + (threadIdx.x>>6)*8;
  float pb = pbias[lane];
  float hin[8], hh[8];
  #pragma unroll
  for (int i = 0; i < 8; ++i) {
    int n = base + i;
    if (n < R) { hin[i] = eluf(inp[n*64+lane] + pb); hh[i] = hid[n*64+lane]; }
    else       { hin[i] = 0.f; hh[i] = 0.f; }
  }
  for (int idx = threadIdx.x; idx < 192*64; idx += 256)
    wl[(idx>>6)*65 + (idx&63)] = wi[idx];
  __syncthreads();
  float gr[8]={0,0,0,0,0,0,0,0}, gz[8]={0,0,0,0,0,0,0,0}, gn[8]={0,0,0,0,0,0,0,0};
  #pragma unroll 16
  for (int k = 0; k < 64; ++k) {
    float wr = wl[lane*65+k], wz = wl[(64+lane)*65+k], wn = wl[(128+lane)*65+k];
    #pragma unroll
    for (int i = 0; i < 8; ++i) {
      float hk = rdlane(hin[i], k);
      gr[i] += hk*wr; gz[i] += hk*wz; gn[i] += hk*wn;
    }
  }
  __syncthreads();
  for (int idx = threadIdx.x; idx < 192*64; idx += 256)
    wl[(idx>>6)*65 + (idx&63)] = wh[idx];
  __syncthreads();
  float hr[8]={0,0,0,0,0,0,0,0}, hz[8]={0,0,0,0,0,0,0,0}, hn[8]={0,0,0,0,0,0,0,0};
  #pragma unroll 16
  for (int k = 0; k < 64; ++k) {
    float wr = wl[lane*65+k], wz = wl[(64+lane)*65+k], wn = wl[(128+lane)*65+k];
    #pragma unroll
    for (int i = 0; i < 8; ++i) {
      float hk = rdlane(hh[i], k);
      hr[i] += hk*wr; hz[i] += hk*wz; hn[i] += hk*wn;
    }
  }
  float bir = bi[lane], biz = bi[64+lane], bin_ = bi[128+lane];
  float bhr = bh[lane], bhz = bh[64+lane], bhn = bh[128+lane];
  #pragma unroll
  for (int i = 0; i < 8; ++i) {
    int n = base + i;
    if (n >= R) continue;
    float r  = sigm(gr[i]+bir + hr[i]+bhr);
    float z  = sigm(gz[i]+biz + hz[i]+bhz);
    float nn = tanhf(gn[i]+bin_ + r*(hn[i]+bhn));
    float o  = (1.f - z)*nn + z*hh[i];
    out[n*64+lane] = fmaxf(o, 0.f);
  }
}

// ================= molecule readout (CSR over sorted batch) =================
__global__ __launch_bounds__(256) void k_molsum_f(const int* __restrict__ gstart,
                                                  const float* __restrict__ x,
                                                  float* __restrict__ outg) {
  int g = blockIdx.x*4 + (threadIdx.x>>6);
  if (g >= NGRAPH) return;
  int lane = threadIdx.x & 63;
  float acc = 0.f;
  int n1 = gstart[g+1];
  for (int n = gstart[g]; n < n1; ++n) acc += x[n*64+lane];
  outg[g*64+lane] = fmaxf(acc, 0.f);
}

__global__ __launch_bounds__(256) void k_mol_fused(const int* __restrict__ gstart,
                                                   const float* __restrict__ outg,
                                                   const float* __restrict__ W,
                                                   const float* __restrict__ attd,
                                                   const float* __restrict__ asn,
                                                   const float* __restrict__ y,
                                                   float* __restrict__ hg) {
  __shared__ float wl[64*65];
  for (int idx = threadIdx.x; idx < 4096; idx += 256) wl[(idx>>6)*65+(idx&63)] = W[idx];
  __syncthreads();
  int g = blockIdx.x*4 + (threadIdx.x>>6);
  if (g >= NGRAPH) return;
  int lane = threadIdx.x & 63;
  float og = outg[g*64+lane];
  float hd = 0.f;
  #pragma unroll
  for (int k = 0; k < 64; ++k) hd += rdlane(og, k) * wl[lane*65+k];
  float p = hd * attd[lane];
  #pragma unroll
  for (int sh = 32; sh > 0; sh >>= 1) p += __shfl_xor(p, sh, 64);
  float addg = p;
  float acc = 0.f, ssum = 0.f;
  int n1 = gstart[g+1];
  for (int n = gstart[g]; n < n1; ++n) {
    float ev = expf(lrelu(asn[n] + addg));
    acc += ev * y[n*64+lane];
    ssum += ev;
  }
  hg[g*64+lane] = acc / (ssum + 1e-16f);
}

__global__ __launch_bounds__(128) void k_final(const float* __restrict__ outg,
                                               const float* __restrict__ W,
                                               const float* __restrict__ b,
                                               float* __restrict__ out) {
  __shared__ float og[64];
  int g = blockIdx.x;
  if (threadIdx.x < 64) og[threadIdx.x] = outg[g*64+threadIdx.x];
  __syncthreads();
  int o = threadIdx.x;
  float acc = b[o];
  for (int k = 0; k < 64; ++k) acc += og[k]*W[o*64+k];
  out[g*128+o] = acc;
}

extern "C" void kernel_launch(void* const* d_in, const int* in_sizes, int n_in,
                              void* d_out, int out_size, void* d_ws, size_t ws_size,
                              hipStream_t stream) {
  const float* x_in     = (const float*)d_in[0];
  const int*   eidx     = (const int*)  d_in[1];
  const float* eattr    = (const float*)d_in[2];
  const int*   batch    = (const int*)  d_in[3];
  const float* lin1_w   = (const float*)d_in[4];
  const float* lin1_b   = (const float*)d_in[5];
  const float* g_lin1_w = (const float*)d_in[6];
  const float* g_att_l  = (const float*)d_in[7];
  const float* g_att_r  = (const float*)d_in[8];
  const float* g_lin2_w = (const float*)d_in[9];
  const float* g_bias   = (const float*)d_in[10];
  const float* gru0_wi  = (const float*)d_in[11];
  const float* gru0_wh  = (const float*)d_in[12];
  const float* gru0_bi  = (const float*)d_in[13];
  const float* gru0_bh  = (const float*)d_in[14];
  const float* conv_lin_w   = (const float*)d_in[15];
  const float* conv_att_src = (const float*)d_in[16];
  const float* conv_att_dst = (const float*)d_in[17];
  const float* conv_bias    = (const float*)d_in[18];
  const float* grul_wi  = (const float*)d_in[19];
  const float* grul_wh  = (const float*)d_in[20];
  const float* grul_bi  = (const float*)d_in[21];
  const float* grul_bh  = (const float*)d_in[22];
  const float* mol_lin_w    = (const float*)d_in[23];
  const float* mol_att_src  = (const float*)d_in[24];
  const float* mol_att_dst  = (const float*)d_in[25];
  const float* mol_bias     = (const float*)d_in[26];
  const float* mgru_wi  = (const float*)d_in[27];
  const float* mgru_wh  = (const float*)d_in[28];
  const float* mgru_bi  = (const float*)d_in[29];
  const float* mgru_bh  = (const float*)d_in[30];
  const float* lin2_w   = (const float*)d_in[31];
  const float* lin2_b   = (const float*)d_in[32];

  const int N64 = N_NODES*64;
  float* ws     = (float*)d_ws;
  float* xA     = ws;               // N*64
  float* xB     = xA + N64;         // N*64
  float* uy     = xB + N64;         // N*128 (gate); first half doubles as hs / y_mol
  float* hagg   = uy + 2*N64;       // N*64
  float* sc1    = hagg + N64;       // N
  float* sc2    = sc1 + N_NODES;    // N
  float* outg   = sc2 + N_NODES;    // G*64
  int* icnt   = (int*)(outg + NGRAPH*64); // N
  int* rowptr = icnt + N_NODES;     // N+1
  int* cursor = rowptr + N_NODES+1; // N
  int* geids  = cursor + N_NODES;   // E
  int* srcp   = geids + N_EDGES;    // E
  int* gstart = srcp + N_EDGES;     // G+1

  const int* src = eidx;
  const int* dst = eidx + N_EDGES;

  const int nbN32 = (N_NODES + 31)/32;
  const int nbN4  = (N_NODES + 3)/4;
  const int nbE   = (N_EDGES + 255)/256;
  const int nbG4  = (NGRAPH + 3)/4;

  // ---- CSR build ----
  hipMemsetAsync(icnt, 0, N_NODES*sizeof(int), stream);
  k_hist<<<nbE, 256, 0, stream>>>(dst, icnt);
  k_scan<<<1, 1024, 0, stream>>>(icnt, rowptr, cursor);
  k_scatter<<<nbE, 256, 0, stream>>>(dst, src, cursor, geids, srcp);
  k_gbound<<<1, 512, 0, stream>>>(batch, gstart);

  // ---- lin1 (+ fused xr = x.h @ g_att_r) ----
  k_lin1<<<nbN32, 256, 0, stream>>>(x_in, lin1_w, lin1_b, xA, g_att_r, sc1);

  // ---- GATEConv ----
  k_mmdual<<<nbN32, 256, 0, stream>>>(xA, g_lin1_w, g_lin2_w, uy, N_NODES);
  k_gate_fused<<<nbN4, 256, 0, stream>>>(rowptr, geids, srcp, eattr, g_lin1_w, g_att_l, uy, sc1, hagg);
  k_gru<<<nbN32, 256, 0, stream>>>(hagg, g_bias, xA, gru0_wi, gru0_wh, gru0_bi, gru0_bh, xB, N_NODES);

  float* xcur = xB; float* xoth = xA;
  float* hs = uy;  // N*64 region reuse

  // ---- GATConv layers ----
  for (int l = 0; l < 2; ++l) {
    k_mm64<<<nbN32, 256, 0, stream>>>(xcur, conv_lin_w + l*64*64, 64, hs, N_NODES,
                                      conv_att_src + l*64, conv_att_dst + l*64, sc1, sc2);
    k_conv_fused<<<nbN4, 256, 0, stream>>>(rowptr, srcp, sc1, sc2, hs, hagg);
    k_gru<<<nbN32, 256, 0, stream>>>(hagg, conv_bias + l*64, xcur,
                                     grul_wi + l*192*64, grul_wh + l*192*64,
                                     grul_bi + l*192, grul_bh + l*192, xoth, N_NODES);
    float* t = xcur; xcur = xoth; xoth = t;
  }

  // ---- molecule readout ----
  k_molsum_f<<<nbG4, 256, 0, stream>>>(gstart, xcur, outg);
  k_mm64<<<nbN32, 256, 0, stream>>>(xcur, mol_lin_w, 64, hs, N_NODES,
                                    mol_att_src, nullptr, sc1, nullptr);
  for (int t = 0; t < 2; ++t) {
    k_mol_fused<<<nbG4, 256, 0, stream>>>(gstart, outg, mol_lin_w, mol_att_dst, sc1, hs, hagg);
    k_gru<<<(NGRAPH+31)/32, 256, 0, stream>>>(hagg, mol_bias, outg,
                                              mgru_wi, mgru_wh, mgru_bi, mgru_bh, outg, NGRAPH);
  }

  // ---- final linear ----
  k_final<<<NGRAPH, 128, 0, stream>>>(outg, lin2_w, lin2_b, (float*)d_out);
}

// Round 4
// 904.642 us; speedup vs baseline: 1.9194x; 1.1049x over previous
//
#include <hip/hip_runtime.h>
#include <math.h>

#define N_NODES 50000
#define N_EDGES 1000000
#define NGRAPH  512
#define INC     39

__device__ __forceinline__ float lrelu(float x){ return fmaxf(0.01f*x, x); }
__device__ __forceinline__ float fexp(float x){ return __builtin_amdgcn_exp2f(x*1.4426950408889634f); }
__device__ __forceinline__ float frcp(float x){ return __builtin_amdgcn_rcpf(x); }
__device__ __forceinline__ float eluf (float x){ return x > 0.f ? x : fexp(x) - 1.f; }
__device__ __forceinline__ float sigm (float x){ return frcp(1.f + fexp(-x)); }
__device__ __forceinline__ float ftanh(float x){
  x = fminf(fmaxf(x, -15.f), 15.f);
  float e = __builtin_amdgcn_exp2f(x*2.8853900817779268f); // exp(2x)
  return (e - 1.f)*frcp(e + 1.f);
}
__device__ __forceinline__ float rdlane(float v, int l){
  return __int_as_float(__builtin_amdgcn_readlane(__float_as_int(v), l));
}

// ================= CSR build =================
__global__ __launch_bounds__(256) void k_hist(const int* __restrict__ dst,
                                              int* __restrict__ cnt) {
  int e = blockIdx.x*256 + threadIdx.x;
  if (e < N_EDGES) atomicAdd(&cnt[dst[e]], 1);
}

__global__ __launch_bounds__(1024) void k_scan(const int* __restrict__ cnt,
                                               int* __restrict__ rowptr,
                                               int* __restrict__ cursor) {
  __shared__ int part[1024];
  const int t = threadIdx.x;
  const int CH = (N_NODES + 1023) / 1024;
  const int base = t * CH;
  int s = 0;
  for (int i = 0; i < CH; ++i) { int idx = base + i; if (idx < N_NODES) s += cnt[idx]; }
  part[t] = s;
  __syncthreads();
  for (int off = 1; off < 1024; off <<= 1) {
    int add = (t >= off) ? part[t - off] : 0;
    __syncthreads();
    part[t] += add;
    __syncthreads();
  }
  int run = (t == 0) ? 0 : part[t - 1];
  for (int i = 0; i < CH; ++i) {
    int idx = base + i;
    if (idx < N_NODES) { rowptr[idx] = run; cursor[idx] = run; run += cnt[idx]; }
  }
  if (t == 1023) rowptr[N_NODES] = run;
}

__global__ __launch_bounds__(256) void k_scatter(const int* __restrict__ dst,
                                                 const int* __restrict__ src,
                                                 int* __restrict__ cursor,
                                                 int* __restrict__ eids,
                                                 int* __restrict__ srcp) {
  int e = blockIdx.x*256 + threadIdx.x;
  if (e < N_EDGES) {
    int p = atomicAdd(&cursor[dst[e]], 1);
    eids[p] = e;
    srcp[p] = src[e];
  }
}

__global__ __launch_bounds__(512) void k_gbound(const int* __restrict__ batch,
                                                int* __restrict__ gstart) {
  int g = threadIdx.x;
  int lo = 0, hi = N_NODES;
  while (lo < hi) { int mid = (lo+hi)>>1; if (batch[mid] < g) lo = mid+1; else hi = mid; }
  gstart[g] = lo;
  if (g == 0) gstart[NGRAPH] = N_NODES;
}

// ================= lin1: K=39, fused per-row dot with v1 =================
__global__ __launch_bounds__(256) void k_lin1(const float* __restrict__ x,
                                              const float* __restrict__ W,
                                              const float* __restrict__ b,
                                              float* __restrict__ out,
                                              const float* __restrict__ v1,
                                              float* __restrict__ o1) {
  __shared__ float wl[64*41];
  for (int idx = threadIdx.x; idx < 64*INC; idx += 256) {
    int r = idx / INC, c = idx - r*INC;
    wl[r*41+c] = W[idx];
  }
  __syncthreads();
  const int lane = threadIdx.x & 63;
  const int base = blockIdx.x*32 + (threadIdx.x>>6)*8;
  float h[8];
  #pragma unroll
  for (int i = 0; i < 8; ++i) {
    int n = base + i;
    h[i] = (n < N_NODES && lane < INC) ? x[n*INC + lane] : 0.f;
  }
  float acc[8] = {0,0,0,0,0,0,0,0};
  #pragma unroll
  for (int k = 0; k < INC; ++k) {
    float wv = wl[lane*41+k];
    #pragma unroll
    for (int i = 0; i < 8; ++i) acc[i] += rdlane(h[i], k) * wv;
  }
  float bb = b[lane];
  float attv = v1[lane];
  #pragma unroll
  for (int i = 0; i < 8; ++i) {
    int n = base + i;
    if (n >= N_NODES) continue;
    float val = lrelu(acc[i] + bb);
    out[n*64+lane] = val;
    float p = val * attv;
    #pragma unroll
    for (int s2 = 32; s2 > 0; s2 >>= 1) p += __shfl_xor(p, s2, 64);
    if (lane == 0) o1[n] = p;
  }
}

// ========== dual matmul -> interleaved float2 {u,y} ==========
__global__ __launch_bounds__(256) void k_mmdual(const float* __restrict__ in,
                                                const float* __restrict__ W1, // [64][80]
                                                const float* __restrict__ W2, // [64][64]
                                                float2* __restrict__ uy, int R) {
  __shared__ float wl[128*65];
  for (int idx = threadIdx.x; idx < 4096; idx += 256) {
    int r = idx >> 6, c = idx & 63;
    wl[r*65+c]      = W1[r*80 + c];
    wl[(64+r)*65+c] = W2[r*64 + c];
  }
  __syncthreads();
  const int lane = threadIdx.x & 63;
  const int base = blockIdx.x*32 + (threadIdx.x>>6)*8;
  float h[8];
  #pragma unroll
  for (int i = 0; i < 8; ++i) { int n = base+i; h[i] = (n < R) ? in[n*64+lane] : 0.f; }
  float accU[8] = {0,0,0,0,0,0,0,0};
  float accY[8] = {0,0,0,0,0,0,0,0};
  for (int k = 0; k < 64; ++k) {
    float wu = wl[lane*65+k], wy = wl[(64+lane)*65+k];
    #pragma unroll
    for (int i = 0; i < 8; ++i) {
      float hk = rdlane(h[i], k);
      accU[i] += hk*wu; accY[i] += hk*wy;
    }
  }
  #pragma unroll
  for (int i = 0; i < 8; ++i) {
    int n = base+i; if (n >= R) continue;
    uy[n*64 + lane] = make_float2(accU[i], accY[i]);
  }
}

// ========== [R,64] @ W(64 rows, rs stride).T, optional fused per-row dots ==========
__global__ __launch_bounds__(256) void k_mm64(const float* __restrict__ in,
                                              const float* __restrict__ W, int rs,
                                              float* __restrict__ out, int R,
                                              const float* __restrict__ v1,
                                              const float* __restrict__ v2,
                                              float* __restrict__ o1,
                                              float* __restrict__ o2) {
  __shared__ float wl[64*65];
  for (int idx = threadIdx.x; idx < 4096; idx += 256) {
    int r = idx >> 6, c = idx & 63;
    wl[r*65+c] = W[r*rs + c];
  }
  __syncthreads();
  const int lane = threadIdx.x & 63;
  const int base = blockIdx.x*32 + (threadIdx.x>>6)*8;
  float h[8];
  #pragma unroll
  for (int i = 0; i < 8; ++i) { int n = base+i; h[i] = (n < R) ? in[n*64+lane] : 0.f; }
  float acc[8] = {0,0,0,0,0,0,0,0};
  for (int k = 0; k < 64; ++k) {
    float wv = wl[lane*65+k];
    #pragma unroll
    for (int i = 0; i < 8; ++i) acc[i] += rdlane(h[i], k) * wv;
  }
  float v1v = v1 ? v1[lane] : 0.f;
  float v2v = v2 ? v2[lane] : 0.f;
  #pragma unroll
  for (int i = 0; i < 8; ++i) {
    int n = base+i; if (n >= R) continue;
    out[n*64+lane] = acc[i];
    if (o1) {
      float p1 = acc[i]*v1v;
      float p2 = acc[i]*v2v;
      #pragma unroll
      for (int s2 = 32; s2 > 0; s2 >>= 1) { p1 += __shfl_xor(p1, s2, 64); p2 += __shfl_xor(p2, s2, 64); }
      if (lane == 0) { o1[n] = p1; if (o2) o2[n] = p2; }
    }
  }
}

// ===== GATEConv fused: per-dst wave, uniform control, s_load indices =====
#define NB 4
__global__ __launch_bounds__(256) void k_gate_fused(const int* __restrict__ rowptr,
                                                    const int* __restrict__ eids,
                                                    const int* __restrict__ srcp,
                                                    const float* __restrict__ ea,
                                                    const float* __restrict__ glin1, // [64][80]
                                                    const float* __restrict__ attl,
                                                    const float2* __restrict__ uy,
                                                    const float* __restrict__ xr,
                                                    float* __restrict__ hagg) {
  const int lane = threadIdx.x & 63;
  float w2r[16];
  #pragma unroll
  for (int j = 0; j < 16; ++j) w2r[j] = glin1[lane*80 + 64 + j];
  float alv = attl[lane];
  const int wid = __builtin_amdgcn_readfirstlane(threadIdx.x >> 6);
  const int d = blockIdx.x*4 + wid;                 // wave-uniform (SGPR)
  const int r0 = __builtin_amdgcn_readfirstlane(rowptr[d]);
  const int r1 = __builtin_amdgcn_readfirstlane(rowptr[d+1]);
  const float xrd = xr[d];
  float acc = 0.f, ssum = 0.f;

  float eaC[NB]; float2 uyC[NB];
  #pragma unroll
  for (int j = 0; j < NB; ++j) {
    int i = r0 + j; i = i < r1 ? i : (r1-1); i = i < 0 ? 0 : i;   // uniform clamp
    int e = eids[i];                                               // s_load
    int s = srcp[i];                                               // s_load
    eaC[j]  = ea[(size_t)e*16 + (lane & 15)];
    uyC[j]  = uy[(size_t)s*64 + lane];
  }

  for (int b = r0; b < r1; b += NB) {
    float eaN[NB]; float2 uyN[NB];
    #pragma unroll
    for (int j = 0; j < NB; ++j) {
      int i = b + NB + j; i = i < r1 ? i : (r1-1); i = i < 0 ? 0 : i;
      int e = eids[i];
      int s = srcp[i];
      eaN[j] = ea[(size_t)e*16 + (lane & 15)];
      uyN[j] = uy[(size_t)s*64 + lane];
    }
    #pragma unroll
    for (int j = 0; j < NB; ++j) {
      if (b + j < r1) {                       // wave-uniform branch
        float v = 0.f;
        #pragma unroll
        for (int jj = 0; jj < 16; ++jj) v = fmaf(rdlane(eaC[j], jj), w2r[jj], v);
        float z = uyC[j].x + v;
        float t = lrelu(z);
        float p = t * alv;
        #pragma unroll
        for (int sh = 32; sh > 0; sh >>= 1) p += __shfl_xor(p, sh, 64);
        float ev = fexp(lrelu(p + xrd));
        acc  = fmaf(ev, uyC[j].y, acc);
        ssum += ev;
      }
    }
    #pragma unroll
    for (int j = 0; j < NB; ++j) { eaC[j] = eaN[j]; uyC[j] = uyN[j]; }
  }
  hagg[d*64+lane] = acc * frcp(ssum + 1e-16f);
}

// ===== GATConv fused: lane-parallel scores, 8-wide register-batched aggregate =====
__global__ __launch_bounds__(256) void k_conv_fused(const int* __restrict__ rowptr,
                                                    const int* __restrict__ srcp,
                                                    const float* __restrict__ asn,
                                                    const float* __restrict__ adn,
                                                    const float* __restrict__ hs,
                                                    float* __restrict__ hagg) {
  __shared__ int   sS[4][64];
  __shared__ float sE[4][64];
  const int w = __builtin_amdgcn_readfirstlane(threadIdx.x >> 6);
  const int lane = threadIdx.x & 63;
  const int d = blockIdx.x*4 + w;
  const int r0 = __builtin_amdgcn_readfirstlane(rowptr[d]);
  const int r1 = __builtin_amdgcn_readfirstlane(rowptr[d+1]);
  float adnd = adn[d];
  float acc = 0.f, ssum = 0.f;
  for (int base = r0; base < r1; base += 64) {
    int i = base + lane;
    int cnt = r1 - base; if (cnt > 64) cnt = 64;
    float ev = 0.f; int s = 0;
    if (i < r1) { s = srcp[i]; ev = fexp(lrelu(asn[s] + adnd)); }
    sS[w][lane] = s; sE[w][lane] = ev;
    ssum += ev;
    for (int jb = 0; jb < cnt; jb += 8) {
      float h8[8], e8[8];
      #pragma unroll
      for (int j = 0; j < 8; ++j) {
        int jj = jb + j;
        if (jj < cnt) {
          int sv = sS[w][jj];
          e8[j] = sE[w][jj];
          h8[j] = hs[sv*64 + lane];
        } else { e8[j] = 0.f; h8[j] = 0.f; }
      }
      #pragma unroll
      for (int j = 0; j < 8; ++j) acc += e8[j] * h8[j];
    }
  }
  #pragma unroll
  for (int sh = 32; sh > 0; sh >>= 1) ssum += __shfl_xor(ssum, sh, 64);
  hagg[d*64+lane] = acc * frcp(ssum + 1e-16f);
}

// ===== fused GRU: out = relu(GRU(elu(inp+pbias), hid)) =====
__global__ __launch_bounds__(256) void k_gru(const float* __restrict__ inp,
                                             const float* __restrict__ pbias,
                                             const float* __restrict__ hid,
                                             const float* __restrict__ wi,
                                             const float* __restrict__ wh,
                                             const float* __restrict__ bi,
                                             const float* __restrict__ bh,
                                             float* __restrict__ out, int R) {
  __shared__ float wl[192*65];
  const int lane = threadIdx.x & 63;
  const int base = blockIdx.x*32 + (threadIdx.x>>6)*8;
  float pb = pbias[lane];
  float hin[8], hh[8];
  #pragma unroll
  for (int i = 0; i < 8; ++i) {
    int n = base + i;
    if (n < R) { hin[i] = eluf(inp[n*64+lane] + pb); hh[i] = hid[n*64+lane]; }
    else       { hin[i] = 0.f; hh[i] = 0.f; }
  }
  for (int idx = threadIdx.x; idx < 192*64; idx += 256)
    wl[(idx>>6)*65 + (idx&63)] = wi[idx];
  __syncthreads();
  float gr[8]={0,0,0,0,0,0,0,0}, gz[8]={0,0,0,0,0,0,0,0}, gn[8]={0,0,0,0,0,0,0,0};
  #pragma unroll 16
  for (int k = 0; k < 64; ++k) {
    float wr = wl[lane*65+k], wz = wl[(64+lane)*65+k], wn = wl[(128+lane)*65+k];
    #pragma unroll
    for (int i = 0; i < 8; ++i) {
      float hk = rdlane(hin[i], k);
      gr[i] += hk*wr; gz[i] += hk*wz; gn[i] += hk*wn;
    }
  }
  __syncthreads();
  for (int idx = threadIdx.x; idx < 192*64; idx += 256)
    wl[(idx>>6)*65 + (idx&63)] = wh[idx];
  __syncthreads();
  float hr[8]={0,0,0,0,0,0,0,0}, hz[8]={0,0,0,0,0,0,0,0}, hn[8]={0,0,0,0,0,0,0,0};
  #pragma unroll 16
  for (int k = 0; k < 64; ++k) {
    float wr = wl[lane*65+k], wz = wl[(64+lane)*65+k], wn = wl[(128+lane)*65+k];
    #pragma unroll
    for (int i = 0; i < 8; ++i) {
      float hk = rdlane(hh[i], k);
      hr[i] += hk*wr; hz[i] += hk*wz; hn[i] += hk*wn;
    }
  }
  float bir = bi[lane], biz = bi[64+lane], bin_ = bi[128+lane];
  float bhr = bh[lane], bhz = bh[64+lane], bhn = bh[128+lane];
  #pragma unroll
  for (int i = 0; i < 8; ++i) {
    int n = base + i;
    if (n >= R) continue;
    float r  = sigm(gr[i]+bir + hr[i]+bhr);
    float z  = sigm(gz[i]+biz + hz[i]+bhz);
    float nn = ftanh(gn[i]+bin_ + r*(hn[i]+bhn));
    float o  = (1.f - z)*nn + z*hh[i];
    out[n*64+lane] = fmaxf(o, 0.f);
  }
}

// ================= molecule readout (CSR over sorted batch) =================
__global__ __launch_bounds__(256) void k_molsum_f(const int* __restrict__ gstart,
                                                  const float* __restrict__ x,
                                                  float* __restrict__ outg) {
  int g = blockIdx.x*4 + (threadIdx.x>>6);
  if (g >= NGRAPH) return;
  int lane = threadIdx.x & 63;
  float acc = 0.f;
  int n1 = gstart[g+1];
  for (int n = gstart[g]; n < n1; ++n) acc += x[n*64+lane];
  outg[g*64+lane] = fmaxf(acc, 0.f);
}

__global__ __launch_bounds__(256) void k_mol_fused(const int* __restrict__ gstart,
                                                   const float* __restrict__ outg,
                                                   const float* __restrict__ W,
                                                   const float* __restrict__ attd,
                                                   const float* __restrict__ asn,
                                                   const float* __restrict__ y,
                                                   float* __restrict__ hg) {
  __shared__ float wl[64*65];
  for (int idx = threadIdx.x; idx < 4096; idx += 256) wl[(idx>>6)*65+(idx&63)] = W[idx];
  __syncthreads();
  int g = blockIdx.x*4 + (threadIdx.x>>6);
  if (g >= NGRAPH) return;
  int lane = threadIdx.x & 63;
  float og = outg[g*64+lane];
  float hd = 0.f;
  #pragma unroll
  for (int k = 0; k < 64; ++k) hd += rdlane(og, k) * wl[lane*65+k];
  float p = hd * attd[lane];
  #pragma unroll
  for (int sh = 32; sh > 0; sh >>= 1) p += __shfl_xor(p, sh, 64);
  float addg = p;
  float acc = 0.f, ssum = 0.f;
  int n1 = gstart[g+1];
  for (int n = gstart[g]; n < n1; ++n) {
    float ev = fexp(lrelu(asn[n] + addg));
    acc += ev * y[n*64+lane];
    ssum += ev;
  }
  hg[g*64+lane] = acc * frcp(ssum + 1e-16f);
}

__global__ __launch_bounds__(128) void k_final(const float* __restrict__ outg,
                                               const float* __restrict__ W,
                                               const float* __restrict__ b,
                                               float* __restrict__ out) {
  __shared__ float og[64];
  int g = blockIdx.x;
  if (threadIdx.x < 64) og[threadIdx.x] = outg[g*64+threadIdx.x];
  __syncthreads();
  int o = threadIdx.x;
  float acc = b[o];
  for (int k = 0; k < 64; ++k) acc += og[k]*W[o*64+k];
  out[g*128+o] = acc;
}

extern "C" void kernel_launch(void* const* d_in, const int* in_sizes, int n_in,
                              void* d_out, int out_size, void* d_ws, size_t ws_size,
                              hipStream_t stream) {
  const float* x_in     = (const float*)d_in[0];
  const int*   eidx     = (const int*)  d_in[1];
  const float* eattr    = (const float*)d_in[2];
  const int*   batch    = (const int*)  d_in[3];
  const float* lin1_w   = (const float*)d_in[4];
  const float* lin1_b   = (const float*)d_in[5];
  const float* g_lin1_w = (const float*)d_in[6];
  const float* g_att_l  = (const float*)d_in[7];
  const float* g_att_r  = (const float*)d_in[8];
  const float* g_lin2_w = (const float*)d_in[9];
  const float* g_bias   = (const float*)d_in[10];
  const float* gru0_wi  = (const float*)d_in[11];
  const float* gru0_wh  = (const float*)d_in[12];
  const float* gru0_bi  = (const float*)d_in[13];
  const float* gru0_bh  = (const float*)d_in[14];
  const float* conv_lin_w   = (const float*)d_in[15];
  const float* conv_att_src = (const float*)d_in[16];
  const float* conv_att_dst = (const float*)d_in[17];
  const float* conv_bias    = (const float*)d_in[18];
  const float* grul_wi  = (const float*)d_in[19];
  const float* grul_wh  = (const float*)d_in[20];
  const float* grul_bi  = (const float*)d_in[21];
  const float* grul_bh  = (const float*)d_in[22];
  const float* mol_lin_w    = (const float*)d_in[23];
  const float* mol_att_src  = (const float*)d_in[24];
  const float* mol_att_dst  = (const float*)d_in[25];
  const float* mol_bias     = (const float*)d_in[26];
  const float* mgru_wi  = (const float*)d_in[27];
  const float* mgru_wh  = (const float*)d_in[28];
  const float* mgru_bi  = (const float*)d_in[29];
  const float* mgru_bh  = (const float*)d_in[30];
  const float* lin2_w   = (const float*)d_in[31];
  const float* lin2_b   = (const float*)d_in[32];

  const int N64 = N_NODES*64;
  float* ws     = (float*)d_ws;
  float* xA     = ws;               // N*64
  float* xB     = xA + N64;         // N*64
  float* uy     = xB + N64;         // N*128 interleaved {u,y}; first N*64 reused as hs
  float* hagg   = uy + 2*N64;       // N*64
  float* sc1    = hagg + N64;       // N
  float* sc2    = sc1 + N_NODES;    // N
  float* outg   = sc2 + N_NODES;    // G*64
  int* icnt   = (int*)(outg + NGRAPH*64); // N
  int* rowptr = icnt + N_NODES;     // N+1
  int* cursor = rowptr + N_NODES+1; // N
  int* geids  = cursor + N_NODES;   // E
  int* srcp   = geids + N_EDGES;    // E
  int* gstart = srcp + N_EDGES;     // G+1

  const int* src = eidx;
  const int* dst = eidx + N_EDGES;

  const int nbN32 = (N_NODES + 31)/32;
  const int nbN4  = (N_NODES + 3)/4;
  const int nbE   = (N_EDGES + 255)/256;
  const int nbG4  = (NGRAPH + 3)/4;

  // ---- CSR build ----
  hipMemsetAsync(icnt, 0, N_NODES*sizeof(int), stream);
  k_hist<<<nbE, 256, 0, stream>>>(dst, icnt);
  k_scan<<<1, 1024, 0, stream>>>(icnt, rowptr, cursor);
  k_scatter<<<nbE, 256, 0, stream>>>(dst, src, cursor, geids, srcp);
  k_gbound<<<1, 512, 0, stream>>>(batch, gstart);

  // ---- lin1 (+ fused xr = x.h @ g_att_r) ----
  k_lin1<<<nbN32, 256, 0, stream>>>(x_in, lin1_w, lin1_b, xA, g_att_r, sc1);

  // ---- GATEConv ----
  k_mmdual<<<nbN32, 256, 0, stream>>>(xA, g_lin1_w, g_lin2_w, (float2*)uy, N_NODES);
  k_gate_fused<<<nbN4, 256, 0, stream>>>(rowptr, geids, srcp, eattr, g_lin1_w, g_att_l,
                                         (const float2*)uy, sc1, hagg);
  k_gru<<<nbN32, 256, 0, stream>>>(hagg, g_bias, xA, gru0_wi, gru0_wh, gru0_bi, gru0_bh, xB, N_NODES);

  float* xcur = xB; float* xoth = xA;
  float* hs = uy;  // N*64 region reuse

  // ---- GATConv layers ----
  for (int l = 0; l < 2; ++l) {
    k_mm64<<<nbN32, 256, 0, stream>>>(xcur, conv_lin_w + l*64*64, 64, hs, N_NODES,
                                      conv_att_src + l*64, conv_att_dst + l*64, sc1, sc2);
    k_conv_fused<<<nbN4, 256, 0, stream>>>(rowptr, srcp, sc1, sc2, hs, hagg);
    k_gru<<<nbN32, 256, 0, stream>>>(hagg, conv_bias + l*64, xcur,
                                     grul_wi + l*192*64, grul_wh + l*192*64,
                                     grul_bi + l*192, grul_bh + l*192, xoth, N_NODES);
    float* t = xcur; xcur = xoth; xoth = t;
  }

  // ---- molecule readout ----
  k_molsum_f<<<nbG4, 256, 0, stream>>>(gstart, xcur, outg);
  k_mm64<<<nbN32, 256, 0, stream>>>(xcur, mol_lin_w, 64, hs, N_NODES,
                                    mol_att_src, nullptr, sc1, nullptr);
  for (int t = 0; t < 2; ++t) {
    k_mol_fused<<<nbG4, 256, 0, stream>>>(gstart, outg, mol_lin_w, mol_att_dst, sc1, hs, hagg);
    k_gru<<<(NGRAPH+31)/32, 256, 0, stream>>>(hagg, mol_bias, outg,
                                              mgru_wi, mgru_wh, mgru_bi, mgru_bh, outg, NGRAPH);
  }

  // ---- final linear ----
  k_final<<<NGRAPH, 128, 0, stream>>>(outg, lin2_w, lin2_b, (float*)d_out);
}

// Round 5
// 789.464 us; speedup vs baseline: 2.1994x; 1.1459x over previous
//
#include <hip/hip_runtime.h>
#include <math.h>

#define N_NODES 50000
#define N_EDGES 1000000
#define NGRAPH  512
#define INC     39
#define SB 200   // scan blocks
#define SC 250   // nodes per scan block (200*250 = 50000)

__device__ __forceinline__ float lrelu(float x){ return fmaxf(0.01f*x, x); }
__device__ __forceinline__ float fexp(float x){ return __builtin_amdgcn_exp2f(x*1.4426950408889634f); }
__device__ __forceinline__ float frcp(float x){ return __builtin_amdgcn_rcpf(x); }
__device__ __forceinline__ float eluf (float x){ return x > 0.f ? x : fexp(x) - 1.f; }
__device__ __forceinline__ float sigm (float x){ return frcp(1.f + fexp(-x)); }
__device__ __forceinline__ float ftanh(float x){
  x = fminf(fmaxf(x, -15.f), 15.f);
  float e = __builtin_amdgcn_exp2f(x*2.8853900817779268f); // exp(2x)
  return (e - 1.f)*frcp(e + 1.f);
}
__device__ __forceinline__ float rdlane(float v, int l){
  return __int_as_float(__builtin_amdgcn_readlane(__float_as_int(v), l));
}

// ================= CSR build =================
__global__ __launch_bounds__(256) void k_hist(const int* __restrict__ dst,
                                              int* __restrict__ cnt) {
  int e = blockIdx.x*256 + threadIdx.x;
  if (e < N_EDGES) atomicAdd(&cnt[dst[e]], 1);
}

__global__ __launch_bounds__(256) void k_scanA(const int* __restrict__ cnt,
                                               int* __restrict__ bsum) {
  __shared__ int s[256];
  int t = threadIdx.x, b = blockIdx.x;
  int v = (t < SC) ? cnt[b*SC + t] : 0;
  s[t] = v; __syncthreads();
  for (int off = 128; off > 0; off >>= 1) {
    if (t < off) s[t] += s[t+off];
    __syncthreads();
  }
  if (t == 0) bsum[b] = s[0];
}

__global__ __launch_bounds__(256) void k_scanB(const int* __restrict__ bsum,
                                               int* __restrict__ boff,
                                               int* __restrict__ rowptrN) {
  __shared__ int s[256];
  int t = threadIdx.x;
  int v = (t < SB) ? bsum[t] : 0;
  s[t] = v; __syncthreads();
  for (int off = 1; off < 256; off <<= 1) {
    int x = (t >= off) ? s[t-off] : 0;
    __syncthreads();
    s[t] += x;
    __syncthreads();
  }
  if (t < SB) boff[t] = s[t] - v;   // exclusive prefix
  if (t == 0) rowptrN[0] = N_EDGES; // rowptr[N_NODES]
}

__global__ __launch_bounds__(256) void k_scanC(const int* __restrict__ cnt,
                                               const int* __restrict__ boff,
                                               int* __restrict__ rowptr,
                                               int* __restrict__ cursor) {
  __shared__ int s[256];
  int t = threadIdx.x, b = blockIdx.x;
  int idx = b*SC + t;
  int v = (t < SC) ? cnt[idx] : 0;
  s[t] = v; __syncthreads();
  for (int off = 1; off < 256; off <<= 1) {
    int x = (t >= off) ? s[t-off] : 0;
    __syncthreads();
    s[t] += x;
    __syncthreads();
  }
  if (t < SC) {
    int val = boff[b] + s[t] - v;
    rowptr[idx] = val;
    cursor[idx] = val;
  }
}

__global__ __launch_bounds__(256) void k_scatter(const int* __restrict__ dst,
                                                 const int* __restrict__ src,
                                                 int* __restrict__ cursor,
                                                 int* __restrict__ eids,
                                                 int* __restrict__ srcp) {
  int e = blockIdx.x*256 + threadIdx.x;
  if (e < N_EDGES) {
    int p = atomicAdd(&cursor[dst[e]], 1);
    eids[p] = e;
    srcp[p] = src[e];
  }
}

__global__ __launch_bounds__(512) void k_gbound(const int* __restrict__ batch,
                                                int* __restrict__ gstart) {
  int g = threadIdx.x;
  int lo = 0, hi = N_NODES;
  while (lo < hi) { int mid = (lo+hi)>>1; if (batch[mid] < g) lo = mid+1; else hi = mid; }
  gstart[g] = lo;
  if (g == 0) gstart[NGRAPH] = N_NODES;
}

// ================= lin1: K=39, fused per-row dot with v1 =================
__global__ __launch_bounds__(256) void k_lin1(const float* __restrict__ x,
                                              const float* __restrict__ W,
                                              const float* __restrict__ b,
                                              float* __restrict__ out,
                                              const float* __restrict__ v1,
                                              float* __restrict__ o1) {
  __shared__ float wl[64*41];
  for (int idx = threadIdx.x; idx < 64*INC; idx += 256) {
    int r = idx / INC, c = idx - r*INC;
    wl[r*41+c] = W[idx];
  }
  __syncthreads();
  const int lane = threadIdx.x & 63;
  const int base = blockIdx.x*32 + (threadIdx.x>>6)*8;
  float h[8];
  #pragma unroll
  for (int i = 0; i < 8; ++i) {
    int n = base + i;
    h[i] = (n < N_NODES && lane < INC) ? x[n*INC + lane] : 0.f;
  }
  float acc[8] = {0,0,0,0,0,0,0,0};
  #pragma unroll
  for (int k = 0; k < INC; ++k) {
    float wv = wl[lane*41+k];
    #pragma unroll
    for (int i = 0; i < 8; ++i) acc[i] += rdlane(h[i], k) * wv;
  }
  float bb = b[lane];
  float attv = v1[lane];
  #pragma unroll
  for (int i = 0; i < 8; ++i) {
    int n = base + i;
    if (n >= N_NODES) continue;
    float val = lrelu(acc[i] + bb);
    out[n*64+lane] = val;
    float p = val * attv;
    #pragma unroll
    for (int s2 = 32; s2 > 0; s2 >>= 1) p += __shfl_xor(p, s2, 64);
    if (lane == 0) o1[n] = p;
  }
}

// ========== dual matmul -> interleaved float2 {u,y} ==========
__global__ __launch_bounds__(256) void k_mmdual(const float* __restrict__ in,
                                                const float* __restrict__ W1, // [64][80]
                                                const float* __restrict__ W2, // [64][64]
                                                float2* __restrict__ uy, int R) {
  __shared__ float wl[128*65];
  for (int idx = threadIdx.x; idx < 4096; idx += 256) {
    int r = idx >> 6, c = idx & 63;
    wl[r*65+c]      = W1[r*80 + c];
    wl[(64+r)*65+c] = W2[r*64 + c];
  }
  __syncthreads();
  const int lane = threadIdx.x & 63;
  const int base = blockIdx.x*32 + (threadIdx.x>>6)*8;
  float h[8];
  #pragma unroll
  for (int i = 0; i < 8; ++i) { int n = base+i; h[i] = (n < R) ? in[n*64+lane] : 0.f; }
  float accU[8] = {0,0,0,0,0,0,0,0};
  float accY[8] = {0,0,0,0,0,0,0,0};
  for (int k = 0; k < 64; ++k) {
    float wu = wl[lane*65+k], wy = wl[(64+lane)*65+k];
    #pragma unroll
    for (int i = 0; i < 8; ++i) {
      float hk = rdlane(h[i], k);
      accU[i] += hk*wu; accY[i] += hk*wy;
    }
  }
  #pragma unroll
  for (int i = 0; i < 8; ++i) {
    int n = base+i; if (n >= R) continue;
    uy[n*64 + lane] = make_float2(accU[i], accY[i]);
  }
}

// ========== [R,64] @ W(64 rows, rs stride).T, optional fused per-row dots ==========
__global__ __launch_bounds__(256) void k_mm64(const float* __restrict__ in,
                                              const float* __restrict__ W, int rs,
                                              float* __restrict__ out, int R,
                                              const float* __restrict__ v1,
                                              const float* __restrict__ v2,
                                              float* __restrict__ o1,
                                              float* __restrict__ o2) {
  __shared__ float wl[64*65];
  for (int idx = threadIdx.x; idx < 4096; idx += 256) {
    int r = idx >> 6, c = idx & 63;
    wl[r*65+c] = W[r*rs + c];
  }
  __syncthreads();
  const int lane = threadIdx.x & 63;
  const int base = blockIdx.x*32 + (threadIdx.x>>6)*8;
  float h[8];
  #pragma unroll
  for (int i = 0; i < 8; ++i) { int n = base+i; h[i] = (n < R) ? in[n*64+lane] : 0.f; }
  float acc[8] = {0,0,0,0,0,0,0,0};
  for (int k = 0; k < 64; ++k) {
    float wv = wl[lane*65+k];
    #pragma unroll
    for (int i = 0; i < 8; ++i) acc[i] += rdlane(h[i], k) * wv;
  }
  float v1v = v1 ? v1[lane] : 0.f;
  float v2v = v2 ? v2[lane] : 0.f;
  #pragma unroll
  for (int i = 0; i < 8; ++i) {
    int n = base+i; if (n >= R) continue;
    out[n*64+lane] = acc[i];
    if (o1) {
      float p1 = acc[i]*v1v;
      float p2 = acc[i]*v2v;
      #pragma unroll
      for (int s2 = 32; s2 > 0; s2 >>= 1) { p1 += __shfl_xor(p1, s2, 64); p2 += __shfl_xor(p2, s2, 64); }
      if (lane == 0) { o1[n] = p1; if (o2) o2[n] = p2; }
    }
  }
}

// ===== GATEConv fused: per-dst wave, uniform control, packed 4-edge reduction =====
#define NB 4
__global__ __launch_bounds__(256) void k_gate_fused(const int* __restrict__ rowptr,
                                                    const int* __restrict__ eids,
                                                    const int* __restrict__ srcp,
                                                    const float* __restrict__ ea,
                                                    const float* __restrict__ glin1, // [64][80]
                                                    const float* __restrict__ attl,
                                                    const float2* __restrict__ uy,
                                                    const float* __restrict__ xr,
                                                    float* __restrict__ hagg) {
  const int lane = threadIdx.x & 63;
  float w2r[16];
  #pragma unroll
  for (int j = 0; j < 16; ++j) w2r[j] = glin1[lane*80 + 64 + j];
  float alv = attl[lane];
  const int wid = __builtin_amdgcn_readfirstlane(threadIdx.x >> 6);
  const int d = blockIdx.x*4 + wid;                 // wave-uniform (SGPR)
  const int r0 = __builtin_amdgcn_readfirstlane(rowptr[d]);
  const int r1 = __builtin_amdgcn_readfirstlane(rowptr[d+1]);
  const float xrd = xr[d];
  float acc = 0.f, ssum = 0.f;

  float eaC[NB]; float2 uyC[NB];
  #pragma unroll
  for (int j = 0; j < NB; ++j) {
    int i = r0 + j; i = i < r1 ? i : (r1-1); i = i < 0 ? 0 : i;   // uniform clamp
    int e = eids[i];                                               // s_load
    int s = srcp[i];                                               // s_load
    eaC[j]  = ea[(size_t)e*16 + (lane & 15)];
    uyC[j]  = uy[(size_t)s*64 + lane];
  }

  for (int b = r0; b < r1; b += NB) {
    float eaN[NB]; float2 uyN[NB];
    #pragma unroll
    for (int j = 0; j < NB; ++j) {
      int i = b + NB + j; i = i < r1 ? i : (r1-1); i = i < 0 ? 0 : i;
      int e = eids[i];
      int s = srcp[i];
      eaN[j] = ea[(size_t)e*16 + (lane & 15)];
      uyN[j] = uy[(size_t)s*64 + lane];
    }
    // --- packed 4-edge score reduction ---
    float pj[NB];
    #pragma unroll
    for (int j = 0; j < NB; ++j) {
      float v = 0.f;
      #pragma unroll
      for (int jj = 0; jj < 16; ++jj) v = fmaf(rdlane(eaC[j], jj), w2r[jj], v);
      float t = lrelu(uyC[j].x + v);
      float p = t * alv;
      p += __shfl_xor(p, 1, 64);
      p += __shfl_xor(p, 2, 64);    // p = 4-lane-group partial, valid in all group lanes
      pj[j] = p;
    }
    int l3 = lane & 3;
    float q = (l3 == 0) ? pj[0] : (l3 == 1) ? pj[1] : (l3 == 2) ? pj[2] : pj[3];
    q += __shfl_xor(q, 4, 64);
    q += __shfl_xor(q, 8, 64);
    q += __shfl_xor(q, 16, 64);
    q += __shfl_xor(q, 32, 64);     // lane j (j<4) now holds full sum for edge j
    #pragma unroll
    for (int j = 0; j < NB; ++j) {
      if (b + j < r1) {             // wave-uniform
        float S = rdlane(q, j);
        float ev = fexp(lrelu(S + xrd));
        acc  = fmaf(ev, uyC[j].y, acc);
        ssum += ev;
      }
    }
    #pragma unroll
    for (int j = 0; j < NB; ++j) { eaC[j] = eaN[j]; uyC[j] = uyN[j]; }
  }
  hagg[d*64+lane] = acc * frcp(ssum + 1e-16f);
}

// ===== GATConv fused: lane-parallel scores, 8-wide register-batched aggregate =====
__global__ __launch_bounds__(256) void k_conv_fused(const int* __restrict__ rowptr,
                                                    const int* __restrict__ srcp,
                                                    const float* __restrict__ asn,
                                                    const float* __restrict__ adn,
                                                    const float* __restrict__ hs,
                                                    float* __restrict__ hagg) {
  __shared__ int   sS[4][64];
  __shared__ float sE[4][64];
  const int w = __builtin_amdgcn_readfirstlane(threadIdx.x >> 6);
  const int lane = threadIdx.x & 63;
  const int d = blockIdx.x*4 + w;
  const int r0 = __builtin_amdgcn_readfirstlane(rowptr[d]);
  const int r1 = __builtin_amdgcn_readfirstlane(rowptr[d+1]);
  float adnd = adn[d];
  float acc = 0.f, ssum = 0.f;
  for (int base = r0; base < r1; base += 64) {
    int i = base + lane;
    int cnt = r1 - base; if (cnt > 64) cnt = 64;
    float ev = 0.f; int s = 0;
    if (i < r1) { s = srcp[i]; ev = fexp(lrelu(asn[s] + adnd)); }
    sS[w][lane] = s; sE[w][lane] = ev;
    ssum += ev;
    for (int jb = 0; jb < cnt; jb += 8) {
      float h8[8], e8[8];
      #pragma unroll
      for (int j = 0; j < 8; ++j) {
        int jj = jb + j;
        if (jj < cnt) {
          int sv = sS[w][jj];
          e8[j] = sE[w][jj];
          h8[j] = hs[sv*64 + lane];
        } else { e8[j] = 0.f; h8[j] = 0.f; }
      }
      #pragma unroll
      for (int j = 0; j < 8; ++j) acc += e8[j] * h8[j];
    }
  }
  #pragma unroll
  for (int sh = 32; sh > 0; sh >>= 1) ssum += __shfl_xor(ssum, sh, 64);
  hagg[d*64+lane] = acc * frcp(ssum + 1e-16f);
}

// ===== fused GRU: out = relu(GRU(elu(inp+pbias), hid)) =====
__global__ __launch_bounds__(256) void k_gru(const float* __restrict__ inp,
                                             const float* __restrict__ pbias,
                                             const float* __restrict__ hid,
                                             const float* __restrict__ wi,
                                             const float* __restrict__ wh,
                                             const float* __restrict__ bi,
                                             const float* __restrict__ bh,
                                             float* __restrict__ out, int R) {
  __shared__ float wl[192*65];
  const int lane = threadIdx.x & 63;
  const int base = blockIdx.x*32 + (threadIdx.x>>6)*8;
  float pb = pbias[lane];
  float hin[8], hh[8];
  #pragma unroll
  for (int i = 0; i < 8; ++i) {
    int n = base + i;
    if (n < R) { hin[i] = eluf(inp[n*64+lane] + pb); hh[i] = hid[n*64+lane]; }
    else       { hin[i] = 0.f; hh[i] = 0.f; }
  }
  for (int idx = threadIdx.x; idx < 192*64; idx += 256)
    wl[(idx>>6)*65 + (idx&63)] = wi[idx];
  __syncthreads();
  float gr[8]={0,0,0,0,0,0,0,0}, gz[8]={0,0,0,0,0,0,0,0}, gn[8]={0,0,0,0,0,0,0,0};
  #pragma unroll 16
  for (int k = 0; k < 64; ++k) {
    float wr = wl[lane*65+k], wz = wl[(64+lane)*65+k], wn = wl[(128+lane)*65+k];
    #pragma unroll
    for (int i = 0; i < 8; ++i) {
      float hk = rdlane(hin[i], k);
      gr[i] += hk*wr; gz[i] += hk*wz; gn[i] += hk*wn;
    }
  }
  __syncthreads();
  for (int idx = threadIdx.x; idx < 192*64; idx += 256)
    wl[(idx>>6)*65 + (idx&63)] = wh[idx];
  __syncthreads();
  float hr[8]={0,0,0,0,0,0,0,0}, hz[8]={0,0,0,0,0,0,0,0}, hn[8]={0,0,0,0,0,0,0,0};
  #pragma unroll 16
  for (int k = 0; k < 64; ++k) {
    float wr = wl[lane*65+k], wz = wl[(64+lane)*65+k], wn = wl[(128+lane)*65+k];
    #pragma unroll
    for (int i = 0; i < 8; ++i) {
      float hk = rdlane(hh[i], k);
      hr[i] += hk*wr; hz[i] += hk*wz; hn[i] += hk*wn;
    }
  }
  float bir = bi[lane], biz = bi[64+lane], bin_ = bi[128+lane];
  float bhr = bh[lane], bhz = bh[64+lane], bhn = bh[128+lane];
  #pragma unroll
  for (int i = 0; i < 8; ++i) {
    int n = base + i;
    if (n >= R) continue;
    float r  = sigm(gr[i]+bir + hr[i]+bhr);
    float z  = sigm(gz[i]+biz + hz[i]+bhz);
    float nn = ftanh(gn[i]+bin_ + r*(hn[i]+bhn));
    float o  = (1.f - z)*nn + z*hh[i];
    out[n*64+lane] = fmaxf(o, 0.f);
  }
}

// ================= molecule readout (CSR over sorted batch) =================
__global__ __launch_bounds__(256) void k_molsum_f(const int* __restrict__ gstart,
                                                  const float* __restrict__ x,
                                                  float* __restrict__ outg) {
  int g = blockIdx.x*4 + (threadIdx.x>>6);
  if (g >= NGRAPH) return;
  int lane = threadIdx.x & 63;
  float acc = 0.f;
  int n1 = gstart[g+1];
  for (int n = gstart[g]; n < n1; ++n) acc += x[n*64+lane];
  outg[g*64+lane] = fmaxf(acc, 0.f);
}

__global__ __launch_bounds__(256) void k_mol_fused(const int* __restrict__ gstart,
                                                   const float* __restrict__ outg,
                                                   const float* __restrict__ W,
                                                   const float* __restrict__ attd,
                                                   const float* __restrict__ asn,
                                                   const float* __restrict__ y,
                                                   float* __restrict__ hg) {
  __shared__ float wl[64*65];
  for (int idx = threadIdx.x; idx < 4096; idx += 256) wl[(idx>>6)*65+(idx&63)] = W[idx];
  __syncthreads();
  int g = blockIdx.x*4 + (threadIdx.x>>6);
  if (g >= NGRAPH) return;
  int lane = threadIdx.x & 63;
  float og = outg[g*64+lane];
  float hd = 0.f;
  #pragma unroll
  for (int k = 0; k < 64; ++k) hd += rdlane(og, k) * wl[lane*65+k];
  float p = hd * attd[lane];
  #pragma unroll
  for (int sh = 32; sh > 0; sh >>= 1) p += __shfl_xor(p, sh, 64);
  float addg = p;
  float acc = 0.f, ssum = 0.f;
  int n1 = gstart[g+1];
  for (int n = gstart[g]; n < n1; ++n) {
    float ev = fexp(lrelu(asn[n] + addg));
    acc += ev * y[n*64+lane];
    ssum += ev;
  }
  hg[g*64+lane] = acc * frcp(ssum + 1e-16f);
}

__global__ __launch_bounds__(128) void k_final(const float* __restrict__ outg,
                                               const float* __restrict__ W,
                                               const float* __restrict__ b,
                                               float* __restrict__ out) {
  __shared__ float og[64];
  int g = blockIdx.x;
  if (threadIdx.x < 64) og[threadIdx.x] = outg[g*64+threadIdx.x];
  __syncthreads();
  int o = threadIdx.x;
  float acc = b[o];
  for (int k = 0; k < 64; ++k) acc += og[k]*W[o*64+k];
  out[g*128+o] = acc;
}

extern "C" void kernel_launch(void* const* d_in, const int* in_sizes, int n_in,
                              void* d_out, int out_size, void* d_ws, size_t ws_size,
                              hipStream_t stream) {
  const float* x_in     = (const float*)d_in[0];
  const int*   eidx     = (const int*)  d_in[1];
  const float* eattr    = (const float*)d_in[2];
  const int*   batch    = (const int*)  d_in[3];
  const float* lin1_w   = (const float*)d_in[4];
  const float* lin1_b   = (const float*)d_in[5];
  const float* g_lin1_w = (const float*)d_in[6];
  const float* g_att_l  = (const float*)d_in[7];
  const float* g_att_r  = (const float*)d_in[8];
  const float* g_lin2_w = (const float*)d_in[9];
  const float* g_bias   = (const float*)d_in[10];
  const float* gru0_wi  = (const float*)d_in[11];
  const float* gru0_wh  = (const float*)d_in[12];
  const float* gru0_bi  = (const float*)d_in[13];
  const float* gru0_bh  = (const float*)d_in[14];
  const float* conv_lin_w   = (const float*)d_in[15];
  const float* conv_att_src = (const float*)d_in[16];
  const float* conv_att_dst = (const float*)d_in[17];
  const float* conv_bias    = (const float*)d_in[18];
  const float* grul_wi  = (const float*)d_in[19];
  const float* grul_wh  = (const float*)d_in[20];
  const float* grul_bi  = (const float*)d_in[21];
  const float* grul_bh  = (const float*)d_in[22];
  const float* mol_lin_w    = (const float*)d_in[23];
  const float* mol_att_src  = (const float*)d_in[24];
  const float* mol_att_dst  = (const float*)d_in[25];
  const float* mol_bias     = (const float*)d_in[26];
  const float* mgru_wi  = (const float*)d_in[27];
  const float* mgru_wh  = (const float*)d_in[28];
  const float* mgru_bi  = (const float*)d_in[29];
  const float* mgru_bh  = (const float*)d_in[30];
  const float* lin2_w   = (const float*)d_in[31];
  const float* lin2_b   = (const float*)d_in[32];

  const int N64 = N_NODES*64;
  float* ws     = (float*)d_ws;
  float* xA     = ws;               // N*64
  float* xB     = xA + N64;         // N*64
  float* uy     = xB + N64;         // N*128 interleaved {u,y}; first N*64 reused as hs
  float* hagg   = uy + 2*N64;       // N*64
  float* sc1    = hagg + N64;       // N
  float* sc2    = sc1 + N_NODES;    // N
  float* outg   = sc2 + N_NODES;    // G*64
  int* icnt   = (int*)(outg + NGRAPH*64); // N
  int* rowptr = icnt + N_NODES;     // N+1
  int* cursor = rowptr + N_NODES+1; // N
  int* geids  = cursor + N_NODES;   // E
  int* srcp   = geids + N_EDGES;    // E
  int* gstart = srcp + N_EDGES;     // G+1
  int* bsum   = gstart + NGRAPH+1;  // SB
  int* boff   = bsum + SB;          // SB

  const int* src = eidx;
  const int* dst = eidx + N_EDGES;

  const int nbN32 = (N_NODES + 31)/32;
  const int nbN4  = (N_NODES + 3)/4;
  const int nbE   = (N_EDGES + 255)/256;
  const int nbG4  = (NGRAPH + 3)/4;

  // ---- CSR build (hierarchical scan) ----
  hipMemsetAsync(icnt, 0, N_NODES*sizeof(int), stream);
  k_hist<<<nbE, 256, 0, stream>>>(dst, icnt);
  k_scanA<<<SB, 256, 0, stream>>>(icnt, bsum);
  k_scanB<<<1, 256, 0, stream>>>(bsum, boff, rowptr + N_NODES);
  k_scanC<<<SB, 256, 0, stream>>>(icnt, boff, rowptr, cursor);
  k_scatter<<<nbE, 256, 0, stream>>>(dst, src, cursor, geids, srcp);
  k_gbound<<<1, 512, 0, stream>>>(batch, gstart);

  // ---- lin1 (+ fused xr = x.h @ g_att_r) ----
  k_lin1<<<nbN32, 256, 0, stream>>>(x_in, lin1_w, lin1_b, xA, g_att_r, sc1);

  // ---- GATEConv ----
  k_mmdual<<<nbN32, 256, 0, stream>>>(xA, g_lin1_w, g_lin2_w, (float2*)uy, N_NODES);
  k_gate_fused<<<nbN4, 256, 0, stream>>>(rowptr, geids, srcp, eattr, g_lin1_w, g_att_l,
                                         (const float2*)uy, sc1, hagg);
  k_gru<<<nbN32, 256, 0, stream>>>(hagg, g_bias, xA, gru0_wi, gru0_wh, gru0_bi, gru0_bh, xB, N_NODES);

  float* xcur = xB; float* xoth = xA;
  float* hs = uy;  // N*64 region reuse

  // ---- GATConv layers ----
  for (int l = 0; l < 2; ++l) {
    k_mm64<<<nbN32, 256, 0, stream>>>(xcur, conv_lin_w + l*64*64, 64, hs, N_NODES,
                                      conv_att_src + l*64, conv_att_dst + l*64, sc1, sc2);
    k_conv_fused<<<nbN4, 256, 0, stream>>>(rowptr, srcp, sc1, sc2, hs, hagg);
    k_gru<<<nbN32, 256, 0, stream>>>(hagg, conv_bias + l*64, xcur,
                                     grul_wi + l*192*64, grul_wh + l*192*64,
                                     grul_bi + l*192, grul_bh + l*192, xoth, N_NODES);
    float* t = xcur; xcur = xoth; xoth = t;
  }

  // ---- molecule readout ----
  k_molsum_f<<<nbG4, 256, 0, stream>>>(gstart, xcur, outg);
  k_mm64<<<nbN32, 256, 0, stream>>>(xcur, mol_lin_w, 64, hs, N_NODES,
                                    mol_att_src, nullptr, sc1, nullptr);
  for (int t = 0; t < 2; ++t) {
    k_mol_fused<<<nbG4, 256, 0, stream>>>(gstart, outg, mol_lin_w, mol_att_dst, sc1, hs, hagg);
    k_gru<<<(NGRAPH+31)/32, 256, 0, stream>>>(hagg, mol_bias, outg,
                                              mgru_wi, mgru_wh, mgru_bi, mgru_bh, outg, NGRAPH);
  }

  // ---- final linear ----
  k_final<<<NGRAPH, 128, 0, stream>>>(outg, lin2_w, lin2_b, (float*)d_out);
}

// Round 6
// 754.565 us; speedup vs baseline: 2.3011x; 1.0462x over previous
//
#include <hip/hip_runtime.h>
#include <math.h>

#define N_NODES 50000
#define N_EDGES 1000000
#define NGRAPH  512
#define INC     39
#define SB 200   // scan blocks
#define SC 250   // nodes per scan block (200*250 = 50000)

__device__ __forceinline__ float lrelu(float x){ return fmaxf(0.01f*x, x); }
__device__ __forceinline__ float fexp(float x){ return __builtin_amdgcn_exp2f(x*1.4426950408889634f); }
__device__ __forceinline__ float frcp(float x){ return __builtin_amdgcn_rcpf(x); }
__device__ __forceinline__ float eluf (float x){ return x > 0.f ? x : fexp(x) - 1.f; }
__device__ __forceinline__ float sigm (float x){ return frcp(1.f + fexp(-x)); }
__device__ __forceinline__ float ftanh(float x){
  x = fminf(fmaxf(x, -15.f), 15.f);
  float e = __builtin_amdgcn_exp2f(x*2.8853900817779268f); // exp(2x)
  return (e - 1.f)*frcp(e + 1.f);
}
__device__ __forceinline__ float rdlane(float v, int l){
  return __int_as_float(__builtin_amdgcn_readlane(__float_as_int(v), l));
}
// pack two fp32 -> 2x bf16 (RNE), lo = a, hi = b
__device__ __forceinline__ unsigned pk_bf16(float a, float b){
  unsigned r;
  asm volatile("v_cvt_pk_bf16_f32 %0, %1, %2" : "=v"(r) : "v"(a), "v"(b));
  return r;
}
__device__ __forceinline__ float bl(unsigned p){ return __uint_as_float(p << 16); }
__device__ __forceinline__ float bh(unsigned p){ return __uint_as_float(p & 0xffff0000u); }

// ================= CSR build =================
__global__ __launch_bounds__(256) void k_hist(const int* __restrict__ dst,
                                              int* __restrict__ cnt) {
  int e = blockIdx.x*256 + threadIdx.x;
  if (e < N_EDGES) atomicAdd(&cnt[dst[e]], 1);
}

__global__ __launch_bounds__(256) void k_scanA(const int* __restrict__ cnt,
                                               int* __restrict__ bsum) {
  __shared__ int s[256];
  int t = threadIdx.x, b = blockIdx.x;
  int v = (t < SC) ? cnt[b*SC + t] : 0;
  s[t] = v; __syncthreads();
  for (int off = 128; off > 0; off >>= 1) {
    if (t < off) s[t] += s[t+off];
    __syncthreads();
  }
  if (t == 0) bsum[b] = s[0];
}

__global__ __launch_bounds__(256) void k_scanB(const int* __restrict__ bsum,
                                               int* __restrict__ boff,
                                               int* __restrict__ rowptrN) {
  __shared__ int s[256];
  int t = threadIdx.x;
  int v = (t < SB) ? bsum[t] : 0;
  s[t] = v; __syncthreads();
  for (int off = 1; off < 256; off <<= 1) {
    int x = (t >= off) ? s[t-off] : 0;
    __syncthreads();
    s[t] += x;
    __syncthreads();
  }
  if (t < SB) boff[t] = s[t] - v;   // exclusive prefix
  if (t == 0) rowptrN[0] = N_EDGES; // rowptr[N_NODES]
}

__global__ __launch_bounds__(256) void k_scanC(const int* __restrict__ cnt,
                                               const int* __restrict__ boff,
                                               int* __restrict__ rowptr,
                                               int* __restrict__ cursor) {
  __shared__ int s[256];
  int t = threadIdx.x, b = blockIdx.x;
  int idx = b*SC + t;
  int v = (t < SC) ? cnt[idx] : 0;
  s[t] = v; __syncthreads();
  for (int off = 1; off < 256; off <<= 1) {
    int x = (t >= off) ? s[t-off] : 0;
    __syncthreads();
    s[t] += x;
    __syncthreads();
  }
  if (t < SC) {
    int val = boff[b] + s[t] - v;
    rowptr[idx] = val;
    cursor[idx] = val;
  }
}

__global__ __launch_bounds__(256) void k_scatter(const int* __restrict__ dst,
                                                 const int* __restrict__ src,
                                                 int* __restrict__ cursor,
                                                 int* __restrict__ eids,
                                                 int* __restrict__ srcp) {
  int e = blockIdx.x*256 + threadIdx.x;
  if (e < N_EDGES) {
    int p = atomicAdd(&cursor[dst[e]], 1);
    eids[p] = e;
    srcp[p] = src[e];
  }
}

__global__ __launch_bounds__(512) void k_gbound(const int* __restrict__ batch,
                                                int* __restrict__ gstart) {
  int g = threadIdx.x;
  int lo = 0, hi = N_NODES;
  while (lo < hi) { int mid = (lo+hi)>>1; if (batch[mid] < g) lo = mid+1; else hi = mid; }
  gstart[g] = lo;
  if (g == 0) gstart[NGRAPH] = N_NODES;
}

// ================= lin1: K=39, fused per-row dot with v1 =================
__global__ __launch_bounds__(256) void k_lin1(const float* __restrict__ x,
                                              const float* __restrict__ W,
                                              const float* __restrict__ b,
                                              float* __restrict__ out,
                                              const float* __restrict__ v1,
                                              float* __restrict__ o1) {
  __shared__ float wl[64*41];
  for (int idx = threadIdx.x; idx < 64*INC; idx += 256) {
    int r = idx / INC, c = idx - r*INC;
    wl[r*41+c] = W[idx];
  }
  __syncthreads();
  const int lane = threadIdx.x & 63;
  const int base = blockIdx.x*32 + (threadIdx.x>>6)*8;
  float h[8];
  #pragma unroll
  for (int i = 0; i < 8; ++i) {
    int n = base + i;
    h[i] = (n < N_NODES && lane < INC) ? x[n*INC + lane] : 0.f;
  }
  float acc[8] = {0,0,0,0,0,0,0,0};
  #pragma unroll
  for (int k = 0; k < INC; ++k) {
    float wv = wl[lane*41+k];
    #pragma unroll
    for (int i = 0; i < 8; ++i) acc[i] += rdlane(h[i], k) * wv;
  }
  float bb = b[lane];
  float attv = v1[lane];
  #pragma unroll
  for (int i = 0; i < 8; ++i) {
    int n = base + i;
    if (n >= N_NODES) continue;
    float val = lrelu(acc[i] + bb);
    out[n*64+lane] = val;
    float p = val * attv;
    #pragma unroll
    for (int s2 = 32; s2 > 0; s2 >>= 1) p += __shfl_xor(p, s2, 64);
    if (lane == 0) o1[n] = p;
  }
}

// ========== dual matmul -> packed bf16 {u,y} one dword per channel ==========
__global__ __launch_bounds__(256) void k_mmdual(const float* __restrict__ in,
                                                const float* __restrict__ W1, // [64][80]
                                                const float* __restrict__ W2, // [64][64]
                                                unsigned* __restrict__ uyp, int R) {
  __shared__ float wl[128*65];
  for (int idx = threadIdx.x; idx < 4096; idx += 256) {
    int r = idx >> 6, c = idx & 63;
    wl[r*65+c]      = W1[r*80 + c];
    wl[(64+r)*65+c] = W2[r*64 + c];
  }
  __syncthreads();
  const int lane = threadIdx.x & 63;
  const int base = blockIdx.x*32 + (threadIdx.x>>6)*8;
  float h[8];
  #pragma unroll
  for (int i = 0; i < 8; ++i) { int n = base+i; h[i] = (n < R) ? in[n*64+lane] : 0.f; }
  float accU[8] = {0,0,0,0,0,0,0,0};
  float accY[8] = {0,0,0,0,0,0,0,0};
  for (int k = 0; k < 64; ++k) {
    float wu = wl[lane*65+k], wy = wl[(64+lane)*65+k];
    #pragma unroll
    for (int i = 0; i < 8; ++i) {
      float hk = rdlane(h[i], k);
      accU[i] += hk*wu; accY[i] += hk*wy;
    }
  }
  #pragma unroll
  for (int i = 0; i < 8; ++i) {
    int n = base+i; if (n >= R) continue;
    uyp[n*64 + lane] = pk_bf16(accU[i], accY[i]);
  }
}

// ========== [R,64] @ W.T; optional fp32 out, optional packed-bf16 pair table,
//            optional fused per-row dots ==========
__global__ __launch_bounds__(256) void k_mm64(const float* __restrict__ in,
                                              const float* __restrict__ W, int rs,
                                              float* __restrict__ out,
                                              unsigned* __restrict__ outp, int R,
                                              const float* __restrict__ v1,
                                              const float* __restrict__ v2,
                                              float* __restrict__ o1,
                                              float* __restrict__ o2) {
  __shared__ float wl[64*65];
  for (int idx = threadIdx.x; idx < 4096; idx += 256) {
    int r = idx >> 6, c = idx & 63;
    wl[r*65+c] = W[r*rs + c];
  }
  __syncthreads();
  const int lane = threadIdx.x & 63;
  const int base = blockIdx.x*32 + (threadIdx.x>>6)*8;
  float h[8];
  #pragma unroll
  for (int i = 0; i < 8; ++i) { int n = base+i; h[i] = (n < R) ? in[n*64+lane] : 0.f; }
  float acc[8] = {0,0,0,0,0,0,0,0};
  for (int k = 0; k < 64; ++k) {
    float wv = wl[lane*65+k];
    #pragma unroll
    for (int i = 0; i < 8; ++i) acc[i] += rdlane(h[i], k) * wv;
  }
  float v1v = v1 ? v1[lane] : 0.f;
  float v2v = v2 ? v2[lane] : 0.f;
  #pragma unroll
  for (int i = 0; i < 8; ++i) {
    int n = base+i; if (n >= R) continue;
    if (out) out[n*64+lane] = acc[i];
    if (outp) {
      float partner = __shfl_xor(acc[i], 1, 64);   // lane 2c gets ch 2c+1
      if ((lane & 1) == 0) outp[n*32 + (lane>>1)] = pk_bf16(acc[i], partner);
    }
    if (o1) {
      float p1 = acc[i]*v1v;
      float p2 = acc[i]*v2v;
      #pragma unroll
      for (int s2 = 32; s2 > 0; s2 >>= 1) { p1 += __shfl_xor(p1, s2, 64); p2 += __shfl_xor(p2, s2, 64); }
      if (lane == 0) { o1[n] = p1; if (o2) o2[n] = p2; }
    }
  }
}

// ===== GATEConv fused: per-dst wave, packed bf16 {u,y} gathers =====
#define NB 4
__global__ __launch_bounds__(256) void k_gate_fused(const int* __restrict__ rowptr,
                                                    const int* __restrict__ eids,
                                                    const int* __restrict__ srcp,
                                                    const float* __restrict__ ea,
                                                    const float* __restrict__ glin1, // [64][80]
                                                    const float* __restrict__ attl,
                                                    const unsigned* __restrict__ uyp,
                                                    const float* __restrict__ xr,
                                                    float* __restrict__ hagg) {
  const int lane = threadIdx.x & 63;
  float w2r[16];
  #pragma unroll
  for (int j = 0; j < 16; ++j) w2r[j] = glin1[lane*80 + 64 + j];
  float alv = attl[lane];
  const int wid = __builtin_amdgcn_readfirstlane(threadIdx.x >> 6);
  const int d = blockIdx.x*4 + wid;                 // wave-uniform (SGPR)
  const int r0 = __builtin_amdgcn_readfirstlane(rowptr[d]);
  const int r1 = __builtin_amdgcn_readfirstlane(rowptr[d+1]);
  const float xrd = xr[d];
  float acc = 0.f, ssum = 0.f;

  float eaC[NB]; unsigned uyC[NB];
  #pragma unroll
  for (int j = 0; j < NB; ++j) {
    int i = r0 + j; i = i < r1 ? i : (r1-1); i = i < 0 ? 0 : i;   // uniform clamp
    int e = eids[i];                                               // s_load
    int s = srcp[i];                                               // s_load
    eaC[j]  = ea[(size_t)e*16 + (lane & 15)];
    uyC[j]  = uyp[s*64 + lane];
  }

  for (int b = r0; b < r1; b += NB) {
    float eaN[NB]; unsigned uyN[NB];
    #pragma unroll
    for (int j = 0; j < NB; ++j) {
      int i = b + NB + j; i = i < r1 ? i : (r1-1); i = i < 0 ? 0 : i;
      int e = eids[i];
      int s = srcp[i];
      eaN[j] = ea[(size_t)e*16 + (lane & 15)];
      uyN[j] = uyp[s*64 + lane];
    }
    // --- packed 4-edge score reduction ---
    float pj[NB];
    #pragma unroll
    for (int j = 0; j < NB; ++j) {
      float v = 0.f;
      #pragma unroll
      for (int jj = 0; jj < 16; ++jj) v = fmaf(rdlane(eaC[j], jj), w2r[jj], v);
      float t = lrelu(bl(uyC[j]) + v);
      float p = t * alv;
      p += __shfl_xor(p, 1, 64);
      p += __shfl_xor(p, 2, 64);    // 4-lane-group partial
      pj[j] = p;
    }
    int l3 = lane & 3;
    float q = (l3 == 0) ? pj[0] : (l3 == 1) ? pj[1] : (l3 == 2) ? pj[2] : pj[3];
    q += __shfl_xor(q, 4, 64);
    q += __shfl_xor(q, 8, 64);
    q += __shfl_xor(q, 16, 64);
    q += __shfl_xor(q, 32, 64);     // lane j (j<4) holds full sum for edge j
    #pragma unroll
    for (int j = 0; j < NB; ++j) {
      if (b + j < r1) {             // wave-uniform
        float S = rdlane(q, j);
        float ev = fexp(lrelu(S + xrd));
        acc  = fmaf(ev, bh(uyC[j]), acc);
        ssum += ev;
      }
    }
    #pragma unroll
    for (int j = 0; j < NB; ++j) { eaC[j] = eaN[j]; uyC[j] = uyN[j]; }
  }
  hagg[d*64+lane] = acc * frcp(ssum + 1e-16f);
}

// ===== GATConv fused: 2 edges per wave (32 lanes x 2 channels each), bf16-packed hs =====
__global__ __launch_bounds__(256) void k_conv_fused(const int* __restrict__ rowptr,
                                                    const int* __restrict__ srcp,
                                                    const float* __restrict__ asn,
                                                    const float* __restrict__ adn,
                                                    const unsigned* __restrict__ hsb,
                                                    float* __restrict__ hagg) {
  __shared__ int   sS[4][64];
  __shared__ float sE[4][64];
  const int w = __builtin_amdgcn_readfirstlane(threadIdx.x >> 6);
  const int lane = threadIdx.x & 63;
  const int slot = lane >> 5;      // which of the 2 concurrent edges
  const int l2   = lane & 31;      // channel-pair index
  const int d = blockIdx.x*4 + w;
  const int r0 = __builtin_amdgcn_readfirstlane(rowptr[d]);
  const int r1 = __builtin_amdgcn_readfirstlane(rowptr[d+1]);
  float adnd = adn[d];
  float accx = 0.f, accy = 0.f, ssum = 0.f;
  for (int base = r0; base < r1; base += 64) {
    int i = base + lane;
    int cnt = r1 - base; if (cnt > 64) cnt = 64;
    float ev = 0.f; int s = 0;
    if (i < r1) { s = srcp[i]; ev = fexp(lrelu(asn[s] + adnd)); }
    sS[w][lane] = s; sE[w][lane] = ev;
    ssum += ev;
    for (int jb = 0; jb < cnt; jb += 16) {
      float e8[8]; unsigned p8[8];
      #pragma unroll
      for (int u = 0; u < 8; ++u) {
        int jj = jb + 2*u + slot;
        int sv; float evv;
        if (jj < cnt) { sv = sS[w][jj]; evv = sE[w][jj]; }
        else          { sv = 0; evv = 0.f; }
        e8[u] = evv;
        p8[u] = hsb[sv*32 + l2];
      }
      #pragma unroll
      for (int u = 0; u < 8; ++u) {
        accx = fmaf(e8[u], bl(p8[u]), accx);
        accy = fmaf(e8[u], bh(p8[u]), accy);
      }
    }
  }
  #pragma unroll
  for (int sh = 32; sh > 0; sh >>= 1) ssum += __shfl_xor(ssum, sh, 64);
  accx += __shfl_xor(accx, 32, 64);
  accy += __shfl_xor(accy, 32, 64);
  float rs = frcp(ssum + 1e-16f);
  if (slot == 0) {
    float2 o = make_float2(accx*rs, accy*rs);
    *(float2*)&hagg[d*64 + 2*l2] = o;
  }
}

// ===== fused GRU: out = relu(GRU(elu(inp+pbias), hid)) =====
__global__ __launch_bounds__(256) void k_gru(const float* __restrict__ inp,
                                             const float* __restrict__ pbias,
                                             const float* __restrict__ hid,
                                             const float* __restrict__ wi,
                                             const float* __restrict__ wh,
                                             const float* __restrict__ bi,
                                             const float* __restrict__ bh2,
                                             float* __restrict__ out, int R) {
  __shared__ float wl[192*65];
  const int lane = threadIdx.x & 63;
  const int base = blockIdx.x*32 + (threadIdx.x>>6)*8;
  float pb = pbias[lane];
  float hin[8], hh[8];
  #pragma unroll
  for (int i = 0; i < 8; ++i) {
    int n = base + i;
    if (n < R) { hin[i] = eluf(inp[n*64+lane] + pb); hh[i] = hid[n*64+lane]; }
    else       { hin[i] = 0.f; hh[i] = 0.f; }
  }
  for (int idx = threadIdx.x; idx < 192*64; idx += 256)
    wl[(idx>>6)*65 + (idx&63)] = wi[idx];
  __syncthreads();
  float gr[8]={0,0,0,0,0,0,0,0}, gz[8]={0,0,0,0,0,0,0,0}, gn[8]={0,0,0,0,0,0,0,0};
  #pragma unroll 16
  for (int k = 0; k < 64; ++k) {
    float wr = wl[lane*65+k], wz = wl[(64+lane)*65+k], wn = wl[(128+lane)*65+k];
    #pragma unroll
    for (int i = 0; i < 8; ++i) {
      float hk = rdlane(hin[i], k);
      gr[i] += hk*wr; gz[i] += hk*wz; gn[i] += hk*wn;
    }
  }
  __syncthreads();
  for (int idx = threadIdx.x; idx < 192*64; idx += 256)
    wl[(idx>>6)*65 + (idx&63)] = wh[idx];
  __syncthreads();
  float hr[8]={0,0,0,0,0,0,0,0}, hz[8]={0,0,0,0,0,0,0,0}, hn[8]={0,0,0,0,0,0,0,0};
  #pragma unroll 16
  for (int k = 0; k < 64; ++k) {
    float wr = wl[lane*65+k], wz = wl[(64+lane)*65+k], wn = wl[(128+lane)*65+k];
    #pragma unroll
    for (int i = 0; i < 8; ++i) {
      float hk = rdlane(hh[i], k);
      hr[i] += hk*wr; hz[i] += hk*wz; hn[i] += hk*wn;
    }
  }
  float bir = bi[lane], biz = bi[64+lane], bin_ = bi[128+lane];
  float bhr = bh2[lane], bhz = bh2[64+lane], bhn = bh2[128+lane];
  #pragma unroll
  for (int i = 0; i < 8; ++i) {
    int n = base + i;
    if (n >= R) continue;
    float r  = sigm(gr[i]+bir + hr[i]+bhr);
    float z  = sigm(gz[i]+biz + hz[i]+bhz);
    float nn = ftanh(gn[i]+bin_ + r*(hn[i]+bhn));
    float o  = (1.f - z)*nn + z*hh[i];
    out[n*64+lane] = fmaxf(o, 0.f);
  }
}

// ================= molecule readout (CSR over sorted batch) =================
__global__ __launch_bounds__(256) void k_molsum_f(const int* __restrict__ gstart,
                                                  const float* __restrict__ x,
                                                  float* __restrict__ outg) {
  int g = blockIdx.x*4 + (threadIdx.x>>6);
  if (g >= NGRAPH) return;
  int lane = threadIdx.x & 63;
  float acc = 0.f;
  int n1 = gstart[g+1];
  for (int n = gstart[g]; n < n1; ++n) acc += x[n*64+lane];
  outg[g*64+lane] = fmaxf(acc, 0.f);
}

__global__ __launch_bounds__(256) void k_mol_fused(const int* __restrict__ gstart,
                                                   const float* __restrict__ outg,
                                                   const float* __restrict__ W,
                                                   const float* __restrict__ attd,
                                                   const float* __restrict__ asn,
                                                   const float* __restrict__ y,
                                                   float* __restrict__ hg) {
  __shared__ float wl[64*65];
  for (int idx = threadIdx.x; idx < 4096; idx += 256) wl[(idx>>6)*65+(idx&63)] = W[idx];
  __syncthreads();
  int g = blockIdx.x*4 + (threadIdx.x>>6);
  if (g >= NGRAPH) return;
  int lane = threadIdx.x & 63;
  float og = outg[g*64+lane];
  float hd = 0.f;
  #pragma unroll
  for (int k = 0; k < 64; ++k) hd += rdlane(og, k) * wl[lane*65+k];
  float p = hd * attd[lane];
  #pragma unroll
  for (int sh = 32; sh > 0; sh >>= 1) p += __shfl_xor(p, sh, 64);
  float addg = p;
  float acc = 0.f, ssum = 0.f;
  int n1 = gstart[g+1];
  for (int n = gstart[g]; n < n1; ++n) {
    float ev = fexp(lrelu(asn[n] + addg));
    acc += ev * y[n*64+lane];
    ssum += ev;
  }
  hg[g*64+lane] = acc * frcp(ssum + 1e-16f);
}

__global__ __launch_bounds__(128) void k_final(const float* __restrict__ outg,
                                               const float* __restrict__ W,
                                               const float* __restrict__ b,
                                               float* __restrict__ out) {
  __shared__ float og[64];
  int g = blockIdx.x;
  if (threadIdx.x < 64) og[threadIdx.x] = outg[g*64+threadIdx.x];
  __syncthreads();
  int o = threadIdx.x;
  float acc = b[o];
  for (int k = 0; k < 64; ++k) acc += og[k]*W[o*64+k];
  out[g*128+o] = acc;
}

extern "C" void kernel_launch(void* const* d_in, const int* in_sizes, int n_in,
                              void* d_out, int out_size, void* d_ws, size_t ws_size,
                              hipStream_t stream) {
  const float* x_in     = (const float*)d_in[0];
  const int*   eidx     = (const int*)  d_in[1];
  const float* eattr    = (const float*)d_in[2];
  const int*   batch    = (const int*)  d_in[3];
  const float* lin1_w   = (const float*)d_in[4];
  const float* lin1_b   = (const float*)d_in[5];
  const float* g_lin1_w = (const float*)d_in[6];
  const float* g_att_l  = (const float*)d_in[7];
  const float* g_att_r  = (const float*)d_in[8];
  const float* g_lin2_w = (const float*)d_in[9];
  const float* g_bias   = (const float*)d_in[10];
  const float* gru0_wi  = (const float*)d_in[11];
  const float* gru0_wh  = (const float*)d_in[12];
  const float* gru0_bi  = (const float*)d_in[13];
  const float* gru0_bh  = (const float*)d_in[14];
  const float* conv_lin_w   = (const float*)d_in[15];
  const float* conv_att_src = (const float*)d_in[16];
  const float* conv_att_dst = (const float*)d_in[17];
  const float* conv_bias    = (const float*)d_in[18];
  const float* grul_wi  = (const float*)d_in[19];
  const float* grul_wh  = (const float*)d_in[20];
  const float* grul_bi  = (const float*)d_in[21];
  const float* grul_bh  = (const float*)d_in[22];
  const float* mol_lin_w    = (const float*)d_in[23];
  const float* mol_att_src  = (const float*)d_in[24];
  const float* mol_att_dst  = (const float*)d_in[25];
  const float* mol_bias     = (const float*)d_in[26];
  const float* mgru_wi  = (const float*)d_in[27];
  const float* mgru_wh  = (const float*)d_in[28];
  const float* mgru_bi  = (const float*)d_in[29];
  const float* mgru_bh  = (const float*)d_in[30];
  const float* lin2_w   = (const float*)d_in[31];
  const float* lin2_b   = (const float*)d_in[32];

  const int N64 = N_NODES*64;
  float* ws     = (float*)d_ws;
  float* xA     = ws;               // N*64
  float* xB     = xA + N64;         // N*64
  float* uy     = xB + N64;         // 2*N*64 region: uyp (uint N*64) / hsb (uint N*32) / y_mol fp32 N*64
  float* hagg   = uy + 2*N64;       // N*64
  float* sc1    = hagg + N64;       // N
  float* sc2    = sc1 + N_NODES;    // N
  float* outg   = sc2 + N_NODES;    // G*64
  int* icnt   = (int*)(outg + NGRAPH*64); // N
  int* rowptr = icnt + N_NODES;     // N+1
  int* cursor = rowptr + N_NODES+1; // N
  int* geids  = cursor + N_NODES;   // E
  int* srcp   = geids + N_EDGES;    // E
  int* gstart = srcp + N_EDGES;     // G+1
  int* bsum   = gstart + NGRAPH+1;  // SB
  int* boff   = bsum + SB;          // SB

  unsigned* uyp = (unsigned*)uy;    // N*64 packed {u,y}
  unsigned* hsb = (unsigned*)uy;    // N*32 packed channel-pairs (reused after gate)

  const int* src = eidx;
  const int* dst = eidx + N_EDGES;

  const int nbN32 = (N_NODES + 31)/32;
  const int nbN4  = (N_NODES + 3)/4;
  const int nbE   = (N_EDGES + 255)/256;
  const int nbG4  = (NGRAPH + 3)/4;

  // ---- CSR build (hierarchical scan) ----
  hipMemsetAsync(icnt, 0, N_NODES*sizeof(int), stream);
  k_hist<<<nbE, 256, 0, stream>>>(dst, icnt);
  k_scanA<<<SB, 256, 0, stream>>>(icnt, bsum);
  k_scanB<<<1, 256, 0, stream>>>(bsum, boff, rowptr + N_NODES);
  k_scanC<<<SB, 256, 0, stream>>>(icnt, boff, rowptr, cursor);
  k_scatter<<<nbE, 256, 0, stream>>>(dst, src, cursor, geids, srcp);
  k_gbound<<<1, 512, 0, stream>>>(batch, gstart);

  // ---- lin1 (+ fused xr = x.h @ g_att_r) ----
  k_lin1<<<nbN32, 256, 0, stream>>>(x_in, lin1_w, lin1_b, xA, g_att_r, sc1);

  // ---- GATEConv ----
  k_mmdual<<<nbN32, 256, 0, stream>>>(xA, g_lin1_w, g_lin2_w, uyp, N_NODES);
  k_gate_fused<<<nbN4, 256, 0, stream>>>(rowptr, geids, srcp, eattr, g_lin1_w, g_att_l,
                                         uyp, sc1, hagg);
  k_gru<<<nbN32, 256, 0, stream>>>(hagg, g_bias, xA, gru0_wi, gru0_wh, gru0_bi, gru0_bh, xB, N_NODES);

  float* xcur = xB; float* xoth = xA;

  // ---- GATConv layers ----
  for (int l = 0; l < 2; ++l) {
    k_mm64<<<nbN32, 256, 0, stream>>>(xcur, conv_lin_w + l*64*64, 64, nullptr, hsb, N_NODES,
                                      conv_att_src + l*64, conv_att_dst + l*64, sc1, sc2);
    k_conv_fused<<<nbN4, 256, 0, stream>>>(rowptr, srcp, sc1, sc2, hsb, hagg);
    k_gru<<<nbN32, 256, 0, stream>>>(hagg, conv_bias + l*64, xcur,
                                     grul_wi + l*192*64, grul_wh + l*192*64,
                                     grul_bi + l*192, grul_bh + l*192, xoth, N_NODES);
    float* t = xcur; xcur = xoth; xoth = t;
  }

  // ---- molecule readout ----
  float* ymol = uy;  // fp32 N*64 reuse
  k_molsum_f<<<nbG4, 256, 0, stream>>>(gstart, xcur, outg);
  k_mm64<<<nbN32, 256, 0, stream>>>(xcur, mol_lin_w, 64, ymol, nullptr, N_NODES,
                                    mol_att_src, nullptr, sc1, nullptr);
  for (int t = 0; t < 2; ++t) {
    k_mol_fused<<<nbG4, 256, 0, stream>>>(gstart, outg, mol_lin_w, mol_att_dst, sc1, ymol, hagg);
    k_gru<<<(NGRAPH+31)/32, 256, 0, stream>>>(hagg, mol_bias, outg,
                                              mgru_wi, mgru_wh, mgru_bi, mgru_bh, outg, NGRAPH);
  }

  // ---- final linear ----
  k_final<<<NGRAPH, 128, 0, stream>>>(outg, lin2_w, lin2_b, (float*)d_out);
}

// Round 7
// 734.693 us; speedup vs baseline: 2.3634x; 1.0270x over previous
//
#include <hip/hip_runtime.h>
#include <math.h>

#define N_NODES 50000
#define N_EDGES 1000000
#define NGRAPH  512
#define INC     39
#define SB 200   // scan blocks
#define SC 250   // nodes per scan block (200*250 = 50000)

typedef __attribute__((ext_vector_type(8))) short bf16x8;
typedef __attribute__((ext_vector_type(4))) float f32x4;

__device__ __forceinline__ float lrelu(float x){ return fmaxf(0.01f*x, x); }
__device__ __forceinline__ float fexp(float x){ return __builtin_amdgcn_exp2f(x*1.4426950408889634f); }
__device__ __forceinline__ float frcp(float x){ return __builtin_amdgcn_rcpf(x); }
__device__ __forceinline__ float eluf (float x){ return x > 0.f ? x : fexp(x) - 1.f; }
__device__ __forceinline__ float sigm (float x){ return frcp(1.f + fexp(-x)); }
__device__ __forceinline__ float ftanh(float x){
  x = fminf(fmaxf(x, -15.f), 15.f);
  float e = __builtin_amdgcn_exp2f(x*2.8853900817779268f); // exp(2x)
  return (e - 1.f)*frcp(e + 1.f);
}
__device__ __forceinline__ float rdlane(float v, int l){
  return __int_as_float(__builtin_amdgcn_readlane(__float_as_int(v), l));
}
// pack two fp32 -> 2x bf16 (RNE), lo = a, hi = b
__device__ __forceinline__ unsigned pk_bf16(float a, float b){
  unsigned r;
  asm volatile("v_cvt_pk_bf16_f32 %0, %1, %2" : "=v"(r) : "v"(a), "v"(b));
  return r;
}
__device__ __forceinline__ float bl(unsigned p){ return __uint_as_float(p << 16); }
__device__ __forceinline__ float bh(unsigned p){ return __uint_as_float(p & 0xffff0000u); }

// ================= CSR build =================
__global__ __launch_bounds__(256) void k_hist(const int* __restrict__ dst,
                                              int* __restrict__ cnt) {
  int e = blockIdx.x*256 + threadIdx.x;
  if (e < N_EDGES) atomicAdd(&cnt[dst[e]], 1);
}

__global__ __launch_bounds__(256) void k_scanA(const int* __restrict__ cnt,
                                               int* __restrict__ bsum) {
  __shared__ int s[256];
  int t = threadIdx.x, b = blockIdx.x;
  int v = (t < SC) ? cnt[b*SC + t] : 0;
  s[t] = v; __syncthreads();
  for (int off = 128; off > 0; off >>= 1) {
    if (t < off) s[t] += s[t+off];
    __syncthreads();
  }
  if (t == 0) bsum[b] = s[0];
}

__global__ __launch_bounds__(256) void k_scanB(const int* __restrict__ bsum,
                                               int* __restrict__ boff,
                                               int* __restrict__ rowptrN) {
  __shared__ int s[256];
  int t = threadIdx.x;
  int v = (t < SB) ? bsum[t] : 0;
  s[t] = v; __syncthreads();
  for (int off = 1; off < 256; off <<= 1) {
    int x = (t >= off) ? s[t-off] : 0;
    __syncthreads();
    s[t] += x;
    __syncthreads();
  }
  if (t < SB) boff[t] = s[t] - v;   // exclusive prefix
  if (t == 0) rowptrN[0] = N_EDGES; // rowptr[N_NODES]
}

__global__ __launch_bounds__(256) void k_scanC(const int* __restrict__ cnt,
                                               const int* __restrict__ boff,
                                               int* __restrict__ rowptr,
                                               int* __restrict__ cursor) {
  __shared__ int s[256];
  int t = threadIdx.x, b = blockIdx.x;
  int idx = b*SC + t;
  int v = (t < SC) ? cnt[idx] : 0;
  s[t] = v; __syncthreads();
  for (int off = 1; off < 256; off <<= 1) {
    int x = (t >= off) ? s[t-off] : 0;
    __syncthreads();
    s[t] += x;
    __syncthreads();
  }
  if (t < SC) {
    int val = boff[b] + s[t] - v;
    rowptr[idx] = val;
    cursor[idx] = val;
  }
}

__global__ __launch_bounds__(256) void k_scatter(const int* __restrict__ dst,
                                                 const int* __restrict__ src,
                                                 int* __restrict__ cursor,
                                                 int2* __restrict__ epack) {
  int e = blockIdx.x*256 + threadIdx.x;
  if (e < N_EDGES) {
    int p = atomicAdd(&cursor[dst[e]], 1);
    epack[p] = make_int2(e, src[e]);
  }
}

__global__ __launch_bounds__(512) void k_gbound(const int* __restrict__ batch,
                                                int* __restrict__ gstart) {
  int g = threadIdx.x;
  int lo = 0, hi = N_NODES;
  while (lo < hi) { int mid = (lo+hi)>>1; if (batch[mid] < g) lo = mid+1; else hi = mid; }
  gstart[g] = lo;
  if (g == 0) gstart[NGRAPH] = N_NODES;
}

// ================= lin1: K=39, fused per-row dot with v1 =================
__global__ __launch_bounds__(256) void k_lin1(const float* __restrict__ x,
                                              const float* __restrict__ W,
                                              const float* __restrict__ b,
                                              float* __restrict__ out,
                                              const float* __restrict__ v1,
                                              float* __restrict__ o1) {
  __shared__ float wl[64*41];
  for (int idx = threadIdx.x; idx < 64*INC; idx += 256) {
    int r = idx / INC, c = idx - r*INC;
    wl[r*41+c] = W[idx];
  }
  __syncthreads();
  const int lane = threadIdx.x & 63;
  const int base = blockIdx.x*32 + (threadIdx.x>>6)*8;
  float h[8];
  #pragma unroll
  for (int i = 0; i < 8; ++i) {
    int n = base + i;
    h[i] = (n < N_NODES && lane < INC) ? x[n*INC + lane] : 0.f;
  }
  float acc[8] = {0,0,0,0,0,0,0,0};
  #pragma unroll
  for (int k = 0; k < INC; ++k) {
    float wv = wl[lane*41+k];
    #pragma unroll
    for (int i = 0; i < 8; ++i) acc[i] += rdlane(h[i], k) * wv;
  }
  float bb = b[lane];
  float attv = v1[lane];
  #pragma unroll
  for (int i = 0; i < 8; ++i) {
    int n = base + i;
    if (n >= N_NODES) continue;
    float val = lrelu(acc[i] + bb);
    out[n*64+lane] = val;
    float p = val * attv;
    #pragma unroll
    for (int s2 = 32; s2 > 0; s2 >>= 1) p += __shfl_xor(p, s2, 64);
    if (lane == 0) o1[n] = p;
  }
}

// ========== dual matmul -> u as bf16 [N][64] ushort, y packed 2ch/dword [N][32] ==========
__global__ __launch_bounds__(256) void k_mmdual(const float* __restrict__ in,
                                                const float* __restrict__ W1, // [64][80]
                                                const float* __restrict__ W2, // [64][64]
                                                unsigned short* __restrict__ ubf,
                                                unsigned* __restrict__ ypk, int R) {
  __shared__ float wl[128*65];
  for (int idx = threadIdx.x; idx < 4096; idx += 256) {
    int r = idx >> 6, c = idx & 63;
    wl[r*65+c]      = W1[r*80 + c];
    wl[(64+r)*65+c] = W2[r*64 + c];
  }
  __syncthreads();
  const int lane = threadIdx.x & 63;
  const int base = blockIdx.x*32 + (threadIdx.x>>6)*8;
  float h[8];
  #pragma unroll
  for (int i = 0; i < 8; ++i) { int n = base+i; h[i] = (n < R) ? in[n*64+lane] : 0.f; }
  float accU[8] = {0,0,0,0,0,0,0,0};
  float accY[8] = {0,0,0,0,0,0,0,0};
  for (int k = 0; k < 64; ++k) {
    float wu = wl[lane*65+k], wy = wl[(64+lane)*65+k];
    #pragma unroll
    for (int i = 0; i < 8; ++i) {
      float hk = rdlane(h[i], k);
      accU[i] += hk*wu; accY[i] += hk*wy;
    }
  }
  #pragma unroll
  for (int i = 0; i < 8; ++i) {
    int n = base+i; if (n >= R) continue;
    ubf[n*64 + lane] = (unsigned short)(pk_bf16(accU[i], 0.f) & 0xffffu);
    float partner = __shfl_xor(accY[i], 1, 64);
    if (!(lane & 1)) ypk[n*32 + (lane>>1)] = pk_bf16(accY[i], partner);
  }
}

// ========== [R,64] @ W.T; optional fp32 out, optional packed-bf16 pair table,
//            optional fused per-row dots ==========
__global__ __launch_bounds__(256) void k_mm64(const float* __restrict__ in,
                                              const float* __restrict__ W, int rs,
                                              float* __restrict__ out,
                                              unsigned* __restrict__ outp, int R,
                                              const float* __restrict__ v1,
                                              const float* __restrict__ v2,
                                              float* __restrict__ o1,
                                              float* __restrict__ o2) {
  __shared__ float wl[64*65];
  for (int idx = threadIdx.x; idx < 4096; idx += 256) {
    int r = idx >> 6, c = idx & 63;
    wl[r*65+c] = W[r*rs + c];
  }
  __syncthreads();
  const int lane = threadIdx.x & 63;
  const int base = blockIdx.x*32 + (threadIdx.x>>6)*8;
  float h[8];
  #pragma unroll
  for (int i = 0; i < 8; ++i) { int n = base+i; h[i] = (n < R) ? in[n*64+lane] : 0.f; }
  float acc[8] = {0,0,0,0,0,0,0,0};
  for (int k = 0; k < 64; ++k) {
    float wv = wl[lane*65+k];
    #pragma unroll
    for (int i = 0; i < 8; ++i) acc[i] += rdlane(h[i], k) * wv;
  }
  float v1v = v1 ? v1[lane] : 0.f;
  float v2v = v2 ? v2[lane] : 0.f;
  #pragma unroll
  for (int i = 0; i < 8; ++i) {
    int n = base+i; if (n >= R) continue;
    if (out) out[n*64+lane] = acc[i];
    if (outp) {
      float partner = __shfl_xor(acc[i], 1, 64);   // lane 2c gets ch 2c+1
      if ((lane & 1) == 0) outp[n*32 + (lane>>1)] = pk_bf16(acc[i], partner);
    }
    if (o1) {
      float p1 = acc[i]*v1v;
      float p2 = acc[i]*v2v;
      #pragma unroll
      for (int s2 = 32; s2 > 0; s2 >>= 1) { p1 += __shfl_xor(p1, s2, 64); p2 += __shfl_xor(p2, s2, 64); }
      if (lane == 0) { o1[n] = p1; if (o2) o2[n] = p2; }
    }
  }
}

// ===== GATE edge scores: 16 edges per MFMA, edge-parallel, writes p_perm (sorted order) =====
// A = EA[16 edges][16k] (slots j=0..3 per lane-group; j=4..7 zero), B = W2^T chunks.
// A and B use the SAME slot->k mapping, so contraction is correct for any HW mapping.
// C/D mapping (HW-verified): col = lane&15 (channel), row = 4*(lane>>4)+reg (edge).
__global__ __launch_bounds__(256) void k_escore(const int2* __restrict__ epack,
                                                const float* __restrict__ ea,
                                                const float* __restrict__ glin1, // [64][80]
                                                const float* __restrict__ attl,
                                                const unsigned short* __restrict__ ubf,
                                                float* __restrict__ pperm) {
  const int lane = threadIdx.x & 63;
  const int l15 = lane & 15, lg = lane >> 4;
  const int gw = blockIdx.x*4 + (threadIdx.x >> 6);
  if (gw >= N_EDGES/64) return;
  float attlv[4];
  unsigned Bu[4][2];
  #pragma unroll
  for (int c = 0; c < 4; ++c) {
    const float4 b = *(const float4*)&glin1[(c*16 + l15)*80 + 64 + lg*4];
    Bu[c][0] = pk_bf16(b.x, b.y);
    Bu[c][1] = pk_bf16(b.z, b.w);
    attlv[c] = attl[c*16 + l15];
  }
  const int* epck = (const int*)epack;
  #pragma unroll 1
  for (int it = 0; it < 4; ++it) {
    const int i0 = gw*64 + it*16;
    int eid = epack[i0 + l15].x;
    const float4 a = *(const float4*)&ea[(size_t)eid*16 + lg*4];
    union { bf16x8 v; unsigned u[4]; } A;
    A.u[0] = pk_bf16(a.x, a.y);
    A.u[1] = pk_bf16(a.z, a.w);
    A.u[2] = 0; A.u[3] = 0;
    int sv[4];
    #pragma unroll
    for (int r = 0; r < 4; ++r) sv[r] = epck[2*(i0 + 4*lg + r) + 1];
    float p[4] = {0.f,0.f,0.f,0.f};
    #pragma unroll
    for (int c = 0; c < 4; ++c) {
      union { bf16x8 v; unsigned u[4]; } B;
      B.u[0] = Bu[c][0]; B.u[1] = Bu[c][1]; B.u[2] = 0; B.u[3] = 0;
      f32x4 z = {0.f,0.f,0.f,0.f};
      f32x4 acc = __builtin_amdgcn_mfma_f32_16x16x32_bf16(A.v, B.v, z, 0, 0, 0);
      #pragma unroll
      for (int r = 0; r < 4; ++r) {
        unsigned uu = ubf[(size_t)sv[r]*64 + c*16 + l15];
        float t = lrelu(__uint_as_float(uu << 16) + acc[r]);
        p[r] = fmaf(t, attlv[c], p[r]);
      }
    }
    #pragma unroll
    for (int r = 0; r < 4; ++r) {
      p[r] += __shfl_xor(p[r], 1, 64);
      p[r] += __shfl_xor(p[r], 2, 64);
      p[r] += __shfl_xor(p[r], 4, 64);
      p[r] += __shfl_xor(p[r], 8, 64);
    }
    if (l15 == 0) *(float4*)&pperm[i0 + 4*lg] = make_float4(p[0], p[1], p[2], p[3]);
  }
}

// ===== GATE aggregation: conv-style, contiguous p_perm, bf16-packed y gathers =====
__global__ __launch_bounds__(256) void k_gate_agg(const int* __restrict__ rowptr,
                                                  const int* __restrict__ epck,
                                                  const float* __restrict__ pperm,
                                                  const float* __restrict__ xr,
                                                  const unsigned* __restrict__ ypk,
                                                  float* __restrict__ hagg) {
  __shared__ int   sS[4][64];
  __shared__ float sE[4][64];
  const int w = __builtin_amdgcn_readfirstlane(threadIdx.x >> 6);
  const int lane = threadIdx.x & 63;
  const int slot = lane >> 5, l2 = lane & 31;
  const int d = blockIdx.x*4 + w;
  const int r0 = __builtin_amdgcn_readfirstlane(rowptr[d]);
  const int r1 = __builtin_amdgcn_readfirstlane(rowptr[d+1]);
  const float xrd = xr[d];
  float accx = 0.f, accy = 0.f, ssum = 0.f;
  for (int base = r0; base < r1; base += 64) {
    int i = base + lane;
    int cnt = r1 - base; if (cnt > 64) cnt = 64;
    float ev = 0.f; int s = 0;
    if (i < r1) { s = epck[2*i+1]; ev = fexp(lrelu(pperm[i] + xrd)); }
    sS[w][lane] = s; sE[w][lane] = ev;
    ssum += ev;
    for (int jb = 0; jb < cnt; jb += 16) {
      float e8[8]; unsigned p8[8];
      #pragma unroll
      for (int u = 0; u < 8; ++u) {
        int jj = jb + 2*u + slot;
        int svv; float evv;
        if (jj < cnt) { svv = sS[w][jj]; evv = sE[w][jj]; }
        else          { svv = 0; evv = 0.f; }
        e8[u] = evv;
        p8[u] = ypk[(size_t)svv*32 + l2];
      }
      #pragma unroll
      for (int u = 0; u < 8; ++u) {
        accx = fmaf(e8[u], bl(p8[u]), accx);
        accy = fmaf(e8[u], bh(p8[u]), accy);
      }
    }
  }
  #pragma unroll
  for (int sh = 32; sh > 0; sh >>= 1) ssum += __shfl_xor(ssum, sh, 64);
  accx += __shfl_xor(accx, 32, 64);
  accy += __shfl_xor(accy, 32, 64);
  float rs = frcp(ssum + 1e-16f);
  if (slot == 0) *(float2*)&hagg[d*64 + 2*l2] = make_float2(accx*rs, accy*rs);
}

// ===== GATConv fused: 2 edges per wave, bf16-packed hs =====
__global__ __launch_bounds__(256) void k_conv_fused(const int* __restrict__ rowptr,
                                                    const int* __restrict__ epck,
                                                    const float* __restrict__ asn,
                                                    const float* __restrict__ adn,
                                                    const unsigned* __restrict__ hsb,
                                                    float* __restrict__ hagg) {
  __shared__ int   sS[4][64];
  __shared__ float sE[4][64];
  const int w = __builtin_amdgcn_readfirstlane(threadIdx.x >> 6);
  const int lane = threadIdx.x & 63;
  const int slot = lane >> 5, l2 = lane & 31;
  const int d = blockIdx.x*4 + w;
  const int r0 = __builtin_amdgcn_readfirstlane(rowptr[d]);
  const int r1 = __builtin_amdgcn_readfirstlane(rowptr[d+1]);
  float adnd = adn[d];
  float accx = 0.f, accy = 0.f, ssum = 0.f;
  for (int base = r0; base < r1; base += 64) {
    int i = base + lane;
    int cnt = r1 - base; if (cnt > 64) cnt = 64;
    float ev = 0.f; int s = 0;
    if (i < r1) { s = epck[2*i+1]; ev = fexp(lrelu(asn[s] + adnd)); }
    sS[w][lane] = s; sE[w][lane] = ev;
    ssum += ev;
    for (int jb = 0; jb < cnt; jb += 16) {
      float e8[8]; unsigned p8[8];
      #pragma unroll
      for (int u = 0; u < 8; ++u) {
        int jj = jb + 2*u + slot;
        int svv; float evv;
        if (jj < cnt) { svv = sS[w][jj]; evv = sE[w][jj]; }
        else          { svv = 0; evv = 0.f; }
        e8[u] = evv;
        p8[u] = hsb[(size_t)svv*32 + l2];
      }
      #pragma unroll
      for (int u = 0; u < 8; ++u) {
        accx = fmaf(e8[u], bl(p8[u]), accx);
        accy = fmaf(e8[u], bh(p8[u]), accy);
      }
    }
  }
  #pragma unroll
  for (int sh = 32; sh > 0; sh >>= 1) ssum += __shfl_xor(ssum, sh, 64);
  accx += __shfl_xor(accx, 32, 64);
  accy += __shfl_xor(accy, 32, 64);
  float rs = frcp(ssum + 1e-16f);
  if (slot == 0) *(float2*)&hagg[d*64 + 2*l2] = make_float2(accx*rs, accy*rs);
}

// ===== fused GRU: out = relu(GRU(elu(inp+pbias), hid)) =====
__global__ __launch_bounds__(256) void k_gru(const float* __restrict__ inp,
                                             const float* __restrict__ pbias,
                                             const float* __restrict__ hid,
                                             const float* __restrict__ wi,
                                             const float* __restrict__ wh,
                                             const float* __restrict__ bi,
                                             const float* __restrict__ bh2,
                                             float* __restrict__ out, int R) {
  __shared__ float wl[192*65];
  const int lane = threadIdx.x & 63;
  const int base = blockIdx.x*32 + (threadIdx.x>>6)*8;
  float pb = pbias[lane];
  float hin[8], hh[8];
  #pragma unroll
  for (int i = 0; i < 8; ++i) {
    int n = base + i;
    if (n < R) { hin[i] = eluf(inp[n*64+lane] + pb); hh[i] = hid[n*64+lane]; }
    else       { hin[i] = 0.f; hh[i] = 0.f; }
  }
  for (int idx = threadIdx.x; idx < 192*64; idx += 256)
    wl[(idx>>6)*65 + (idx&63)] = wi[idx];
  __syncthreads();
  float gr[8]={0,0,0,0,0,0,0,0}, gz[8]={0,0,0,0,0,0,0,0}, gn[8]={0,0,0,0,0,0,0,0};
  #pragma unroll 16
  for (int k = 0; k < 64; ++k) {
    float wr = wl[lane*65+k], wz = wl[(64+lane)*65+k], wn = wl[(128+lane)*65+k];
    #pragma unroll
    for (int i = 0; i < 8; ++i) {
      float hk = rdlane(hin[i], k);
      gr[i] += hk*wr; gz[i] += hk*wz; gn[i] += hk*wn;
    }
  }
  __syncthreads();
  for (int idx = threadIdx.x; idx < 192*64; idx += 256)
    wl[(idx>>6)*65 + (idx&63)] = wh[idx];
  __syncthreads();
  float hr[8]={0,0,0,0,0,0,0,0}, hz[8]={0,0,0,0,0,0,0,0}, hn[8]={0,0,0,0,0,0,0,0};
  #pragma unroll 16
  for (int k = 0; k < 64; ++k) {
    float wr = wl[lane*65+k], wz = wl[(64+lane)*65+k], wn = wl[(128+lane)*65+k];
    #pragma unroll
    for (int i = 0; i < 8; ++i) {
      float hk = rdlane(hh[i], k);
      hr[i] += hk*wr; hz[i] += hk*wz; hn[i] += hk*wn;
    }
  }
  float bir = bi[lane], biz = bi[64+lane], bin_ = bi[128+lane];
  float bhr = bh2[lane], bhz = bh2[64+lane], bhn = bh2[128+lane];
  #pragma unroll
  for (int i = 0; i < 8; ++i) {
    int n = base + i;
    if (n >= R) continue;
    float r  = sigm(gr[i]+bir + hr[i]+bhr);
    float z  = sigm(gz[i]+biz + hz[i]+bhz);
    float nn = ftanh(gn[i]+bin_ + r*(hn[i]+bhn));
    float o  = (1.f - z)*nn + z*hh[i];
    out[n*64+lane] = fmaxf(o, 0.f);
  }
}

// ================= molecule readout (CSR over sorted batch) =================
__global__ __launch_bounds__(256) void k_molsum_f(const int* __restrict__ gstart,
                                                  const float* __restrict__ x,
                                                  float* __restrict__ outg) {
  int g = blockIdx.x*4 + (threadIdx.x>>6);
  if (g >= NGRAPH) return;
  int lane = threadIdx.x & 63;
  float acc = 0.f;
  int n1 = gstart[g+1];
  for (int n = gstart[g]; n < n1; ++n) acc += x[n*64+lane];
  outg[g*64+lane] = fmaxf(acc, 0.f);
}

__global__ __launch_bounds__(256) void k_mol_fused(const int* __restrict__ gstart,
                                                   const float* __restrict__ outg,
                                                   const float* __restrict__ W,
                                                   const float* __restrict__ attd,
                                                   const float* __restrict__ asn,
                                                   const float* __restrict__ y,
                                                   float* __restrict__ hg) {
  __shared__ float wl[64*65];
  for (int idx = threadIdx.x; idx < 4096; idx += 256) wl[(idx>>6)*65+(idx&63)] = W[idx];
  __syncthreads();
  int g = blockIdx.x*4 + (threadIdx.x>>6);
  if (g >= NGRAPH) return;
  int lane = threadIdx.x & 63;
  float og = outg[g*64+lane];
  float hd = 0.f;
  #pragma unroll
  for (int k = 0; k < 64; ++k) hd += rdlane(og, k) * wl[lane*65+k];
  float p = hd * attd[lane];
  #pragma unroll
  for (int sh = 32; sh > 0; sh >>= 1) p += __shfl_xor(p, sh, 64);
  float addg = p;
  float acc = 0.f, ssum = 0.f;
  int n1 = gstart[g+1];
  for (int n = gstart[g]; n < n1; ++n) {
    float ev = fexp(lrelu(asn[n] + addg));
    acc += ev * y[n*64+lane];
    ssum += ev;
  }
  hg[g*64+lane] = acc * frcp(ssum + 1e-16f);
}

__global__ __launch_bounds__(128) void k_final(const float* __restrict__ outg,
                                               const float* __restrict__ W,
                                               const float* __restrict__ b,
                                               float* __restrict__ out) {
  __shared__ float og[64];
  int g = blockIdx.x;
  if (threadIdx.x < 64) og[threadIdx.x] = outg[g*64+threadIdx.x];
  __syncthreads();
  int o = threadIdx.x;
  float acc = b[o];
  for (int k = 0; k < 64; ++k) acc += og[k]*W[o*64+k];
  out[g*128+o] = acc;
}

extern "C" void kernel_launch(void* const* d_in, const int* in_sizes, int n_in,
                              void* d_out, int out_size, void* d_ws, size_t ws_size,
                              hipStream_t stream) {
  const float* x_in     = (const float*)d_in[0];
  const int*   eidx     = (const int*)  d_in[1];
  const float* eattr    = (const float*)d_in[2];
  const int*   batch    = (const int*)  d_in[3];
  const float* lin1_w   = (const float*)d_in[4];
  const float* lin1_b   = (const float*)d_in[5];
  const float* g_lin1_w = (const float*)d_in[6];
  const float* g_att_l  = (const float*)d_in[7];
  const float* g_att_r  = (const float*)d_in[8];
  const float* g_lin2_w = (const float*)d_in[9];
  const float* g_bias   = (const float*)d_in[10];
  const float* gru0_wi  = (const float*)d_in[11];
  const float* gru0_wh  = (const float*)d_in[12];
  const float* gru0_bi  = (const float*)d_in[13];
  const float* gru0_bh  = (const float*)d_in[14];
  const float* conv_lin_w   = (const float*)d_in[15];
  const float* conv_att_src = (const float*)d_in[16];
  const float* conv_att_dst = (const float*)d_in[17];
  const float* conv_bias    = (const float*)d_in[18];
  const float* grul_wi  = (const float*)d_in[19];
  const float* grul_wh  = (const float*)d_in[20];
  const float* grul_bi  = (const float*)d_in[21];
  const float* grul_bh  = (const float*)d_in[22];
  const float* mol_lin_w    = (const float*)d_in[23];
  const float* mol_att_src  = (const float*)d_in[24];
  const float* mol_att_dst  = (const float*)d_in[25];
  const float* mol_bias     = (const float*)d_in[26];
  const float* mgru_wi  = (const float*)d_in[27];
  const float* mgru_wh  = (const float*)d_in[28];
  const float* mgru_bi  = (const float*)d_in[29];
  const float* mgru_bh  = (const float*)d_in[30];
  const float* lin2_w   = (const float*)d_in[31];
  const float* lin2_b   = (const float*)d_in[32];

  const int N64 = N_NODES*64;
  float* ws     = (float*)d_ws;
  float* xA     = ws;               // N*64
  float* xB     = xA + N64;         // N*64
  float* uy     = xB + N64;         // 2*N64 region: ubf(ushort N*64)+ypk(uint N*32) / hsb / ymol
  float* hagg   = uy + 2*N64;       // N*64
  float* sc1    = hagg + N64;       // N
  float* sc2    = sc1 + N_NODES;    // N
  float* pperm  = sc2 + N_NODES;    // E (edge scores, sorted order)
  float* outg   = pperm + N_EDGES;  // G*64
  int* icnt   = (int*)(outg + NGRAPH*64); // N
  int* rowptr = icnt + N_NODES;     // N+2 (pad for int2 alignment)
  int* cursor = rowptr + N_NODES+2; // N
  int2* epack = (int2*)(cursor + N_NODES); // E int2 {eid, src}
  int* gstart = (int*)(epack + N_EDGES);   // G+1
  int* bsum   = gstart + NGRAPH+1;  // SB
  int* boff   = bsum + SB;          // SB

  unsigned short* ubf = (unsigned short*)uy;       // N*64 bf16 u
  unsigned* ypk = (unsigned*)(uy + N64);           // N*32 packed y
  unsigned* hsb = (unsigned*)uy;                   // N*32 packed hs (reused after gate)
  int* epck = (int*)epack;

  const int* src = eidx;
  const int* dst = eidx + N_EDGES;

  const int nbN32 = (N_NODES + 31)/32;
  const int nbN4  = (N_NODES + 3)/4;
  const int nbE   = (N_EDGES + 255)/256;
  const int nbG4  = (NGRAPH + 3)/4;
  const int nbES  = (N_EDGES/64 + 3)/4;   // escore: 64 edges per wave

  // ---- CSR build (hierarchical scan) ----
  hipMemsetAsync(icnt, 0, N_NODES*sizeof(int), stream);
  k_hist<<<nbE, 256, 0, stream>>>(dst, icnt);
  k_scanA<<<SB, 256, 0, stream>>>(icnt, bsum);
  k_scanB<<<1, 256, 0, stream>>>(bsum, boff, rowptr + N_NODES);
  k_scanC<<<SB, 256, 0, stream>>>(icnt, boff, rowptr, cursor);
  k_scatter<<<nbE, 256, 0, stream>>>(dst, src, cursor, epack);
  k_gbound<<<1, 512, 0, stream>>>(batch, gstart);

  // ---- lin1 (+ fused xr = x.h @ g_att_r) ----
  k_lin1<<<nbN32, 256, 0, stream>>>(x_in, lin1_w, lin1_b, xA, g_att_r, sc1);

  // ---- GATEConv ----
  k_mmdual<<<nbN32, 256, 0, stream>>>(xA, g_lin1_w, g_lin2_w, ubf, ypk, N_NODES);
  k_escore<<<nbES, 256, 0, stream>>>(epack, eattr, g_lin1_w, g_att_l, ubf, pperm);
  k_gate_agg<<<nbN4, 256, 0, stream>>>(rowptr, epck, pperm, sc1, ypk, hagg);
  k_gru<<<nbN32, 256, 0, stream>>>(hagg, g_bias, xA, gru0_wi, gru0_wh, gru0_bi, gru0_bh, xB, N_NODES);

  float* xcur = xB; float* xoth = xA;

  // ---- GATConv layers ----
  for (int l = 0; l < 2; ++l) {
    k_mm64<<<nbN32, 256, 0, stream>>>(xcur, conv_lin_w + l*64*64, 64, nullptr, hsb, N_NODES,
                                      conv_att_src + l*64, conv_att_dst + l*64, sc1, sc2);
    k_conv_fused<<<nbN4, 256, 0, stream>>>(rowptr, epck, sc1, sc2, hsb, hagg);
    k_gru<<<nbN32, 256, 0, stream>>>(hagg, conv_bias + l*64, xcur,
                                     grul_wi + l*192*64, grul_wh + l*192*64,
                                     grul_bi + l*192, grul_bh + l*192, xoth, N_NODES);
    float* t = xcur; xcur = xoth; xoth = t;
  }

  // ---- molecule readout ----
  float* ymol = uy;  // fp32 N*64 reuse
  k_molsum_f<<<nbG4, 256, 0, stream>>>(gstart, xcur, outg);
  k_mm64<<<nbN32, 256, 0, stream>>>(xcur, mol_lin_w, 64, ymol, nullptr, N_NODES,
                                    mol_att_src, nullptr, sc1, nullptr);
  for (int t = 0; t < 2; ++t) {
    k_mol_fused<<<nbG4, 256, 0, stream>>>(gstart, outg, mol_lin_w, mol_att_dst, sc1, ymol, hagg);
    k_gru<<<(NGRAPH+31)/32, 256, 0, stream>>>(hagg, mol_bias, outg,
                                              mgru_wi, mgru_wh, mgru_bi, mgru_bh, outg, NGRAPH);
  }

  // ---- final linear ----
  k_final<<<NGRAPH, 128, 0, stream>>>(outg, lin2_w, lin2_b, (float*)d_out);
}

// Round 8
// 625.740 us; speedup vs baseline: 2.7749x; 1.1741x over previous
//
#include <hip/hip_runtime.h>
#include <math.h>

#define N_NODES 50000
#define N_EDGES 1000000
#define NGRAPH  512
#define INC     39
#define SB 200   // scan blocks
#define SC 250   // nodes per scan block (200*250 = 50000)

typedef __attribute__((ext_vector_type(8))) short bf16x8;
typedef __attribute__((ext_vector_type(4))) float f32x4;

__device__ __forceinline__ float lrelu(float x){ return fmaxf(0.01f*x, x); }
__device__ __forceinline__ float fexp(float x){ return __builtin_amdgcn_exp2f(x*1.4426950408889634f); }
__device__ __forceinline__ float frcp(float x){ return __builtin_amdgcn_rcpf(x); }
__device__ __forceinline__ float eluf (float x){ return x > 0.f ? x : fexp(x) - 1.f; }
__device__ __forceinline__ float sigm (float x){ return frcp(1.f + fexp(-x)); }
__device__ __forceinline__ float ftanh(float x){
  x = fminf(fmaxf(x, -15.f), 15.f);
  float e = __builtin_amdgcn_exp2f(x*2.8853900817779268f); // exp(2x)
  return (e - 1.f)*frcp(e + 1.f);
}
__device__ __forceinline__ float rdlane(float v, int l){
  return __int_as_float(__builtin_amdgcn_readlane(__float_as_int(v), l));
}
// pack two fp32 -> 2x bf16 (RNE), lo = a, hi = b
__device__ __forceinline__ unsigned pk_bf16(float a, float b){
  unsigned r;
  asm volatile("v_cvt_pk_bf16_f32 %0, %1, %2" : "=v"(r) : "v"(a), "v"(b));
  return r;
}
__device__ __forceinline__ float bl(unsigned p){ return __uint_as_float(p << 16); }
__device__ __forceinline__ float bh(unsigned p){ return __uint_as_float(p & 0xffff0000u); }

// ================= CSR build =================
__global__ __launch_bounds__(256) void k_hist(const int* __restrict__ dst,
                                              int* __restrict__ cnt) {
  int e = blockIdx.x*256 + threadIdx.x;
  if (e < N_EDGES) atomicAdd(&cnt[dst[e]], 1);
}

__global__ __launch_bounds__(256) void k_scanA(const int* __restrict__ cnt,
                                               int* __restrict__ bsum) {
  __shared__ int s[256];
  int t = threadIdx.x, b = blockIdx.x;
  int v = (t < SC) ? cnt[b*SC + t] : 0;
  s[t] = v; __syncthreads();
  for (int off = 128; off > 0; off >>= 1) {
    if (t < off) s[t] += s[t+off];
    __syncthreads();
  }
  if (t == 0) bsum[b] = s[0];
}

__global__ __launch_bounds__(256) void k_scanB(const int* __restrict__ bsum,
                                               int* __restrict__ boff,
                                               int* __restrict__ rowptrN) {
  __shared__ int s[256];
  int t = threadIdx.x;
  int v = (t < SB) ? bsum[t] : 0;
  s[t] = v; __syncthreads();
  for (int off = 1; off < 256; off <<= 1) {
    int x = (t >= off) ? s[t-off] : 0;
    __syncthreads();
    s[t] += x;
    __syncthreads();
  }
  if (t < SB) boff[t] = s[t] - v;   // exclusive prefix
  if (t == 0) rowptrN[0] = N_EDGES; // rowptr[N_NODES]
}

__global__ __launch_bounds__(256) void k_scanC(const int* __restrict__ cnt,
                                               const int* __restrict__ boff,
                                               int* __restrict__ rowptr,
                                               int* __restrict__ cursor) {
  __shared__ int s[256];
  int t = threadIdx.x, b = blockIdx.x;
  int idx = b*SC + t;
  int v = (t < SC) ? cnt[idx] : 0;
  s[t] = v; __syncthreads();
  for (int off = 1; off < 256; off <<= 1) {
    int x = (t >= off) ? s[t-off] : 0;
    __syncthreads();
    s[t] += x;
    __syncthreads();
  }
  if (t < SC) {
    int val = boff[b] + s[t] - v;
    rowptr[idx] = val;
    cursor[idx] = val;
  }
}

__global__ __launch_bounds__(256) void k_scatter(const int* __restrict__ dst,
                                                 const int* __restrict__ src,
                                                 int* __restrict__ cursor,
                                                 int2* __restrict__ epack) {
  int e = blockIdx.x*256 + threadIdx.x;
  if (e < N_EDGES) {
    int p = atomicAdd(&cursor[dst[e]], 1);
    epack[p] = make_int2(e, src[e]);
  }
}

__global__ __launch_bounds__(512) void k_gbound(const int* __restrict__ batch,
                                                int* __restrict__ gstart) {
  int g = threadIdx.x;
  int lo = 0, hi = N_NODES;
  while (lo < hi) { int mid = (lo+hi)>>1; if (batch[mid] < g) lo = mid+1; else hi = mid; }
  gstart[g] = lo;
  if (g == 0) gstart[NGRAPH] = N_NODES;
}

// ================= bf16 weight prepack: wi,wh [192][64] each =================
__global__ __launch_bounds__(256) void k_wpack(const float* __restrict__ wi,
                                               const float* __restrict__ wh,
                                               unsigned short* __restrict__ o) {
  int i = blockIdx.x*256 + threadIdx.x;
  if (i < 192*64)      o[i]          = (unsigned short)(pk_bf16(wi[i], 0.f) & 0xffffu);
  else if (i < 2*192*64) o[i]        = (unsigned short)(pk_bf16(wh[i - 192*64], 0.f) & 0xffffu);
}

// ================= lin1: K=39, fused per-row dot with v1 =================
__global__ __launch_bounds__(256) void k_lin1(const float* __restrict__ x,
                                              const float* __restrict__ W,
                                              const float* __restrict__ b,
                                              float* __restrict__ out,
                                              const float* __restrict__ v1,
                                              float* __restrict__ o1) {
  __shared__ float wl[64*41];
  for (int idx = threadIdx.x; idx < 64*INC; idx += 256) {
    int r = idx / INC, c = idx - r*INC;
    wl[r*41+c] = W[idx];
  }
  __syncthreads();
  const int lane = threadIdx.x & 63;
  const int base = blockIdx.x*32 + (threadIdx.x>>6)*8;
  float h[8];
  #pragma unroll
  for (int i = 0; i < 8; ++i) {
    int n = base + i;
    h[i] = (n < N_NODES && lane < INC) ? x[n*INC + lane] : 0.f;
  }
  float acc[8] = {0,0,0,0,0,0,0,0};
  #pragma unroll
  for (int k = 0; k < INC; ++k) {
    float wv = wl[lane*41+k];
    #pragma unroll
    for (int i = 0; i < 8; ++i) acc[i] += rdlane(h[i], k) * wv;
  }
  float bb = b[lane];
  float attv = v1[lane];
  #pragma unroll
  for (int i = 0; i < 8; ++i) {
    int n = base + i;
    if (n >= N_NODES) continue;
    float val = lrelu(acc[i] + bb);
    out[n*64+lane] = val;
    float p = val * attv;
    #pragma unroll
    for (int s2 = 32; s2 > 0; s2 >>= 1) p += __shfl_xor(p, s2, 64);
    if (lane == 0) o1[n] = p;
  }
}

// ========== dual matmul -> u as bf16 [N][64] ushort, y packed 2ch/dword [N][32] ==========
__global__ __launch_bounds__(256) void k_mmdual(const float* __restrict__ in,
                                                const float* __restrict__ W1, // [64][80]
                                                const float* __restrict__ W2, // [64][64]
                                                unsigned short* __restrict__ ubf,
                                                unsigned* __restrict__ ypk, int R) {
  __shared__ float wl[128*65];
  for (int idx = threadIdx.x; idx < 4096; idx += 256) {
    int r = idx >> 6, c = idx & 63;
    wl[r*65+c]      = W1[r*80 + c];
    wl[(64+r)*65+c] = W2[r*64 + c];
  }
  __syncthreads();
  const int lane = threadIdx.x & 63;
  const int base = blockIdx.x*32 + (threadIdx.x>>6)*8;
  float h[8];
  #pragma unroll
  for (int i = 0; i < 8; ++i) { int n = base+i; h[i] = (n < R) ? in[n*64+lane] : 0.f; }
  float accU[8] = {0,0,0,0,0,0,0,0};
  float accY[8] = {0,0,0,0,0,0,0,0};
  for (int k = 0; k < 64; ++k) {
    float wu = wl[lane*65+k], wy = wl[(64+lane)*65+k];
    #pragma unroll
    for (int i = 0; i < 8; ++i) {
      float hk = rdlane(h[i], k);
      accU[i] += hk*wu; accY[i] += hk*wy;
    }
  }
  #pragma unroll
  for (int i = 0; i < 8; ++i) {
    int n = base+i; if (n >= R) continue;
    ubf[n*64 + lane] = (unsigned short)(pk_bf16(accU[i], 0.f) & 0xffffu);
    float partner = __shfl_xor(accY[i], 1, 64);
    if (!(lane & 1)) ypk[n*32 + (lane>>1)] = pk_bf16(accY[i], partner);
  }
}

// ========== [R,64] @ W.T; optional fp32 out, optional packed-bf16 pair table,
//            optional fused per-row dots ==========
__global__ __launch_bounds__(256) void k_mm64(const float* __restrict__ in,
                                              const float* __restrict__ W, int rs,
                                              float* __restrict__ out,
                                              unsigned* __restrict__ outp, int R,
                                              const float* __restrict__ v1,
                                              const float* __restrict__ v2,
                                              float* __restrict__ o1,
                                              float* __restrict__ o2) {
  __shared__ float wl[64*65];
  for (int idx = threadIdx.x; idx < 4096; idx += 256) {
    int r = idx >> 6, c = idx & 63;
    wl[r*65+c] = W[r*rs + c];
  }
  __syncthreads();
  const int lane = threadIdx.x & 63;
  const int base = blockIdx.x*32 + (threadIdx.x>>6)*8;
  float h[8];
  #pragma unroll
  for (int i = 0; i < 8; ++i) { int n = base+i; h[i] = (n < R) ? in[n*64+lane] : 0.f; }
  float acc[8] = {0,0,0,0,0,0,0,0};
  for (int k = 0; k < 64; ++k) {
    float wv = wl[lane*65+k];
    #pragma unroll
    for (int i = 0; i < 8; ++i) acc[i] += rdlane(h[i], k) * wv;
  }
  float v1v = v1 ? v1[lane] : 0.f;
  float v2v = v2 ? v2[lane] : 0.f;
  #pragma unroll
  for (int i = 0; i < 8; ++i) {
    int n = base+i; if (n >= R) continue;
    if (out) out[n*64+lane] = acc[i];
    if (outp) {
      float partner = __shfl_xor(acc[i], 1, 64);   // lane 2c gets ch 2c+1
      if ((lane & 1) == 0) outp[n*32 + (lane>>1)] = pk_bf16(acc[i], partner);
    }
    if (o1) {
      float p1 = acc[i]*v1v;
      float p2 = acc[i]*v2v;
      #pragma unroll
      for (int s2 = 32; s2 > 0; s2 >>= 1) { p1 += __shfl_xor(p1, s2, 64); p2 += __shfl_xor(p2, s2, 64); }
      if (lane == 0) { o1[n] = p1; if (o2) o2[n] = p2; }
    }
  }
}

// ===== GATE edge scores: 16 edges per MFMA, edge-parallel, writes p_perm (sorted order) =====
__global__ __launch_bounds__(256) void k_escore(const int2* __restrict__ epack,
                                                const float* __restrict__ ea,
                                                const float* __restrict__ glin1, // [64][80]
                                                const float* __restrict__ attl,
                                                const unsigned short* __restrict__ ubf,
                                                float* __restrict__ pperm) {
  const int lane = threadIdx.x & 63;
  const int l15 = lane & 15, lg = lane >> 4;
  const int gw = blockIdx.x*4 + (threadIdx.x >> 6);
  if (gw >= N_EDGES/64) return;
  float attlv[4];
  unsigned Bu[4][2];
  #pragma unroll
  for (int c = 0; c < 4; ++c) {
    const float4 b = *(const float4*)&glin1[(c*16 + l15)*80 + 64 + lg*4];
    Bu[c][0] = pk_bf16(b.x, b.y);
    Bu[c][1] = pk_bf16(b.z, b.w);
    attlv[c] = attl[c*16 + l15];
  }
  const int* epck = (const int*)epack;
  #pragma unroll 1
  for (int it = 0; it < 4; ++it) {
    const int i0 = gw*64 + it*16;
    int eid = epack[i0 + l15].x;
    const float4 a = *(const float4*)&ea[(size_t)eid*16 + lg*4];
    union { bf16x8 v; unsigned u[4]; } A;
    A.u[0] = pk_bf16(a.x, a.y);
    A.u[1] = pk_bf16(a.z, a.w);
    A.u[2] = 0; A.u[3] = 0;
    int sv[4];
    #pragma unroll
    for (int r = 0; r < 4; ++r) sv[r] = epck[2*(i0 + 4*lg + r) + 1];
    float p[4] = {0.f,0.f,0.f,0.f};
    #pragma unroll
    for (int c = 0; c < 4; ++c) {
      union { bf16x8 v; unsigned u[4]; } B;
      B.u[0] = Bu[c][0]; B.u[1] = Bu[c][1]; B.u[2] = 0; B.u[3] = 0;
      f32x4 z = {0.f,0.f,0.f,0.f};
      f32x4 acc = __builtin_amdgcn_mfma_f32_16x16x32_bf16(A.v, B.v, z, 0, 0, 0);
      #pragma unroll
      for (int r = 0; r < 4; ++r) {
        unsigned uu = ubf[(size_t)sv[r]*64 + c*16 + l15];
        float t = lrelu(__uint_as_float(uu << 16) + acc[r]);
        p[r] = fmaf(t, attlv[c], p[r]);
      }
    }
    #pragma unroll
    for (int r = 0; r < 4; ++r) {
      p[r] += __shfl_xor(p[r], 1, 64);
      p[r] += __shfl_xor(p[r], 2, 64);
      p[r] += __shfl_xor(p[r], 4, 64);
      p[r] += __shfl_xor(p[r], 8, 64);
    }
    if (l15 == 0) *(float4*)&pperm[i0 + 4*lg] = make_float4(p[0], p[1], p[2], p[3]);
  }
}

// ===== GATE aggregation: conv-style, contiguous p_perm, bf16-packed y gathers =====
__global__ __launch_bounds__(256) void k_gate_agg(const int* __restrict__ rowptr,
                                                  const int* __restrict__ epck,
                                                  const float* __restrict__ pperm,
                                                  const float* __restrict__ xr,
                                                  const unsigned* __restrict__ ypk,
                                                  float* __restrict__ hagg) {
  __shared__ int   sS[4][64];
  __shared__ float sE[4][64];
  const int w = __builtin_amdgcn_readfirstlane(threadIdx.x >> 6);
  const int lane = threadIdx.x & 63;
  const int slot = lane >> 5, l2 = lane & 31;
  const int d = blockIdx.x*4 + w;
  const int r0 = __builtin_amdgcn_readfirstlane(rowptr[d]);
  const int r1 = __builtin_amdgcn_readfirstlane(rowptr[d+1]);
  const float xrd = xr[d];
  float accx = 0.f, accy = 0.f, ssum = 0.f;
  for (int base = r0; base < r1; base += 64) {
    int i = base + lane;
    int cnt = r1 - base; if (cnt > 64) cnt = 64;
    float ev = 0.f; int s = 0;
    if (i < r1) { s = epck[2*i+1]; ev = fexp(lrelu(pperm[i] + xrd)); }
    sS[w][lane] = s; sE[w][lane] = ev;
    ssum += ev;
    for (int jb = 0; jb < cnt; jb += 16) {
      float e8[8]; unsigned p8[8];
      #pragma unroll
      for (int u = 0; u < 8; ++u) {
        int jj = jb + 2*u + slot;
        int svv; float evv;
        if (jj < cnt) { svv = sS[w][jj]; evv = sE[w][jj]; }
        else          { svv = 0; evv = 0.f; }
        e8[u] = evv;
        p8[u] = ypk[(size_t)svv*32 + l2];
      }
      #pragma unroll
      for (int u = 0; u < 8; ++u) {
        accx = fmaf(e8[u], bl(p8[u]), accx);
        accy = fmaf(e8[u], bh(p8[u]), accy);
      }
    }
  }
  #pragma unroll
  for (int sh = 32; sh > 0; sh >>= 1) ssum += __shfl_xor(ssum, sh, 64);
  accx += __shfl_xor(accx, 32, 64);
  accy += __shfl_xor(accy, 32, 64);
  float rs = frcp(ssum + 1e-16f);
  if (slot == 0) *(float2*)&hagg[d*64 + 2*l2] = make_float2(accx*rs, accy*rs);
}

// ===== GATConv fused: 2 edges per wave, bf16-packed hs =====
__global__ __launch_bounds__(256) void k_conv_fused(const int* __restrict__ rowptr,
                                                    const int* __restrict__ epck,
                                                    const float* __restrict__ asn,
                                                    const float* __restrict__ adn,
                                                    const unsigned* __restrict__ hsb,
                                                    float* __restrict__ hagg) {
  __shared__ int   sS[4][64];
  __shared__ float sE[4][64];
  const int w = __builtin_amdgcn_readfirstlane(threadIdx.x >> 6);
  const int lane = threadIdx.x & 63;
  const int slot = lane >> 5, l2 = lane & 31;
  const int d = blockIdx.x*4 + w;
  const int r0 = __builtin_amdgcn_readfirstlane(rowptr[d]);
  const int r1 = __builtin_amdgcn_readfirstlane(rowptr[d+1]);
  float adnd = adn[d];
  float accx = 0.f, accy = 0.f, ssum = 0.f;
  for (int base = r0; base < r1; base += 64) {
    int i = base + lane;
    int cnt = r1 - base; if (cnt > 64) cnt = 64;
    float ev = 0.f; int s = 0;
    if (i < r1) { s = epck[2*i+1]; ev = fexp(lrelu(asn[s] + adnd)); }
    sS[w][lane] = s; sE[w][lane] = ev;
    ssum += ev;
    for (int jb = 0; jb < cnt; jb += 16) {
      float e8[8]; unsigned p8[8];
      #pragma unroll
      for (int u = 0; u < 8; ++u) {
        int jj = jb + 2*u + slot;
        int svv; float evv;
        if (jj < cnt) { svv = sS[w][jj]; evv = sE[w][jj]; }
        else          { svv = 0; evv = 0.f; }
        e8[u] = evv;
        p8[u] = hsb[(size_t)svv*32 + l2];
      }
      #pragma unroll
      for (int u = 0; u < 8; ++u) {
        accx = fmaf(e8[u], bl(p8[u]), accx);
        accy = fmaf(e8[u], bh(p8[u]), accy);
      }
    }
  }
  #pragma unroll
  for (int sh = 32; sh > 0; sh >>= 1) ssum += __shfl_xor(ssum, sh, 64);
  accx += __shfl_xor(accx, 32, 64);
  accy += __shfl_xor(accy, 32, 64);
  float rs = frcp(ssum + 1e-16f);
  if (slot == 0) *(float2*)&hagg[d*64 + 2*l2] = make_float2(accx*rs, accy*rs);
}

// ===== MFMA GRU: out = relu(GRU(elu(inp+pbias), hid)), wave = 16 nodes =====
// A row = lane&15 (node), B col = lane&15 (gate channel within 16-tile),
// C/D: col = lane&15, row = 4*(lane>>4)+reg  [HW-verified mapping]
__global__ __launch_bounds__(256) void k_gruM(const float* __restrict__ inp,
                                              const float* __restrict__ pbias,
                                              const float* __restrict__ hid,
                                              const unsigned short* __restrict__ wibf,
                                              const unsigned short* __restrict__ whbf,
                                              const float* __restrict__ bi,
                                              const float* __restrict__ bh2,
                                              float* __restrict__ out, int R) {
  const int lane = threadIdx.x & 63;
  const int l15 = lane & 15, lg = lane >> 4;
  const int n0 = blockIdx.x*64 + (threadIdx.x >> 6)*16;
  if (n0 >= R) return;
  union BF { bf16x8 v; unsigned u[4]; };
  BF Ai[2], Ah[2];
  const int arow = n0 + l15;
  const bool av = arow < R;
  const float* ibase = inp + (size_t)arow*64;
  const float* hbase = hid + (size_t)arow*64;
  #pragma unroll
  for (int c = 0; c < 2; ++c) {
    const int k0 = c*32 + lg*8;
    float4 p0 = *(const float4*)&pbias[k0];
    float4 p1 = *(const float4*)&pbias[k0+4];
    float4 v0, v1, h0, h1;
    if (av) {
      v0 = *(const float4*)&ibase[k0];   v1 = *(const float4*)&ibase[k0+4];
      h0 = *(const float4*)&hbase[k0];   h1 = *(const float4*)&hbase[k0+4];
    } else {
      v0 = v1 = h0 = h1 = make_float4(0.f,0.f,0.f,0.f);
      p0 = p1 = make_float4(0.f,0.f,0.f,0.f);
    }
    Ai[c].u[0] = pk_bf16(eluf(v0.x+p0.x), eluf(v0.y+p0.y));
    Ai[c].u[1] = pk_bf16(eluf(v0.z+p0.z), eluf(v0.w+p0.w));
    Ai[c].u[2] = pk_bf16(eluf(v1.x+p1.x), eluf(v1.y+p1.y));
    Ai[c].u[3] = pk_bf16(eluf(v1.z+p1.z), eluf(v1.w+p1.w));
    Ah[c].u[0] = pk_bf16(h0.x, h0.y);
    Ah[c].u[1] = pk_bf16(h0.z, h0.w);
    Ah[c].u[2] = pk_bf16(h1.x, h1.y);
    Ah[c].u[3] = pk_bf16(h1.z, h1.w);
  }
  f32x4 rz[8], ni[4], nh[4];
  #pragma unroll
  for (int t = 0; t < 8; ++t) rz[t] = (f32x4){0.f,0.f,0.f,0.f};
  #pragma unroll
  for (int t = 0; t < 4; ++t) { ni[t] = (f32x4){0.f,0.f,0.f,0.f}; nh[t] = (f32x4){0.f,0.f,0.f,0.f}; }
  #pragma unroll
  for (int t = 0; t < 12; ++t) {
    BF Bi0, Bi1, Bh0, Bh1;
    const size_t off = ((size_t)(t*16 + l15))*64 + lg*8;
    Bi0.v = *(const bf16x8*)&wibf[off];
    Bi1.v = *(const bf16x8*)&wibf[off + 32];
    Bh0.v = *(const bf16x8*)&whbf[off];
    Bh1.v = *(const bf16x8*)&whbf[off + 32];
    if (t < 8) {
      f32x4 a = rz[t];
      a = __builtin_amdgcn_mfma_f32_16x16x32_bf16(Ai[0].v, Bi0.v, a, 0, 0, 0);
      a = __builtin_amdgcn_mfma_f32_16x16x32_bf16(Ai[1].v, Bi1.v, a, 0, 0, 0);
      a = __builtin_amdgcn_mfma_f32_16x16x32_bf16(Ah[0].v, Bh0.v, a, 0, 0, 0);
      a = __builtin_amdgcn_mfma_f32_16x16x32_bf16(Ah[1].v, Bh1.v, a, 0, 0, 0);
      rz[t] = a;
    } else {
      f32x4 a = ni[t-8];
      a = __builtin_amdgcn_mfma_f32_16x16x32_bf16(Ai[0].v, Bi0.v, a, 0, 0, 0);
      a = __builtin_amdgcn_mfma_f32_16x16x32_bf16(Ai[1].v, Bi1.v, a, 0, 0, 0);
      ni[t-8] = a;
      f32x4 b = nh[t-8];
      b = __builtin_amdgcn_mfma_f32_16x16x32_bf16(Ah[0].v, Bh0.v, b, 0, 0, 0);
      b = __builtin_amdgcn_mfma_f32_16x16x32_bf16(Ah[1].v, Bh1.v, b, 0, 0, 0);
      nh[t-8] = b;
    }
  }
  float bsum[8], binv[4], bhnv[4];
  #pragma unroll
  for (int t = 0; t < 8; ++t) bsum[t] = bi[t*16+l15] + bh2[t*16+l15];
  #pragma unroll
  for (int t = 0; t < 4; ++t) {
    binv[t] = bi[128 + t*16 + l15];
    bhnv[t] = bh2[128 + t*16 + l15];
  }
  #pragma unroll
  for (int reg = 0; reg < 4; ++reg) {
    const int node = n0 + 4*lg + reg;
    if (node >= R) continue;
    #pragma unroll
    for (int tt = 0; tt < 4; ++tt) {
      float r  = sigm(rz[tt][reg] + bsum[tt]);
      float z  = sigm(rz[4+tt][reg] + bsum[4+tt]);
      float nn = ftanh(ni[tt][reg] + binv[tt] + r*(nh[tt][reg] + bhnv[tt]));
      float hh = hid[(size_t)node*64 + tt*16 + l15];
      float o  = (1.f - z)*nn + z*hh;
      out[(size_t)node*64 + tt*16 + l15] = fmaxf(o, 0.f);
    }
  }
}

// ================= molecule readout (CSR over sorted batch) =================
__global__ __launch_bounds__(256) void k_molsum_f(const int* __restrict__ gstart,
                                                  const float* __restrict__ x,
                                                  float* __restrict__ outg) {
  int g = blockIdx.x*4 + (threadIdx.x>>6);
  if (g >= NGRAPH) return;
  int lane = threadIdx.x & 63;
  float acc = 0.f;
  int n1 = gstart[g+1];
  for (int n = gstart[g]; n < n1; ++n) acc += x[n*64+lane];
  outg[g*64+lane] = fmaxf(acc, 0.f);
}

__global__ __launch_bounds__(256) void k_mol_fused(const int* __restrict__ gstart,
                                                   const float* __restrict__ outg,
                                                   const float* __restrict__ W,
                                                   const float* __restrict__ attd,
                                                   const float* __restrict__ asn,
                                                   const float* __restrict__ y,
                                                   float* __restrict__ hg) {
  __shared__ float wl[64*65];
  for (int idx = threadIdx.x; idx < 4096; idx += 256) wl[(idx>>6)*65+(idx&63)] = W[idx];
  __syncthreads();
  int g = blockIdx.x*4 + (threadIdx.x>>6);
  if (g >= NGRAPH) return;
  int lane = threadIdx.x & 63;
  float og = outg[g*64+lane];
  float hd = 0.f;
  #pragma unroll
  for (int k = 0; k < 64; ++k) hd += rdlane(og, k) * wl[lane*65+k];
  float p = hd * attd[lane];
  #pragma unroll
  for (int sh = 32; sh > 0; sh >>= 1) p += __shfl_xor(p, sh, 64);
  float addg = p;
  float acc = 0.f, ssum = 0.f;
  int n1 = gstart[g+1];
  for (int n = gstart[g]; n < n1; ++n) {
    float ev = fexp(lrelu(asn[n] + addg));
    acc += ev * y[n*64+lane];
    ssum += ev;
  }
  hg[g*64+lane] = acc * frcp(ssum + 1e-16f);
}

__global__ __launch_bounds__(128) void k_final(const float* __restrict__ outg,
                                               const float* __restrict__ W,
                                               const float* __restrict__ b,
                                               float* __restrict__ out) {
  __shared__ float og[64];
  int g = blockIdx.x;
  if (threadIdx.x < 64) og[threadIdx.x] = outg[g*64+threadIdx.x];
  __syncthreads();
  int o = threadIdx.x;
  float acc = b[o];
  for (int k = 0; k < 64; ++k) acc += og[k]*W[o*64+k];
  out[g*128+o] = acc;
}

extern "C" void kernel_launch(void* const* d_in, const int* in_sizes, int n_in,
                              void* d_out, int out_size, void* d_ws, size_t ws_size,
                              hipStream_t stream) {
  const float* x_in     = (const float*)d_in[0];
  const int*   eidx     = (const int*)  d_in[1];
  const float* eattr    = (const float*)d_in[2];
  const int*   batch    = (const int*)  d_in[3];
  const float* lin1_w   = (const float*)d_in[4];
  const float* lin1_b   = (const float*)d_in[5];
  const float* g_lin1_w = (const float*)d_in[6];
  const float* g_att_l  = (const float*)d_in[7];
  const float* g_att_r  = (const float*)d_in[8];
  const float* g_lin2_w = (const float*)d_in[9];
  const float* g_bias   = (const float*)d_in[10];
  const float* gru0_wi  = (const float*)d_in[11];
  const float* gru0_wh  = (const float*)d_in[12];
  const float* gru0_bi  = (const float*)d_in[13];
  const float* gru0_bh  = (const float*)d_in[14];
  const float* conv_lin_w   = (const float*)d_in[15];
  const float* conv_att_src = (const float*)d_in[16];
  const float* conv_att_dst = (const float*)d_in[17];
  const float* conv_bias    = (const float*)d_in[18];
  const float* grul_wi  = (const float*)d_in[19];
  const float* grul_wh  = (const float*)d_in[20];
  const float* grul_bi  = (const float*)d_in[21];
  const float* grul_bh  = (const float*)d_in[22];
  const float* mol_lin_w    = (const float*)d_in[23];
  const float* mol_att_src  = (const float*)d_in[24];
  const float* mol_att_dst  = (const float*)d_in[25];
  const float* mol_bias     = (const float*)d_in[26];
  const float* mgru_wi  = (const float*)d_in[27];
  const float* mgru_wh  = (const float*)d_in[28];
  const float* mgru_bi  = (const float*)d_in[29];
  const float* mgru_bh  = (const float*)d_in[30];
  const float* lin2_w   = (const float*)d_in[31];
  const float* lin2_b   = (const float*)d_in[32];

  const int N64 = N_NODES*64;
  float* ws     = (float*)d_ws;
  float* xA     = ws;               // N*64
  float* xB     = xA + N64;         // N*64
  float* uy     = xB + N64;         // 2*N64 region: ubf(ushort N*64)+ypk(uint N*32) / hsb / ymol
  float* hagg   = uy + 2*N64;       // N*64
  float* sc1    = hagg + N64;       // N
  float* sc2    = sc1 + N_NODES;    // N
  float* pperm  = sc2 + N_NODES;    // E (edge scores, sorted order)
  float* outg   = pperm + N_EDGES;  // G*64
  int* icnt   = (int*)(outg + NGRAPH*64); // N
  int* rowptr = icnt + N_NODES;     // N+2 (pad for int2 alignment)
  int* cursor = rowptr + N_NODES+2; // N
  int2* epack = (int2*)(cursor + N_NODES); // E int2 {eid, src}
  int* gstart = (int*)(epack + N_EDGES);   // G+1
  int* bsum   = gstart + NGRAPH+1;  // SB
  int* boff   = bsum + SB;          // SB
  unsigned short* wpk = (unsigned short*)(boff + SB + 4); // 4 pairs * 2*192*64 bf16

  unsigned short* ubf = (unsigned short*)uy;       // N*64 bf16 u
  unsigned* ypk = (unsigned*)(uy + N64);           // N*32 packed y
  unsigned* hsb = (unsigned*)uy;                   // N*32 packed hs (reused after gate)
  int* epck = (int*)epack;

  const int* src = eidx;
  const int* dst = eidx + N_EDGES;

  const int nbN32 = (N_NODES + 31)/32;
  const int nbN4  = (N_NODES + 3)/4;
  const int nbN64 = (N_NODES + 63)/64;
  const int nbE   = (N_EDGES + 255)/256;
  const int nbG4  = (NGRAPH + 3)/4;
  const int nbES  = (N_EDGES/64 + 3)/4;   // escore: 64 edges per wave
  const int PAIR  = 2*192*64;             // ushorts per GRU pair

  // ---- CSR build (hierarchical scan) ----
  hipMemsetAsync(icnt, 0, N_NODES*sizeof(int), stream);
  k_hist<<<nbE, 256, 0, stream>>>(dst, icnt);
  k_scanA<<<SB, 256, 0, stream>>>(icnt, bsum);
  k_scanB<<<1, 256, 0, stream>>>(bsum, boff, rowptr + N_NODES);
  k_scanC<<<SB, 256, 0, stream>>>(icnt, boff, rowptr, cursor);
  k_scatter<<<nbE, 256, 0, stream>>>(dst, src, cursor, epack);
  k_gbound<<<1, 512, 0, stream>>>(batch, gstart);

  // ---- GRU weight prepack (bf16) ----
  k_wpack<<<(PAIR+255)/256, 256, 0, stream>>>(gru0_wi, gru0_wh, wpk);
  k_wpack<<<(PAIR+255)/256, 256, 0, stream>>>(grul_wi, grul_wh, wpk + PAIR);
  k_wpack<<<(PAIR+255)/256, 256, 0, stream>>>(grul_wi + 192*64, grul_wh + 192*64, wpk + 2*PAIR);
  k_wpack<<<(PAIR+255)/256, 256, 0, stream>>>(mgru_wi, mgru_wh, wpk + 3*PAIR);

  // ---- lin1 (+ fused xr = x.h @ g_att_r) ----
  k_lin1<<<nbN32, 256, 0, stream>>>(x_in, lin1_w, lin1_b, xA, g_att_r, sc1);

  // ---- GATEConv ----
  k_mmdual<<<nbN32, 256, 0, stream>>>(xA, g_lin1_w, g_lin2_w, ubf, ypk, N_NODES);
  k_escore<<<nbES, 256, 0, stream>>>(epack, eattr, g_lin1_w, g_att_l, ubf, pperm);
  k_gate_agg<<<nbN4, 256, 0, stream>>>(rowptr, epck, pperm, sc1, ypk, hagg);
  k_gruM<<<nbN64, 256, 0, stream>>>(hagg, g_bias, xA, wpk, wpk + 192*64,
                                    gru0_bi, gru0_bh, xB, N_NODES);

  float* xcur = xB; float* xoth = xA;

  // ---- GATConv layers ----
  for (int l = 0; l < 2; ++l) {
    k_mm64<<<nbN32, 256, 0, stream>>>(xcur, conv_lin_w + l*64*64, 64, nullptr, hsb, N_NODES,
                                      conv_att_src + l*64, conv_att_dst + l*64, sc1, sc2);
    k_conv_fused<<<nbN4, 256, 0, stream>>>(rowptr, epck, sc1, sc2, hsb, hagg);
    k_gruM<<<nbN64, 256, 0, stream>>>(hagg, conv_bias + l*64, xcur,
                                      wpk + (1+l)*PAIR, wpk + (1+l)*PAIR + 192*64,
                                      grul_bi + l*192, grul_bh + l*192, xoth, N_NODES);
    float* t = xcur; xcur = xoth; xoth = t;
  }

  // ---- molecule readout ----
  float* ymol = uy;  // fp32 N*64 reuse
  k_molsum_f<<<nbG4, 256, 0, stream>>>(gstart, xcur, outg);
  k_mm64<<<nbN32, 256, 0, stream>>>(xcur, mol_lin_w, 64, ymol, nullptr, N_NODES,
                                    mol_att_src, nullptr, sc1, nullptr);
  for (int t = 0; t < 2; ++t) {
    k_mol_fused<<<nbG4, 256, 0, stream>>>(gstart, outg, mol_lin_w, mol_att_dst, sc1, ymol, hagg);
    k_gruM<<<(NGRAPH+63)/64, 256, 0, stream>>>(hagg, mol_bias, outg,
                                               wpk + 3*PAIR, wpk + 3*PAIR + 192*64,
                                               mgru_bi, mgru_bh, outg, NGRAPH);
  }

  // ---- final linear ----
  k_final<<<NGRAPH, 128, 0, stream>>>(outg, lin2_w, lin2_b, (float*)d_out);
}

// Round 9
// 577.137 us; speedup vs baseline: 3.0086x; 1.0842x over previous
//
#include <hip/hip_runtime.h>
#include <math.h>

#define N_NODES 50000
#define N_EDGES 1000000
#define NGRAPH  512
#define INC     39
#define SB 200   // scan blocks
#define SC 250   // nodes per scan block (200*250 = 50000)
#define NBKT 196 // dst buckets of 256 nodes
#define BIN_BLK 4096

typedef __attribute__((ext_vector_type(8))) short bf16x8;
typedef __attribute__((ext_vector_type(4))) float f32x4;

__device__ __forceinline__ float lrelu(float x){ return fmaxf(0.01f*x, x); }
__device__ __forceinline__ float fexp(float x){ return __builtin_amdgcn_exp2f(x*1.4426950408889634f); }
__device__ __forceinline__ float frcp(float x){ return __builtin_amdgcn_rcpf(x); }
__device__ __forceinline__ float eluf (float x){ return x > 0.f ? x : fexp(x) - 1.f; }
__device__ __forceinline__ float sigm (float x){ return frcp(1.f + fexp(-x)); }
__device__ __forceinline__ float ftanh(float x){
  x = fminf(fmaxf(x, -15.f), 15.f);
  float e = __builtin_amdgcn_exp2f(x*2.8853900817779268f); // exp(2x)
  return (e - 1.f)*frcp(e + 1.f);
}
__device__ __forceinline__ float rdlane(float v, int l){
  return __int_as_float(__builtin_amdgcn_readlane(__float_as_int(v), l));
}
__device__ __forceinline__ unsigned pk_bf16(float a, float b){
  unsigned r;
  asm volatile("v_cvt_pk_bf16_f32 %0, %1, %2" : "=v"(r) : "v"(a), "v"(b));
  return r;
}
__device__ __forceinline__ float bl(unsigned p){ return __uint_as_float(p << 16); }
__device__ __forceinline__ float bh(unsigned p){ return __uint_as_float(p & 0xffff0000u); }

// ================= CSR build =================
__global__ __launch_bounds__(256) void k_hist(const int* __restrict__ dst,
                                              int* __restrict__ cnt) {
  int e = blockIdx.x*256 + threadIdx.x;
  if (e < N_EDGES) atomicAdd(&cnt[dst[e]], 1);
}

__global__ __launch_bounds__(256) void k_scanA(const int* __restrict__ cnt,
                                               int* __restrict__ bsum) {
  __shared__ int s[256];
  int t = threadIdx.x, b = blockIdx.x;
  int v = (t < SC) ? cnt[b*SC + t] : 0;
  s[t] = v; __syncthreads();
  for (int off = 128; off > 0; off >>= 1) {
    if (t < off) s[t] += s[t+off];
    __syncthreads();
  }
  if (t == 0) bsum[b] = s[0];
}

__global__ __launch_bounds__(256) void k_scanB(const int* __restrict__ bsum,
                                               int* __restrict__ boff,
                                               int* __restrict__ rowptrN) {
  __shared__ int s[256];
  int t = threadIdx.x;
  int v = (t < SB) ? bsum[t] : 0;
  s[t] = v; __syncthreads();
  for (int off = 1; off < 256; off <<= 1) {
    int x = (t >= off) ? s[t-off] : 0;
    __syncthreads();
    s[t] += x;
    __syncthreads();
  }
  if (t < SB) boff[t] = s[t] - v;   // exclusive prefix
  if (t == 0) rowptrN[0] = N_EDGES; // rowptr[N_NODES]
}

__global__ __launch_bounds__(256) void k_scanC(const int* __restrict__ cnt,
                                               const int* __restrict__ boff,
                                               int* __restrict__ rowptr) {
  __shared__ int s[256];
  int t = threadIdx.x, b = blockIdx.x;
  int idx = b*SC + t;
  int v = (t < SC) ? cnt[idx] : 0;
  s[t] = v; __syncthreads();
  for (int off = 1; off < 256; off <<= 1) {
    int x = (t >= off) ? s[t-off] : 0;
    __syncthreads();
    s[t] += x;
    __syncthreads();
  }
  if (t < SC) rowptr[idx] = boff[b] + s[t] - v;
}

__global__ __launch_bounds__(256) void k_bstart(const int* __restrict__ rowptr,
                                                int* __restrict__ bstart,
                                                int* __restrict__ bcur) {
  int b = threadIdx.x;
  if (b <= NBKT) {
    int idx = b*256; if (idx > N_NODES) idx = N_NODES;
    int v = rowptr[idx];
    bstart[b] = v;
    if (b < NBKT) bcur[b] = v;
  }
}

// ===== Pass A: bin edges into 196 coarse buckets (locality-friendly runs) =====
__global__ __launch_bounds__(1024) void k_binA(const int* __restrict__ dst,
                                               const int* __restrict__ src,
                                               const float* __restrict__ p,
                                               int* __restrict__ bcur,
                                               int2* __restrict__ binned) {
  __shared__ int lcnt[NBKT];
  __shared__ int lbase[NBKT];
  __shared__ int gbase[NBKT];
  __shared__ int tmp[256];
  __shared__ int totsh;
  __shared__ int2 stage[BIN_BLK];
  const int t = threadIdx.x;
  const int e0 = blockIdx.x * BIN_BLK;
  for (int i = t; i < NBKT; i += 1024) lcnt[i] = 0;
  __syncthreads();
  int myb[4], myr[4], myd[4], mys[4]; float myp[4];
  #pragma unroll
  for (int u = 0; u < 4; ++u) {
    int e = e0 + u*1024 + t;
    if (e < N_EDGES) {
      int d = dst[e];
      myd[u] = d; mys[u] = src[e]; myp[u] = p[e];
      int b = d >> 8;
      myb[u] = b;
      myr[u] = atomicAdd(&lcnt[b], 1);
    } else myb[u] = -1;
  }
  __syncthreads();
  // exclusive scan of lcnt (256-wide Hillis-Steele covers 196)
  if (t < 256) tmp[t] = (t < NBKT) ? lcnt[t] : 0;
  __syncthreads();
  for (int off = 1; off < 256; off <<= 1) {
    int v = (t >= off && t < 256) ? tmp[t-off] : 0;
    __syncthreads();
    if (t < 256) tmp[t] += v;
    __syncthreads();
  }
  if (t < NBKT) lbase[t] = tmp[t] - lcnt[t];
  if (t == NBKT-1) totsh = tmp[t];
  if (t < NBKT && lcnt[t] > 0) gbase[t] = atomicAdd(&bcur[t], lcnt[t]);
  __syncthreads();
  #pragma unroll
  for (int u = 0; u < 4; ++u) {
    if (myb[u] >= 0) {
      int x = (mys[u] & 0xffff) | ((myd[u] & 255) << 16) | (myb[u] << 24);
      stage[lbase[myb[u]] + myr[u]] = make_int2(x, __float_as_int(myp[u]));
    }
  }
  __syncthreads();
  const int tot = totsh;
  for (int i = t; i < tot; i += 1024) {
    int2 r = stage[i];
    int b = (unsigned)r.x >> 24;
    binned[gbase[b] + (i - lbase[b])] = r;
  }
}

// ===== Pass B: sort each bucket to final CSR order (contiguous 40KB window) =====
__global__ __launch_bounds__(1024) void k_binB(const int* __restrict__ rowptr,
                                               const int* __restrict__ bstart,
                                               const int2* __restrict__ binned,
                                               int2* __restrict__ sorted) {
  __shared__ int lcnt[256];
  const int b = blockIdx.x;
  const int base = bstart[b], end = bstart[b+1];
  const int t = threadIdx.x;
  if (t < 256) lcnt[t] = 0;
  __syncthreads();
  for (int i = base + t; i < end; i += 1024) {
    int2 r = binned[i];
    int dlow = (r.x >> 16) & 255;
    int rank = atomicAdd(&lcnt[dlow], 1);
    int pos = rowptr[b*256 + dlow] + rank;
    sorted[pos] = r;
  }
}

__global__ __launch_bounds__(512) void k_gbound(const int* __restrict__ batch,
                                                int* __restrict__ gstart) {
  int g = threadIdx.x;
  int lo = 0, hi = N_NODES;
  while (lo < hi) { int mid = (lo+hi)>>1; if (batch[mid] < g) lo = mid+1; else hi = mid; }
  gstart[g] = lo;
  if (g == 0) gstart[NGRAPH] = N_NODES;
}

// ================= bf16 weight prepack: wi,wh [192][64] each =================
__global__ __launch_bounds__(256) void k_wpack(const float* __restrict__ wi,
                                               const float* __restrict__ wh,
                                               unsigned short* __restrict__ o) {
  int i = blockIdx.x*256 + threadIdx.x;
  if (i < 192*64)      o[i]          = (unsigned short)(pk_bf16(wi[i], 0.f) & 0xffffu);
  else if (i < 2*192*64) o[i]        = (unsigned short)(pk_bf16(wh[i - 192*64], 0.f) & 0xffffu);
}

// ================= lin1: K=39, fused per-row dot with v1 =================
__global__ __launch_bounds__(256) void k_lin1(const float* __restrict__ x,
                                              const float* __restrict__ W,
                                              const float* __restrict__ b,
                                              float* __restrict__ out,
                                              const float* __restrict__ v1,
                                              float* __restrict__ o1) {
  __shared__ float wl[64*41];
  for (int idx = threadIdx.x; idx < 64*INC; idx += 256) {
    int r = idx / INC, c = idx - r*INC;
    wl[r*41+c] = W[idx];
  }
  __syncthreads();
  const int lane = threadIdx.x & 63;
  const int base = blockIdx.x*32 + (threadIdx.x>>6)*8;
  float h[8];
  #pragma unroll
  for (int i = 0; i < 8; ++i) {
    int n = base + i;
    h[i] = (n < N_NODES && lane < INC) ? x[n*INC + lane] : 0.f;
  }
  float acc[8] = {0,0,0,0,0,0,0,0};
  #pragma unroll
  for (int k = 0; k < INC; ++k) {
    float wv = wl[lane*41+k];
    #pragma unroll
    for (int i = 0; i < 8; ++i) acc[i] += rdlane(h[i], k) * wv;
  }
  float bb = b[lane];
  float attv = v1[lane];
  #pragma unroll
  for (int i = 0; i < 8; ++i) {
    int n = base + i;
    if (n >= N_NODES) continue;
    float val = lrelu(acc[i] + bb);
    out[n*64+lane] = val;
    float p = val * attv;
    #pragma unroll
    for (int s2 = 32; s2 > 0; s2 >>= 1) p += __shfl_xor(p, s2, 64);
    if (lane == 0) o1[n] = p;
  }
}

// ========== dual matmul -> u as bf16 [N][64] ushort, y packed 2ch/dword [N][32] ==========
__global__ __launch_bounds__(256) void k_mmdual(const float* __restrict__ in,
                                                const float* __restrict__ W1, // [64][80]
                                                const float* __restrict__ W2, // [64][64]
                                                unsigned short* __restrict__ ubf,
                                                unsigned* __restrict__ ypk, int R) {
  __shared__ float wl[128*65];
  for (int idx = threadIdx.x; idx < 4096; idx += 256) {
    int r = idx >> 6, c = idx & 63;
    wl[r*65+c]      = W1[r*80 + c];
    wl[(64+r)*65+c] = W2[r*64 + c];
  }
  __syncthreads();
  const int lane = threadIdx.x & 63;
  const int base = blockIdx.x*32 + (threadIdx.x>>6)*8;
  float h[8];
  #pragma unroll
  for (int i = 0; i < 8; ++i) { int n = base+i; h[i] = (n < R) ? in[n*64+lane] : 0.f; }
  float accU[8] = {0,0,0,0,0,0,0,0};
  float accY[8] = {0,0,0,0,0,0,0,0};
  for (int k = 0; k < 64; ++k) {
    float wu = wl[lane*65+k], wy = wl[(64+lane)*65+k];
    #pragma unroll
    for (int i = 0; i < 8; ++i) {
      float hk = rdlane(h[i], k);
      accU[i] += hk*wu; accY[i] += hk*wy;
    }
  }
  #pragma unroll
  for (int i = 0; i < 8; ++i) {
    int n = base+i; if (n >= R) continue;
    ubf[n*64 + lane] = (unsigned short)(pk_bf16(accU[i], 0.f) & 0xffffu);
    float partner = __shfl_xor(accY[i], 1, 64);
    if (!(lane & 1)) ypk[n*32 + (lane>>1)] = pk_bf16(accY[i], partner);
  }
}

// ========== [R,64] @ W.T; optional packed-bf16 pair table + fused per-row dots ==========
__global__ __launch_bounds__(256) void k_mm64(const float* __restrict__ in,
                                              const float* __restrict__ W, int rs,
                                              float* __restrict__ out,
                                              unsigned* __restrict__ outp, int R,
                                              const float* __restrict__ v1,
                                              const float* __restrict__ v2,
                                              float* __restrict__ o1,
                                              float* __restrict__ o2) {
  __shared__ float wl[64*65];
  for (int idx = threadIdx.x; idx < 4096; idx += 256) {
    int r = idx >> 6, c = idx & 63;
    wl[r*65+c] = W[r*rs + c];
  }
  __syncthreads();
  const int lane = threadIdx.x & 63;
  const int base = blockIdx.x*32 + (threadIdx.x>>6)*8;
  float h[8];
  #pragma unroll
  for (int i = 0; i < 8; ++i) { int n = base+i; h[i] = (n < R) ? in[n*64+lane] : 0.f; }
  float acc[8] = {0,0,0,0,0,0,0,0};
  for (int k = 0; k < 64; ++k) {
    float wv = wl[lane*65+k];
    #pragma unroll
    for (int i = 0; i < 8; ++i) acc[i] += rdlane(h[i], k) * wv;
  }
  float v1v = v1 ? v1[lane] : 0.f;
  float v2v = v2 ? v2[lane] : 0.f;
  #pragma unroll
  for (int i = 0; i < 8; ++i) {
    int n = base+i; if (n >= R) continue;
    if (out) out[n*64+lane] = acc[i];
    if (outp) {
      float partner = __shfl_xor(acc[i], 1, 64);   // lane 2c gets ch 2c+1
      if ((lane & 1) == 0) outp[n*32 + (lane>>1)] = pk_bf16(acc[i], partner);
    }
    if (o1) {
      float p1 = acc[i]*v1v;
      float p2 = acc[i]*v2v;
      #pragma unroll
      for (int s2 = 32; s2 > 0; s2 >>= 1) { p1 += __shfl_xor(p1, s2, 64); p2 += __shfl_xor(p2, s2, 64); }
      if (lane == 0) { o1[n] = p1; if (o2) o2[n] = p2; }
    }
  }
}

// ===== GATE edge scores in ORIGINAL edge order: coalesced ea, writes p[e] =====
__global__ __launch_bounds__(256) void k_escore(const int* __restrict__ srcarr,
                                                const float* __restrict__ ea,
                                                const float* __restrict__ glin1, // [64][80]
                                                const float* __restrict__ attl,
                                                const unsigned short* __restrict__ ubf,
                                                float* __restrict__ pout) {
  const int lane = threadIdx.x & 63;
  const int l15 = lane & 15, lg = lane >> 4;
  const int gw = blockIdx.x*4 + (threadIdx.x >> 6);
  if (gw >= N_EDGES/64) return;
  float attlv[4];
  unsigned Bu[4][2];
  #pragma unroll
  for (int c = 0; c < 4; ++c) {
    const float4 b = *(const float4*)&glin1[(c*16 + l15)*80 + 64 + lg*4];
    Bu[c][0] = pk_bf16(b.x, b.y);
    Bu[c][1] = pk_bf16(b.z, b.w);
    attlv[c] = attl[c*16 + l15];
  }
  #pragma unroll 1
  for (int it = 0; it < 4; ++it) {
    const int i0 = gw*64 + it*16;
    const float4 a = *(const float4*)&ea[(size_t)(i0 + l15)*16 + lg*4];  // coalesced
    union { bf16x8 v; unsigned u[4]; } A;
    A.u[0] = pk_bf16(a.x, a.y);
    A.u[1] = pk_bf16(a.z, a.w);
    A.u[2] = 0; A.u[3] = 0;
    int sv[4];
    #pragma unroll
    for (int r = 0; r < 4; ++r) sv[r] = srcarr[i0 + 4*lg + r];
    float p[4] = {0.f,0.f,0.f,0.f};
    #pragma unroll
    for (int c = 0; c < 4; ++c) {
      union { bf16x8 v; unsigned u[4]; } B;
      B.u[0] = Bu[c][0]; B.u[1] = Bu[c][1]; B.u[2] = 0; B.u[3] = 0;
      f32x4 z = {0.f,0.f,0.f,0.f};
      f32x4 acc = __builtin_amdgcn_mfma_f32_16x16x32_bf16(A.v, B.v, z, 0, 0, 0);
      #pragma unroll
      for (int r = 0; r < 4; ++r) {
        unsigned uu = ubf[(size_t)sv[r]*64 + c*16 + l15];
        float t = lrelu(__uint_as_float(uu << 16) + acc[r]);
        p[r] = fmaf(t, attlv[c], p[r]);
      }
    }
    #pragma unroll
    for (int r = 0; r < 4; ++r) {
      p[r] += __shfl_xor(p[r], 1, 64);
      p[r] += __shfl_xor(p[r], 2, 64);
      p[r] += __shfl_xor(p[r], 4, 64);
      p[r] += __shfl_xor(p[r], 8, 64);
    }
    if (l15 == 0) *(float4*)&pout[i0 + 4*lg] = make_float4(p[0], p[1], p[2], p[3]);
  }
}

// ===== GATE aggregation: sorted records {src|dlow|bkt, p}, bf16-packed y gathers =====
__global__ __launch_bounds__(256) void k_gate_agg(const int* __restrict__ rowptr,
                                                  const int2* __restrict__ sorted,
                                                  const float* __restrict__ xr,
                                                  const unsigned* __restrict__ ypk,
                                                  float* __restrict__ hagg) {
  __shared__ int   sS[4][64];
  __shared__ float sE[4][64];
  const int w = __builtin_amdgcn_readfirstlane(threadIdx.x >> 6);
  const int lane = threadIdx.x & 63;
  const int slot = lane >> 5, l2 = lane & 31;
  const int d = blockIdx.x*4 + w;
  const int r0 = __builtin_amdgcn_readfirstlane(rowptr[d]);
  const int r1 = __builtin_amdgcn_readfirstlane(rowptr[d+1]);
  const float xrd = xr[d];
  float accx = 0.f, accy = 0.f, ssum = 0.f;
  for (int base = r0; base < r1; base += 64) {
    int i = base + lane;
    int cnt = r1 - base; if (cnt > 64) cnt = 64;
    float ev = 0.f; int s = 0;
    if (i < r1) {
      int2 r = sorted[i];
      s = r.x & 0xffff;
      ev = fexp(lrelu(__int_as_float(r.y) + xrd));
    }
    sS[w][lane] = s; sE[w][lane] = ev;
    ssum += ev;
    for (int jb = 0; jb < cnt; jb += 16) {
      float e8[8]; unsigned p8[8];
      #pragma unroll
      for (int u = 0; u < 8; ++u) {
        int jj = jb + 2*u + slot;
        int svv; float evv;
        if (jj < cnt) { svv = sS[w][jj]; evv = sE[w][jj]; }
        else          { svv = 0; evv = 0.f; }
        e8[u] = evv;
        p8[u] = ypk[(size_t)svv*32 + l2];
      }
      #pragma unroll
      for (int u = 0; u < 8; ++u) {
        accx = fmaf(e8[u], bl(p8[u]), accx);
        accy = fmaf(e8[u], bh(p8[u]), accy);
      }
    }
  }
  #pragma unroll
  for (int sh = 32; sh > 0; sh >>= 1) ssum += __shfl_xor(ssum, sh, 64);
  accx += __shfl_xor(accx, 32, 64);
  accy += __shfl_xor(accy, 32, 64);
  float rs = frcp(ssum + 1e-16f);
  if (slot == 0) *(float2*)&hagg[d*64 + 2*l2] = make_float2(accx*rs, accy*rs);
}

// ===== GATConv fused: 2 edges per wave, bf16-packed hs, sorted src =====
__global__ __launch_bounds__(256) void k_conv_fused(const int* __restrict__ rowptr,
                                                    const int2* __restrict__ sorted,
                                                    const float* __restrict__ asn,
                                                    const float* __restrict__ adn,
                                                    const unsigned* __restrict__ hsb,
                                                    float* __restrict__ hagg) {
  __shared__ int   sS[4][64];
  __shared__ float sE[4][64];
  const int w = __builtin_amdgcn_readfirstlane(threadIdx.x >> 6);
  const int lane = threadIdx.x & 63;
  const int slot = lane >> 5, l2 = lane & 31;
  const int d = blockIdx.x*4 + w;
  const int r0 = __builtin_amdgcn_readfirstlane(rowptr[d]);
  const int r1 = __builtin_amdgcn_readfirstlane(rowptr[d+1]);
  float adnd = adn[d];
  float accx = 0.f, accy = 0.f, ssum = 0.f;
  for (int base = r0; base < r1; base += 64) {
    int i = base + lane;
    int cnt = r1 - base; if (cnt > 64) cnt = 64;
    float ev = 0.f; int s = 0;
    if (i < r1) { s = sorted[i].x & 0xffff; ev = fexp(lrelu(asn[s] + adnd)); }
    sS[w][lane] = s; sE[w][lane] = ev;
    ssum += ev;
    for (int jb = 0; jb < cnt; jb += 16) {
      float e8[8]; unsigned p8[8];
      #pragma unroll
      for (int u = 0; u < 8; ++u) {
        int jj = jb + 2*u + slot;
        int svv; float evv;
        if (jj < cnt) { svv = sS[w][jj]; evv = sE[w][jj]; }
        else          { svv = 0; evv = 0.f; }
        e8[u] = evv;
        p8[u] = hsb[(size_t)svv*32 + l2];
      }
      #pragma unroll
      for (int u = 0; u < 8; ++u) {
        accx = fmaf(e8[u], bl(p8[u]), accx);
        accy = fmaf(e8[u], bh(p8[u]), accy);
      }
    }
  }
  #pragma unroll
  for (int sh = 32; sh > 0; sh >>= 1) ssum += __shfl_xor(ssum, sh, 64);
  accx += __shfl_xor(accx, 32, 64);
  accy += __shfl_xor(accy, 32, 64);
  float rs = frcp(ssum + 1e-16f);
  if (slot == 0) *(float2*)&hagg[d*64 + 2*l2] = make_float2(accx*rs, accy*rs);
}

// ===== MFMA GRU: out = relu(GRU(elu(inp+pbias), hid)), wave = 16 nodes =====
__global__ __launch_bounds__(256) void k_gruM(const float* __restrict__ inp,
                                              const float* __restrict__ pbias,
                                              const float* __restrict__ hid,
                                              const unsigned short* __restrict__ wibf,
                                              const unsigned short* __restrict__ whbf,
                                              const float* __restrict__ bi,
                                              const float* __restrict__ bh2,
                                              float* __restrict__ out, int R) {
  const int lane = threadIdx.x & 63;
  const int l15 = lane & 15, lg = lane >> 4;
  const int n0 = blockIdx.x*64 + (threadIdx.x >> 6)*16;
  if (n0 >= R) return;
  union BF { bf16x8 v; unsigned u[4]; };
  BF Ai[2], Ah[2];
  const int arow = n0 + l15;
  const bool av = arow < R;
  const float* ibase = inp + (size_t)arow*64;
  const float* hbase = hid + (size_t)arow*64;
  #pragma unroll
  for (int c = 0; c < 2; ++c) {
    const int k0 = c*32 + lg*8;
    float4 p0 = *(const float4*)&pbias[k0];
    float4 p1 = *(const float4*)&pbias[k0+4];
    float4 v0, v1, h0, h1;
    if (av) {
      v0 = *(const float4*)&ibase[k0];   v1 = *(const float4*)&ibase[k0+4];
      h0 = *(const float4*)&hbase[k0];   h1 = *(const float4*)&hbase[k0+4];
    } else {
      v0 = v1 = h0 = h1 = make_float4(0.f,0.f,0.f,0.f);
      p0 = p1 = make_float4(0.f,0.f,0.f,0.f);
    }
    Ai[c].u[0] = pk_bf16(eluf(v0.x+p0.x), eluf(v0.y+p0.y));
    Ai[c].u[1] = pk_bf16(eluf(v0.z+p0.z), eluf(v0.w+p0.w));
    Ai[c].u[2] = pk_bf16(eluf(v1.x+p1.x), eluf(v1.y+p1.y));
    Ai[c].u[3] = pk_bf16(eluf(v1.z+p1.z), eluf(v1.w+p1.w));
    Ah[c].u[0] = pk_bf16(h0.x, h0.y);
    Ah[c].u[1] = pk_bf16(h0.z, h0.w);
    Ah[c].u[2] = pk_bf16(h1.x, h1.y);
    Ah[c].u[3] = pk_bf16(h1.z, h1.w);
  }
  f32x4 rz[8], ni[4], nh[4];
  #pragma unroll
  for (int t = 0; t < 8; ++t) rz[t] = (f32x4){0.f,0.f,0.f,0.f};
  #pragma unroll
  for (int t = 0; t < 4; ++t) { ni[t] = (f32x4){0.f,0.f,0.f,0.f}; nh[t] = (f32x4){0.f,0.f,0.f,0.f}; }
  #pragma unroll
  for (int t = 0; t < 12; ++t) {
    BF Bi0, Bi1, Bh0, Bh1;
    const size_t off = ((size_t)(t*16 + l15))*64 + lg*8;
    Bi0.v = *(const bf16x8*)&wibf[off];
    Bi1.v = *(const bf16x8*)&wibf[off + 32];
    Bh0.v = *(const bf16x8*)&whbf[off];
    Bh1.v = *(const bf16x8*)&whbf[off + 32];
    if (t < 8) {
      f32x4 a = rz[t];
      a = __builtin_amdgcn_mfma_f32_16x16x32_bf16(Ai[0].v, Bi0.v, a, 0, 0, 0);
      a = __builtin_amdgcn_mfma_f32_16x16x32_bf16(Ai[1].v, Bi1.v, a, 0, 0, 0);
      a = __builtin_amdgcn_mfma_f32_16x16x32_bf16(Ah[0].v, Bh0.v, a, 0, 0, 0);
      a = __builtin_amdgcn_mfma_f32_16x16x32_bf16(Ah[1].v, Bh1.v, a, 0, 0, 0);
      rz[t] = a;
    } else {
      f32x4 a = ni[t-8];
      a = __builtin_amdgcn_mfma_f32_16x16x32_bf16(Ai[0].v, Bi0.v, a, 0, 0, 0);
      a = __builtin_amdgcn_mfma_f32_16x16x32_bf16(Ai[1].v, Bi1.v, a, 0, 0, 0);
      ni[t-8] = a;
      f32x4 b = nh[t-8];
      b = __builtin_amdgcn_mfma_f32_16x16x32_bf16(Ah[0].v, Bh0.v, b, 0, 0, 0);
      b = __builtin_amdgcn_mfma_f32_16x16x32_bf16(Ah[1].v, Bh1.v, b, 0, 0, 0);
      nh[t-8] = b;
    }
  }
  float bsum[8], binv[4], bhnv[4];
  #pragma unroll
  for (int t = 0; t < 8; ++t) bsum[t] = bi[t*16+l15] + bh2[t*16+l15];
  #pragma unroll
  for (int t = 0; t < 4; ++t) {
    binv[t] = bi[128 + t*16 + l15];
    bhnv[t] = bh2[128 + t*16 + l15];
  }
  #pragma unroll
  for (int reg = 0; reg < 4; ++reg) {
    const int node = n0 + 4*lg + reg;
    if (node >= R) continue;
    #pragma unroll
    for (int tt = 0; tt < 4; ++tt) {
      float r  = sigm(rz[tt][reg] + bsum[tt]);
      float z  = sigm(rz[4+tt][reg] + bsum[4+tt]);
      float nn = ftanh(ni[tt][reg] + binv[tt] + r*(nh[tt][reg] + bhnv[tt]));
      float hh = hid[(size_t)node*64 + tt*16 + l15];
      float o  = (1.f - z)*nn + z*hh;
      out[(size_t)node*64 + tt*16 + l15] = fmaxf(o, 0.f);
    }
  }
}

// ================= molecule readout (CSR over sorted batch) =================
__global__ __launch_bounds__(256) void k_molsum_f(const int* __restrict__ gstart,
                                                  const float* __restrict__ x,
                                                  float* __restrict__ outg) {
  int g = blockIdx.x*4 + (threadIdx.x>>6);
  if (g >= NGRAPH) return;
  int lane = threadIdx.x & 63;
  float acc = 0.f;
  int n1 = gstart[g+1];
  for (int n = gstart[g]; n < n1; ++n) acc += x[n*64+lane];
  outg[g*64+lane] = fmaxf(acc, 0.f);
}

__global__ __launch_bounds__(256) void k_mol_fused(const int* __restrict__ gstart,
                                                   const float* __restrict__ outg,
                                                   const float* __restrict__ W,
                                                   const float* __restrict__ attd,
                                                   const float* __restrict__ asn,
                                                   const float* __restrict__ y,
                                                   float* __restrict__ hg) {
  __shared__ float wl[64*65];
  for (int idx = threadIdx.x; idx < 4096; idx += 256) wl[(idx>>6)*65+(idx&63)] = W[idx];
  __syncthreads();
  int g = blockIdx.x*4 + (threadIdx.x>>6);
  if (g >= NGRAPH) return;
  int lane = threadIdx.x & 63;
  float og = outg[g*64+lane];
  float hd = 0.f;
  #pragma unroll
  for (int k = 0; k < 64; ++k) hd += rdlane(og, k) * wl[lane*65+k];
  float p = hd * attd[lane];
  #pragma unroll
  for (int sh = 32; sh > 0; sh >>= 1) p += __shfl_xor(p, sh, 64);
  float addg = p;
  float acc = 0.f, ssum = 0.f;
  int n1 = gstart[g+1];
  for (int n = gstart[g]; n < n1; ++n) {
    float ev = fexp(lrelu(asn[n] + addg));
    acc += ev * y[n*64+lane];
    ssum += ev;
  }
  hg[g*64+lane] = acc * frcp(ssum + 1e-16f);
}

__global__ __launch_bounds__(128) void k_final(const float* __restrict__ outg,
                                               const float* __restrict__ W,
                                               const float* __restrict__ b,
                                               float* __restrict__ out) {
  __shared__ float og[64];
  int g = blockIdx.x;
  if (threadIdx.x < 64) og[threadIdx.x] = outg[g*64+threadIdx.x];
  __syncthreads();
  int o = threadIdx.x;
  float acc = b[o];
  for (int k = 0; k < 64; ++k) acc += og[k]*W[o*64+k];
  out[g*128+o] = acc;
}

extern "C" void kernel_launch(void* const* d_in, const int* in_sizes, int n_in,
                              void* d_out, int out_size, void* d_ws, size_t ws_size,
                              hipStream_t stream) {
  const float* x_in     = (const float*)d_in[0];
  const int*   eidx     = (const int*)  d_in[1];
  const float* eattr    = (const float*)d_in[2];
  const int*   batch    = (const int*)  d_in[3];
  const float* lin1_w   = (const float*)d_in[4];
  const float* lin1_b   = (const float*)d_in[5];
  const float* g_lin1_w = (const float*)d_in[6];
  const float* g_att_l  = (const float*)d_in[7];
  const float* g_att_r  = (const float*)d_in[8];
  const float* g_lin2_w = (const float*)d_in[9];
  const float* g_bias   = (const float*)d_in[10];
  const float* gru0_wi  = (const float*)d_in[11];
  const float* gru0_wh  = (const float*)d_in[12];
  const float* gru0_bi  = (const float*)d_in[13];
  const float* gru0_bh  = (const float*)d_in[14];
  const float* conv_lin_w   = (const float*)d_in[15];
  const float* conv_att_src = (const float*)d_in[16];
  const float* conv_att_dst = (const float*)d_in[17];
  const float* conv_bias    = (const float*)d_in[18];
  const float* grul_wi  = (const float*)d_in[19];
  const float* grul_wh  = (const float*)d_in[20];
  const float* grul_bi  = (const float*)d_in[21];
  const float* grul_bh  = (const float*)d_in[22];
  const float* mol_lin_w    = (const float*)d_in[23];
  const float* mol_att_src  = (const float*)d_in[24];
  const float* mol_att_dst  = (const float*)d_in[25];
  const float* mol_bias     = (const float*)d_in[26];
  const float* mgru_wi  = (const float*)d_in[27];
  const float* mgru_wh  = (const float*)d_in[28];
  const float* mgru_bi  = (const float*)d_in[29];
  const float* mgru_bh  = (const float*)d_in[30];
  const float* lin2_w   = (const float*)d_in[31];
  const float* lin2_b   = (const float*)d_in[32];

  const int N64 = N_NODES*64;
  float* ws     = (float*)d_ws;
  float* xA     = ws;               // N*64
  float* xB     = xA + N64;         // N*64
  float* uy     = xB + N64;         // 2*N64 region: ubf(ushort N*64)+ypk(uint N*32) / hsb / ymol
  float* hagg   = uy + 2*N64;       // N*64
  float* sc1    = hagg + N64;       // N
  float* sc2    = sc1 + N_NODES;    // N
  float* pbuf   = sc2 + N_NODES;    // E (edge scores, ORIGINAL order)
  float* outg   = pbuf + N_EDGES;   // G*64
  int* icnt   = (int*)(outg + NGRAPH*64); // N
  int* rowptr = icnt + N_NODES;     // N+2
  int2* binned = (int2*)(rowptr + N_NODES + 2); // E
  int2* sorted = binned + N_EDGES;  // E
  int* gstart = (int*)(sorted + N_EDGES); // G+1
  int* bsum   = gstart + NGRAPH+1;  // SB
  int* boff   = bsum + SB;          // SB
  int* bstart = boff + SB;          // NBKT+1
  int* bcur   = bstart + NBKT+1;    // NBKT
  unsigned short* wpk = (unsigned short*)(bcur + NBKT + 4); // 4 pairs * 2*192*64 bf16

  unsigned short* ubf = (unsigned short*)uy;       // N*64 bf16 u
  unsigned* ypk = (unsigned*)(uy + N64);           // N*32 packed y
  unsigned* hsb = (unsigned*)uy;                   // N*32 packed hs (reused after gate)

  const int* src = eidx;
  const int* dst = eidx + N_EDGES;

  const int nbN32 = (N_NODES + 31)/32;
  const int nbN4  = (N_NODES + 3)/4;
  const int nbN64 = (N_NODES + 63)/64;
  const int nbE   = (N_EDGES + 255)/256;
  const int nbG4  = (NGRAPH + 3)/4;
  const int nbES  = (N_EDGES/64 + 3)/4;   // escore: 64 edges per wave
  const int PAIR  = 2*192*64;             // ushorts per GRU pair

  // ---- CSR rowptr (hierarchical scan) ----
  hipMemsetAsync(icnt, 0, N_NODES*sizeof(int), stream);
  k_hist<<<nbE, 256, 0, stream>>>(dst, icnt);
  k_scanA<<<SB, 256, 0, stream>>>(icnt, bsum);
  k_scanB<<<1, 256, 0, stream>>>(bsum, boff, rowptr + N_NODES);
  k_scanC<<<SB, 256, 0, stream>>>(icnt, boff, rowptr);
  k_bstart<<<1, 256, 0, stream>>>(rowptr, bstart, bcur);
  k_gbound<<<1, 512, 0, stream>>>(batch, gstart);

  // ---- GRU weight prepack (bf16) ----
  k_wpack<<<(PAIR+255)/256, 256, 0, stream>>>(gru0_wi, gru0_wh, wpk);
  k_wpack<<<(PAIR+255)/256, 256, 0, stream>>>(grul_wi, grul_wh, wpk + PAIR);
  k_wpack<<<(PAIR+255)/256, 256, 0, stream>>>(grul_wi + 192*64, grul_wh + 192*64, wpk + 2*PAIR);
  k_wpack<<<(PAIR+255)/256, 256, 0, stream>>>(mgru_wi, mgru_wh, wpk + 3*PAIR);

  // ---- lin1 (+ fused xr = x.h @ g_att_r) ----
  k_lin1<<<nbN32, 256, 0, stream>>>(x_in, lin1_w, lin1_b, xA, g_att_r, sc1);

  // ---- GATEConv: scores in original order, then locality-aware bin sort ----
  k_mmdual<<<nbN32, 256, 0, stream>>>(xA, g_lin1_w, g_lin2_w, ubf, ypk, N_NODES);
  k_escore<<<nbES, 256, 0, stream>>>(src, eattr, g_lin1_w, g_att_l, ubf, pbuf);
  k_binA<<<(N_EDGES + BIN_BLK-1)/BIN_BLK, 1024, 0, stream>>>(dst, src, pbuf, bcur, binned);
  k_binB<<<NBKT, 1024, 0, stream>>>(rowptr, bstart, binned, sorted);
  k_gate_agg<<<nbN4, 256, 0, stream>>>(rowptr, sorted, sc1, ypk, hagg);
  k_gruM<<<nbN64, 256, 0, stream>>>(hagg, g_bias, xA, wpk, wpk + 192*64,
                                    gru0_bi, gru0_bh, xB, N_NODES);

  float* xcur = xB; float* xoth = xA;

  // ---- GATConv layers ----
  for (int l = 0; l < 2; ++l) {
    k_mm64<<<nbN32, 256, 0, stream>>>(xcur, conv_lin_w + l*64*64, 64, nullptr, hsb, N_NODES,
                                      conv_att_src + l*64, conv_att_dst + l*64, sc1, sc2);
    k_conv_fused<<<nbN4, 256, 0, stream>>>(rowptr, sorted, sc1, sc2, hsb, hagg);
    k_gruM<<<nbN64, 256, 0, stream>>>(hagg, conv_bias + l*64, xcur,
                                      wpk + (1+l)*PAIR, wpk + (1+l)*PAIR + 192*64,
                                      grul_bi + l*192, grul_bh + l*192, xoth, N_NODES);
    float* t = xcur; xcur = xoth; xoth = t;
  }

  // ---- molecule readout ----
  float* ymol = uy;  // fp32 N*64 reuse
  k_molsum_f<<<nbG4, 256, 0, stream>>>(gstart, xcur, outg);
  k_mm64<<<nbN32, 256, 0, stream>>>(xcur, mol_lin_w, 64, ymol, nullptr, N_NODES,
                                    mol_att_src, nullptr, sc1, nullptr);
  for (int t = 0; t < 2; ++t) {
    k_mol_fused<<<nbG4, 256, 0, stream>>>(gstart, outg, mol_lin_w, mol_att_dst, sc1, ymol, hagg);
    k_gruM<<<(NGRAPH+63)/64, 256, 0, stream>>>(hagg, mol_bias, outg,
                                               wpk + 3*PAIR, wpk + 3*PAIR + 192*64,
                                               mgru_bi, mgru_bh, outg, NGRAPH);
  }

  // ---- final linear ----
  k_final<<<NGRAPH, 128, 0, stream>>>(outg, lin2_w, lin2_b, (float*)d_out);
}

// Round 10
// 564.382 us; speedup vs baseline: 3.0766x; 1.0226x over previous
//
#include <hip/hip_runtime.h>
#include <math.h>

#define N_NODES 50000
#define N_EDGES 1000000
#define NGRAPH  512
#define INC     39
#define SB 200   // scan blocks
#define SC 250   // nodes per scan block (200*250 = 50000)
#define NBKT 196 // dst buckets of 256 nodes
#define BIN_BLK 4096

typedef __attribute__((ext_vector_type(8))) short bf16x8;
typedef __attribute__((ext_vector_type(4))) float f32x4;
typedef __attribute__((ext_vector_type(4))) int i32x4;

__device__ __forceinline__ float lrelu(float x){ return fmaxf(0.01f*x, x); }
__device__ __forceinline__ float fexp(float x){ return __builtin_amdgcn_exp2f(x*1.4426950408889634f); }
__device__ __forceinline__ float frcp(float x){ return __builtin_amdgcn_rcpf(x); }
__device__ __forceinline__ float eluf (float x){ return x > 0.f ? x : fexp(x) - 1.f; }
__device__ __forceinline__ float sigm (float x){ return frcp(1.f + fexp(-x)); }
__device__ __forceinline__ float ftanh(float x){
  x = fminf(fmaxf(x, -15.f), 15.f);
  float e = __builtin_amdgcn_exp2f(x*2.8853900817779268f); // exp(2x)
  return (e - 1.f)*frcp(e + 1.f);
}
__device__ __forceinline__ float rdlane(float v, int l){
  return __int_as_float(__builtin_amdgcn_readlane(__float_as_int(v), l));
}
__device__ __forceinline__ unsigned pk_bf16(float a, float b){
  unsigned r;
  asm volatile("v_cvt_pk_bf16_f32 %0, %1, %2" : "=v"(r) : "v"(a), "v"(b));
  return r;
}
__device__ __forceinline__ float bl(unsigned p){ return __uint_as_float(p << 16); }
__device__ __forceinline__ float bh(unsigned p){ return __uint_as_float(p & 0xffff0000u); }

// ================= CSR build =================
__global__ __launch_bounds__(256) void k_hist(const int* __restrict__ dst,
                                              int* __restrict__ cnt) {
  int e = blockIdx.x*256 + threadIdx.x;
  if (e < N_EDGES) atomicAdd(&cnt[dst[e]], 1);
}

__global__ __launch_bounds__(256) void k_scanA(const int* __restrict__ cnt,
                                               int* __restrict__ bsum) {
  __shared__ int s[256];
  int t = threadIdx.x, b = blockIdx.x;
  int v = (t < SC) ? cnt[b*SC + t] : 0;
  s[t] = v; __syncthreads();
  for (int off = 128; off > 0; off >>= 1) {
    if (t < off) s[t] += s[t+off];
    __syncthreads();
  }
  if (t == 0) bsum[b] = s[0];
}

__global__ __launch_bounds__(256) void k_scanB(const int* __restrict__ bsum,
                                               int* __restrict__ boff,
                                               int* __restrict__ rowptrN) {
  __shared__ int s[256];
  int t = threadIdx.x;
  int v = (t < SB) ? bsum[t] : 0;
  s[t] = v; __syncthreads();
  for (int off = 1; off < 256; off <<= 1) {
    int x = (t >= off) ? s[t-off] : 0;
    __syncthreads();
    s[t] += x;
    __syncthreads();
  }
  if (t < SB) boff[t] = s[t] - v;   // exclusive prefix
  if (t == 0) rowptrN[0] = N_EDGES; // rowptr[N_NODES]
}

__global__ __launch_bounds__(256) void k_scanC(const int* __restrict__ cnt,
                                               const int* __restrict__ boff,
                                               int* __restrict__ rowptr) {
  __shared__ int s[256];
  int t = threadIdx.x, b = blockIdx.x;
  int idx = b*SC + t;
  int v = (t < SC) ? cnt[idx] : 0;
  s[t] = v; __syncthreads();
  for (int off = 1; off < 256; off <<= 1) {
    int x = (t >= off) ? s[t-off] : 0;
    __syncthreads();
    s[t] += x;
    __syncthreads();
  }
  if (t < SC) rowptr[idx] = boff[b] + s[t] - v;
}

__global__ __launch_bounds__(256) void k_bstart(const int* __restrict__ rowptr,
                                                int* __restrict__ bstart,
                                                int* __restrict__ bcur) {
  int b = threadIdx.x;
  if (b <= NBKT) {
    int idx = b*256; if (idx > N_NODES) idx = N_NODES;
    int v = rowptr[idx];
    bstart[b] = v;
    if (b < NBKT) bcur[b] = v;
  }
}

// ===== Pass A: bin edges into 196 coarse buckets (locality-friendly runs) =====
__global__ __launch_bounds__(1024) void k_binA(const int* __restrict__ dst,
                                               const int* __restrict__ src,
                                               const float* __restrict__ p,
                                               int* __restrict__ bcur,
                                               int2* __restrict__ binned) {
  __shared__ int lcnt[NBKT];
  __shared__ int lbase[NBKT];
  __shared__ int gbase[NBKT];
  __shared__ int tmp[256];
  __shared__ int totsh;
  __shared__ int2 stage[BIN_BLK];
  const int t = threadIdx.x;
  const int e0 = blockIdx.x * BIN_BLK;
  for (int i = t; i < NBKT; i += 1024) lcnt[i] = 0;
  __syncthreads();
  int myb[4], myr[4], myd[4], mys[4]; float myp[4];
  #pragma unroll
  for (int u = 0; u < 4; ++u) {
    int e = e0 + u*1024 + t;
    if (e < N_EDGES) {
      int d = dst[e];
      myd[u] = d; mys[u] = src[e]; myp[u] = p[e];
      int b = d >> 8;
      myb[u] = b;
      myr[u] = atomicAdd(&lcnt[b], 1);
    } else myb[u] = -1;
  }
  __syncthreads();
  if (t < 256) tmp[t] = (t < NBKT) ? lcnt[t] : 0;
  __syncthreads();
  for (int off = 1; off < 256; off <<= 1) {
    int v = (t >= off && t < 256) ? tmp[t-off] : 0;
    __syncthreads();
    if (t < 256) tmp[t] += v;
    __syncthreads();
  }
  if (t < NBKT) lbase[t] = tmp[t] - lcnt[t];
  if (t == NBKT-1) totsh = tmp[t];
  if (t < NBKT && lcnt[t] > 0) gbase[t] = atomicAdd(&bcur[t], lcnt[t]);
  __syncthreads();
  #pragma unroll
  for (int u = 0; u < 4; ++u) {
    if (myb[u] >= 0) {
      int x = (mys[u] & 0xffff) | ((myd[u] & 255) << 16) | (myb[u] << 24);
      stage[lbase[myb[u]] + myr[u]] = make_int2(x, __float_as_int(myp[u]));
    }
  }
  __syncthreads();
  const int tot = totsh;
  for (int i = t; i < tot; i += 1024) {
    int2 r = stage[i];
    int b = (unsigned)r.x >> 24;
    binned[gbase[b] + (i - lbase[b])] = r;
  }
}

// ===== Pass B: sort each bucket to final CSR order (contiguous window) =====
__global__ __launch_bounds__(1024) void k_binB(const int* __restrict__ rowptr,
                                               const int* __restrict__ bstart,
                                               const int2* __restrict__ binned,
                                               int2* __restrict__ sorted) {
  __shared__ int lcnt[256];
  const int b = blockIdx.x;
  const int base = bstart[b], end = bstart[b+1];
  const int t = threadIdx.x;
  if (t < 256) lcnt[t] = 0;
  __syncthreads();
  for (int i = base + t; i < end; i += 1024) {
    int2 r = binned[i];
    int dlow = (r.x >> 16) & 255;
    int rank = atomicAdd(&lcnt[dlow], 1);
    int pos = rowptr[b*256 + dlow] + rank;
    sorted[pos] = r;
  }
}

__global__ __launch_bounds__(512) void k_gbound(const int* __restrict__ batch,
                                                int* __restrict__ gstart) {
  int g = threadIdx.x;
  int lo = 0, hi = N_NODES;
  while (lo < hi) { int mid = (lo+hi)>>1; if (batch[mid] < g) lo = mid+1; else hi = mid; }
  gstart[g] = lo;
  if (g == 0) gstart[NGRAPH] = N_NODES;
}

// ================= bf16 weight prepack: wi,wh [192][64] each =================
__global__ __launch_bounds__(256) void k_wpack(const float* __restrict__ wi,
                                               const float* __restrict__ wh,
                                               unsigned short* __restrict__ o) {
  int i = blockIdx.x*256 + threadIdx.x;
  if (i < 192*64)      o[i]          = (unsigned short)(pk_bf16(wi[i], 0.f) & 0xffffu);
  else if (i < 2*192*64) o[i]        = (unsigned short)(pk_bf16(wh[i - 192*64], 0.f) & 0xffffu);
}

// ================= lin1: K=39, fused per-row dot with v1 =================
__global__ __launch_bounds__(256) void k_lin1(const float* __restrict__ x,
                                              const float* __restrict__ W,
                                              const float* __restrict__ b,
                                              float* __restrict__ out,
                                              const float* __restrict__ v1,
                                              float* __restrict__ o1) {
  __shared__ float wl[64*41];
  for (int idx = threadIdx.x; idx < 64*INC; idx += 256) {
    int r = idx / INC, c = idx - r*INC;
    wl[r*41+c] = W[idx];
  }
  __syncthreads();
  const int lane = threadIdx.x & 63;
  const int base = blockIdx.x*32 + (threadIdx.x>>6)*8;
  float h[8];
  #pragma unroll
  for (int i = 0; i < 8; ++i) {
    int n = base + i;
    h[i] = (n < N_NODES && lane < INC) ? x[n*INC + lane] : 0.f;
  }
  float acc[8] = {0,0,0,0,0,0,0,0};
  #pragma unroll
  for (int k = 0; k < INC; ++k) {
    float wv = wl[lane*41+k];
    #pragma unroll
    for (int i = 0; i < 8; ++i) acc[i] += rdlane(h[i], k) * wv;
  }
  float bb = b[lane];
  float attv = v1[lane];
  #pragma unroll
  for (int i = 0; i < 8; ++i) {
    int n = base + i;
    if (n >= N_NODES) continue;
    float val = lrelu(acc[i] + bb);
    out[n*64+lane] = val;
    float p = val * attv;
    #pragma unroll
    for (int s2 = 32; s2 > 0; s2 >>= 1) p += __shfl_xor(p, s2, 64);
    if (lane == 0) o1[n] = p;
  }
}

// ========== dual matmul -> u as bf16 [N][64] ushort, y packed 2ch/dword [N][32] ==========
__global__ __launch_bounds__(256) void k_mmdual(const float* __restrict__ in,
                                                const float* __restrict__ W1, // [64][80]
                                                const float* __restrict__ W2, // [64][64]
                                                unsigned short* __restrict__ ubf,
                                                unsigned* __restrict__ ypk, int R) {
  __shared__ float wl[128*65];
  for (int idx = threadIdx.x; idx < 4096; idx += 256) {
    int r = idx >> 6, c = idx & 63;
    wl[r*65+c]      = W1[r*80 + c];
    wl[(64+r)*65+c] = W2[r*64 + c];
  }
  __syncthreads();
  const int lane = threadIdx.x & 63;
  const int base = blockIdx.x*32 + (threadIdx.x>>6)*8;
  float h[8];
  #pragma unroll
  for (int i = 0; i < 8; ++i) { int n = base+i; h[i] = (n < R) ? in[n*64+lane] : 0.f; }
  float accU[8] = {0,0,0,0,0,0,0,0};
  float accY[8] = {0,0,0,0,0,0,0,0};
  for (int k = 0; k < 64; ++k) {
    float wu = wl[lane*65+k], wy = wl[(64+lane)*65+k];
    #pragma unroll
    for (int i = 0; i < 8; ++i) {
      float hk = rdlane(h[i], k);
      accU[i] += hk*wu; accY[i] += hk*wy;
    }
  }
  #pragma unroll
  for (int i = 0; i < 8; ++i) {
    int n = base+i; if (n >= R) continue;
    ubf[n*64 + lane] = (unsigned short)(pk_bf16(accU[i], 0.f) & 0xffffu);
    float partner = __shfl_xor(accY[i], 1, 64);
    if (!(lane & 1)) ypk[n*32 + (lane>>1)] = pk_bf16(accY[i], partner);
  }
}

// ========== [R,64] @ W.T; optional packed-bf16 pair table + fused per-row dots ==========
__global__ __launch_bounds__(256) void k_mm64(const float* __restrict__ in,
                                              const float* __restrict__ W, int rs,
                                              float* __restrict__ out,
                                              unsigned* __restrict__ outp, int R,
                                              const float* __restrict__ v1,
                                              const float* __restrict__ v2,
                                              float* __restrict__ o1,
                                              float* __restrict__ o2) {
  __shared__ float wl[64*65];
  for (int idx = threadIdx.x; idx < 4096; idx += 256) {
    int r = idx >> 6, c = idx & 63;
    wl[r*65+c] = W[r*rs + c];
  }
  __syncthreads();
  const int lane = threadIdx.x & 63;
  const int base = blockIdx.x*32 + (threadIdx.x>>6)*8;
  float h[8];
  #pragma unroll
  for (int i = 0; i < 8; ++i) { int n = base+i; h[i] = (n < R) ? in[n*64+lane] : 0.f; }
  float acc[8] = {0,0,0,0,0,0,0,0};
  for (int k = 0; k < 64; ++k) {
    float wv = wl[lane*65+k];
    #pragma unroll
    for (int i = 0; i < 8; ++i) acc[i] += rdlane(h[i], k) * wv;
  }
  float v1v = v1 ? v1[lane] : 0.f;
  float v2v = v2 ? v2[lane] : 0.f;
  #pragma unroll
  for (int i = 0; i < 8; ++i) {
    int n = base+i; if (n >= R) continue;
    if (out) out[n*64+lane] = acc[i];
    if (outp) {
      float partner = __shfl_xor(acc[i], 1, 64);   // lane 2c gets ch 2c+1
      if ((lane & 1) == 0) outp[n*32 + (lane>>1)] = pk_bf16(acc[i], partner);
    }
    if (o1) {
      float p1 = acc[i]*v1v;
      float p2 = acc[i]*v2v;
      #pragma unroll
      for (int s2 = 32; s2 > 0; s2 >>= 1) { p1 += __shfl_xor(p1, s2, 64); p2 += __shfl_xor(p2, s2, 64); }
      if (lane == 0) { o1[n] = p1; if (o2) o2[n] = p2; }
    }
  }
}

// ===== GATE edge scores, original order, software-pipelined u-gathers + NT streaming =====
__global__ __launch_bounds__(256) void k_escore(const int* __restrict__ srcarr,
                                                const float* __restrict__ ea,
                                                const float* __restrict__ glin1, // [64][80]
                                                const float* __restrict__ attl,
                                                const unsigned short* __restrict__ ubf,
                                                float* __restrict__ pout) {
  const int lane = threadIdx.x & 63;
  const int l15 = lane & 15, lg = lane >> 4;
  const int gw = blockIdx.x*4 + (threadIdx.x >> 6);
  if (gw >= N_EDGES/64) return;
  float attlv[4];
  unsigned Bu[4][2];
  #pragma unroll
  for (int c = 0; c < 4; ++c) {
    const float4 b = *(const float4*)&glin1[(c*16 + l15)*80 + 64 + lg*4];
    Bu[c][0] = pk_bf16(b.x, b.y);
    Bu[c][1] = pk_bf16(b.z, b.w);
    attlv[c] = attl[c*16 + l15];
  }
  const int i0 = gw*64;
  // ---- prefetch ALL indices and ea tiles ----
  i32x4 sv[4];
  #pragma unroll
  for (int it = 0; it < 4; ++it)
    sv[it] = *(const i32x4*)&srcarr[i0 + it*16 + 4*lg];
  f32x4 a[4];
  #pragma unroll
  for (int it = 0; it < 4; ++it)
    a[it] = __builtin_nontemporal_load((const f32x4*)&ea[(size_t)(i0 + it*16 + l15)*16 + lg*4]);
  // ---- double-buffered u-gathers: issue tile it+1's gathers before tile it's compute ----
  unsigned short ug0[4][4], ug1[4][4];
  #pragma unroll
  for (int c = 0; c < 4; ++c)
    #pragma unroll
    for (int r = 0; r < 4; ++r)
      ug0[c][r] = ubf[(size_t)sv[0][r]*64 + c*16 + l15];
  #pragma unroll
  for (int it = 0; it < 4; ++it) {
    // issue next tile's gathers
    if (it + 1 < 4) {
      #pragma unroll
      for (int c = 0; c < 4; ++c)
        #pragma unroll
        for (int r = 0; r < 4; ++r)
          ug1[c][r] = ubf[(size_t)sv[it+1][r]*64 + c*16 + l15];
    }
    union { bf16x8 v; unsigned u[4]; } A;
    A.u[0] = pk_bf16(a[it][0], a[it][1]);
    A.u[1] = pk_bf16(a[it][2], a[it][3]);
    A.u[2] = 0; A.u[3] = 0;
    float p[4] = {0.f,0.f,0.f,0.f};
    #pragma unroll
    for (int c = 0; c < 4; ++c) {
      union { bf16x8 v; unsigned u[4]; } B;
      B.u[0] = Bu[c][0]; B.u[1] = Bu[c][1]; B.u[2] = 0; B.u[3] = 0;
      f32x4 z = {0.f,0.f,0.f,0.f};
      f32x4 acc = __builtin_amdgcn_mfma_f32_16x16x32_bf16(A.v, B.v, z, 0, 0, 0);
      #pragma unroll
      for (int r = 0; r < 4; ++r) {
        float t = lrelu(__uint_as_float(((unsigned)ug0[c][r]) << 16) + acc[r]);
        p[r] = fmaf(t, attlv[c], p[r]);
      }
    }
    #pragma unroll
    for (int r = 0; r < 4; ++r) {
      p[r] += __shfl_xor(p[r], 1, 64);
      p[r] += __shfl_xor(p[r], 2, 64);
      p[r] += __shfl_xor(p[r], 4, 64);
      p[r] += __shfl_xor(p[r], 8, 64);
    }
    if (l15 == 0) {
      f32x4 o = {p[0], p[1], p[2], p[3]};
      __builtin_nontemporal_store(o, (f32x4*)&pout[i0 + it*16 + 4*lg]);
    }
    // rotate buffers (compile-time after full unroll)
    #pragma unroll
    for (int c = 0; c < 4; ++c)
      #pragma unroll
      for (int r = 0; r < 4; ++r)
        ug0[c][r] = ug1[c][r];
  }
}

// ===== GATE aggregation: sorted records {src|dlow|bkt, p}, bf16-packed y gathers =====
__global__ __launch_bounds__(256) void k_gate_agg(const int* __restrict__ rowptr,
                                                  const int2* __restrict__ sorted,
                                                  const float* __restrict__ xr,
                                                  const unsigned* __restrict__ ypk,
                                                  float* __restrict__ hagg) {
  __shared__ int   sS[4][64];
  __shared__ float sE[4][64];
  const int w = __builtin_amdgcn_readfirstlane(threadIdx.x >> 6);
  const int lane = threadIdx.x & 63;
  const int slot = lane >> 5, l2 = lane & 31;
  const int d = blockIdx.x*4 + w;
  const int r0 = __builtin_amdgcn_readfirstlane(rowptr[d]);
  const int r1 = __builtin_amdgcn_readfirstlane(rowptr[d+1]);
  const float xrd = xr[d];
  float accx = 0.f, accy = 0.f, ssum = 0.f;
  for (int base = r0; base < r1; base += 64) {
    int i = base + lane;
    int cnt = r1 - base; if (cnt > 64) cnt = 64;
    float ev = 0.f; int s = 0;
    if (i < r1) {
      int2 r = sorted[i];
      s = r.x & 0xffff;
      ev = fexp(lrelu(__int_as_float(r.y) + xrd));
    }
    sS[w][lane] = s; sE[w][lane] = ev;
    ssum += ev;
    for (int jb = 0; jb < cnt; jb += 16) {
      float e8[8]; unsigned p8[8];
      #pragma unroll
      for (int u = 0; u < 8; ++u) {
        int jj = jb + 2*u + slot;
        int svv; float evv;
        if (jj < cnt) { svv = sS[w][jj]; evv = sE[w][jj]; }
        else          { svv = 0; evv = 0.f; }
        e8[u] = evv;
        p8[u] = ypk[(size_t)svv*32 + l2];
      }
      #pragma unroll
      for (int u = 0; u < 8; ++u) {
        accx = fmaf(e8[u], bl(p8[u]), accx);
        accy = fmaf(e8[u], bh(p8[u]), accy);
      }
    }
  }
  #pragma unroll
  for (int sh = 32; sh > 0; sh >>= 1) ssum += __shfl_xor(ssum, sh, 64);
  accx += __shfl_xor(accx, 32, 64);
  accy += __shfl_xor(accy, 32, 64);
  float rs = frcp(ssum + 1e-16f);
  if (slot == 0) *(float2*)&hagg[d*64 + 2*l2] = make_float2(accx*rs, accy*rs);
}

// ===== GATConv fused: 2 edges per wave, bf16-packed hs, sorted src =====
__global__ __launch_bounds__(256) void k_conv_fused(const int* __restrict__ rowptr,
                                                    const int2* __restrict__ sorted,
                                                    const float* __restrict__ asn,
                                                    const float* __restrict__ adn,
                                                    const unsigned* __restrict__ hsb,
                                                    float* __restrict__ hagg) {
  __shared__ int   sS[4][64];
  __shared__ float sE[4][64];
  const int w = __builtin_amdgcn_readfirstlane(threadIdx.x >> 6);
  const int lane = threadIdx.x & 63;
  const int slot = lane >> 5, l2 = lane & 31;
  const int d = blockIdx.x*4 + w;
  const int r0 = __builtin_amdgcn_readfirstlane(rowptr[d]);
  const int r1 = __builtin_amdgcn_readfirstlane(rowptr[d+1]);
  float adnd = adn[d];
  float accx = 0.f, accy = 0.f, ssum = 0.f;
  for (int base = r0; base < r1; base += 64) {
    int i = base + lane;
    int cnt = r1 - base; if (cnt > 64) cnt = 64;
    float ev = 0.f; int s = 0;
    if (i < r1) { s = sorted[i].x & 0xffff; ev = fexp(lrelu(asn[s] + adnd)); }
    sS[w][lane] = s; sE[w][lane] = ev;
    ssum += ev;
    for (int jb = 0; jb < cnt; jb += 16) {
      float e8[8]; unsigned p8[8];
      #pragma unroll
      for (int u = 0; u < 8; ++u) {
        int jj = jb + 2*u + slot;
        int svv; float evv;
        if (jj < cnt) { svv = sS[w][jj]; evv = sE[w][jj]; }
        else          { svv = 0; evv = 0.f; }
        e8[u] = evv;
        p8[u] = hsb[(size_t)svv*32 + l2];
      }
      #pragma unroll
      for (int u = 0; u < 8; ++u) {
        accx = fmaf(e8[u], bl(p8[u]), accx);
        accy = fmaf(e8[u], bh(p8[u]), accy);
      }
    }
  }
  #pragma unroll
  for (int sh = 32; sh > 0; sh >>= 1) ssum += __shfl_xor(ssum, sh, 64);
  accx += __shfl_xor(accx, 32, 64);
  accy += __shfl_xor(accy, 32, 64);
  float rs = frcp(ssum + 1e-16f);
  if (slot == 0) *(float2*)&hagg[d*64 + 2*l2] = make_float2(accx*rs, accy*rs);
}

// ===== MFMA GRU: out = relu(GRU(elu(inp+pbias), hid)), wave = 16 nodes =====
__global__ __launch_bounds__(256) void k_gruM(const float* __restrict__ inp,
                                              const float* __restrict__ pbias,
                                              const float* __restrict__ hid,
                                              const unsigned short* __restrict__ wibf,
                                              const unsigned short* __restrict__ whbf,
                                              const float* __restrict__ bi,
                                              const float* __restrict__ bh2,
                                              float* __restrict__ out, int R) {
  const int lane = threadIdx.x & 63;
  const int l15 = lane & 15, lg = lane >> 4;
  const int n0 = blockIdx.x*64 + (threadIdx.x >> 6)*16;
  if (n0 >= R) return;
  union BF { bf16x8 v; unsigned u[4]; };
  BF Ai[2], Ah[2];
  const int arow = n0 + l15;
  const bool av = arow < R;
  const float* ibase = inp + (size_t)arow*64;
  const float* hbase = hid + (size_t)arow*64;
  #pragma unroll
  for (int c = 0; c < 2; ++c) {
    const int k0 = c*32 + lg*8;
    float4 p0 = *(const float4*)&pbias[k0];
    float4 p1 = *(const float4*)&pbias[k0+4];
    float4 v0, v1, h0, h1;
    if (av) {
      v0 = *(const float4*)&ibase[k0];   v1 = *(const float4*)&ibase[k0+4];
      h0 = *(const float4*)&hbase[k0];   h1 = *(const float4*)&hbase[k0+4];
    } else {
      v0 = v1 = h0 = h1 = make_float4(0.f,0.f,0.f,0.f);
      p0 = p1 = make_float4(0.f,0.f,0.f,0.f);
    }
    Ai[c].u[0] = pk_bf16(eluf(v0.x+p0.x), eluf(v0.y+p0.y));
    Ai[c].u[1] = pk_bf16(eluf(v0.z+p0.z), eluf(v0.w+p0.w));
    Ai[c].u[2] = pk_bf16(eluf(v1.x+p1.x), eluf(v1.y+p1.y));
    Ai[c].u[3] = pk_bf16(eluf(v1.z+p1.z), eluf(v1.w+p1.w));
    Ah[c].u[0] = pk_bf16(h0.x, h0.y);
    Ah[c].u[1] = pk_bf16(h0.z, h0.w);
    Ah[c].u[2] = pk_bf16(h1.x, h1.y);
    Ah[c].u[3] = pk_bf16(h1.z, h1.w);
  }
  f32x4 rz[8], ni[4], nh[4];
  #pragma unroll
  for (int t = 0; t < 8; ++t) rz[t] = (f32x4){0.f,0.f,0.f,0.f};
  #pragma unroll
  for (int t = 0; t < 4; ++t) { ni[t] = (f32x4){0.f,0.f,0.f,0.f}; nh[t] = (f32x4){0.f,0.f,0.f,0.f}; }
  #pragma unroll
  for (int t = 0; t < 12; ++t) {
    BF Bi0, Bi1, Bh0, Bh1;
    const size_t off = ((size_t)(t*16 + l15))*64 + lg*8;
    Bi0.v = *(const bf16x8*)&wibf[off];
    Bi1.v = *(const bf16x8*)&wibf[off + 32];
    Bh0.v = *(const bf16x8*)&whbf[off];
    Bh1.v = *(const bf16x8*)&whbf[off + 32];
    if (t < 8) {
      f32x4 a = rz[t];
      a = __builtin_amdgcn_mfma_f32_16x16x32_bf16(Ai[0].v, Bi0.v, a, 0, 0, 0);
      a = __builtin_amdgcn_mfma_f32_16x16x32_bf16(Ai[1].v, Bi1.v, a, 0, 0, 0);
      a = __builtin_amdgcn_mfma_f32_16x16x32_bf16(Ah[0].v, Bh0.v, a, 0, 0, 0);
      a = __builtin_amdgcn_mfma_f32_16x16x32_bf16(Ah[1].v, Bh1.v, a, 0, 0, 0);
      rz[t] = a;
    } else {
      f32x4 a = ni[t-8];
      a = __builtin_amdgcn_mfma_f32_16x16x32_bf16(Ai[0].v, Bi0.v, a, 0, 0, 0);
      a = __builtin_amdgcn_mfma_f32_16x16x32_bf16(Ai[1].v, Bi1.v, a, 0, 0, 0);
      ni[t-8] = a;
      f32x4 b = nh[t-8];
      b = __builtin_amdgcn_mfma_f32_16x16x32_bf16(Ah[0].v, Bh0.v, b, 0, 0, 0);
      b = __builtin_amdgcn_mfma_f32_16x16x32_bf16(Ah[1].v, Bh1.v, b, 0, 0, 0);
      nh[t-8] = b;
    }
  }
  float bsum[8], binv[4], bhnv[4];
  #pragma unroll
  for (int t = 0; t < 8; ++t) bsum[t] = bi[t*16+l15] + bh2[t*16+l15];
  #pragma unroll
  for (int t = 0; t < 4; ++t) {
    binv[t] = bi[128 + t*16 + l15];
    bhnv[t] = bh2[128 + t*16 + l15];
  }
  #pragma unroll
  for (int reg = 0; reg < 4; ++reg) {
    const int node = n0 + 4*lg + reg;
    if (node >= R) continue;
    #pragma unroll
    for (int tt = 0; tt < 4; ++tt) {
      float r  = sigm(rz[tt][reg] + bsum[tt]);
      float z  = sigm(rz[4+tt][reg] + bsum[4+tt]);
      float nn = ftanh(ni[tt][reg] + binv[tt] + r*(nh[tt][reg] + bhnv[tt]));
      float hh = hid[(size_t)node*64 + tt*16 + l15];
      float o  = (1.f - z)*nn + z*hh;
      out[(size_t)node*64 + tt*16 + l15] = fmaxf(o, 0.f);
    }
  }
}

// ================= molecule readout (CSR over sorted batch) =================
__global__ __launch_bounds__(256) void k_molsum_f(const int* __restrict__ gstart,
                                                  const float* __restrict__ x,
                                                  float* __restrict__ outg) {
  int g = blockIdx.x*4 + (threadIdx.x>>6);
  if (g >= NGRAPH) return;
  int lane = threadIdx.x & 63;
  float acc = 0.f;
  int n1 = gstart[g+1];
  for (int n = gstart[g]; n < n1; ++n) acc += x[n*64+lane];
  outg[g*64+lane] = fmaxf(acc, 0.f);
}

__global__ __launch_bounds__(256) void k_mol_fused(const int* __restrict__ gstart,
                                                   const float* __restrict__ outg,
                                                   const float* __restrict__ W,
                                                   const float* __restrict__ attd,
                                                   const float* __restrict__ asn,
                                                   const float* __restrict__ y,
                                                   float* __restrict__ hg) {
  __shared__ float wl[64*65];
  for (int idx = threadIdx.x; idx < 4096; idx += 256) wl[(idx>>6)*65+(idx&63)] = W[idx];
  __syncthreads();
  int g = blockIdx.x*4 + (threadIdx.x>>6);
  if (g >= NGRAPH) return;
  int lane = threadIdx.x & 63;
  float og = outg[g*64+lane];
  float hd = 0.f;
  #pragma unroll
  for (int k = 0; k < 64; ++k) hd += rdlane(og, k) * wl[lane*65+k];
  float p = hd * attd[lane];
  #pragma unroll
  for (int sh = 32; sh > 0; sh >>= 1) p += __shfl_xor(p, sh, 64);
  float addg = p;
  float acc = 0.f, ssum = 0.f;
  int n1 = gstart[g+1];
  for (int n = gstart[g]; n < n1; ++n) {
    float ev = fexp(lrelu(asn[n] + addg));
    acc += ev * y[n*64+lane];
    ssum += ev;
  }
  hg[g*64+lane] = acc * frcp(ssum + 1e-16f);
}

__global__ __launch_bounds__(128) void k_final(const float* __restrict__ outg,
                                               const float* __restrict__ W,
                                               const float* __restrict__ b,
                                               float* __restrict__ out) {
  __shared__ float og[64];
  int g = blockIdx.x;
  if (threadIdx.x < 64) og[threadIdx.x] = outg[g*64+threadIdx.x];
  __syncthreads();
  int o = threadIdx.x;
  float acc = b[o];
  for (int k = 0; k < 64; ++k) acc += og[k]*W[o*64+k];
  out[g*128+o] = acc;
}

extern "C" void kernel_launch(void* const* d_in, const int* in_sizes, int n_in,
                              void* d_out, int out_size, void* d_ws, size_t ws_size,
                              hipStream_t stream) {
  const float* x_in     = (const float*)d_in[0];
  const int*   eidx     = (const int*)  d_in[1];
  const float* eattr    = (const float*)d_in[2];
  const int*   batch    = (const int*)  d_in[3];
  const float* lin1_w   = (const float*)d_in[4];
  const float* lin1_b   = (const float*)d_in[5];
  const float* g_lin1_w = (const float*)d_in[6];
  const float* g_att_l  = (const float*)d_in[7];
  const float* g_att_r  = (const float*)d_in[8];
  const float* g_lin2_w = (const float*)d_in[9];
  const float* g_bias   = (const float*)d_in[10];
  const float* gru0_wi  = (const float*)d_in[11];
  const float* gru0_wh  = (const float*)d_in[12];
  const float* gru0_bi  = (const float*)d_in[13];
  const float* gru0_bh  = (const float*)d_in[14];
  const float* conv_lin_w   = (const float*)d_in[15];
  const float* conv_att_src = (const float*)d_in[16];
  const float* conv_att_dst = (const float*)d_in[17];
  const float* conv_bias    = (const float*)d_in[18];
  const float* grul_wi  = (const float*)d_in[19];
  const float* grul_wh  = (const float*)d_in[20];
  const float* grul_bi  = (const float*)d_in[21];
  const float* grul_bh  = (const float*)d_in[22];
  const float* mol_lin_w    = (const float*)d_in[23];
  const float* mol_att_src  = (const float*)d_in[24];
  const float* mol_att_dst  = (const float*)d_in[25];
  const float* mol_bias     = (const float*)d_in[26];
  const float* mgru_wi  = (const float*)d_in[27];
  const float* mgru_wh  = (const float*)d_in[28];
  const float* mgru_bi  = (const float*)d_in[29];
  const float* mgru_bh  = (const float*)d_in[30];
  const float* lin2_w   = (const float*)d_in[31];
  const float* lin2_b   = (const float*)d_in[32];

  const int N64 = N_NODES*64;
  float* ws     = (float*)d_ws;
  float* xA     = ws;               // N*64
  float* xB     = xA + N64;         // N*64
  float* uy     = xB + N64;         // 2*N64 region: ubf(ushort N*64)+ypk(uint N*32) / hsb / ymol
  float* hagg   = uy + 2*N64;       // N*64
  float* sc1    = hagg + N64;       // N
  float* sc2    = sc1 + N_NODES;    // N
  float* pbuf   = sc2 + N_NODES;    // E (edge scores, ORIGINAL order)
  float* outg   = pbuf + N_EDGES;   // G*64
  int* icnt   = (int*)(outg + NGRAPH*64); // N
  int* rowptr = icnt + N_NODES;     // N+2
  int2* binned = (int2*)(rowptr + N_NODES + 2); // E
  int2* sorted = binned + N_EDGES;  // E
  int* gstart = (int*)(sorted + N_EDGES); // G+1
  int* bsum   = gstart + NGRAPH+1;  // SB
  int* boff   = bsum + SB;          // SB
  int* bstart = boff + SB;          // NBKT+1
  int* bcur   = bstart + NBKT+1;    // NBKT
  unsigned short* wpk = (unsigned short*)(bcur + NBKT + 4); // 4 pairs * 2*192*64 bf16

  unsigned short* ubf = (unsigned short*)uy;       // N*64 bf16 u
  unsigned* ypk = (unsigned*)(uy + N64);           // N*32 packed y
  unsigned* hsb = (unsigned*)uy;                   // N*32 packed hs (reused after gate)

  const int* src = eidx;
  const int* dst = eidx + N_EDGES;

  const int nbN32 = (N_NODES + 31)/32;
  const int nbN4  = (N_NODES + 3)/4;
  const int nbN64 = (N_NODES + 63)/64;
  const int nbE   = (N_EDGES + 255)/256;
  const int nbG4  = (NGRAPH + 3)/4;
  const int nbES  = (N_EDGES/64 + 3)/4;   // escore: 64 edges per wave
  const int PAIR  = 2*192*64;             // ushorts per GRU pair

  // ---- CSR rowptr (hierarchical scan) ----
  hipMemsetAsync(icnt, 0, N_NODES*sizeof(int), stream);
  k_hist<<<nbE, 256, 0, stream>>>(dst, icnt);
  k_scanA<<<SB, 256, 0, stream>>>(icnt, bsum);
  k_scanB<<<1, 256, 0, stream>>>(bsum, boff, rowptr + N_NODES);
  k_scanC<<<SB, 256, 0, stream>>>(icnt, boff, rowptr);
  k_bstart<<<1, 256, 0, stream>>>(rowptr, bstart, bcur);
  k_gbound<<<1, 512, 0, stream>>>(batch, gstart);

  // ---- GRU weight prepack (bf16) ----
  k_wpack<<<(PAIR+255)/256, 256, 0, stream>>>(gru0_wi, gru0_wh, wpk);
  k_wpack<<<(PAIR+255)/256, 256, 0, stream>>>(grul_wi, grul_wh, wpk + PAIR);
  k_wpack<<<(PAIR+255)/256, 256, 0, stream>>>(grul_wi + 192*64, grul_wh + 192*64, wpk + 2*PAIR);
  k_wpack<<<(PAIR+255)/256, 256, 0, stream>>>(mgru_wi, mgru_wh, wpk + 3*PAIR);

  // ---- lin1 (+ fused xr = x.h @ g_att_r) ----
  k_lin1<<<nbN32, 256, 0, stream>>>(x_in, lin1_w, lin1_b, xA, g_att_r, sc1);

  // ---- GATEConv: scores in original order, then locality-aware bin sort ----
  k_mmdual<<<nbN32, 256, 0, stream>>>(xA, g_lin1_w, g_lin2_w, ubf, ypk, N_NODES);
  k_escore<<<nbES, 256, 0, stream>>>(src, eattr, g_lin1_w, g_att_l, ubf, pbuf);
  k_binA<<<(N_EDGES + BIN_BLK-1)/BIN_BLK, 1024, 0, stream>>>(dst, src, pbuf, bcur, binned);
  k_binB<<<NBKT, 1024, 0, stream>>>(rowptr, bstart, binned, sorted);
  k_gate_agg<<<nbN4, 256, 0, stream>>>(rowptr, sorted, sc1, ypk, hagg);
  k_gruM<<<nbN64, 256, 0, stream>>>(hagg, g_bias, xA, wpk, wpk + 192*64,
                                    gru0_bi, gru0_bh, xB, N_NODES);

  float* xcur = xB; float* xoth = xA;

  // ---- GATConv layers ----
  for (int l = 0; l < 2; ++l) {
    k_mm64<<<nbN32, 256, 0, stream>>>(xcur, conv_lin_w + l*64*64, 64, nullptr, hsb, N_NODES,
                                      conv_att_src + l*64, conv_att_dst + l*64, sc1, sc2);
    k_conv_fused<<<nbN4, 256, 0, stream>>>(rowptr, sorted, sc1, sc2, hsb, hagg);
    k_gruM<<<nbN64, 256, 0, stream>>>(hagg, conv_bias + l*64, xcur,
                                      wpk + (1+l)*PAIR, wpk + (1+l)*PAIR + 192*64,
                                      grul_bi + l*192, grul_bh + l*192, xoth, N_NODES);
    float* t = xcur; xcur = xoth; xoth = t;
  }

  // ---- molecule readout ----
  float* ymol = uy;  // fp32 N*64 reuse
  k_molsum_f<<<nbG4, 256, 0, stream>>>(gstart, xcur, outg);
  k_mm64<<<nbN32, 256, 0, stream>>>(xcur, mol_lin_w, 64, ymol, nullptr, N_NODES,
                                    mol_att_src, nullptr, sc1, nullptr);
  for (int t = 0; t < 2; ++t) {
    k_mol_fused<<<nbG4, 256, 0, stream>>>(gstart, outg, mol_lin_w, mol_att_dst, sc1, ymol, hagg);
    k_gruM<<<(NGRAPH+63)/64, 256, 0, stream>>>(hagg, mol_bias, outg,
                                               wpk + 3*PAIR, wpk + 3*PAIR + 192*64,
                                               mgru_bi, mgru_bh, outg, NGRAPH);
  }

  // ---- final linear ----
  k_final<<<NGRAPH, 128, 0, stream>>>(outg, lin2_w, lin2_b, (float*)d_out);
}

// Round 11
// 496.107 us; speedup vs baseline: 3.5000x; 1.1376x over previous
//
#include <hip/hip_runtime.h>
#include <math.h>

#define N_NODES 50000
#define N_EDGES 1000000
#define NGRAPH  512
#define INC     39
#define SB 200   // scan blocks
#define SC 250   // nodes per scan block (200*250 = 50000)
#define NBKT 196 // dst buckets of 256 nodes
#define BIN_BLK 4096

typedef __attribute__((ext_vector_type(8))) short bf16x8;
typedef __attribute__((ext_vector_type(4))) float f32x4;
typedef __attribute__((ext_vector_type(4))) int i32x4;

__device__ __forceinline__ float lrelu(float x){ return fmaxf(0.01f*x, x); }
__device__ __forceinline__ float fexp(float x){ return __builtin_amdgcn_exp2f(x*1.4426950408889634f); }
__device__ __forceinline__ float frcp(float x){ return __builtin_amdgcn_rcpf(x); }
__device__ __forceinline__ float eluf (float x){ return x > 0.f ? x : fexp(x) - 1.f; }
__device__ __forceinline__ float sigm (float x){ return frcp(1.f + fexp(-x)); }
__device__ __forceinline__ float ftanh(float x){
  x = fminf(fmaxf(x, -15.f), 15.f);
  float e = __builtin_amdgcn_exp2f(x*2.8853900817779268f); // exp(2x)
  return (e - 1.f)*frcp(e + 1.f);
}
__device__ __forceinline__ float rdlane(float v, int l){
  return __int_as_float(__builtin_amdgcn_readlane(__float_as_int(v), l));
}
__device__ __forceinline__ unsigned pk_bf16(float a, float b){
  unsigned r;
  asm volatile("v_cvt_pk_bf16_f32 %0, %1, %2" : "=v"(r) : "v"(a), "v"(b));
  return r;
}
__device__ __forceinline__ float bl(unsigned p){ return __uint_as_float(p << 16); }
__device__ __forceinline__ float bh(unsigned p){ return __uint_as_float(p & 0xffff0000u); }

// ================= CSR build =================
__global__ __launch_bounds__(256) void k_hist(const int* __restrict__ dst,
                                              int* __restrict__ cnt) {
  int e = blockIdx.x*256 + threadIdx.x;
  if (e < N_EDGES) atomicAdd(&cnt[dst[e]], 1);
}

__global__ __launch_bounds__(256) void k_scanA(const int* __restrict__ cnt,
                                               int* __restrict__ bsum) {
  __shared__ int s[256];
  int t = threadIdx.x, b = blockIdx.x;
  int v = (t < SC) ? cnt[b*SC + t] : 0;
  s[t] = v; __syncthreads();
  for (int off = 128; off > 0; off >>= 1) {
    if (t < off) s[t] += s[t+off];
    __syncthreads();
  }
  if (t == 0) bsum[b] = s[0];
}

__global__ __launch_bounds__(256) void k_scanB(const int* __restrict__ bsum,
                                               int* __restrict__ boff,
                                               int* __restrict__ rowptrN) {
  __shared__ int s[256];
  int t = threadIdx.x;
  int v = (t < SB) ? bsum[t] : 0;
  s[t] = v; __syncthreads();
  for (int off = 1; off < 256; off <<= 1) {
    int x = (t >= off) ? s[t-off] : 0;
    __syncthreads();
    s[t] += x;
    __syncthreads();
  }
  if (t < SB) boff[t] = s[t] - v;   // exclusive prefix
  if (t == 0) rowptrN[0] = N_EDGES; // rowptr[N_NODES]
}

__global__ __launch_bounds__(256) void k_scanC(const int* __restrict__ cnt,
                                               const int* __restrict__ boff,
                                               int* __restrict__ rowptr) {
  __shared__ int s[256];
  int t = threadIdx.x, b = blockIdx.x;
  int idx = b*SC + t;
  int v = (t < SC) ? cnt[idx] : 0;
  s[t] = v; __syncthreads();
  for (int off = 1; off < 256; off <<= 1) {
    int x = (t >= off) ? s[t-off] : 0;
    __syncthreads();
    s[t] += x;
    __syncthreads();
  }
  if (t < SC) rowptr[idx] = boff[b] + s[t] - v;
}

__global__ __launch_bounds__(256) void k_bstart(const int* __restrict__ rowptr,
                                                int* __restrict__ bstart,
                                                int* __restrict__ bcur) {
  int b = threadIdx.x;
  if (b <= NBKT) {
    int idx = b*256; if (idx > N_NODES) idx = N_NODES;
    int v = rowptr[idx];
    bstart[b] = v;
    if (b < NBKT) bcur[b] = v;
  }
}

// ===== Pass A: bin edges into 196 coarse buckets =====
__global__ __launch_bounds__(1024) void k_binA(const int* __restrict__ dst,
                                               const int* __restrict__ src,
                                               const float* __restrict__ p,
                                               int* __restrict__ bcur,
                                               int2* __restrict__ binned) {
  __shared__ int lcnt[NBKT];
  __shared__ int lbase[NBKT];
  __shared__ int gbase[NBKT];
  __shared__ int tmp[256];
  __shared__ int totsh;
  __shared__ int2 stage[BIN_BLK];
  const int t = threadIdx.x;
  const int e0 = blockIdx.x * BIN_BLK;
  for (int i = t; i < NBKT; i += 1024) lcnt[i] = 0;
  __syncthreads();
  int myb[4], myr[4], myd[4], mys[4]; float myp[4];
  #pragma unroll
  for (int u = 0; u < 4; ++u) {
    int e = e0 + u*1024 + t;
    if (e < N_EDGES) {
      int d = dst[e];
      myd[u] = d; mys[u] = src[e]; myp[u] = p[e];
      int b = d >> 8;
      myb[u] = b;
      myr[u] = atomicAdd(&lcnt[b], 1);
    } else myb[u] = -1;
  }
  __syncthreads();
  if (t < 256) tmp[t] = (t < NBKT) ? lcnt[t] : 0;
  __syncthreads();
  for (int off = 1; off < 256; off <<= 1) {
    int v = (t >= off && t < 256) ? tmp[t-off] : 0;
    __syncthreads();
    if (t < 256) tmp[t] += v;
    __syncthreads();
  }
  if (t < NBKT) lbase[t] = tmp[t] - lcnt[t];
  if (t == NBKT-1) totsh = tmp[t];
  if (t < NBKT && lcnt[t] > 0) gbase[t] = atomicAdd(&bcur[t], lcnt[t]);
  __syncthreads();
  #pragma unroll
  for (int u = 0; u < 4; ++u) {
    if (myb[u] >= 0) {
      int x = (mys[u] & 0xffff) | ((myd[u] & 255) << 16) | (myb[u] << 24);
      stage[lbase[myb[u]] + myr[u]] = make_int2(x, __float_as_int(myp[u]));
    }
  }
  __syncthreads();
  const int tot = totsh;
  for (int i = t; i < tot; i += 1024) {
    int2 r = stage[i];
    int b = (unsigned)r.x >> 24;
    binned[gbase[b] + (i - lbase[b])] = r;
  }
}

// ===== Pass B: sort each bucket to final CSR order =====
__global__ __launch_bounds__(1024) void k_binB(const int* __restrict__ rowptr,
                                               const int* __restrict__ bstart,
                                               const int2* __restrict__ binned,
                                               int2* __restrict__ sorted) {
  __shared__ int lcnt[256];
  const int b = blockIdx.x;
  const int base = bstart[b], end = bstart[b+1];
  const int t = threadIdx.x;
  if (t < 256) lcnt[t] = 0;
  __syncthreads();
  for (int i = base + t; i < end; i += 1024) {
    int2 r = binned[i];
    int dlow = (r.x >> 16) & 255;
    int rank = atomicAdd(&lcnt[dlow], 1);
    int pos = rowptr[b*256 + dlow] + rank;
    sorted[pos] = r;
  }
}

__global__ __launch_bounds__(512) void k_gbound(const int* __restrict__ batch,
                                                int* __restrict__ gstart) {
  int g = threadIdx.x;
  int lo = 0, hi = N_NODES;
  while (lo < hi) { int mid = (lo+hi)>>1; if (batch[mid] < g) lo = mid+1; else hi = mid; }
  gstart[g] = lo;
  if (g == 0) gstart[NGRAPH] = N_NODES;
}

// ================= bf16 weight prepack: wi,wh [192][64] each =================
__global__ __launch_bounds__(256) void k_wpack(const float* __restrict__ wi,
                                               const float* __restrict__ wh,
                                               unsigned short* __restrict__ o) {
  int i = blockIdx.x*256 + threadIdx.x;
  if (i < 192*64)      o[i]          = (unsigned short)(pk_bf16(wi[i], 0.f) & 0xffffu);
  else if (i < 2*192*64) o[i]        = (unsigned short)(pk_bf16(wh[i - 192*64], 0.f) & 0xffffu);
}

// ================= lin1: K=39, fused per-row dot with v1 =================
__global__ __launch_bounds__(256) void k_lin1(const float* __restrict__ x,
                                              const float* __restrict__ W,
                                              const float* __restrict__ b,
                                              float* __restrict__ out,
                                              const float* __restrict__ v1,
                                              float* __restrict__ o1) {
  __shared__ float wl[64*41];
  for (int idx = threadIdx.x; idx < 64*INC; idx += 256) {
    int r = idx / INC, c = idx - r*INC;
    wl[r*41+c] = W[idx];
  }
  __syncthreads();
  const int lane = threadIdx.x & 63;
  const int base = blockIdx.x*32 + (threadIdx.x>>6)*8;
  float h[8];
  #pragma unroll
  for (int i = 0; i < 8; ++i) {
    int n = base + i;
    h[i] = (n < N_NODES && lane < INC) ? x[n*INC + lane] : 0.f;
  }
  float acc[8] = {0,0,0,0,0,0,0,0};
  #pragma unroll
  for (int k = 0; k < INC; ++k) {
    float wv = wl[lane*41+k];
    #pragma unroll
    for (int i = 0; i < 8; ++i) acc[i] += rdlane(h[i], k) * wv;
  }
  float bb = b[lane];
  float attv = v1[lane];
  #pragma unroll
  for (int i = 0; i < 8; ++i) {
    int n = base + i;
    if (n >= N_NODES) continue;
    float val = lrelu(acc[i] + bb);
    out[n*64+lane] = val;
    float p = val * attv;
    #pragma unroll
    for (int s2 = 32; s2 > 0; s2 >>= 1) p += __shfl_xor(p, s2, 64);
    if (lane == 0) o1[n] = p;
  }
}

// ========== dual matmul -> u as bf16 [N][64] ushort, y packed 2ch/dword [N][32] ==========
__global__ __launch_bounds__(256) void k_mmdual(const float* __restrict__ in,
                                                const float* __restrict__ W1, // [64][80]
                                                const float* __restrict__ W2, // [64][64]
                                                unsigned short* __restrict__ ubf,
                                                unsigned* __restrict__ ypk, int R) {
  __shared__ float wl[128*65];
  for (int idx = threadIdx.x; idx < 4096; idx += 256) {
    int r = idx >> 6, c = idx & 63;
    wl[r*65+c]      = W1[r*80 + c];
    wl[(64+r)*65+c] = W2[r*64 + c];
  }
  __syncthreads();
  const int lane = threadIdx.x & 63;
  const int base = blockIdx.x*32 + (threadIdx.x>>6)*8;
  float h[8];
  #pragma unroll
  for (int i = 0; i < 8; ++i) { int n = base+i; h[i] = (n < R) ? in[n*64+lane] : 0.f; }
  float accU[8] = {0,0,0,0,0,0,0,0};
  float accY[8] = {0,0,0,0,0,0,0,0};
  for (int k = 0; k < 64; ++k) {
    float wu = wl[lane*65+k], wy = wl[(64+lane)*65+k];
    #pragma unroll
    for (int i = 0; i < 8; ++i) {
      float hk = rdlane(h[i], k);
      accU[i] += hk*wu; accY[i] += hk*wy;
    }
  }
  #pragma unroll
  for (int i = 0; i < 8; ++i) {
    int n = base+i; if (n >= R) continue;
    ubf[n*64 + lane] = (unsigned short)(pk_bf16(accU[i], 0.f) & 0xffffu);
    float partner = __shfl_xor(accY[i], 1, 64);
    if (!(lane & 1)) ypk[n*32 + (lane>>1)] = pk_bf16(accY[i], partner);
  }
}

// ========== [R,64] @ W.T; optional packed-bf16 pair table + fused per-row dots ==========
__global__ __launch_bounds__(256) void k_mm64(const float* __restrict__ in,
                                              const float* __restrict__ W, int rs,
                                              float* __restrict__ out,
                                              unsigned* __restrict__ outp, int R,
                                              const float* __restrict__ v1,
                                              const float* __restrict__ v2,
                                              float* __restrict__ o1,
                                              float* __restrict__ o2) {
  __shared__ float wl[64*65];
  for (int idx = threadIdx.x; idx < 4096; idx += 256) {
    int r = idx >> 6, c = idx & 63;
    wl[r*65+c] = W[r*rs + c];
  }
  __syncthreads();
  const int lane = threadIdx.x & 63;
  const int base = blockIdx.x*32 + (threadIdx.x>>6)*8;
  float h[8];
  #pragma unroll
  for (int i = 0; i < 8; ++i) { int n = base+i; h[i] = (n < R) ? in[n*64+lane] : 0.f; }
  float acc[8] = {0,0,0,0,0,0,0,0};
  for (int k = 0; k < 64; ++k) {
    float wv = wl[lane*65+k];
    #pragma unroll
    for (int i = 0; i < 8; ++i) acc[i] += rdlane(h[i], k) * wv;
  }
  float v1v = v1 ? v1[lane] : 0.f;
  float v2v = v2 ? v2[lane] : 0.f;
  #pragma unroll
  for (int i = 0; i < 8; ++i) {
    int n = base+i; if (n >= R) continue;
    if (out) out[n*64+lane] = acc[i];
    if (outp) {
      float partner = __shfl_xor(acc[i], 1, 64);   // lane 2c gets ch 2c+1
      if ((lane & 1) == 0) outp[n*32 + (lane>>1)] = pk_bf16(acc[i], partner);
    }
    if (o1) {
      float p1 = acc[i]*v1v;
      float p2 = acc[i]*v2v;
      #pragma unroll
      for (int s2 = 32; s2 > 0; s2 >>= 1) { p1 += __shfl_xor(p1, s2, 64); p2 += __shfl_xor(p2, s2, 64); }
      if (lane == 0) { o1[n] = p1; if (o2) o2[n] = p2; }
    }
  }
}

// ===== GATE edge scores, original order, software-pipelined u-gathers + NT streaming =====
__global__ __launch_bounds__(256) void k_escore(const int* __restrict__ srcarr,
                                                const float* __restrict__ ea,
                                                const float* __restrict__ glin1, // [64][80]
                                                const float* __restrict__ attl,
                                                const unsigned short* __restrict__ ubf,
                                                float* __restrict__ pout) {
  const int lane = threadIdx.x & 63;
  const int l15 = lane & 15, lg = lane >> 4;
  const int gw = blockIdx.x*4 + (threadIdx.x >> 6);
  if (gw >= N_EDGES/64) return;
  float attlv[4];
  unsigned Bu[4][2];
  #pragma unroll
  for (int c = 0; c < 4; ++c) {
    const float4 b = *(const float4*)&glin1[(c*16 + l15)*80 + 64 + lg*4];
    Bu[c][0] = pk_bf16(b.x, b.y);
    Bu[c][1] = pk_bf16(b.z, b.w);
    attlv[c] = attl[c*16 + l15];
  }
  const int i0 = gw*64;
  i32x4 sv[4];
  #pragma unroll
  for (int it = 0; it < 4; ++it)
    sv[it] = *(const i32x4*)&srcarr[i0 + it*16 + 4*lg];
  f32x4 a[4];
  #pragma unroll
  for (int it = 0; it < 4; ++it)
    a[it] = __builtin_nontemporal_load((const f32x4*)&ea[(size_t)(i0 + it*16 + l15)*16 + lg*4]);
  unsigned short ug0[4][4], ug1[4][4];
  #pragma unroll
  for (int c = 0; c < 4; ++c)
    #pragma unroll
    for (int r = 0; r < 4; ++r)
      ug0[c][r] = ubf[(size_t)sv[0][r]*64 + c*16 + l15];
  #pragma unroll
  for (int it = 0; it < 4; ++it) {
    if (it + 1 < 4) {
      #pragma unroll
      for (int c = 0; c < 4; ++c)
        #pragma unroll
        for (int r = 0; r < 4; ++r)
          ug1[c][r] = ubf[(size_t)sv[it+1][r]*64 + c*16 + l15];
    }
    union { bf16x8 v; unsigned u[4]; } A;
    A.u[0] = pk_bf16(a[it][0], a[it][1]);
    A.u[1] = pk_bf16(a[it][2], a[it][3]);
    A.u[2] = 0; A.u[3] = 0;
    float p[4] = {0.f,0.f,0.f,0.f};
    #pragma unroll
    for (int c = 0; c < 4; ++c) {
      union { bf16x8 v; unsigned u[4]; } B;
      B.u[0] = Bu[c][0]; B.u[1] = Bu[c][1]; B.u[2] = 0; B.u[3] = 0;
      f32x4 z = {0.f,0.f,0.f,0.f};
      f32x4 acc = __builtin_amdgcn_mfma_f32_16x16x32_bf16(A.v, B.v, z, 0, 0, 0);
      #pragma unroll
      for (int r = 0; r < 4; ++r) {
        float t = lrelu(__uint_as_float(((unsigned)ug0[c][r]) << 16) + acc[r]);
        p[r] = fmaf(t, attlv[c], p[r]);
      }
    }
    #pragma unroll
    for (int r = 0; r < 4; ++r) {
      p[r] += __shfl_xor(p[r], 1, 64);
      p[r] += __shfl_xor(p[r], 2, 64);
      p[r] += __shfl_xor(p[r], 4, 64);
      p[r] += __shfl_xor(p[r], 8, 64);
    }
    if (l15 == 0) {
      f32x4 o = {p[0], p[1], p[2], p[3]};
      __builtin_nontemporal_store(o, (f32x4*)&pout[i0 + it*16 + 4*lg]);
    }
    #pragma unroll
    for (int c = 0; c < 4; ++c)
      #pragma unroll
      for (int r = 0; r < 4; ++r)
        ug0[c][r] = ug1[c][r];
  }
}

// ===== GATE aggregation: sorted records {src|dlow|bkt, p}, bf16-packed y gathers =====
__global__ __launch_bounds__(256) void k_gate_agg(const int* __restrict__ rowptr,
                                                  const int2* __restrict__ sorted,
                                                  const float* __restrict__ xr,
                                                  const unsigned* __restrict__ ypk,
                                                  float* __restrict__ hagg) {
  __shared__ int   sS[4][64];
  __shared__ float sE[4][64];
  const int w = __builtin_amdgcn_readfirstlane(threadIdx.x >> 6);
  const int lane = threadIdx.x & 63;
  const int slot = lane >> 5, l2 = lane & 31;
  const int d = blockIdx.x*4 + w;
  const int r0 = __builtin_amdgcn_readfirstlane(rowptr[d]);
  const int r1 = __builtin_amdgcn_readfirstlane(rowptr[d+1]);
  const float xrd = xr[d];
  float accx = 0.f, accy = 0.f, ssum = 0.f;
  for (int base = r0; base < r1; base += 64) {
    int i = base + lane;
    int cnt = r1 - base; if (cnt > 64) cnt = 64;
    float ev = 0.f; int s = 0;
    if (i < r1) {
      int2 r = sorted[i];
      s = r.x & 0xffff;
      ev = fexp(lrelu(__int_as_float(r.y) + xrd));
    }
    sS[w][lane] = s; sE[w][lane] = ev;
    ssum += ev;
    for (int jb = 0; jb < cnt; jb += 16) {
      float e8[8]; unsigned p8[8];
      #pragma unroll
      for (int u = 0; u < 8; ++u) {
        int jj = jb + 2*u + slot;
        int svv; float evv;
        if (jj < cnt) { svv = sS[w][jj]; evv = sE[w][jj]; }
        else          { svv = 0; evv = 0.f; }
        e8[u] = evv;
        p8[u] = ypk[(size_t)svv*32 + l2];
      }
      #pragma unroll
      for (int u = 0; u < 8; ++u) {
        accx = fmaf(e8[u], bl(p8[u]), accx);
        accy = fmaf(e8[u], bh(p8[u]), accy);
      }
    }
  }
  #pragma unroll
  for (int sh = 32; sh > 0; sh >>= 1) ssum += __shfl_xor(ssum, sh, 64);
  accx += __shfl_xor(accx, 32, 64);
  accy += __shfl_xor(accy, 32, 64);
  float rs = frcp(ssum + 1e-16f);
  if (slot == 0) *(float2*)&hagg[d*64 + 2*l2] = make_float2(accx*rs, accy*rs);
}

// ===== GATConv fused: 2 edges per wave, bf16-packed hs, sorted src =====
__global__ __launch_bounds__(256) void k_conv_fused(const int* __restrict__ rowptr,
                                                    const int2* __restrict__ sorted,
                                                    const float* __restrict__ asn,
                                                    const float* __restrict__ adn,
                                                    const unsigned* __restrict__ hsb,
                                                    float* __restrict__ hagg) {
  __shared__ int   sS[4][64];
  __shared__ float sE[4][64];
  const int w = __builtin_amdgcn_readfirstlane(threadIdx.x >> 6);
  const int lane = threadIdx.x & 63;
  const int slot = lane >> 5, l2 = lane & 31;
  const int d = blockIdx.x*4 + w;
  const int r0 = __builtin_amdgcn_readfirstlane(rowptr[d]);
  const int r1 = __builtin_amdgcn_readfirstlane(rowptr[d+1]);
  float adnd = adn[d];
  float accx = 0.f, accy = 0.f, ssum = 0.f;
  for (int base = r0; base < r1; base += 64) {
    int i = base + lane;
    int cnt = r1 - base; if (cnt > 64) cnt = 64;
    float ev = 0.f; int s = 0;
    if (i < r1) { s = sorted[i].x & 0xffff; ev = fexp(lrelu(asn[s] + adnd)); }
    sS[w][lane] = s; sE[w][lane] = ev;
    ssum += ev;
    for (int jb = 0; jb < cnt; jb += 16) {
      float e8[8]; unsigned p8[8];
      #pragma unroll
      for (int u = 0; u < 8; ++u) {
        int jj = jb + 2*u + slot;
        int svv; float evv;
        if (jj < cnt) { svv = sS[w][jj]; evv = sE[w][jj]; }
        else          { svv = 0; evv = 0.f; }
        e8[u] = evv;
        p8[u] = hsb[(size_t)svv*32 + l2];
      }
      #pragma unroll
      for (int u = 0; u < 8; ++u) {
        accx = fmaf(e8[u], bl(p8[u]), accx);
        accy = fmaf(e8[u], bh(p8[u]), accy);
      }
    }
  }
  #pragma unroll
  for (int sh = 32; sh > 0; sh >>= 1) ssum += __shfl_xor(ssum, sh, 64);
  accx += __shfl_xor(accx, 32, 64);
  accy += __shfl_xor(accy, 32, 64);
  float rs = frcp(ssum + 1e-16f);
  if (slot == 0) *(float2*)&hagg[d*64 + 2*l2] = make_float2(accx*rs, accy*rs);
}

// ===== MFMA GRU: out = relu(GRU(elu(inp+pbias), hid)), wave = 16 nodes =====
__global__ __launch_bounds__(256) void k_gruM(const float* __restrict__ inp,
                                              const float* __restrict__ pbias,
                                              const float* __restrict__ hid,
                                              const unsigned short* __restrict__ wibf,
                                              const unsigned short* __restrict__ whbf,
                                              const float* __restrict__ bi,
                                              const float* __restrict__ bh2,
                                              float* __restrict__ out, int R) {
  const int lane = threadIdx.x & 63;
  const int l15 = lane & 15, lg = lane >> 4;
  const int n0 = blockIdx.x*64 + (threadIdx.x >> 6)*16;
  if (n0 >= R) return;
  union BF { bf16x8 v; unsigned u[4]; };
  BF Ai[2], Ah[2];
  const int arow = n0 + l15;
  const bool av = arow < R;
  const float* ibase = inp + (size_t)arow*64;
  const float* hbase = hid + (size_t)arow*64;
  #pragma unroll
  for (int c = 0; c < 2; ++c) {
    const int k0 = c*32 + lg*8;
    float4 p0 = *(const float4*)&pbias[k0];
    float4 p1 = *(const float4*)&pbias[k0+4];
    float4 v0, v1, h0, h1;
    if (av) {
      v0 = *(const float4*)&ibase[k0];   v1 = *(const float4*)&ibase[k0+4];
      h0 = *(const float4*)&hbase[k0];   h1 = *(const float4*)&hbase[k0+4];
    } else {
      v0 = v1 = h0 = h1 = make_float4(0.f,0.f,0.f,0.f);
      p0 = p1 = make_float4(0.f,0.f,0.f,0.f);
    }
    Ai[c].u[0] = pk_bf16(eluf(v0.x+p0.x), eluf(v0.y+p0.y));
    Ai[c].u[1] = pk_bf16(eluf(v0.z+p0.z), eluf(v0.w+p0.w));
    Ai[c].u[2] = pk_bf16(eluf(v1.x+p1.x), eluf(v1.y+p1.y));
    Ai[c].u[3] = pk_bf16(eluf(v1.z+p1.z), eluf(v1.w+p1.w));
    Ah[c].u[0] = pk_bf16(h0.x, h0.y);
    Ah[c].u[1] = pk_bf16(h0.z, h0.w);
    Ah[c].u[2] = pk_bf16(h1.x, h1.y);
    Ah[c].u[3] = pk_bf16(h1.z, h1.w);
  }
  f32x4 rz[8], ni[4], nh[4];
  #pragma unroll
  for (int t = 0; t < 8; ++t) rz[t] = (f32x4){0.f,0.f,0.f,0.f};
  #pragma unroll
  for (int t = 0; t < 4; ++t) { ni[t] = (f32x4){0.f,0.f,0.f,0.f}; nh[t] = (f32x4){0.f,0.f,0.f,0.f}; }
  #pragma unroll
  for (int t = 0; t < 12; ++t) {
    BF Bi0, Bi1, Bh0, Bh1;
    const size_t off = ((size_t)(t*16 + l15))*64 + lg*8;
    Bi0.v = *(const bf16x8*)&wibf[off];
    Bi1.v = *(const bf16x8*)&wibf[off + 32];
    Bh0.v = *(const bf16x8*)&whbf[off];
    Bh1.v = *(const bf16x8*)&whbf[off + 32];
    if (t < 8) {
      f32x4 a = rz[t];
      a = __builtin_amdgcn_mfma_f32_16x16x32_bf16(Ai[0].v, Bi0.v, a, 0, 0, 0);
      a = __builtin_amdgcn_mfma_f32_16x16x32_bf16(Ai[1].v, Bi1.v, a, 0, 0, 0);
      a = __builtin_amdgcn_mfma_f32_16x16x32_bf16(Ah[0].v, Bh0.v, a, 0, 0, 0);
      a = __builtin_amdgcn_mfma_f32_16x16x32_bf16(Ah[1].v, Bh1.v, a, 0, 0, 0);
      rz[t] = a;
    } else {
      f32x4 a = ni[t-8];
      a = __builtin_amdgcn_mfma_f32_16x16x32_bf16(Ai[0].v, Bi0.v, a, 0, 0, 0);
      a = __builtin_amdgcn_mfma_f32_16x16x32_bf16(Ai[1].v, Bi1.v, a, 0, 0, 0);
      ni[t-8] = a;
      f32x4 b = nh[t-8];
      b = __builtin_amdgcn_mfma_f32_16x16x32_bf16(Ah[0].v, Bh0.v, b, 0, 0, 0);
      b = __builtin_amdgcn_mfma_f32_16x16x32_bf16(Ah[1].v, Bh1.v, b, 0, 0, 0);
      nh[t-8] = b;
    }
  }
  float bsum[8], binv[4], bhnv[4];
  #pragma unroll
  for (int t = 0; t < 8; ++t) bsum[t] = bi[t*16+l15] + bh2[t*16+l15];
  #pragma unroll
  for (int t = 0; t < 4; ++t) {
    binv[t] = bi[128 + t*16 + l15];
    bhnv[t] = bh2[128 + t*16 + l15];
  }
  #pragma unroll
  for (int reg = 0; reg < 4; ++reg) {
    const int node = n0 + 4*lg + reg;
    if (node >= R) continue;
    #pragma unroll
    for (int tt = 0; tt < 4; ++tt) {
      float r  = sigm(rz[tt][reg] + bsum[tt]);
      float z  = sigm(rz[4+tt][reg] + bsum[4+tt]);
      float nn = ftanh(ni[tt][reg] + binv[tt] + r*(nh[tt][reg] + bhnv[tt]));
      float hh = hid[(size_t)node*64 + tt*16 + l15];
      float o  = (1.f - z)*nn + z*hh;
      out[(size_t)node*64 + tt*16 + l15] = fmaxf(o, 0.f);
    }
  }
}

// ================= molecule readout, split-K (8 slices per graph) =================
__global__ __launch_bounds__(256) void k_molsum_p(const int* __restrict__ gstart,
                                                  const float* __restrict__ x,
                                                  float* __restrict__ part) {
  int idx = blockIdx.x*4 + (threadIdx.x>>6);       // g*8 + slice
  if (idx >= NGRAPH*8) return;
  int g = idx >> 3, sl = idx & 7;
  int lane = threadIdx.x & 63;
  int n0 = gstart[g], n1 = gstart[g+1];
  int len = n1 - n0;
  int b0 = n0 + (len*sl >> 3), b1 = n0 + (len*(sl+1) >> 3);
  float acc = 0.f;
  for (int n = b0; n < b1; ++n) acc += x[n*64+lane];
  part[idx*64+lane] = acc;
}

__global__ __launch_bounds__(256) void k_molsum_c(const float* __restrict__ part,
                                                  float* __restrict__ outg) {
  int g = blockIdx.x*4 + (threadIdx.x>>6);
  if (g >= NGRAPH) return;
  int lane = threadIdx.x & 63;
  float a = 0.f;
  #pragma unroll
  for (int s = 0; s < 8; ++s) a += part[(g*8+s)*64+lane];
  outg[g*64+lane] = fmaxf(a, 0.f);
}

__global__ __launch_bounds__(256) void k_molhd(const float* __restrict__ outg,
                                               const float* __restrict__ W,
                                               const float* __restrict__ attd,
                                               float* __restrict__ addg) {
  __shared__ float wl[64*65];
  for (int idx = threadIdx.x; idx < 4096; idx += 256) wl[(idx>>6)*65+(idx&63)] = W[idx];
  __syncthreads();
  int g = blockIdx.x*4 + (threadIdx.x>>6);
  if (g >= NGRAPH) return;
  int lane = threadIdx.x & 63;
  float og = outg[g*64+lane];
  float hd = 0.f;
  #pragma unroll
  for (int k = 0; k < 64; ++k) hd += rdlane(og, k) * wl[lane*65+k];
  float p = hd * attd[lane];
  #pragma unroll
  for (int sh = 32; sh > 0; sh >>= 1) p += __shfl_xor(p, sh, 64);
  if (lane == 0) addg[g] = p;
}

__global__ __launch_bounds__(256) void k_molp(const int* __restrict__ gstart,
                                              const float* __restrict__ addg,
                                              const float* __restrict__ asn,
                                              const float* __restrict__ y,
                                              float* __restrict__ part_acc,
                                              float* __restrict__ part_ss) {
  int idx = blockIdx.x*4 + (threadIdx.x>>6);       // g*8 + slice
  if (idx >= NGRAPH*8) return;
  int g = idx >> 3, sl = idx & 7;
  int lane = threadIdx.x & 63;
  int n0 = gstart[g], n1 = gstart[g+1];
  int len = n1 - n0;
  int b0 = n0 + (len*sl >> 3), b1 = n0 + (len*(sl+1) >> 3);
  float adg = addg[g];
  float acc = 0.f, ss = 0.f;
  for (int n = b0; n < b1; ++n) {
    float ev = fexp(lrelu(asn[n] + adg));
    acc += ev * y[n*64+lane];
    ss  += ev;
  }
  part_acc[idx*64+lane] = acc;
  if (lane == 0) part_ss[idx] = ss;
}

__global__ __launch_bounds__(256) void k_molc(const float* __restrict__ part_acc,
                                              const float* __restrict__ part_ss,
                                              float* __restrict__ hg) {
  int g = blockIdx.x*4 + (threadIdx.x>>6);
  if (g >= NGRAPH) return;
  int lane = threadIdx.x & 63;
  float a = 0.f, ss = 0.f;
  #pragma unroll
  for (int s = 0; s < 8; ++s) {
    a  += part_acc[(g*8+s)*64+lane];
    ss += part_ss[g*8+s];
  }
  hg[g*64+lane] = a * frcp(ss + 1e-16f);
}

__global__ __launch_bounds__(128) void k_final(const float* __restrict__ outg,
                                               const float* __restrict__ W,
                                               const float* __restrict__ b,
                                               float* __restrict__ out) {
  __shared__ float og[64];
  int g = blockIdx.x;
  if (threadIdx.x < 64) og[threadIdx.x] = outg[g*64+threadIdx.x];
  __syncthreads();
  int o = threadIdx.x;
  float acc = b[o];
  for (int k = 0; k < 64; ++k) acc += og[k]*W[o*64+k];
  out[g*128+o] = acc;
}

extern "C" void kernel_launch(void* const* d_in, const int* in_sizes, int n_in,
                              void* d_out, int out_size, void* d_ws, size_t ws_size,
                              hipStream_t stream) {
  const float* x_in     = (const float*)d_in[0];
  const int*   eidx     = (const int*)  d_in[1];
  const float* eattr    = (const float*)d_in[2];
  const int*   batch    = (const int*)  d_in[3];
  const float* lin1_w   = (const float*)d_in[4];
  const float* lin1_b   = (const float*)d_in[5];
  const float* g_lin1_w = (const float*)d_in[6];
  const float* g_att_l  = (const float*)d_in[7];
  const float* g_att_r  = (const float*)d_in[8];
  const float* g_lin2_w = (const float*)d_in[9];
  const float* g_bias   = (const float*)d_in[10];
  const float* gru0_wi  = (const float*)d_in[11];
  const float* gru0_wh  = (const float*)d_in[12];
  const float* gru0_bi  = (const float*)d_in[13];
  const float* gru0_bh  = (const float*)d_in[14];
  const float* conv_lin_w   = (const float*)d_in[15];
  const float* conv_att_src = (const float*)d_in[16];
  const float* conv_att_dst = (const float*)d_in[17];
  const float* conv_bias    = (const float*)d_in[18];
  const float* grul_wi  = (const float*)d_in[19];
  const float* grul_wh  = (const float*)d_in[20];
  const float* grul_bi  = (const float*)d_in[21];
  const float* grul_bh  = (const float*)d_in[22];
  const float* mol_lin_w    = (const float*)d_in[23];
  const float* mol_att_src  = (const float*)d_in[24];
  const float* mol_att_dst  = (const float*)d_in[25];
  const float* mol_bias     = (const float*)d_in[26];
  const float* mgru_wi  = (const float*)d_in[27];
  const float* mgru_wh  = (const float*)d_in[28];
  const float* mgru_bi  = (const float*)d_in[29];
  const float* mgru_bh  = (const float*)d_in[30];
  const float* lin2_w   = (const float*)d_in[31];
  const float* lin2_b   = (const float*)d_in[32];

  const int N64 = N_NODES*64;
  float* ws     = (float*)d_ws;
  float* xA     = ws;               // N*64
  float* xB     = xA + N64;         // N*64
  float* uy     = xB + N64;         // 2*N64 region: ubf(ushort N*64)+ypk(uint N*32) / hsb / ymol
  float* hagg   = uy + 2*N64;       // N*64
  float* sc1    = hagg + N64;       // N
  float* sc2    = sc1 + N_NODES;    // N
  float* pbuf   = sc2 + N_NODES;    // E (edge scores, ORIGINAL order)
  float* outg   = pbuf + N_EDGES;   // G*64
  int* icnt   = (int*)(outg + NGRAPH*64); // N
  int* rowptr = icnt + N_NODES;     // N+2
  int2* binned = (int2*)(rowptr + N_NODES + 2); // E  (reused: mol partials)
  int2* sorted = binned + N_EDGES;  // E
  int* gstart = (int*)(sorted + N_EDGES); // G+1
  int* bsum   = gstart + NGRAPH+1;  // SB
  int* boff   = bsum + SB;          // SB
  int* bstart = boff + SB;          // NBKT+1
  int* bcur   = bstart + NBKT+1;    // NBKT
  unsigned short* wpk = (unsigned short*)(bcur + NBKT + 4); // 4 pairs * 2*192*64 bf16

  unsigned short* ubf = (unsigned short*)uy;       // N*64 bf16 u
  unsigned* ypk = (unsigned*)(uy + N64);           // N*32 packed y
  unsigned* hsb = (unsigned*)uy;                   // N*32 packed hs (reused after gate)

  // mol partial buffers (reuse binned region, free after k_binB)
  float* part_acc = (float*)binned;                // G*8*64
  float* part_ss  = part_acc + NGRAPH*8*64;        // G*8
  float* addg     = part_ss + NGRAPH*8;            // G

  const int* src = eidx;
  const int* dst = eidx + N_EDGES;

  const int nbN32 = (N_NODES + 31)/32;
  const int nbN4  = (N_NODES + 3)/4;
  const int nbN64 = (N_NODES + 63)/64;
  const int nbE   = (N_EDGES + 255)/256;
  const int nbG4  = (NGRAPH + 3)/4;
  const int nbG8  = (NGRAPH*8 + 3)/4;
  const int nbES  = (N_EDGES/64 + 3)/4;   // escore: 64 edges per wave
  const int PAIR  = 2*192*64;             // ushorts per GRU pair

  // ---- CSR rowptr (hierarchical scan) ----
  hipMemsetAsync(icnt, 0, N_NODES*sizeof(int), stream);
  k_hist<<<nbE, 256, 0, stream>>>(dst, icnt);
  k_scanA<<<SB, 256, 0, stream>>>(icnt, bsum);
  k_scanB<<<1, 256, 0, stream>>>(bsum, boff, rowptr + N_NODES);
  k_scanC<<<SB, 256, 0, stream>>>(icnt, boff, rowptr);
  k_bstart<<<1, 256, 0, stream>>>(rowptr, bstart, bcur);
  k_gbound<<<1, 512, 0, stream>>>(batch, gstart);

  // ---- GRU weight prepack (bf16) ----
  k_wpack<<<(PAIR+255)/256, 256, 0, stream>>>(gru0_wi, gru0_wh, wpk);
  k_wpack<<<(PAIR+255)/256, 256, 0, stream>>>(grul_wi, grul_wh, wpk + PAIR);
  k_wpack<<<(PAIR+255)/256, 256, 0, stream>>>(grul_wi + 192*64, grul_wh + 192*64, wpk + 2*PAIR);
  k_wpack<<<(PAIR+255)/256, 256, 0, stream>>>(mgru_wi, mgru_wh, wpk + 3*PAIR);

  // ---- lin1 (+ fused xr = x.h @ g_att_r) ----
  k_lin1<<<nbN32, 256, 0, stream>>>(x_in, lin1_w, lin1_b, xA, g_att_r, sc1);

  // ---- GATEConv: scores in original order, then locality-aware bin sort ----
  k_mmdual<<<nbN32, 256, 0, stream>>>(xA, g_lin1_w, g_lin2_w, ubf, ypk, N_NODES);
  k_escore<<<nbES, 256, 0, stream>>>(src, eattr, g_lin1_w, g_att_l, ubf, pbuf);
  k_binA<<<(N_EDGES + BIN_BLK-1)/BIN_BLK, 1024, 0, stream>>>(dst, src, pbuf, bcur, binned);
  k_binB<<<NBKT, 1024, 0, stream>>>(rowptr, bstart, binned, sorted);
  k_gate_agg<<<nbN4, 256, 0, stream>>>(rowptr, sorted, sc1, ypk, hagg);
  k_gruM<<<nbN64, 256, 0, stream>>>(hagg, g_bias, xA, wpk, wpk + 192*64,
                                    gru0_bi, gru0_bh, xB, N_NODES);

  float* xcur = xB; float* xoth = xA;

  // ---- GATConv layers ----
  for (int l = 0; l < 2; ++l) {
    k_mm64<<<nbN32, 256, 0, stream>>>(xcur, conv_lin_w + l*64*64, 64, nullptr, hsb, N_NODES,
                                      conv_att_src + l*64, conv_att_dst + l*64, sc1, sc2);
    k_conv_fused<<<nbN4, 256, 0, stream>>>(rowptr, sorted, sc1, sc2, hsb, hagg);
    k_gruM<<<nbN64, 256, 0, stream>>>(hagg, conv_bias + l*64, xcur,
                                      wpk + (1+l)*PAIR, wpk + (1+l)*PAIR + 192*64,
                                      grul_bi + l*192, grul_bh + l*192, xoth, N_NODES);
    float* t = xcur; xcur = xoth; xoth = t;
  }

  // ---- molecule readout (split-K over node slices) ----
  float* ymol = uy;  // fp32 N*64 reuse
  k_molsum_p<<<nbG8, 256, 0, stream>>>(gstart, xcur, part_acc);
  k_molsum_c<<<nbG4, 256, 0, stream>>>(part_acc, outg);
  k_mm64<<<nbN32, 256, 0, stream>>>(xcur, mol_lin_w, 64, ymol, nullptr, N_NODES,
                                    mol_att_src, nullptr, sc1, nullptr);
  for (int t = 0; t < 2; ++t) {
    k_molhd<<<nbG4, 256, 0, stream>>>(outg, mol_lin_w, mol_att_dst, addg);
    k_molp<<<nbG8, 256, 0, stream>>>(gstart, addg, sc1, ymol, part_acc, part_ss);
    k_molc<<<nbG4, 256, 0, stream>>>(part_acc, part_ss, hagg);
    k_gruM<<<(NGRAPH+63)/64, 256, 0, stream>>>(hagg, mol_bias, outg,
                                               wpk + 3*PAIR, wpk + 3*PAIR + 192*64,
                                               mgru_bi, mgru_bh, outg, NGRAPH);
  }

  // ---- final linear ----
  k_final<<<NGRAPH, 128, 0, stream>>>(outg, lin2_w, lin2_b, (float*)d_out);
}

// Round 12
// 454.706 us; speedup vs baseline: 3.8186x; 1.0910x over previous
//
#include <hip/hip_runtime.h>
#include <math.h>

#define N_NODES 50000
#define N_EDGES 1000000
#define NGRAPH  512
#define INC     39
#define NBKT 196 // dst buckets of 256 nodes
#define BIN_BLK 4096

typedef __attribute__((ext_vector_type(8))) short bf16x8;
typedef __attribute__((ext_vector_type(4))) float f32x4;
typedef __attribute__((ext_vector_type(4))) int i32x4;

__device__ __forceinline__ float lrelu(float x){ return fmaxf(0.01f*x, x); }
__device__ __forceinline__ float fexp(float x){ return __builtin_amdgcn_exp2f(x*1.4426950408889634f); }
__device__ __forceinline__ float frcp(float x){ return __builtin_amdgcn_rcpf(x); }
__device__ __forceinline__ float eluf (float x){ return x > 0.f ? x : fexp(x) - 1.f; }
__device__ __forceinline__ float sigm (float x){ return frcp(1.f + fexp(-x)); }
__device__ __forceinline__ float ftanh(float x){
  x = fminf(fmaxf(x, -15.f), 15.f);
  float e = __builtin_amdgcn_exp2f(x*2.8853900817779268f); // exp(2x)
  return (e - 1.f)*frcp(e + 1.f);
}
__device__ __forceinline__ float rdlane(float v, int l){
  return __int_as_float(__builtin_amdgcn_readlane(__float_as_int(v), l));
}
__device__ __forceinline__ unsigned pk_bf16(float a, float b){
  unsigned r;
  asm volatile("v_cvt_pk_bf16_f32 %0, %1, %2" : "=v"(r) : "v"(a), "v"(b));
  return r;
}
__device__ __forceinline__ float bl(unsigned p){ return __uint_as_float(p << 16); }
__device__ __forceinline__ float bh(unsigned p){ return __uint_as_float(p & 0xffff0000u); }
__device__ __forceinline__ float tobf16f(float v){ return __uint_as_float(pk_bf16(v, 0.f) << 16); }

// ================= bucket histogram (196 coarse buckets) =================
__global__ __launch_bounds__(256) void k_bhist(const int* __restrict__ dst,
                                               int* __restrict__ bcnt) {
  __shared__ int h[NBKT];
  for (int i = threadIdx.x; i < NBKT; i += 256) h[i] = 0;
  __syncthreads();
  const int e0 = blockIdx.x * BIN_BLK;
  #pragma unroll 4
  for (int u = 0; u < 16; ++u) {
    int e = e0 + u*256 + threadIdx.x;
    if (e < N_EDGES) atomicAdd(&h[dst[e] >> 8], 1);
  }
  __syncthreads();
  for (int i = threadIdx.x; i < NBKT; i += 256) if (h[i]) atomicAdd(&bcnt[i], h[i]);
}

__global__ __launch_bounds__(256) void k_bscan(const int* __restrict__ bcnt,
                                               int* __restrict__ bstart,
                                               int* __restrict__ bcur,
                                               int* __restrict__ rowptrN) {
  __shared__ int s[256];
  int t = threadIdx.x;
  int v = (t < NBKT) ? bcnt[t] : 0;
  s[t] = v; __syncthreads();
  for (int off = 1; off < 256; off <<= 1) {
    int x = (t >= off) ? s[t-off] : 0;
    __syncthreads();
    s[t] += x;
    __syncthreads();
  }
  if (t < NBKT) { int st = s[t] - v; bstart[t] = st; bcur[t] = st; }
  if (t == 0) { bstart[NBKT] = N_EDGES; rowptrN[0] = N_EDGES; }
}

// ===== Pass A: bin edges into 196 coarse buckets =====
__global__ __launch_bounds__(1024) void k_binA(const int* __restrict__ dst,
                                               const int* __restrict__ src,
                                               const float* __restrict__ p,
                                               int* __restrict__ bcur,
                                               int2* __restrict__ binned) {
  __shared__ int lcnt[NBKT];
  __shared__ int lbase[NBKT];
  __shared__ int gbase[NBKT];
  __shared__ int tmp[256];
  __shared__ int totsh;
  __shared__ int2 stage[BIN_BLK];
  const int t = threadIdx.x;
  const int e0 = blockIdx.x * BIN_BLK;
  for (int i = t; i < NBKT; i += 1024) lcnt[i] = 0;
  __syncthreads();
  int myb[4], myr[4], myd[4], mys[4]; float myp[4];
  #pragma unroll
  for (int u = 0; u < 4; ++u) {
    int e = e0 + u*1024 + t;
    if (e < N_EDGES) {
      int d = dst[e];
      myd[u] = d; mys[u] = src[e]; myp[u] = p[e];
      int b = d >> 8;
      myb[u] = b;
      myr[u] = atomicAdd(&lcnt[b], 1);
    } else myb[u] = -1;
  }
  __syncthreads();
  if (t < 256) tmp[t] = (t < NBKT) ? lcnt[t] : 0;
  __syncthreads();
  for (int off = 1; off < 256; off <<= 1) {
    int v = (t >= off && t < 256) ? tmp[t-off] : 0;
    __syncthreads();
    if (t < 256) tmp[t] += v;
    __syncthreads();
  }
  if (t < NBKT) lbase[t] = tmp[t] - lcnt[t];
  if (t == NBKT-1) totsh = tmp[t];
  if (t < NBKT && lcnt[t] > 0) gbase[t] = atomicAdd(&bcur[t], lcnt[t]);
  __syncthreads();
  #pragma unroll
  for (int u = 0; u < 4; ++u) {
    if (myb[u] >= 0) {
      int x = (mys[u] & 0xffff) | ((myd[u] & 255) << 16) | (myb[u] << 24);
      stage[lbase[myb[u]] + myr[u]] = make_int2(x, __float_as_int(myp[u]));
    }
  }
  __syncthreads();
  const int tot = totsh;
  for (int i = t; i < tot; i += 1024) {
    int2 r = stage[i];
    int b = (unsigned)r.x >> 24;
    binned[gbase[b] + (i - lbase[b])] = r;
  }
}

// ===== Pass B: per-bucket two-pass — build rowptr AND final CSR order =====
__global__ __launch_bounds__(1024) void k_binB(const int* __restrict__ bstart,
                                               const int2* __restrict__ binned,
                                               int2* __restrict__ sorted,
                                               int* __restrict__ rowptr) {
  __shared__ int lcnt[256];
  __shared__ int loc[256];
  const int b = blockIdx.x;
  const int base = bstart[b], end = bstart[b+1];
  const int t = threadIdx.x;
  if (t < 256) lcnt[t] = 0;
  __syncthreads();
  for (int i = base + t; i < end; i += 1024)
    atomicAdd(&lcnt[(binned[i].x >> 16) & 255], 1);
  __syncthreads();
  if (t < 256) loc[t] = lcnt[t];
  __syncthreads();
  for (int off = 1; off < 256; off <<= 1) {
    int v = (t >= off && t < 256) ? loc[t-off] : 0;
    __syncthreads();
    if (t < 256) loc[t] += v;
    __syncthreads();
  }
  if (t < 256) {
    int st = base + loc[t] - lcnt[t];
    loc[t] = st;
    int node = b*256 + t;
    if (node < N_NODES) rowptr[node] = st;
    lcnt[t] = 0;
  }
  __syncthreads();
  for (int i = base + t; i < end; i += 1024) {
    int2 r = binned[i];
    int dlow = (r.x >> 16) & 255;
    int rank = atomicAdd(&lcnt[dlow], 1);
    sorted[loc[dlow] + rank] = r;
  }
}

__global__ __launch_bounds__(512) void k_gbound(const int* __restrict__ batch,
                                                int* __restrict__ gstart) {
  int g = threadIdx.x;
  int lo = 0, hi = N_NODES;
  while (lo < hi) { int mid = (lo+hi)>>1; if (batch[mid] < g) lo = mid+1; else hi = mid; }
  gstart[g] = lo;
  if (g == 0) gstart[NGRAPH] = N_NODES;
}

// ================= bf16 weight prepack: wi,wh [192][64] each =================
__global__ __launch_bounds__(256) void k_wpack(const float* __restrict__ wi,
                                               const float* __restrict__ wh,
                                               unsigned short* __restrict__ o) {
  int i = blockIdx.x*256 + threadIdx.x;
  if (i < 192*64)      o[i]          = (unsigned short)(pk_bf16(wi[i], 0.f) & 0xffffu);
  else if (i < 2*192*64) o[i]        = (unsigned short)(pk_bf16(wh[i - 192*64], 0.f) & 0xffffu);
}

// ===== MFMA lin1: wave = 16 nodes, K=39 padded; x split hi/lo bf16 (~fp32 acc) =====
// K layout: [hi x 0..38 pad->48 | lo x 0..38 pad->48] = 96 -> 3 chunks of 32.
__global__ __launch_bounds__(256) void k_lin1M(const float* __restrict__ x,
                                               const float* __restrict__ W,  // [64][39]
                                               const float* __restrict__ b,
                                               const float* __restrict__ v1,
                                               float* __restrict__ out,
                                               float* __restrict__ o1) {
  const int lane = threadIdx.x & 63;
  const int l15 = lane & 15, lg = lane >> 4;   // lg in 0..3
  const int n0 = blockIdx.x*64 + (threadIdx.x >> 6)*16;
  if (n0 >= N_NODES) return;
  union BF { bf16x8 v; unsigned u[4]; };
  // chunk mapping: kv0 = c*32+lg*8; kv0<48 -> hi(x[kv0+j]); else -> lo(x[kv0-48+j])
  BF Bf[3][4];
  #pragma unroll
  for (int c = 0; c < 3; ++c) {
    int kv0 = c*32 + lg*8;
    int off = (kv0 < 48) ? kv0 : (kv0 - 48);
    int cnt = 39 - off; cnt = cnt < 0 ? 0 : (cnt > 8 ? 8 : cnt);
    #pragma unroll
    for (int ct = 0; ct < 4; ++ct) {
      const float* wrow = W + (ct*16 + l15)*INC;
      float w8[8];
      #pragma unroll
      for (int j = 0; j < 8; ++j) w8[j] = (j < cnt) ? wrow[off+j] : 0.f;
      Bf[c][ct].u[0] = pk_bf16(w8[0], w8[1]);
      Bf[c][ct].u[1] = pk_bf16(w8[2], w8[3]);
      Bf[c][ct].u[2] = pk_bf16(w8[4], w8[5]);
      Bf[c][ct].u[3] = pk_bf16(w8[6], w8[7]);
    }
  }
  const int arow = n0 + l15;
  const bool av = arow < N_NODES;
  const float* xrow = x + (size_t)arow*INC;
  BF A[3];
  #pragma unroll
  for (int c = 0; c < 3; ++c) {
    int kv0 = c*32 + lg*8;
    int islo = (kv0 >= 48);
    int off = islo ? (kv0 - 48) : kv0;
    int cnt = 39 - off; cnt = cnt < 0 ? 0 : (cnt > 8 ? 8 : cnt);
    float a8[8];
    #pragma unroll
    for (int j = 0; j < 8; ++j) {
      float v = (av && j < cnt) ? xrow[off+j] : 0.f;
      if (islo) v = v - tobf16f(v);
      a8[j] = v;
    }
    A[c].u[0] = pk_bf16(a8[0], a8[1]);
    A[c].u[1] = pk_bf16(a8[2], a8[3]);
    A[c].u[2] = pk_bf16(a8[4], a8[5]);
    A[c].u[3] = pk_bf16(a8[6], a8[7]);
  }
  f32x4 acc[4];
  #pragma unroll
  for (int ct = 0; ct < 4; ++ct) acc[ct] = (f32x4){0.f,0.f,0.f,0.f};
  #pragma unroll
  for (int c = 0; c < 3; ++c)
    #pragma unroll
    for (int ct = 0; ct < 4; ++ct)
      acc[ct] = __builtin_amdgcn_mfma_f32_16x16x32_bf16(A[c].v, Bf[c][ct].v, acc[ct], 0, 0, 0);
  float bb[4], attv[4];
  #pragma unroll
  for (int ct = 0; ct < 4; ++ct) { bb[ct] = b[ct*16+l15]; attv[ct] = v1[ct*16+l15]; }
  #pragma unroll
  for (int reg = 0; reg < 4; ++reg) {
    const int node = n0 + 4*lg + reg;   // D: col=lane&15, row=4*(lane>>4)+reg
    const bool nv = node < N_NODES;
    float pr = 0.f;
    #pragma unroll
    for (int ct = 0; ct < 4; ++ct) {
      float val = lrelu(acc[ct][reg] + bb[ct]);
      if (nv) out[(size_t)node*64 + ct*16 + l15] = val;
      pr = fmaf(val, attv[ct], pr);
    }
    pr += __shfl_xor(pr, 1, 64);
    pr += __shfl_xor(pr, 2, 64);
    pr += __shfl_xor(pr, 4, 64);
    pr += __shfl_xor(pr, 8, 64);
    if (l15 == 0 && nv) o1[node] = pr;
  }
}

// ========== dual matmul -> u as bf16 [N][64] ushort, y packed 2ch/dword [N][32] ==========
__global__ __launch_bounds__(256) void k_mmdual(const float* __restrict__ in,
                                                const float* __restrict__ W1, // [64][80]
                                                const float* __restrict__ W2, // [64][64]
                                                unsigned short* __restrict__ ubf,
                                                unsigned* __restrict__ ypk, int R) {
  __shared__ float wl[128*65];
  for (int idx = threadIdx.x; idx < 4096; idx += 256) {
    int r = idx >> 6, c = idx & 63;
    wl[r*65+c]      = W1[r*80 + c];
    wl[(64+r)*65+c] = W2[r*64 + c];
  }
  __syncthreads();
  const int lane = threadIdx.x & 63;
  const int base = blockIdx.x*32 + (threadIdx.x>>6)*8;
  float h[8];
  #pragma unroll
  for (int i = 0; i < 8; ++i) { int n = base+i; h[i] = (n < R) ? in[n*64+lane] : 0.f; }
  float accU[8] = {0,0,0,0,0,0,0,0};
  float accY[8] = {0,0,0,0,0,0,0,0};
  for (int k = 0; k < 64; ++k) {
    float wu = wl[lane*65+k], wy = wl[(64+lane)*65+k];
    #pragma unroll
    for (int i = 0; i < 8; ++i) {
      float hk = rdlane(h[i], k);
      accU[i] += hk*wu; accY[i] += hk*wy;
    }
  }
  #pragma unroll
  for (int i = 0; i < 8; ++i) {
    int n = base+i; if (n >= R) continue;
    ubf[n*64 + lane] = (unsigned short)(pk_bf16(accU[i], 0.f) & 0xffffu);
    float partner = __shfl_xor(accY[i], 1, 64);
    if (!(lane & 1)) ypk[n*32 + (lane>>1)] = pk_bf16(accY[i], partner);
  }
}

// ========== [R,64] @ W.T; optional packed-bf16 pair table + fused per-row dots ==========
__global__ __launch_bounds__(256) void k_mm64(const float* __restrict__ in,
                                              const float* __restrict__ W, int rs,
                                              float* __restrict__ out,
                                              unsigned* __restrict__ outp, int R,
                                              const float* __restrict__ v1,
                                              const float* __restrict__ v2,
                                              float* __restrict__ o1,
                                              float* __restrict__ o2) {
  __shared__ float wl[64*65];
  for (int idx = threadIdx.x; idx < 4096; idx += 256) {
    int r = idx >> 6, c = idx & 63;
    wl[r*65+c] = W[r*rs + c];
  }
  __syncthreads();
  const int lane = threadIdx.x & 63;
  const int base = blockIdx.x*32 + (threadIdx.x>>6)*8;
  float h[8];
  #pragma unroll
  for (int i = 0; i < 8; ++i) { int n = base+i; h[i] = (n < R) ? in[n*64+lane] : 0.f; }
  float acc[8] = {0,0,0,0,0,0,0,0};
  for (int k = 0; k < 64; ++k) {
    float wv = wl[lane*65+k];
    #pragma unroll
    for (int i = 0; i < 8; ++i) acc[i] += rdlane(h[i], k) * wv;
  }
  float v1v = v1 ? v1[lane] : 0.f;
  float v2v = v2 ? v2[lane] : 0.f;
  #pragma unroll
  for (int i = 0; i < 8; ++i) {
    int n = base+i; if (n >= R) continue;
    if (out) out[n*64+lane] = acc[i];
    if (outp) {
      float partner = __shfl_xor(acc[i], 1, 64);
      if ((lane & 1) == 0) outp[n*32 + (lane>>1)] = pk_bf16(acc[i], partner);
    }
    if (o1) {
      float p1 = acc[i]*v1v;
      float p2 = acc[i]*v2v;
      #pragma unroll
      for (int s2 = 32; s2 > 0; s2 >>= 1) { p1 += __shfl_xor(p1, s2, 64); p2 += __shfl_xor(p2, s2, 64); }
      if (lane == 0) { o1[n] = p1; if (o2) o2[n] = p2; }
    }
  }
}

// ===== GATE edge scores, original order, software-pipelined u-gathers + NT streaming =====
__global__ __launch_bounds__(256) void k_escore(const int* __restrict__ srcarr,
                                                const float* __restrict__ ea,
                                                const float* __restrict__ glin1, // [64][80]
                                                const float* __restrict__ attl,
                                                const unsigned short* __restrict__ ubf,
                                                float* __restrict__ pout) {
  const int lane = threadIdx.x & 63;
  const int l15 = lane & 15, lg = lane >> 4;
  const int gw = blockIdx.x*4 + (threadIdx.x >> 6);
  if (gw >= N_EDGES/64) return;
  float attlv[4];
  unsigned Bu[4][2];
  #pragma unroll
  for (int c = 0; c < 4; ++c) {
    const float4 b = *(const float4*)&glin1[(c*16 + l15)*80 + 64 + lg*4];
    Bu[c][0] = pk_bf16(b.x, b.y);
    Bu[c][1] = pk_bf16(b.z, b.w);
    attlv[c] = attl[c*16 + l15];
  }
  const int i0 = gw*64;
  i32x4 sv[4];
  #pragma unroll
  for (int it = 0; it < 4; ++it)
    sv[it] = *(const i32x4*)&srcarr[i0 + it*16 + 4*lg];
  f32x4 a[4];
  #pragma unroll
  for (int it = 0; it < 4; ++it)
    a[it] = __builtin_nontemporal_load((const f32x4*)&ea[(size_t)(i0 + it*16 + l15)*16 + lg*4]);
  unsigned short ug0[4][4], ug1[4][4];
  #pragma unroll
  for (int c = 0; c < 4; ++c)
    #pragma unroll
    for (int r = 0; r < 4; ++r)
      ug0[c][r] = ubf[(size_t)sv[0][r]*64 + c*16 + l15];
  #pragma unroll
  for (int it = 0; it < 4; ++it) {
    if (it + 1 < 4) {
      #pragma unroll
      for (int c = 0; c < 4; ++c)
        #pragma unroll
        for (int r = 0; r < 4; ++r)
          ug1[c][r] = ubf[(size_t)sv[it+1][r]*64 + c*16 + l15];
    }
    union { bf16x8 v; unsigned u[4]; } A;
    A.u[0] = pk_bf16(a[it][0], a[it][1]);
    A.u[1] = pk_bf16(a[it][2], a[it][3]);
    A.u[2] = 0; A.u[3] = 0;
    float p[4] = {0.f,0.f,0.f,0.f};
    #pragma unroll
    for (int c = 0; c < 4; ++c) {
      union { bf16x8 v; unsigned u[4]; } B;
      B.u[0] = Bu[c][0]; B.u[1] = Bu[c][1]; B.u[2] = 0; B.u[3] = 0;
      f32x4 z = {0.f,0.f,0.f,0.f};
      f32x4 acc = __builtin_amdgcn_mfma_f32_16x16x32_bf16(A.v, B.v, z, 0, 0, 0);
      #pragma unroll
      for (int r = 0; r < 4; ++r) {
        float t = lrelu(__uint_as_float(((unsigned)ug0[c][r]) << 16) + acc[r]);
        p[r] = fmaf(t, attlv[c], p[r]);
      }
    }
    #pragma unroll
    for (int r = 0; r < 4; ++r) {
      p[r] += __shfl_xor(p[r], 1, 64);
      p[r] += __shfl_xor(p[r], 2, 64);
      p[r] += __shfl_xor(p[r], 4, 64);
      p[r] += __shfl_xor(p[r], 8, 64);
    }
    if (l15 == 0) {
      f32x4 o = {p[0], p[1], p[2], p[3]};
      __builtin_nontemporal_store(o, (f32x4*)&pout[i0 + it*16 + 4*lg]);
    }
    #pragma unroll
    for (int c = 0; c < 4; ++c)
      #pragma unroll
      for (int r = 0; r < 4; ++r)
        ug0[c][r] = ug1[c][r];
  }
}

// ===== GATE aggregation: sorted records {src|dlow|bkt, p}, bf16-packed y gathers =====
__global__ __launch_bounds__(256) void k_gate_agg(const int* __restrict__ rowptr,
                                                  const int2* __restrict__ sorted,
                                                  const float* __restrict__ xr,
                                                  const unsigned* __restrict__ ypk,
                                                  float* __restrict__ hagg) {
  __shared__ int   sS[4][64];
  __shared__ float sE[4][64];
  const int w = __builtin_amdgcn_readfirstlane(threadIdx.x >> 6);
  const int lane = threadIdx.x & 63;
  const int slot = lane >> 5, l2 = lane & 31;
  const int d = blockIdx.x*4 + w;
  const int r0 = __builtin_amdgcn_readfirstlane(rowptr[d]);
  const int r1 = __builtin_amdgcn_readfirstlane(rowptr[d+1]);
  const float xrd = xr[d];
  float accx = 0.f, accy = 0.f, ssum = 0.f;
  for (int base = r0; base < r1; base += 64) {
    int i = base + lane;
    int cnt = r1 - base; if (cnt > 64) cnt = 64;
    float ev = 0.f; int s = 0;
    if (i < r1) {
      int2 r = sorted[i];
      s = r.x & 0xffff;
      ev = fexp(lrelu(__int_as_float(r.y) + xrd));
    }
    sS[w][lane] = s; sE[w][lane] = ev;
    ssum += ev;
    for (int jb = 0; jb < cnt; jb += 16) {
      float e8[8]; unsigned p8[8];
      #pragma unroll
      for (int u = 0; u < 8; ++u) {
        int jj = jb + 2*u + slot;
        int svv; float evv;
        if (jj < cnt) { svv = sS[w][jj]; evv = sE[w][jj]; }
        else          { svv = 0; evv = 0.f; }
        e8[u] = evv;
        p8[u] = ypk[(size_t)svv*32 + l2];
      }
      #pragma unroll
      for (int u = 0; u < 8; ++u) {
        accx = fmaf(e8[u], bl(p8[u]), accx);
        accy = fmaf(e8[u], bh(p8[u]), accy);
      }
    }
  }
  #pragma unroll
  for (int sh = 32; sh > 0; sh >>= 1) ssum += __shfl_xor(ssum, sh, 64);
  accx += __shfl_xor(accx, 32, 64);
  accy += __shfl_xor(accy, 32, 64);
  float rs = frcp(ssum + 1e-16f);
  if (slot == 0) *(float2*)&hagg[d*64 + 2*l2] = make_float2(accx*rs, accy*rs);
}

// ===== GATConv fused: 2 edges per wave, bf16-packed hs, sorted src =====
__global__ __launch_bounds__(256) void k_conv_fused(const int* __restrict__ rowptr,
                                                    const int2* __restrict__ sorted,
                                                    const float* __restrict__ asn,
                                                    const float* __restrict__ adn,
                                                    const unsigned* __restrict__ hsb,
                                                    float* __restrict__ hagg) {
  __shared__ int   sS[4][64];
  __shared__ float sE[4][64];
  const int w = __builtin_amdgcn_readfirstlane(threadIdx.x >> 6);
  const int lane = threadIdx.x & 63;
  const int slot = lane >> 5, l2 = lane & 31;
  const int d = blockIdx.x*4 + w;
  const int r0 = __builtin_amdgcn_readfirstlane(rowptr[d]);
  const int r1 = __builtin_amdgcn_readfirstlane(rowptr[d+1]);
  float adnd = adn[d];
  float accx = 0.f, accy = 0.f, ssum = 0.f;
  for (int base = r0; base < r1; base += 64) {
    int i = base + lane;
    int cnt = r1 - base; if (cnt > 64) cnt = 64;
    float ev = 0.f; int s = 0;
    if (i < r1) { s = sorted[i].x & 0xffff; ev = fexp(lrelu(asn[s] + adnd)); }
    sS[w][lane] = s; sE[w][lane] = ev;
    ssum += ev;
    for (int jb = 0; jb < cnt; jb += 16) {
      float e8[8]; unsigned p8[8];
      #pragma unroll
      for (int u = 0; u < 8; ++u) {
        int jj = jb + 2*u + slot;
        int svv; float evv;
        if (jj < cnt) { svv = sS[w][jj]; evv = sE[w][jj]; }
        else          { svv = 0; evv = 0.f; }
        e8[u] = evv;
        p8[u] = hsb[(size_t)svv*32 + l2];
      }
      #pragma unroll
      for (int u = 0; u < 8; ++u) {
        accx = fmaf(e8[u], bl(p8[u]), accx);
        accy = fmaf(e8[u], bh(p8[u]), accy);
      }
    }
  }
  #pragma unroll
  for (int sh = 32; sh > 0; sh >>= 1) ssum += __shfl_xor(ssum, sh, 64);
  accx += __shfl_xor(accx, 32, 64);
  accy += __shfl_xor(accy, 32, 64);
  float rs = frcp(ssum + 1e-16f);
  if (slot == 0) *(float2*)&hagg[d*64 + 2*l2] = make_float2(accx*rs, accy*rs);
}

// ===== MFMA GRU: out = relu(GRU(elu(inp+pbias), hid)), wave = 16 nodes =====
__global__ __launch_bounds__(256) void k_gruM(const float* __restrict__ inp,
                                              const float* __restrict__ pbias,
                                              const float* __restrict__ hid,
                                              const unsigned short* __restrict__ wibf,
                                              const unsigned short* __restrict__ whbf,
                                              const float* __restrict__ bi,
                                              const float* __restrict__ bh2,
                                              float* __restrict__ out, int R) {
  const int lane = threadIdx.x & 63;
  const int l15 = lane & 15, lg = lane >> 4;
  const int n0 = blockIdx.x*64 + (threadIdx.x >> 6)*16;
  if (n0 >= R) return;
  union BF { bf16x8 v; unsigned u[4]; };
  BF Ai[2], Ah[2];
  const int arow = n0 + l15;
  const bool av = arow < R;
  const float* ibase = inp + (size_t)arow*64;
  const float* hbase = hid + (size_t)arow*64;
  #pragma unroll
  for (int c = 0; c < 2; ++c) {
    const int k0 = c*32 + lg*8;
    float4 p0 = *(const float4*)&pbias[k0];
    float4 p1 = *(const float4*)&pbias[k0+4];
    float4 v0, v1, h0, h1;
    if (av) {
      v0 = *(const float4*)&ibase[k0];   v1 = *(const float4*)&ibase[k0+4];
      h0 = *(const float4*)&hbase[k0];   h1 = *(const float4*)&hbase[k0+4];
    } else {
      v0 = v1 = h0 = h1 = make_float4(0.f,0.f,0.f,0.f);
      p0 = p1 = make_float4(0.f,0.f,0.f,0.f);
    }
    Ai[c].u[0] = pk_bf16(eluf(v0.x+p0.x), eluf(v0.y+p0.y));
    Ai[c].u[1] = pk_bf16(eluf(v0.z+p0.z), eluf(v0.w+p0.w));
    Ai[c].u[2] = pk_bf16(eluf(v1.x+p1.x), eluf(v1.y+p1.y));
    Ai[c].u[3] = pk_bf16(eluf(v1.z+p1.z), eluf(v1.w+p1.w));
    Ah[c].u[0] = pk_bf16(h0.x, h0.y);
    Ah[c].u[1] = pk_bf16(h0.z, h0.w);
    Ah[c].u[2] = pk_bf16(h1.x, h1.y);
    Ah[c].u[3] = pk_bf16(h1.z, h1.w);
  }
  f32x4 rz[8], ni[4], nh[4];
  #pragma unroll
  for (int t = 0; t < 8; ++t) rz[t] = (f32x4){0.f,0.f,0.f,0.f};
  #pragma unroll
  for (int t = 0; t < 4; ++t) { ni[t] = (f32x4){0.f,0.f,0.f,0.f}; nh[t] = (f32x4){0.f,0.f,0.f,0.f}; }
  #pragma unroll
  for (int t = 0; t < 12; ++t) {
    BF Bi0, Bi1, Bh0, Bh1;
    const size_t off = ((size_t)(t*16 + l15))*64 + lg*8;
    Bi0.v = *(const bf16x8*)&wibf[off];
    Bi1.v = *(const bf16x8*)&wibf[off + 32];
    Bh0.v = *(const bf16x8*)&whbf[off];
    Bh1.v = *(const bf16x8*)&whbf[off + 32];
    if (t < 8) {
      f32x4 a = rz[t];
      a = __builtin_amdgcn_mfma_f32_16x16x32_bf16(Ai[0].v, Bi0.v, a, 0, 0, 0);
      a = __builtin_amdgcn_mfma_f32_16x16x32_bf16(Ai[1].v, Bi1.v, a, 0, 0, 0);
      a = __builtin_amdgcn_mfma_f32_16x16x32_bf16(Ah[0].v, Bh0.v, a, 0, 0, 0);
      a = __builtin_amdgcn_mfma_f32_16x16x32_bf16(Ah[1].v, Bh1.v, a, 0, 0, 0);
      rz[t] = a;
    } else {
      f32x4 a = ni[t-8];
      a = __builtin_amdgcn_mfma_f32_16x16x32_bf16(Ai[0].v, Bi0.v, a, 0, 0, 0);
      a = __builtin_amdgcn_mfma_f32_16x16x32_bf16(Ai[1].v, Bi1.v, a, 0, 0, 0);
      ni[t-8] = a;
      f32x4 b = nh[t-8];
      b = __builtin_amdgcn_mfma_f32_16x16x32_bf16(Ah[0].v, Bh0.v, b, 0, 0, 0);
      b = __builtin_amdgcn_mfma_f32_16x16x32_bf16(Ah[1].v, Bh1.v, b, 0, 0, 0);
      nh[t-8] = b;
    }
  }
  float bsum[8], binv[4], bhnv[4];
  #pragma unroll
  for (int t = 0; t < 8; ++t) bsum[t] = bi[t*16+l15] + bh2[t*16+l15];
  #pragma unroll
  for (int t = 0; t < 4; ++t) {
    binv[t] = bi[128 + t*16 + l15];
    bhnv[t] = bh2[128 + t*16 + l15];
  }
  #pragma unroll
  for (int reg = 0; reg < 4; ++reg) {
    const int node = n0 + 4*lg + reg;
    if (node >= R) continue;
    #pragma unroll
    for (int tt = 0; tt < 4; ++tt) {
      float r  = sigm(rz[tt][reg] + bsum[tt]);
      float z  = sigm(rz[4+tt][reg] + bsum[4+tt]);
      float nn = ftanh(ni[tt][reg] + binv[tt] + r*(nh[tt][reg] + bhnv[tt]));
      float hh = hid[(size_t)node*64 + tt*16 + l15];
      float o  = (1.f - z)*nn + z*hh;
      out[(size_t)node*64 + tt*16 + l15] = fmaxf(o, 0.f);
    }
  }
}

// ================= molecule readout, split-K (8 slices per graph) =================
__global__ __launch_bounds__(256) void k_molsum_p(const int* __restrict__ gstart,
                                                  const float* __restrict__ x,
                                                  float* __restrict__ part) {
  int idx = blockIdx.x*4 + (threadIdx.x>>6);
  if (idx >= NGRAPH*8) return;
  int g = idx >> 3, sl = idx & 7;
  int lane = threadIdx.x & 63;
  int n0 = gstart[g], n1 = gstart[g+1];
  int len = n1 - n0;
  int b0 = n0 + (len*sl >> 3), b1 = n0 + (len*(sl+1) >> 3);
  float acc = 0.f;
  for (int n = b0; n < b1; ++n) acc += x[n*64+lane];
  part[idx*64+lane] = acc;
}

__global__ __launch_bounds__(256) void k_molsum_c(const float* __restrict__ part,
                                                  float* __restrict__ outg) {
  int g = blockIdx.x*4 + (threadIdx.x>>6);
  if (g >= NGRAPH) return;
  int lane = threadIdx.x & 63;
  float a = 0.f;
  #pragma unroll
  for (int s = 0; s < 8; ++s) a += part[(g*8+s)*64+lane];
  outg[g*64+lane] = fmaxf(a, 0.f);
}

__global__ __launch_bounds__(256) void k_molhd(const float* __restrict__ outg,
                                               const float* __restrict__ W,
                                               const float* __restrict__ attd,
                                               float* __restrict__ addg) {
  __shared__ float wl[64*65];
  for (int idx = threadIdx.x; idx < 4096; idx += 256) wl[(idx>>6)*65+(idx&63)] = W[idx];
  __syncthreads();
  int g = blockIdx.x*4 + (threadIdx.x>>6);
  if (g >= NGRAPH) return;
  int lane = threadIdx.x & 63;
  float og = outg[g*64+lane];
  float hd = 0.f;
  #pragma unroll
  for (int k = 0; k < 64; ++k) hd += rdlane(og, k) * wl[lane*65+k];
  float p = hd * attd[lane];
  #pragma unroll
  for (int sh = 32; sh > 0; sh >>= 1) p += __shfl_xor(p, sh, 64);
  if (lane == 0) addg[g] = p;
}

__global__ __launch_bounds__(256) void k_molp(const int* __restrict__ gstart,
                                              const float* __restrict__ addg,
                                              const float* __restrict__ asn,
                                              const float* __restrict__ y,
                                              float* __restrict__ part_acc,
                                              float* __restrict__ part_ss) {
  int idx = blockIdx.x*4 + (threadIdx.x>>6);
  if (idx >= NGRAPH*8) return;
  int g = idx >> 3, sl = idx & 7;
  int lane = threadIdx.x & 63;
  int n0 = gstart[g], n1 = gstart[g+1];
  int len = n1 - n0;
  int b0 = n0 + (len*sl >> 3), b1 = n0 + (len*(sl+1) >> 3);
  float adg = addg[g];
  float acc = 0.f, ss = 0.f;
  for (int n = b0; n < b1; ++n) {
    float ev = fexp(lrelu(asn[n] + adg));
    acc += ev * y[n*64+lane];
    ss  += ev;
  }
  part_acc[idx*64+lane] = acc;
  if (lane == 0) part_ss[idx] = ss;
}

__global__ __launch_bounds__(256) void k_molc(const float* __restrict__ part_acc,
                                              const float* __restrict__ part_ss,
                                              float* __restrict__ hg) {
  int g = blockIdx.x*4 + (threadIdx.x>>6);
  if (g >= NGRAPH) return;
  int lane = threadIdx.x & 63;
  float a = 0.f, ss = 0.f;
  #pragma unroll
  for (int s = 0; s < 8; ++s) {
    a  += part_acc[(g*8+s)*64+lane];
    ss += part_ss[g*8+s];
  }
  hg[g*64+lane] = a * frcp(ss + 1e-16f);
}

__global__ __launch_bounds__(128) void k_final(const float* __restrict__ outg,
                                               const float* __restrict__ W,
                                               const float* __restrict__ b,
                                               float* __restrict__ out) {
  __shared__ float og[64];
  int g = blockIdx.x;
  if (threadIdx.x < 64) og[threadIdx.x] = outg[g*64+threadIdx.x];
  __syncthreads();
  int o = threadIdx.x;
  float acc = b[o];
  for (int k = 0; k < 64; ++k) acc += og[k]*W[o*64+k];
  out[g*128+o] = acc;
}

extern "C" void kernel_launch(void* const* d_in, const int* in_sizes, int n_in,
                              void* d_out, int out_size, void* d_ws, size_t ws_size,
                              hipStream_t stream) {
  const float* x_in     = (const float*)d_in[0];
  const int*   eidx     = (const int*)  d_in[1];
  const float* eattr    = (const float*)d_in[2];
  const int*   batch    = (const int*)  d_in[3];
  const float* lin1_w   = (const float*)d_in[4];
  const float* lin1_b   = (const float*)d_in[5];
  const float* g_lin1_w = (const float*)d_in[6];
  const float* g_att_l  = (const float*)d_in[7];
  const float* g_att_r  = (const float*)d_in[8];
  const float* g_lin2_w = (const float*)d_in[9];
  const float* g_bias   = (const float*)d_in[10];
  const float* gru0_wi  = (const float*)d_in[11];
  const float* gru0_wh  = (const float*)d_in[12];
  const float* gru0_bi  = (const float*)d_in[13];
  const float* gru0_bh  = (const float*)d_in[14];
  const float* conv_lin_w   = (const float*)d_in[15];
  const float* conv_att_src = (const float*)d_in[16];
  const float* conv_att_dst = (const float*)d_in[17];
  const float* conv_bias    = (const float*)d_in[18];
  const float* grul_wi  = (const float*)d_in[19];
  const float* grul_wh  = (const float*)d_in[20];
  const float* grul_bi  = (const float*)d_in[21];
  const float* grul_bh  = (const float*)d_in[22];
  const float* mol_lin_w    = (const float*)d_in[23];
  const float* mol_att_src  = (const float*)d_in[24];
  const float* mol_att_dst  = (const float*)d_in[25];
  const float* mol_bias     = (const float*)d_in[26];
  const float* mgru_wi  = (const float*)d_in[27];
  const float* mgru_wh  = (const float*)d_in[28];
  const float* mgru_bi  = (const float*)d_in[29];
  const float* mgru_bh  = (const float*)d_in[30];
  const float* lin2_w   = (const float*)d_in[31];
  const float* lin2_b   = (const float*)d_in[32];

  const int N64 = N_NODES*64;
  float* ws     = (float*)d_ws;
  float* xA     = ws;               // N*64
  float* xB     = xA + N64;         // N*64
  float* uy     = xB + N64;         // 2*N64: ubf(ushort N*64)+ypk(uint N*32) / hsb / ymol
  float* hagg   = uy + 2*N64;       // N*64
  float* sc1    = hagg + N64;       // N
  float* sc2    = sc1 + N_NODES;    // N
  float* pbuf   = sc2 + N_NODES;    // E (edge scores, ORIGINAL order)
  float* outg   = pbuf + N_EDGES;   // G*64
  int* bcnt   = (int*)(outg + NGRAPH*64); // NBKT (bucket histogram)
  int* rowptr = bcnt + N_NODES;     // N+2
  int2* binned = (int2*)(rowptr + N_NODES + 2); // E  (reused: mol partials)
  int2* sorted = binned + N_EDGES;  // E
  int* gstart = (int*)(sorted + N_EDGES); // G+1
  int* bstart = gstart + NGRAPH+1;  // NBKT+1
  int* bcur   = bstart + NBKT+1;    // NBKT
  unsigned short* wpk = (unsigned short*)(bcur + NBKT + 4); // 4 pairs * 2*192*64 bf16

  unsigned short* ubf = (unsigned short*)uy;       // N*64 bf16 u
  unsigned* ypk = (unsigned*)(uy + N64);           // N*32 packed y
  unsigned* hsb = (unsigned*)uy;                   // N*32 packed hs (reused after gate)

  float* part_acc = (float*)binned;                // G*8*64
  float* part_ss  = part_acc + NGRAPH*8*64;        // G*8
  float* addg     = part_ss + NGRAPH*8;            // G

  const int* src = eidx;
  const int* dst = eidx + N_EDGES;

  const int nbN32 = (N_NODES + 31)/32;
  const int nbN4  = (N_NODES + 3)/4;
  const int nbN64 = (N_NODES + 63)/64;
  const int nbG4  = (NGRAPH + 3)/4;
  const int nbG8  = (NGRAPH*8 + 3)/4;
  const int nbES  = (N_EDGES/64 + 3)/4;
  const int nbBIN = (N_EDGES + BIN_BLK-1)/BIN_BLK;
  const int PAIR  = 2*192*64;

  // ---- bucket histogram + scan (CSR rowptr comes from k_binB) ----
  hipMemsetAsync(bcnt, 0, NBKT*sizeof(int), stream);
  k_bhist<<<nbBIN, 256, 0, stream>>>(dst, bcnt);
  k_bscan<<<1, 256, 0, stream>>>(bcnt, bstart, bcur, rowptr + N_NODES);
  k_gbound<<<1, 512, 0, stream>>>(batch, gstart);

  // ---- GRU weight prepack (bf16) ----
  k_wpack<<<(PAIR+255)/256, 256, 0, stream>>>(gru0_wi, gru0_wh, wpk);
  k_wpack<<<(PAIR+255)/256, 256, 0, stream>>>(grul_wi, grul_wh, wpk + PAIR);
  k_wpack<<<(PAIR+255)/256, 256, 0, stream>>>(grul_wi + 192*64, grul_wh + 192*64, wpk + 2*PAIR);
  k_wpack<<<(PAIR+255)/256, 256, 0, stream>>>(mgru_wi, mgru_wh, wpk + 3*PAIR);

  // ---- lin1 via MFMA (hi/lo split x, fused xr dot) ----
  k_lin1M<<<nbN64, 256, 0, stream>>>(x_in, lin1_w, lin1_b, g_att_r, xA, sc1);

  // ---- GATEConv: scores in original order, then locality-aware bin sort ----
  k_mmdual<<<nbN32, 256, 0, stream>>>(xA, g_lin1_w, g_lin2_w, ubf, ypk, N_NODES);
  k_escore<<<nbES, 256, 0, stream>>>(src, eattr, g_lin1_w, g_att_l, ubf, pbuf);
  k_binA<<<nbBIN, 1024, 0, stream>>>(dst, src, pbuf, bcur, binned);
  k_binB<<<NBKT, 1024, 0, stream>>>(bstart, binned, sorted, rowptr);
  k_gate_agg<<<nbN4, 256, 0, stream>>>(rowptr, sorted, sc1, ypk, hagg);
  k_gruM<<<nbN64, 256, 0, stream>>>(hagg, g_bias, xA, wpk, wpk + 192*64,
                                    gru0_bi, gru0_bh, xB, N_NODES);

  float* xcur = xB; float* xoth = xA;

  // ---- GATConv layers ----
  for (int l = 0; l < 2; ++l) {
    k_mm64<<<nbN32, 256, 0, stream>>>(xcur, conv_lin_w + l*64*64, 64, nullptr, hsb, N_NODES,
                                      conv_att_src + l*64, conv_att_dst + l*64, sc1, sc2);
    k_conv_fused<<<nbN4, 256, 0, stream>>>(rowptr, sorted, sc1, sc2, hsb, hagg);
    k_gruM<<<nbN64, 256, 0, stream>>>(hagg, conv_bias + l*64, xcur,
                                      wpk + (1+l)*PAIR, wpk + (1+l)*PAIR + 192*64,
                                      grul_bi + l*192, grul_bh + l*192, xoth, N_NODES);
    float* t = xcur; xcur = xoth; xoth = t;
  }

  // ---- molecule readout (split-K over node slices) ----
  float* ymol = uy;
  k_molsum_p<<<nbG8, 256, 0, stream>>>(gstart, xcur, part_acc);
  k_molsum_c<<<nbG4, 256, 0, stream>>>(part_acc, outg);
  k_mm64<<<nbN32, 256, 0, stream>>>(xcur, mol_lin_w, 64, ymol, nullptr, N_NODES,
                                    mol_att_src, nullptr, sc1, nullptr);
  for (int t = 0; t < 2; ++t) {
    k_molhd<<<nbG4, 256, 0, stream>>>(outg, mol_lin_w, mol_att_dst, addg);
    k_molp<<<nbG8, 256, 0, stream>>>(gstart, addg, sc1, ymol, part_acc, part_ss);
    k_molc<<<nbG4, 256, 0, stream>>>(part_acc, part_ss, hagg);
    k_gruM<<<(NGRAPH+63)/64, 256, 0, stream>>>(hagg, mol_bias, outg,
                                               wpk + 3*PAIR, wpk + 3*PAIR + 192*64,
                                               mgru_bi, mgru_bh, outg, NGRAPH);
  }

  // ---- final linear ----
  k_final<<<NGRAPH, 128, 0, stream>>>(outg, lin2_w, lin2_b, (float*)d_out);
}

// Round 13
// 419.227 us; speedup vs baseline: 4.1418x; 1.0846x over previous
//
#include <hip/hip_runtime.h>
#include <math.h>

#define N_NODES 50000
#define N_EDGES 1000000
#define NGRAPH  512
#define INC     39
#define NBKT 196 // dst buckets of 256 nodes
#define BIN_BLK 4096
#define PAIR_C (2*192*64)

typedef __attribute__((ext_vector_type(8))) short bf16x8;
typedef __attribute__((ext_vector_type(4))) float f32x4;
typedef __attribute__((ext_vector_type(4))) int i32x4;

__device__ __forceinline__ float lrelu(float x){ return fmaxf(0.01f*x, x); }
__device__ __forceinline__ float fexp(float x){ return __builtin_amdgcn_exp2f(x*1.4426950408889634f); }
__device__ __forceinline__ float frcp(float x){ return __builtin_amdgcn_rcpf(x); }
__device__ __forceinline__ float eluf (float x){ return x > 0.f ? x : fexp(x) - 1.f; }
__device__ __forceinline__ float sigm (float x){ return frcp(1.f + fexp(-x)); }
__device__ __forceinline__ float ftanh(float x){
  x = fminf(fmaxf(x, -15.f), 15.f);
  float e = __builtin_amdgcn_exp2f(x*2.8853900817779268f); // exp(2x)
  return (e - 1.f)*frcp(e + 1.f);
}
__device__ __forceinline__ float rdlane(float v, int l){
  return __int_as_float(__builtin_amdgcn_readlane(__float_as_int(v), l));
}
__device__ __forceinline__ unsigned pk_bf16(float a, float b){
  unsigned r;
  asm volatile("v_cvt_pk_bf16_f32 %0, %1, %2" : "=v"(r) : "v"(a), "v"(b));
  return r;
}
__device__ __forceinline__ float bl(unsigned p){ return __uint_as_float(p << 16); }
__device__ __forceinline__ float bh(unsigned p){ return __uint_as_float(p & 0xffff0000u); }
__device__ __forceinline__ float tobf16f(float v){ return __uint_as_float(pk_bf16(v, 0.f) << 16); }

// ================= bucket histogram (196 coarse buckets) =================
__global__ __launch_bounds__(256) void k_bhist(const int* __restrict__ dst,
                                               int* __restrict__ bcnt) {
  __shared__ int h[NBKT];
  for (int i = threadIdx.x; i < NBKT; i += 256) h[i] = 0;
  __syncthreads();
  const int e0 = blockIdx.x * BIN_BLK;
  #pragma unroll 4
  for (int u = 0; u < 16; ++u) {
    int e = e0 + u*256 + threadIdx.x;
    if (e < N_EDGES) atomicAdd(&h[dst[e] >> 8], 1);
  }
  __syncthreads();
  for (int i = threadIdx.x; i < NBKT; i += 256) if (h[i]) atomicAdd(&bcnt[i], h[i]);
}

// ===== merged: bucket scan + bcur init + graph bounds =====
__global__ __launch_bounds__(512) void k_setup(const int* __restrict__ bcnt,
                                               int* __restrict__ bstart,
                                               int* __restrict__ bcur,
                                               int* __restrict__ rowptrN,
                                               const int* __restrict__ batch,
                                               int* __restrict__ gstart) {
  __shared__ int s[256];
  const int t = threadIdx.x;
  int v = 0;
  if (t < 256) { v = (t < NBKT) ? bcnt[t] : 0; s[t] = v; }
  __syncthreads();
  for (int off = 1; off < 256; off <<= 1) {
    int x = (t >= off && t < 256) ? s[t-off] : 0;
    __syncthreads();
    if (t < 256) s[t] += x;
    __syncthreads();
  }
  if (t < NBKT) { int st = s[t] - v; bstart[t] = st; bcur[t] = st; }
  if (t == 0) { bstart[NBKT] = N_EDGES; rowptrN[0] = N_EDGES; }
  // graph bounds via binary search
  int g = t;
  int lo = 0, hi = N_NODES;
  while (lo < hi) { int mid = (lo+hi)>>1; if (batch[mid] < g) lo = mid+1; else hi = mid; }
  gstart[g] = lo;
  if (g == 0) gstart[NGRAPH] = N_NODES;
}

// ===== Pass A: bin edges into 196 coarse buckets =====
__global__ __launch_bounds__(1024) void k_binA(const int* __restrict__ dst,
                                               const int* __restrict__ src,
                                               const float* __restrict__ p,
                                               int* __restrict__ bcur,
                                               int2* __restrict__ binned) {
  __shared__ int lcnt[NBKT];
  __shared__ int lbase[NBKT];
  __shared__ int gbase[NBKT];
  __shared__ int tmp[256];
  __shared__ int totsh;
  __shared__ int2 stage[BIN_BLK];
  const int t = threadIdx.x;
  const int e0 = blockIdx.x * BIN_BLK;
  for (int i = t; i < NBKT; i += 1024) lcnt[i] = 0;
  __syncthreads();
  int myb[4], myr[4], myd[4], mys[4]; float myp[4];
  #pragma unroll
  for (int u = 0; u < 4; ++u) {
    int e = e0 + u*1024 + t;
    if (e < N_EDGES) {
      int d = dst[e];
      myd[u] = d; mys[u] = src[e]; myp[u] = p[e];
      int b = d >> 8;
      myb[u] = b;
      myr[u] = atomicAdd(&lcnt[b], 1);
    } else myb[u] = -1;
  }
  __syncthreads();
  if (t < 256) tmp[t] = (t < NBKT) ? lcnt[t] : 0;
  __syncthreads();
  for (int off = 1; off < 256; off <<= 1) {
    int v = (t >= off && t < 256) ? tmp[t-off] : 0;
    __syncthreads();
    if (t < 256) tmp[t] += v;
    __syncthreads();
  }
  if (t < NBKT) lbase[t] = tmp[t] - lcnt[t];
  if (t == NBKT-1) totsh = tmp[t];
  if (t < NBKT && lcnt[t] > 0) gbase[t] = atomicAdd(&bcur[t], lcnt[t]);
  __syncthreads();
  #pragma unroll
  for (int u = 0; u < 4; ++u) {
    if (myb[u] >= 0) {
      int x = (mys[u] & 0xffff) | ((myd[u] & 255) << 16) | (myb[u] << 24);
      stage[lbase[myb[u]] + myr[u]] = make_int2(x, __float_as_int(myp[u]));
    }
  }
  __syncthreads();
  const int tot = totsh;
  for (int i = t; i < tot; i += 1024) {
    int2 r = stage[i];
    int b = (unsigned)r.x >> 24;
    binned[gbase[b] + (i - lbase[b])] = r;
  }
}

// ===== Pass B: per-bucket two-pass — build rowptr AND final CSR order =====
__global__ __launch_bounds__(1024) void k_binB(const int* __restrict__ bstart,
                                               const int2* __restrict__ binned,
                                               int2* __restrict__ sorted,
                                               int* __restrict__ rowptr) {
  __shared__ int lcnt[256];
  __shared__ int loc[256];
  const int b = blockIdx.x;
  const int base = bstart[b], end = bstart[b+1];
  const int t = threadIdx.x;
  if (t < 256) lcnt[t] = 0;
  __syncthreads();
  for (int i = base + t; i < end; i += 1024)
    atomicAdd(&lcnt[(binned[i].x >> 16) & 255], 1);
  __syncthreads();
  if (t < 256) loc[t] = lcnt[t];
  __syncthreads();
  for (int off = 1; off < 256; off <<= 1) {
    int v = (t >= off && t < 256) ? loc[t-off] : 0;
    __syncthreads();
    if (t < 256) loc[t] += v;
    __syncthreads();
  }
  if (t < 256) {
    int st = base + loc[t] - lcnt[t];
    loc[t] = st;
    int node = b*256 + t;
    if (node < N_NODES) rowptr[node] = st;
    lcnt[t] = 0;
  }
  __syncthreads();
  for (int i = base + t; i < end; i += 1024) {
    int2 r = binned[i];
    int dlow = (r.x >> 16) & 255;
    int rank = atomicAdd(&lcnt[dlow], 1);
    sorted[loc[dlow] + rank] = r;
  }
}

// ================= bf16 weight prepack: 4 GRU pairs in one launch =================
__global__ __launch_bounds__(256) void k_wpack4(const float* __restrict__ a0, const float* __restrict__ b0,
                                                const float* __restrict__ a1, const float* __restrict__ b1,
                                                const float* __restrict__ a2, const float* __restrict__ b2,
                                                const float* __restrict__ a3, const float* __restrict__ b3,
                                                unsigned short* __restrict__ o) {
  int i = blockIdx.x*256 + threadIdx.x;
  if (i >= 4*PAIR_C) return;
  int pair = i / PAIR_C;
  int r = i - pair*PAIR_C;
  bool hi = r >= 192*64;
  int rr = hi ? r - 192*64 : r;
  const float* s;
  if      (pair == 0) s = hi ? b0 : a0;
  else if (pair == 1) s = hi ? b1 : a1;
  else if (pair == 2) s = hi ? b2 : a2;
  else                s = hi ? b3 : a3;
  o[i] = (unsigned short)(pk_bf16(s[rr], 0.f) & 0xffffu);
}

// ===== MFMA lin1: wave = 16 nodes, K=39 padded; x split hi/lo bf16 =====
__global__ __launch_bounds__(256) void k_lin1M(const float* __restrict__ x,
                                               const float* __restrict__ W,  // [64][39]
                                               const float* __restrict__ b,
                                               const float* __restrict__ v1,
                                               float* __restrict__ out,
                                               float* __restrict__ o1) {
  const int lane = threadIdx.x & 63;
  const int l15 = lane & 15, lg = lane >> 4;
  const int n0 = blockIdx.x*64 + (threadIdx.x >> 6)*16;
  if (n0 >= N_NODES) return;
  union BF { bf16x8 v; unsigned u[4]; };
  BF Bf[3][4];
  #pragma unroll
  for (int c = 0; c < 3; ++c) {
    int kv0 = c*32 + lg*8;
    int off = (kv0 < 48) ? kv0 : (kv0 - 48);
    int cnt = 39 - off; cnt = cnt < 0 ? 0 : (cnt > 8 ? 8 : cnt);
    #pragma unroll
    for (int ct = 0; ct < 4; ++ct) {
      const float* wrow = W + (ct*16 + l15)*INC;
      float w8[8];
      #pragma unroll
      for (int j = 0; j < 8; ++j) w8[j] = (j < cnt) ? wrow[off+j] : 0.f;
      Bf[c][ct].u[0] = pk_bf16(w8[0], w8[1]);
      Bf[c][ct].u[1] = pk_bf16(w8[2], w8[3]);
      Bf[c][ct].u[2] = pk_bf16(w8[4], w8[5]);
      Bf[c][ct].u[3] = pk_bf16(w8[6], w8[7]);
    }
  }
  const int arow = n0 + l15;
  const bool av = arow < N_NODES;
  const float* xrow = x + (size_t)arow*INC;
  BF A[3];
  #pragma unroll
  for (int c = 0; c < 3; ++c) {
    int kv0 = c*32 + lg*8;
    int islo = (kv0 >= 48);
    int off = islo ? (kv0 - 48) : kv0;
    int cnt = 39 - off; cnt = cnt < 0 ? 0 : (cnt > 8 ? 8 : cnt);
    float a8[8];
    #pragma unroll
    for (int j = 0; j < 8; ++j) {
      float v = (av && j < cnt) ? xrow[off+j] : 0.f;
      if (islo) v = v - tobf16f(v);
      a8[j] = v;
    }
    A[c].u[0] = pk_bf16(a8[0], a8[1]);
    A[c].u[1] = pk_bf16(a8[2], a8[3]);
    A[c].u[2] = pk_bf16(a8[4], a8[5]);
    A[c].u[3] = pk_bf16(a8[6], a8[7]);
  }
  f32x4 acc[4];
  #pragma unroll
  for (int ct = 0; ct < 4; ++ct) acc[ct] = (f32x4){0.f,0.f,0.f,0.f};
  #pragma unroll
  for (int c = 0; c < 3; ++c)
    #pragma unroll
    for (int ct = 0; ct < 4; ++ct)
      acc[ct] = __builtin_amdgcn_mfma_f32_16x16x32_bf16(A[c].v, Bf[c][ct].v, acc[ct], 0, 0, 0);
  float bb[4], attv[4];
  #pragma unroll
  for (int ct = 0; ct < 4; ++ct) { bb[ct] = b[ct*16+l15]; attv[ct] = v1[ct*16+l15]; }
  #pragma unroll
  for (int reg = 0; reg < 4; ++reg) {
    const int node = n0 + 4*lg + reg;
    const bool nv = node < N_NODES;
    float pr = 0.f;
    #pragma unroll
    for (int ct = 0; ct < 4; ++ct) {
      float val = lrelu(acc[ct][reg] + bb[ct]);
      if (nv) out[(size_t)node*64 + ct*16 + l15] = val;
      pr = fmaf(val, attv[ct], pr);
    }
    pr += __shfl_xor(pr, 1, 64);
    pr += __shfl_xor(pr, 2, 64);
    pr += __shfl_xor(pr, 4, 64);
    pr += __shfl_xor(pr, 8, 64);
    if (l15 == 0 && nv) o1[node] = pr;
  }
}

// ===== MFMA dual matmul: u (bf16 pairs into ubf region) + y (packed) =====
__global__ __launch_bounds__(256) void k_mmdualM(const float* __restrict__ in,
                                                 const float* __restrict__ W1, // [64][80]
                                                 const float* __restrict__ W2, // [64][64]
                                                 unsigned* __restrict__ ubf32, // N*32 dwords (= ushort N*64)
                                                 unsigned* __restrict__ ypk, int R) {
  const int lane = threadIdx.x & 63;
  const int l15 = lane & 15, lg = lane >> 4;
  const int n0 = blockIdx.x*64 + (threadIdx.x >> 6)*16;
  if (n0 >= R) return;
  union BF { bf16x8 v; unsigned u[4]; };
  BF B1[4][2], B2[4][2];
  #pragma unroll
  for (int ct = 0; ct < 4; ++ct) {
    #pragma unroll
    for (int c = 0; c < 2; ++c) {
      const float* w1 = W1 + (size_t)(ct*16 + l15)*80 + c*32 + lg*8;
      const float* w2 = W2 + (size_t)(ct*16 + l15)*64 + c*32 + lg*8;
      B1[ct][c].u[0] = pk_bf16(w1[0], w1[1]);
      B1[ct][c].u[1] = pk_bf16(w1[2], w1[3]);
      B1[ct][c].u[2] = pk_bf16(w1[4], w1[5]);
      B1[ct][c].u[3] = pk_bf16(w1[6], w1[7]);
      B2[ct][c].u[0] = pk_bf16(w2[0], w2[1]);
      B2[ct][c].u[1] = pk_bf16(w2[2], w2[3]);
      B2[ct][c].u[2] = pk_bf16(w2[4], w2[5]);
      B2[ct][c].u[3] = pk_bf16(w2[6], w2[7]);
    }
  }
  const int arow = n0 + l15;
  const bool av = arow < R;
  const float* xr = in + (size_t)arow*64;
  BF A[2];
  #pragma unroll
  for (int c = 0; c < 2; ++c) {
    const int k0 = c*32 + lg*8;
    float4 v0, v1;
    if (av) { v0 = *(const float4*)&xr[k0]; v1 = *(const float4*)&xr[k0+4]; }
    else    { v0 = v1 = make_float4(0.f,0.f,0.f,0.f); }
    A[c].u[0] = pk_bf16(v0.x, v0.y);
    A[c].u[1] = pk_bf16(v0.z, v0.w);
    A[c].u[2] = pk_bf16(v1.x, v1.y);
    A[c].u[3] = pk_bf16(v1.z, v1.w);
  }
  f32x4 aU[4], aY[4];
  #pragma unroll
  for (int ct = 0; ct < 4; ++ct) { aU[ct] = (f32x4){0.f,0.f,0.f,0.f}; aY[ct] = (f32x4){0.f,0.f,0.f,0.f}; }
  #pragma unroll
  for (int c = 0; c < 2; ++c)
    #pragma unroll
    for (int ct = 0; ct < 4; ++ct) {
      aU[ct] = __builtin_amdgcn_mfma_f32_16x16x32_bf16(A[c].v, B1[ct][c].v, aU[ct], 0, 0, 0);
      aY[ct] = __builtin_amdgcn_mfma_f32_16x16x32_bf16(A[c].v, B2[ct][c].v, aY[ct], 0, 0, 0);
    }
  #pragma unroll
  for (int reg = 0; reg < 4; ++reg) {
    const int node = n0 + 4*lg + reg;
    const bool nv = node < R;
    #pragma unroll
    for (int ct = 0; ct < 4; ++ct) {
      float uu = aU[ct][reg], yy = aY[ct][reg];
      float up = __shfl_xor(uu, 1, 64);
      float yp = __shfl_xor(yy, 1, 64);
      if (!(l15 & 1) && nv) {
        unsigned idx = (unsigned)node*32 + ct*8 + (l15>>1);
        ubf32[idx] = pk_bf16(uu, up);
        ypk[idx]   = pk_bf16(yy, yp);
      }
    }
  }
}

// ===== MFMA mm64: [R,64]@W.T; optional fp32 out / packed out / dual dots; hilo for fp32-grade =====
__global__ __launch_bounds__(256) void k_mm64M(const float* __restrict__ in,
                                               const float* __restrict__ W, int rs,
                                               float* __restrict__ out,
                                               unsigned* __restrict__ outp, int R,
                                               const float* __restrict__ v1,
                                               const float* __restrict__ v2,
                                               float* __restrict__ o1,
                                               float* __restrict__ o2, int hilo) {
  const int lane = threadIdx.x & 63;
  const int l15 = lane & 15, lg = lane >> 4;
  const int n0 = blockIdx.x*64 + (threadIdx.x >> 6)*16;
  if (n0 >= R) return;
  union BF { bf16x8 v; unsigned u[4]; };
  BF Bf[4][2];
  #pragma unroll
  for (int ct = 0; ct < 4; ++ct) {
    #pragma unroll
    for (int c = 0; c < 2; ++c) {
      const float* w = W + (size_t)(ct*16 + l15)*rs + c*32 + lg*8;
      Bf[ct][c].u[0] = pk_bf16(w[0], w[1]);
      Bf[ct][c].u[1] = pk_bf16(w[2], w[3]);
      Bf[ct][c].u[2] = pk_bf16(w[4], w[5]);
      Bf[ct][c].u[3] = pk_bf16(w[6], w[7]);
    }
  }
  const int arow = n0 + l15;
  const bool av = arow < R;
  const float* xr = in + (size_t)arow*64;
  BF A[2], Alo[2];
  #pragma unroll
  for (int c = 0; c < 2; ++c) {
    const int k0 = c*32 + lg*8;
    float f[8];
    if (av) {
      float4 v0 = *(const float4*)&xr[k0];
      float4 v1l = *(const float4*)&xr[k0+4];
      f[0]=v0.x; f[1]=v0.y; f[2]=v0.z; f[3]=v0.w;
      f[4]=v1l.x; f[5]=v1l.y; f[6]=v1l.z; f[7]=v1l.w;
    } else {
      #pragma unroll
      for (int j = 0; j < 8; ++j) f[j] = 0.f;
    }
    A[c].u[0] = pk_bf16(f[0], f[1]);
    A[c].u[1] = pk_bf16(f[2], f[3]);
    A[c].u[2] = pk_bf16(f[4], f[5]);
    A[c].u[3] = pk_bf16(f[6], f[7]);
    if (hilo) {
      float l[8];
      #pragma unroll
      for (int j = 0; j < 8; ++j) l[j] = f[j] - tobf16f(f[j]);
      Alo[c].u[0] = pk_bf16(l[0], l[1]);
      Alo[c].u[1] = pk_bf16(l[2], l[3]);
      Alo[c].u[2] = pk_bf16(l[4], l[5]);
      Alo[c].u[3] = pk_bf16(l[6], l[7]);
    }
  }
  f32x4 acc[4];
  #pragma unroll
  for (int ct = 0; ct < 4; ++ct) acc[ct] = (f32x4){0.f,0.f,0.f,0.f};
  #pragma unroll
  for (int c = 0; c < 2; ++c)
    #pragma unroll
    for (int ct = 0; ct < 4; ++ct) {
      acc[ct] = __builtin_amdgcn_mfma_f32_16x16x32_bf16(A[c].v, Bf[ct][c].v, acc[ct], 0, 0, 0);
      if (hilo)
        acc[ct] = __builtin_amdgcn_mfma_f32_16x16x32_bf16(Alo[c].v, Bf[ct][c].v, acc[ct], 0, 0, 0);
    }
  float v1v[4], v2v[4];
  #pragma unroll
  for (int ct = 0; ct < 4; ++ct) {
    v1v[ct] = v1 ? v1[ct*16+l15] : 0.f;
    v2v[ct] = v2 ? v2[ct*16+l15] : 0.f;
  }
  #pragma unroll
  for (int reg = 0; reg < 4; ++reg) {
    const int node = n0 + 4*lg + reg;
    const bool nv = node < R;
    float pr1 = 0.f, pr2 = 0.f;
    #pragma unroll
    for (int ct = 0; ct < 4; ++ct) {
      float val = acc[ct][reg];
      if (out && nv) out[(size_t)node*64 + ct*16 + l15] = val;
      if (outp) {
        float partner = __shfl_xor(val, 1, 64);
        if (!(l15 & 1) && nv) outp[(unsigned)node*32 + ct*8 + (l15>>1)] = pk_bf16(val, partner);
      }
      pr1 = fmaf(val, v1v[ct], pr1);
      pr2 = fmaf(val, v2v[ct], pr2);
    }
    if (o1) {
      pr1 += __shfl_xor(pr1, 1, 64); pr2 += __shfl_xor(pr2, 1, 64);
      pr1 += __shfl_xor(pr1, 2, 64); pr2 += __shfl_xor(pr2, 2, 64);
      pr1 += __shfl_xor(pr1, 4, 64); pr2 += __shfl_xor(pr2, 4, 64);
      pr1 += __shfl_xor(pr1, 8, 64); pr2 += __shfl_xor(pr2, 8, 64);
      if (l15 == 0 && nv) { o1[node] = pr1; if (o2) o2[node] = pr2; }
    }
  }
}

// ===== GATE edge scores, original order, software-pipelined u-gathers + NT streaming =====
__global__ __launch_bounds__(256) void k_escore(const int* __restrict__ srcarr,
                                                const float* __restrict__ ea,
                                                const float* __restrict__ glin1, // [64][80]
                                                const float* __restrict__ attl,
                                                const unsigned short* __restrict__ ubf,
                                                float* __restrict__ pout) {
  const int lane = threadIdx.x & 63;
  const int l15 = lane & 15, lg = lane >> 4;
  const int gw = blockIdx.x*4 + (threadIdx.x >> 6);
  if (gw >= N_EDGES/64) return;
  float attlv[4];
  unsigned Bu[4][2];
  #pragma unroll
  for (int c = 0; c < 4; ++c) {
    const float4 b = *(const float4*)&glin1[(c*16 + l15)*80 + 64 + lg*4];
    Bu[c][0] = pk_bf16(b.x, b.y);
    Bu[c][1] = pk_bf16(b.z, b.w);
    attlv[c] = attl[c*16 + l15];
  }
  const int i0 = gw*64;
  i32x4 sv[4];
  #pragma unroll
  for (int it = 0; it < 4; ++it)
    sv[it] = *(const i32x4*)&srcarr[i0 + it*16 + 4*lg];
  f32x4 a[4];
  #pragma unroll
  for (int it = 0; it < 4; ++it)
    a[it] = __builtin_nontemporal_load((const f32x4*)&ea[(size_t)(i0 + it*16 + l15)*16 + lg*4]);
  unsigned short ug0[4][4], ug1[4][4];
  #pragma unroll
  for (int c = 0; c < 4; ++c)
    #pragma unroll
    for (int r = 0; r < 4; ++r)
      ug0[c][r] = ubf[(size_t)sv[0][r]*64 + c*16 + l15];
  #pragma unroll
  for (int it = 0; it < 4; ++it) {
    if (it + 1 < 4) {
      #pragma unroll
      for (int c = 0; c < 4; ++c)
        #pragma unroll
        for (int r = 0; r < 4; ++r)
          ug1[c][r] = ubf[(size_t)sv[it+1][r]*64 + c*16 + l15];
    }
    union { bf16x8 v; unsigned u[4]; } A;
    A.u[0] = pk_bf16(a[it][0], a[it][1]);
    A.u[1] = pk_bf16(a[it][2], a[it][3]);
    A.u[2] = 0; A.u[3] = 0;
    float p[4] = {0.f,0.f,0.f,0.f};
    #pragma unroll
    for (int c = 0; c < 4; ++c) {
      union { bf16x8 v; unsigned u[4]; } B;
      B.u[0] = Bu[c][0]; B.u[1] = Bu[c][1]; B.u[2] = 0; B.u[3] = 0;
      f32x4 z = {0.f,0.f,0.f,0.f};
      f32x4 acc = __builtin_amdgcn_mfma_f32_16x16x32_bf16(A.v, B.v, z, 0, 0, 0);
      #pragma unroll
      for (int r = 0; r < 4; ++r) {
        float t = lrelu(__uint_as_float(((unsigned)ug0[c][r]) << 16) + acc[r]);
        p[r] = fmaf(t, attlv[c], p[r]);
      }
    }
    #pragma unroll
    for (int r = 0; r < 4; ++r) {
      p[r] += __shfl_xor(p[r], 1, 64);
      p[r] += __shfl_xor(p[r], 2, 64);
      p[r] += __shfl_xor(p[r], 4, 64);
      p[r] += __shfl_xor(p[r], 8, 64);
    }
    if (l15 == 0) {
      f32x4 o = {p[0], p[1], p[2], p[3]};
      __builtin_nontemporal_store(o, (f32x4*)&pout[i0 + it*16 + 4*lg]);
    }
    #pragma unroll
    for (int c = 0; c < 4; ++c)
      #pragma unroll
      for (int r = 0; r < 4; ++r)
        ug0[c][r] = ug1[c][r];
  }
}

// ===== GATE aggregation: sorted records {src|dlow|bkt, p}, bf16-packed y gathers =====
__global__ __launch_bounds__(256) void k_gate_agg(const int* __restrict__ rowptr,
                                                  const int2* __restrict__ sorted,
                                                  const float* __restrict__ xr,
                                                  const unsigned* __restrict__ ypk,
                                                  float* __restrict__ hagg) {
  __shared__ int   sS[4][64];
  __shared__ float sE[4][64];
  const int w = __builtin_amdgcn_readfirstlane(threadIdx.x >> 6);
  const int lane = threadIdx.x & 63;
  const int slot = lane >> 5, l2 = lane & 31;
  const int d = blockIdx.x*4 + w;
  const int r0 = __builtin_amdgcn_readfirstlane(rowptr[d]);
  const int r1 = __builtin_amdgcn_readfirstlane(rowptr[d+1]);
  const float xrd = xr[d];
  float accx = 0.f, accy = 0.f, ssum = 0.f;
  for (int base = r0; base < r1; base += 64) {
    int i = base + lane;
    int cnt = r1 - base; if (cnt > 64) cnt = 64;
    float ev = 0.f; int s = 0;
    if (i < r1) {
      int2 r = sorted[i];
      s = r.x & 0xffff;
      ev = fexp(lrelu(__int_as_float(r.y) + xrd));
    }
    sS[w][lane] = s; sE[w][lane] = ev;
    ssum += ev;
    for (int jb = 0; jb < cnt; jb += 16) {
      float e8[8]; unsigned p8[8];
      #pragma unroll
      for (int u = 0; u < 8; ++u) {
        int jj = jb + 2*u + slot;
        int svv; float evv;
        if (jj < cnt) { svv = sS[w][jj]; evv = sE[w][jj]; }
        else          { svv = 0; evv = 0.f; }
        e8[u] = evv;
        p8[u] = ypk[(size_t)svv*32 + l2];
      }
      #pragma unroll
      for (int u = 0; u < 8; ++u) {
        accx = fmaf(e8[u], bl(p8[u]), accx);
        accy = fmaf(e8[u], bh(p8[u]), accy);
      }
    }
  }
  #pragma unroll
  for (int sh = 32; sh > 0; sh >>= 1) ssum += __shfl_xor(ssum, sh, 64);
  accx += __shfl_xor(accx, 32, 64);
  accy += __shfl_xor(accy, 32, 64);
  float rs = frcp(ssum + 1e-16f);
  if (slot == 0) *(float2*)&hagg[d*64 + 2*l2] = make_float2(accx*rs, accy*rs);
}

// ===== GATConv fused: 2 edges per wave, bf16-packed hs, sorted src =====
__global__ __launch_bounds__(256) void k_conv_fused(const int* __restrict__ rowptr,
                                                    const int2* __restrict__ sorted,
                                                    const float* __restrict__ asn,
                                                    const float* __restrict__ adn,
                                                    const unsigned* __restrict__ hsb,
                                                    float* __restrict__ hagg) {
  __shared__ int   sS[4][64];
  __shared__ float sE[4][64];
  const int w = __builtin_amdgcn_readfirstlane(threadIdx.x >> 6);
  const int lane = threadIdx.x & 63;
  const int slot = lane >> 5, l2 = lane & 31;
  const int d = blockIdx.x*4 + w;
  const int r0 = __builtin_amdgcn_readfirstlane(rowptr[d]);
  const int r1 = __builtin_amdgcn_readfirstlane(rowptr[d+1]);
  float adnd = adn[d];
  float accx = 0.f, accy = 0.f, ssum = 0.f;
  for (int base = r0; base < r1; base += 64) {
    int i = base + lane;
    int cnt = r1 - base; if (cnt > 64) cnt = 64;
    float ev = 0.f; int s = 0;
    if (i < r1) { s = sorted[i].x & 0xffff; ev = fexp(lrelu(asn[s] + adnd)); }
    sS[w][lane] = s; sE[w][lane] = ev;
    ssum += ev;
    for (int jb = 0; jb < cnt; jb += 16) {
      float e8[8]; unsigned p8[8];
      #pragma unroll
      for (int u = 0; u < 8; ++u) {
        int jj = jb + 2*u + slot;
        int svv; float evv;
        if (jj < cnt) { svv = sS[w][jj]; evv = sE[w][jj]; }
        else          { svv = 0; evv = 0.f; }
        e8[u] = evv;
        p8[u] = hsb[(size_t)svv*32 + l2];
      }
      #pragma unroll
      for (int u = 0; u < 8; ++u) {
        accx = fmaf(e8[u], bl(p8[u]), accx);
        accy = fmaf(e8[u], bh(p8[u]), accy);
      }
    }
  }
  #pragma unroll
  for (int sh = 32; sh > 0; sh >>= 1) ssum += __shfl_xor(ssum, sh, 64);
  accx += __shfl_xor(accx, 32, 64);
  accy += __shfl_xor(accy, 32, 64);
  float rs = frcp(ssum + 1e-16f);
  if (slot == 0) *(float2*)&hagg[d*64 + 2*l2] = make_float2(accx*rs, accy*rs);
}

// ===== MFMA GRU: out = relu(GRU(elu(inp+pbias), hid)), wave = 16 nodes =====
__global__ __launch_bounds__(256) void k_gruM(const float* __restrict__ inp,
                                              const float* __restrict__ pbias,
                                              const float* __restrict__ hid,
                                              const unsigned short* __restrict__ wibf,
                                              const unsigned short* __restrict__ whbf,
                                              const float* __restrict__ bi,
                                              const float* __restrict__ bh2,
                                              float* __restrict__ out, int R) {
  const int lane = threadIdx.x & 63;
  const int l15 = lane & 15, lg = lane >> 4;
  const int n0 = blockIdx.x*64 + (threadIdx.x >> 6)*16;
  if (n0 >= R) return;
  union BF { bf16x8 v; unsigned u[4]; };
  BF Ai[2], Ah[2];
  const int arow = n0 + l15;
  const bool av = arow < R;
  const float* ibase = inp + (size_t)arow*64;
  const float* hbase = hid + (size_t)arow*64;
  #pragma unroll
  for (int c = 0; c < 2; ++c) {
    const int k0 = c*32 + lg*8;
    float4 p0 = *(const float4*)&pbias[k0];
    float4 p1 = *(const float4*)&pbias[k0+4];
    float4 v0, v1, h0, h1;
    if (av) {
      v0 = *(const float4*)&ibase[k0];   v1 = *(const float4*)&ibase[k0+4];
      h0 = *(const float4*)&hbase[k0];   h1 = *(const float4*)&hbase[k0+4];
    } else {
      v0 = v1 = h0 = h1 = make_float4(0.f,0.f,0.f,0.f);
      p0 = p1 = make_float4(0.f,0.f,0.f,0.f);
    }
    Ai[c].u[0] = pk_bf16(eluf(v0.x+p0.x), eluf(v0.y+p0.y));
    Ai[c].u[1] = pk_bf16(eluf(v0.z+p0.z), eluf(v0.w+p0.w));
    Ai[c].u[2] = pk_bf16(eluf(v1.x+p1.x), eluf(v1.y+p1.y));
    Ai[c].u[3] = pk_bf16(eluf(v1.z+p1.z), eluf(v1.w+p1.w));
    Ah[c].u[0] = pk_bf16(h0.x, h0.y);
    Ah[c].u[1] = pk_bf16(h0.z, h0.w);
    Ah[c].u[2] = pk_bf16(h1.x, h1.y);
    Ah[c].u[3] = pk_bf16(h1.z, h1.w);
  }
  f32x4 rz[8], ni[4], nh[4];
  #pragma unroll
  for (int t = 0; t < 8; ++t) rz[t] = (f32x4){0.f,0.f,0.f,0.f};
  #pragma unroll
  for (int t = 0; t < 4; ++t) { ni[t] = (f32x4){0.f,0.f,0.f,0.f}; nh[t] = (f32x4){0.f,0.f,0.f,0.f}; }
  #pragma unroll
  for (int t = 0; t < 12; ++t) {
    BF Bi0, Bi1, Bh0, Bh1;
    const size_t off = ((size_t)(t*16 + l15))*64 + lg*8;
    Bi0.v = *(const bf16x8*)&wibf[off];
    Bi1.v = *(const bf16x8*)&wibf[off + 32];
    Bh0.v = *(const bf16x8*)&whbf[off];
    Bh1.v = *(const bf16x8*)&whbf[off + 32];
    if (t < 8) {
      f32x4 a = rz[t];
      a = __builtin_amdgcn_mfma_f32_16x16x32_bf16(Ai[0].v, Bi0.v, a, 0, 0, 0);
      a = __builtin_amdgcn_mfma_f32_16x16x32_bf16(Ai[1].v, Bi1.v, a, 0, 0, 0);
      a = __builtin_amdgcn_mfma_f32_16x16x32_bf16(Ah[0].v, Bh0.v, a, 0, 0, 0);
      a = __builtin_amdgcn_mfma_f32_16x16x32_bf16(Ah[1].v, Bh1.v, a, 0, 0, 0);
      rz[t] = a;
    } else {
      f32x4 a = ni[t-8];
      a = __builtin_amdgcn_mfma_f32_16x16x32_bf16(Ai[0].v, Bi0.v, a, 0, 0, 0);
      a = __builtin_amdgcn_mfma_f32_16x16x32_bf16(Ai[1].v, Bi1.v, a, 0, 0, 0);
      ni[t-8] = a;
      f32x4 b = nh[t-8];
      b = __builtin_amdgcn_mfma_f32_16x16x32_bf16(Ah[0].v, Bh0.v, b, 0, 0, 0);
      b = __builtin_amdgcn_mfma_f32_16x16x32_bf16(Ah[1].v, Bh1.v, b, 0, 0, 0);
      nh[t-8] = b;
    }
  }
  float bsum[8], binv[4], bhnv[4];
  #pragma unroll
  for (int t = 0; t < 8; ++t) bsum[t] = bi[t*16+l15] + bh2[t*16+l15];
  #pragma unroll
  for (int t = 0; t < 4; ++t) {
    binv[t] = bi[128 + t*16 + l15];
    bhnv[t] = bh2[128 + t*16 + l15];
  }
  #pragma unroll
  for (int reg = 0; reg < 4; ++reg) {
    const int node = n0 + 4*lg + reg;
    if (node >= R) continue;
    #pragma unroll
    for (int tt = 0; tt < 4; ++tt) {
      float r  = sigm(rz[tt][reg] + bsum[tt]);
      float z  = sigm(rz[4+tt][reg] + bsum[4+tt]);
      float nn = ftanh(ni[tt][reg] + binv[tt] + r*(nh[tt][reg] + bhnv[tt]));
      float hh = hid[(size_t)node*64 + tt*16 + l15];
      float o  = (1.f - z)*nn + z*hh;
      out[(size_t)node*64 + tt*16 + l15] = fmaxf(o, 0.f);
    }
  }
}

// ================= molecule readout, split-K (8 slices per graph) =================
__global__ __launch_bounds__(256) void k_molsum_p(const int* __restrict__ gstart,
                                                  const float* __restrict__ x,
                                                  float* __restrict__ part) {
  int idx = blockIdx.x*4 + (threadIdx.x>>6);
  if (idx >= NGRAPH*8) return;
  int g = idx >> 3, sl = idx & 7;
  int lane = threadIdx.x & 63;
  int n0 = gstart[g], n1 = gstart[g+1];
  int len = n1 - n0;
  int b0 = n0 + (len*sl >> 3), b1 = n0 + (len*(sl+1) >> 3);
  float acc = 0.f;
  for (int n = b0; n < b1; ++n) acc += x[n*64+lane];
  part[idx*64+lane] = acc;
}

__global__ __launch_bounds__(256) void k_molsum_c(const float* __restrict__ part,
                                                  float* __restrict__ outg) {
  int g = blockIdx.x*4 + (threadIdx.x>>6);
  if (g >= NGRAPH) return;
  int lane = threadIdx.x & 63;
  float a = 0.f;
  #pragma unroll
  for (int s = 0; s < 8; ++s) a += part[(g*8+s)*64+lane];
  outg[g*64+lane] = fmaxf(a, 0.f);
}

__global__ __launch_bounds__(256) void k_molhd(const float* __restrict__ outg,
                                               const float* __restrict__ W,
                                               const float* __restrict__ attd,
                                               float* __restrict__ addg) {
  __shared__ float wl[64*65];
  for (int idx = threadIdx.x; idx < 4096; idx += 256) wl[(idx>>6)*65+(idx&63)] = W[idx];
  __syncthreads();
  int g = blockIdx.x*4 + (threadIdx.x>>6);
  if (g >= NGRAPH) return;
  int lane = threadIdx.x & 63;
  float og = outg[g*64+lane];
  float hd = 0.f;
  #pragma unroll
  for (int k = 0; k < 64; ++k) hd += rdlane(og, k) * wl[lane*65+k];
  float p = hd * attd[lane];
  #pragma unroll
  for (int sh = 32; sh > 0; sh >>= 1) p += __shfl_xor(p, sh, 64);
  if (lane == 0) addg[g] = p;
}

__global__ __launch_bounds__(256) void k_molp(const int* __restrict__ gstart,
                                              const float* __restrict__ addg,
                                              const float* __restrict__ asn,
                                              const float* __restrict__ y,
                                              float* __restrict__ part_acc,
                                              float* __restrict__ part_ss) {
  int idx = blockIdx.x*4 + (threadIdx.x>>6);
  if (idx >= NGRAPH*8) return;
  int g = idx >> 3, sl = idx & 7;
  int lane = threadIdx.x & 63;
  int n0 = gstart[g], n1 = gstart[g+1];
  int len = n1 - n0;
  int b0 = n0 + (len*sl >> 3), b1 = n0 + (len*(sl+1) >> 3);
  float adg = addg[g];
  float acc = 0.f, ss = 0.f;
  for (int n = b0; n < b1; ++n) {
    float ev = fexp(lrelu(asn[n] + adg));
    acc += ev * y[n*64+lane];
    ss  += ev;
  }
  part_acc[idx*64+lane] = acc;
  if (lane == 0) part_ss[idx] = ss;
}

__global__ __launch_bounds__(256) void k_molc(const float* __restrict__ part_acc,
                                              const float* __restrict__ part_ss,
                                              float* __restrict__ hg) {
  int g = blockIdx.x*4 + (threadIdx.x>>6);
  if (g >= NGRAPH) return;
  int lane = threadIdx.x & 63;
  float a = 0.f, ss = 0.f;
  #pragma unroll
  for (int s = 0; s < 8; ++s) {
    a  += part_acc[(g*8+s)*64+lane];
    ss += part_ss[g*8+s];
  }
  hg[g*64+lane] = a * frcp(ss + 1e-16f);
}

__global__ __launch_bounds__(128) void k_final(const float* __restrict__ outg,
                                               const float* __restrict__ W,
                                               const float* __restrict__ b,
                                               float* __restrict__ out) {
  __shared__ float og[64];
  int g = blockIdx.x;
  if (threadIdx.x < 64) og[threadIdx.x] = outg[g*64+threadIdx.x];
  __syncthreads();
  int o = threadIdx.x;
  float acc = b[o];
  for (int k = 0; k < 64; ++k) acc += og[k]*W[o*64+k];
  out[g*128+o] = acc;
}

extern "C" void kernel_launch(void* const* d_in, const int* in_sizes, int n_in,
                              void* d_out, int out_size, void* d_ws, size_t ws_size,
                              hipStream_t stream) {
  const float* x_in     = (const float*)d_in[0];
  const int*   eidx     = (const int*)  d_in[1];
  const float* eattr    = (const float*)d_in[2];
  const int*   batch    = (const int*)  d_in[3];
  const float* lin1_w   = (const float*)d_in[4];
  const float* lin1_b   = (const float*)d_in[5];
  const float* g_lin1_w = (const float*)d_in[6];
  const float* g_att_l  = (const float*)d_in[7];
  const float* g_att_r  = (const float*)d_in[8];
  const float* g_lin2_w = (const float*)d_in[9];
  const float* g_bias   = (const float*)d_in[10];
  const float* gru0_wi  = (const float*)d_in[11];
  const float* gru0_wh  = (const float*)d_in[12];
  const float* gru0_bi  = (const float*)d_in[13];
  const float* gru0_bh  = (const float*)d_in[14];
  const float* conv_lin_w   = (const float*)d_in[15];
  const float* conv_att_src = (const float*)d_in[16];
  const float* conv_att_dst = (const float*)d_in[17];
  const float* conv_bias    = (const float*)d_in[18];
  const float* grul_wi  = (const float*)d_in[19];
  const float* grul_wh  = (const float*)d_in[20];
  const float* grul_bi  = (const float*)d_in[21];
  const float* grul_bh  = (const float*)d_in[22];
  const float* mol_lin_w    = (const float*)d_in[23];
  const float* mol_att_src  = (const float*)d_in[24];
  const float* mol_att_dst  = (const float*)d_in[25];
  const float* mol_bias     = (const float*)d_in[26];
  const float* mgru_wi  = (const float*)d_in[27];
  const float* mgru_wh  = (const float*)d_in[28];
  const float* mgru_bi  = (const float*)d_in[29];
  const float* mgru_bh  = (const float*)d_in[30];
  const float* lin2_w   = (const float*)d_in[31];
  const float* lin2_b   = (const float*)d_in[32];

  const int N64 = N_NODES*64;
  float* ws     = (float*)d_ws;
  float* xA     = ws;               // N*64
  float* xB     = xA + N64;         // N*64
  float* uy     = xB + N64;         // 2*N64: ubf(ushort N*64)+ypk(uint N*32) / hsb / ymol
  float* hagg   = uy + 2*N64;       // N*64
  float* sc1    = hagg + N64;       // N
  float* sc2    = sc1 + N_NODES;    // N
  float* pbuf   = sc2 + N_NODES;    // E (edge scores, ORIGINAL order)
  float* outg   = pbuf + N_EDGES;   // G*64
  int* bcnt   = (int*)(outg + NGRAPH*64); // NBKT
  int* rowptr = bcnt + N_NODES;     // N+2
  int2* binned = (int2*)(rowptr + N_NODES + 2); // E  (reused: mol partials)
  int2* sorted = binned + N_EDGES;  // E
  int* gstart = (int*)(sorted + N_EDGES); // G+1
  int* bstart = gstart + NGRAPH+1;  // NBKT+1
  int* bcur   = bstart + NBKT+1;    // NBKT
  unsigned short* wpk = (unsigned short*)(bcur + NBKT + 4); // 4 pairs * PAIR_C bf16

  unsigned short* ubf = (unsigned short*)uy;       // N*64 bf16 u
  unsigned* ubf32 = (unsigned*)uy;                 // same region, dword view
  unsigned* ypk = (unsigned*)(uy + N64);           // N*32 packed y
  unsigned* hsb = (unsigned*)uy;                   // N*32 packed hs (reused after gate)

  float* part_acc = (float*)binned;                // G*8*64
  float* part_ss  = part_acc + NGRAPH*8*64;        // G*8
  float* addg     = part_ss + NGRAPH*8;            // G

  const int* src = eidx;
  const int* dst = eidx + N_EDGES;

  const int nbN4  = (N_NODES + 3)/4;
  const int nbN64 = (N_NODES + 63)/64;
  const int nbG4  = (NGRAPH + 3)/4;
  const int nbG8  = (NGRAPH*8 + 3)/4;
  const int nbES  = (N_EDGES/64 + 3)/4;
  const int nbBIN = (N_EDGES + BIN_BLK-1)/BIN_BLK;

  // ---- bucket histogram + merged setup (scan + graph bounds) ----
  hipMemsetAsync(bcnt, 0, NBKT*sizeof(int), stream);
  k_bhist<<<nbBIN, 256, 0, stream>>>(dst, bcnt);
  k_setup<<<1, 512, 0, stream>>>(bcnt, bstart, bcur, rowptr + N_NODES, batch, gstart);

  // ---- GRU weight prepack (bf16, one launch) ----
  k_wpack4<<<(4*PAIR_C + 255)/256, 256, 0, stream>>>(gru0_wi, gru0_wh,
                                                     grul_wi, grul_wh,
                                                     grul_wi + 192*64, grul_wh + 192*64,
                                                     mgru_wi, mgru_wh, wpk);

  // ---- lin1 via MFMA (hi/lo split x, fused xr dot) ----
  k_lin1M<<<nbN64, 256, 0, stream>>>(x_in, lin1_w, lin1_b, g_att_r, xA, sc1);

  // ---- GATEConv: scores in original order, then locality-aware bin sort ----
  k_mmdualM<<<nbN64, 256, 0, stream>>>(xA, g_lin1_w, g_lin2_w, ubf32, ypk, N_NODES);
  k_escore<<<nbES, 256, 0, stream>>>(src, eattr, g_lin1_w, g_att_l, ubf, pbuf);
  k_binA<<<nbBIN, 1024, 0, stream>>>(dst, src, pbuf, bcur, binned);
  k_binB<<<NBKT, 1024, 0, stream>>>(bstart, binned, sorted, rowptr);
  k_gate_agg<<<nbN4, 256, 0, stream>>>(rowptr, sorted, sc1, ypk, hagg);
  k_gruM<<<nbN64, 256, 0, stream>>>(hagg, g_bias, xA, wpk, wpk + 192*64,
                                    gru0_bi, gru0_bh, xB, N_NODES);

  float* xcur = xB; float* xoth = xA;

  // ---- GATConv layers ----
  for (int l = 0; l < 2; ++l) {
    k_mm64M<<<nbN64, 256, 0, stream>>>(xcur, conv_lin_w + l*64*64, 64, nullptr, hsb, N_NODES,
                                       conv_att_src + l*64, conv_att_dst + l*64, sc1, sc2, 0);
    k_conv_fused<<<nbN4, 256, 0, stream>>>(rowptr, sorted, sc1, sc2, hsb, hagg);
    k_gruM<<<nbN64, 256, 0, stream>>>(hagg, conv_bias + l*64, xcur,
                                      wpk + (1+l)*PAIR_C, wpk + (1+l)*PAIR_C + 192*64,
                                      grul_bi + l*192, grul_bh + l*192, xoth, N_NODES);
    float* t = xcur; xcur = xoth; xoth = t;
  }

  // ---- molecule readout (split-K over node slices) ----
  float* ymol = uy;
  k_molsum_p<<<nbG8, 256, 0, stream>>>(gstart, xcur, part_acc);
  k_molsum_c<<<nbG4, 256, 0, stream>>>(part_acc, outg);
  k_mm64M<<<nbN64, 256, 0, stream>>>(xcur, mol_lin_w, 64, ymol, nullptr, N_NODES,
                                     mol_att_src, nullptr, sc1, nullptr, 1);
  for (int t = 0; t < 2; ++t) {
    k_molhd<<<nbG4, 256, 0, stream>>>(outg, mol_lin_w, mol_att_dst, addg);
    k_molp<<<nbG8, 256, 0, stream>>>(gstart, addg, sc1, ymol, part_acc, part_ss);
    k_molc<<<nbG4, 256, 0, stream>>>(part_acc, part_ss, hagg);
    k_gruM<<<(NGRAPH+63)/64, 256, 0, stream>>>(hagg, mol_bias, outg,
                                               wpk + 3*PAIR_C, wpk + 3*PAIR_C + 192*64,
                                               mgru_bi, mgru_bh, outg, NGRAPH);
  }

  // ---- final linear ----
  k_final<<<NGRAPH, 128, 0, stream>>>(outg, lin2_w, lin2_b, (float*)d_out);
}